// Round 5
// baseline (1033.885 us; speedup 1.0000x reference)
//
#include <hip/hip_runtime.h>
#include <math.h>

#define DI __device__ __forceinline__

// ---- problem constants ----
#define BB 32
#define SEQ 512
#define KF 101
#define EE 128
#define HH 8
#define EHH 1024
#define LL 3
#define ADIM 200
#define NATOM 119
#define NTOK (BB*SEQ)   // 16384
#define CB 8            // batches per chunk
#define NCHUNK (BB/CB)  // 4
#define CTOK (CB*SEQ)   // 4096 tokens per chunk

// R19: embed_ln was LDS-issue-bound (1200 scalar ds_read/thread, 4-way
// conflicts = 42us). Rewrite: pdd_W as float2 ds_read_b64 (conflict-free),
// str row held in 2 VGPRs + v_readlane broadcast (SALU pipe), each pdd
// load reused across 4 tokens (per-token fmaf order unchanged). attn:
// mid-barrier RESTORED (R17 removal caused cross-wave P-scatter/PV-read
// LDS contention: one 30.7ms dispatch w/ 2.49M bank conflicts; likely the
// R3 flake). atomemb + fuse_b folded into prep_k roles (-2 launches).

typedef unsigned short u16;
typedef __attribute__((ext_vector_type(8))) short bf16x8;
typedef __attribute__((ext_vector_type(4))) float f32x4;

DI float bf2f(u16 s){ union{unsigned int u; float f;} x; x.u = ((unsigned int)s)<<16; return x.f; }
DI u16 f2bf(float f){
  union{float f; unsigned int u;} x; x.f = f;
  unsigned int u = x.u;
  u += 0x7fffu + ((u>>16)&1u);           // RNE
  return (u16)(u>>16);
}
DI float rdl(float v, int l){
  return __int_as_float(__builtin_amdgcn_readlane(__float_as_int(v), l));
}

// =================== sentinel ===================
__global__ void sentinel_k(float* out, float v, int n){
  int i = blockIdx.x*64 + threadIdx.x;
  if (i < n) out[i] = v;
}

// =================== embed + layer-0 LN (64 tokens/block, 16 waves) ===================
// x = atom_emb[idx] + str[1:]@pdd_W ; xn = LN(x, g0, b0)
// Wave handles 4 tokens; pdd loads (float2, conflict-free) shared across
// tokens; str broadcast via v_readlane from 2 VGPRs (SALU, no LDS).
__global__ __launch_bounds__(1024) void embed_ln_k(
    const float* __restrict__ str_fea, const int* __restrict__ comp_fea,
    const float* __restrict__ atom_emb, const float* __restrict__ pdd_W,
    const float* __restrict__ g, const float* __restrict__ bta,
    float* __restrict__ x, float* __restrict__ x_init, float* __restrict__ w,
    u16* __restrict__ xn)
{
  const int t0 = blockIdx.x*64;
  const int tid = threadIdx.x;
  const int wv = tid>>6, lane = tid&63;
  __shared__ float2 sPdd[100*64];      // [j][pair] = pdd_W[j][2p..2p+1], 51.2 KB
  for (int k2=tid; k2<100*64; k2+=1024)
    sPdd[k2] = ((const float2*)pdd_W)[k2];

  // per-wave: 4 tokens; str row in 2 VGPRs (lanes 0..63 hold str[0..63],
  // lanes 0..36 hold str[64..100] in sv1)
  float sv0[4], sv1[4];
  int idx[4];
  #pragma unroll
  for (int tk=0; tk<4; ++tk){
    const int t = t0 + wv*4 + tk;
    const float* sr0 = str_fea + (size_t)t*KF;
    sv0[tk] = sr0[lane];
    sv1[tk] = (lane+64 < KF) ? sr0[lane+64] : 0.f;
    idx[tk] = comp_fea[t];
  }
  __syncthreads();

  float a0[4],a1[4],a2[4],a3[4],c0[4],c1[4],c2[4],c3[4];
  #pragma unroll
  for (int tk=0; tk<4; ++tk){
    const float2 ae = ((const float2*)(atom_emb + (size_t)idx[tk]*EE))[lane];
    a0[tk]=ae.x; a1[tk]=0.f; a2[tk]=0.f; a3[tk]=0.f;
    c0[tk]=ae.y; c1[tk]=0.f; c2[tk]=0.f; c3[tk]=0.f;
  }
  #pragma unroll
  for (int j=0; j<100; j+=4){
    const float2 w0 = sPdd[(j  )*64 + lane];
    const float2 w1 = sPdd[(j+1)*64 + lane];
    const float2 w2 = sPdd[(j+2)*64 + lane];
    const float2 w3 = sPdd[(j+3)*64 + lane];
    #pragma unroll
    for (int tk=0; tk<4; ++tk){
      const float s1 = (1+j<64) ? rdl(sv0[tk],1+j) : rdl(sv1[tk],1+j-64);
      const float s2 = (2+j<64) ? rdl(sv0[tk],2+j) : rdl(sv1[tk],2+j-64);
      const float s3 = (3+j<64) ? rdl(sv0[tk],3+j) : rdl(sv1[tk],3+j-64);
      const float s4 = (4+j<64) ? rdl(sv0[tk],4+j) : rdl(sv1[tk],4+j-64);
      a0[tk] = fmaf(s1, w0.x, a0[tk]);  c0[tk] = fmaf(s1, w0.y, c0[tk]);
      a1[tk] = fmaf(s2, w1.x, a1[tk]);  c1[tk] = fmaf(s2, w1.y, c1[tk]);
      a2[tk] = fmaf(s3, w2.x, a2[tk]);  c2[tk] = fmaf(s3, w2.y, c2[tk]);
      a3[tk] = fmaf(s4, w3.x, a3[tk]);  c3[tk] = fmaf(s4, w3.y, c3[tk]);
    }
  }
  const float2 gg = ((const float2*)g)[lane];
  const float2 bb = ((const float2*)bta)[lane];
  #pragma unroll
  for (int tk=0; tk<4; ++tk){
    const int t = t0 + wv*4 + tk;
    const float vx = (a0[tk]+a1[tk])+(a2[tk]+a3[tk]);
    const float vy = (c0[tk]+c1[tk])+(c2[tk]+c3[tk]);
    ((float2*)(x      + (size_t)t*EE))[lane] = make_float2(vx, vy);
    ((float2*)(x_init + (size_t)t*EE))[lane] = make_float2(vx, vy);
    if (lane==0) w[t] = sv0[tk];
    // LN (identical order to old ln_k)
    float s = vx + vy;
    #pragma unroll
    for (int off=32; off; off>>=1) s += __shfl_xor(s, off);
    const float mean = s*(1.0f/128.0f);
    const float d0 = vx-mean, d1 = vy-mean;
    float q = d0*d0 + d1*d1;
    #pragma unroll
    for (int off=32; off; off>>=1) q += __shfl_xor(q, off);
    const float rstd = rsqrtf(q*(1.0f/128.0f) + 1e-5f);
    u16* o = xn + (size_t)t*EE + lane*2;
    o[0] = f2bf(d0*rstd*gg.x + bb.x);
    o[1] = f2bf(d1*rstd*gg.y + bb.y);
  }
}

// =================== merged weight prep (+atomemb +fuse_b roles) ===================
DI void trans32(const float* __restrict__ W, u16* __restrict__ WT,
                int Nn, int Kk, int srcCol0, int n0, int k0, int tid,
                u16 (&tile)[32][33])
{
  const int lr = tid>>5, lc = tid&31;
  #pragma unroll
  for (int i=0;i<4;i++)
    tile[lr+i*8][lc] = f2bf(W[(size_t)(k0+lr+i*8)*Nn + srcCol0 + lc]);
  __syncthreads();
  #pragma unroll
  for (int i=0;i<4;i++)
    WT[(size_t)(n0+lr+i*8)*Kk + k0 + lc] = tile[lc][lr+i*8];
}

// roles: [0,1152) qkvT | [1152,1200) ffnT | [1200,1584) outWT |
//        [1584,13872) oW cconv | [13872,13908) qkv bias reorder |
//        [13908,14027) atomemb | [14027,14030) fuse_b
__global__ __launch_bounds__(256) void prep_k(
    const float* __restrict__ qkv_W, u16* __restrict__ qkvWT,
    const float* __restrict__ ffn_W, u16* __restrict__ ffnWT,
    const float* __restrict__ out_W, u16* __restrict__ outWT,
    const float* __restrict__ o_W,  u16* __restrict__ oWb,
    const float* __restrict__ qkv_b, float* __restrict__ rqkv_b,
    const float* __restrict__ atom_table, const float* __restrict__ comp_W,
    const float* __restrict__ comp_b, const float* __restrict__ pdd_b,
    float* __restrict__ atom_emb,
    const float* __restrict__ o_b, const float* __restrict__ out_b,
    float* __restrict__ fb)
{
  __shared__ u16 tile[32][33];
  __shared__ float sbuf[456];          // atomemb: sAtom[200]+red[256]; fuse_b: red[256]
  int bid = blockIdx.x;
  const int tid = threadIdx.x;
  if (bid < 1152){
    const int xb = bid%96, yb = (bid/96)%4, zb = bid/384;
    const int n0 = xb*32, k0 = yb*32;
    int c0;
    if (n0 < 2048) c0 = (n0>>8)*384 + (n0&255);
    else { const int m0 = n0-2048; c0 = (m0>>7)*384 + 256 + (m0&127); }
    trans32(qkv_W + (size_t)zb*EE*3*EHH, qkvWT + (size_t)zb*3*EHH*EE,
            3*EHH, EE, c0, n0, k0, tid, tile);
    return;
  }
  bid -= 1152;
  if (bid < 48){
    const int xb = bid%4, yb = (bid/4)%4, zb = bid/16;
    trans32(ffn_W + (size_t)zb*EE*EE, ffnWT + (size_t)zb*EE*EE,
            EE, EE, xb*32, xb*32, yb*32, tid, tile);
    return;
  }
  bid -= 48;
  if (bid < 384){
    const int xb = bid%4, yb = (bid/4)%32, zb = bid/128;
    trans32(out_W + (size_t)zb*EHH*EE, outWT + (size_t)zb*EE*EHH,
            EE, EHH, xb*32, xb*32, yb*32, tid, tile);
    return;
  }
  bid -= 384;
  if (bid < 12288){
    const int i = bid*256 + tid;
    oWb[i] = f2bf(o_W[i]);
    return;
  }
  bid -= 12288;
  if (bid < 36){
    const int l = bid/12;
    const int n = (bid%12)*256 + tid;
    int c;
    if (n < 2048) c = (n>>8)*384 + (n&255);
    else { const int m = n-2048; c = (m>>7)*384 + 256 + (m&127); }
    rqkv_b[(size_t)l*3*EHH + n] = qkv_b[(size_t)l*3*EHH + c];
    return;
  }
  bid -= 36;
  if (bid < NATOM){
    // atom embedding: atom_emb[a] = comp_b + pdd_b + atom_table[a]@comp_W
    const int a = bid;
    const int e = tid & 127, half = tid >> 7;
    float* sAtom = sbuf;
    float* red   = sbuf + 200;
    for (int d=tid; d<ADIM; d+=256) sAtom[d] = atom_table[a*ADIM+d];
    __syncthreads();
    float acc = half ? 0.f : (comp_b[e] + pdd_b[e]);
    const int d0 = half*100;
    #pragma unroll 4
    for (int d=d0; d<d0+100; d++) acc = fmaf(sAtom[d], comp_W[d*EE+e], acc);
    red[tid] = acc;
    __syncthreads();
    if (half==0) atom_emb[a*EE+e] = red[e] + red[128+e];
    return;
  }
  bid -= NATOM;
  {
    // fb = o_b@out_W + out_b (2-way k-split)
    const int ly = bid;
    const float* ob = o_b + (size_t)ly*EHH;
    const float* oW = out_W + (size_t)ly*EHH*EE;
    const int n = tid & 127, seg = tid >> 7;
    float acc = 0.f;
    const int kb = seg*512;
    #pragma unroll 4
    for (int k2=kb; k2<kb+512; ++k2) acc = fmaf(ob[k2], oW[(size_t)k2*EE+n], acc);
    float* red = sbuf + 200;
    red[tid] = acc;
    __syncthreads();
    if (seg==0)
      fb[(size_t)ly*EE + n] = out_b[(size_t)ly*EE + n] + (red[n] + red[128+n]);
  }
}

// =================== MFMA bf16 GEMM (layer-batched via z strides) ===================
// A: M x Kk bf16 row-major. BT: Nn x Kk bf16 (pre-transposed B).
// EPI 0: store bf16; 4: bf16 transposed store (no bias);
// EPI 7 (QKV router): col<2048 -> ((u16*)C)[row*2048+col];
//                     col>=2048 -> ((u16*)C2)[(col-2048)*Mdim+row] (V^T).
template<int EPI, int BM, int BN, int BK>
__global__ __launch_bounds__(256) void mgemm_k(
    const u16* __restrict__ A, const u16* __restrict__ BT,
    const float* __restrict__ bias, void* __restrict__ Cv,
    int Nn, int Kk, int Mdim, void* __restrict__ C2,
    size_t sA, size_t sBT, size_t sCb)
{
  const int lz = blockIdx.z;
  A  += (size_t)lz*sA;
  BT += (size_t)lz*sBT;
  void* C = (void*)((char*)Cv + (size_t)lz*sCb);

  constexpr int LDK = BK + 8;
  __shared__ u16 As[BM*LDK];
  __shared__ u16 Bs[BN*LDK];
  const int tid = threadIdx.x;
  const int m0 = blockIdx.y*BM, n0 = blockIdx.x*BN;
  constexpr int WMN = (BM>=128)?2:1;
  constexpr int WNN = 4/WMN;
  constexpr int WM = BM/WMN;
  constexpr int WN = BN/WNN;
  constexpr int FM = WM/16, FN = WN/16;
  const int wv = tid>>6, lane = tid&63;
  const int wm = (wv/WNN)*WM;
  const int wn = (wv%WNN)*WN;
  const int lm = lane&15, lq = lane>>4;

  f32x4 acc[FM][FN];
  #pragma unroll
  for (int i=0;i<FM;i++)
    #pragma unroll
    for (int j=0;j<FN;j++) acc[i][j] = (f32x4){0.f,0.f,0.f,0.f};

  constexpr int ACH = BM*BK/8;
  constexpr int BCH = BN*BK/8;

  for (int k0=0; k0<Kk; k0+=BK){
    #pragma unroll
    for (int c = tid; c < ACH; c += 256){
      const int r = c/(BK/8), kg = c - r*(BK/8);
      const float4 v = *(const float4*)(A + (size_t)(m0+r)*Kk + k0 + kg*8);
      *(float4*)&As[r*LDK + kg*8] = v;
    }
    #pragma unroll
    for (int c = tid; c < BCH; c += 256){
      const int r = c/(BK/8), kg = c - r*(BK/8);
      const float4 v = *(const float4*)(BT + (size_t)(n0+r)*Kk + k0 + kg*8);
      *(float4*)&Bs[r*LDK + kg*8] = v;
    }
    __syncthreads();
    #pragma unroll
    for (int kk=0; kk<BK/32; kk++){
      bf16x8 af[FM], bfr[FN];
      #pragma unroll
      for (int i=0;i<FM;i++)
        af[i] = *(const bf16x8*)&As[(wm + i*16 + lm)*LDK + kk*32 + lq*8];
      #pragma unroll
      for (int j=0;j<FN;j++)
        bfr[j] = *(const bf16x8*)&Bs[(wn + j*16 + lm)*LDK + kk*32 + lq*8];
      #pragma unroll
      for (int i=0;i<FM;i++)
        #pragma unroll
        for (int j=0;j<FN;j++)
          acc[i][j] = __builtin_amdgcn_mfma_f32_16x16x32_bf16(af[i], bfr[j], acc[i][j], 0, 0, 0);
    }
    __syncthreads();
  }
  #pragma unroll
  for (int i=0;i<FM;i++){
    #pragma unroll
    for (int j=0;j<FN;j++){
      const int col = n0 + wn + j*16 + lm;
      const float bv = (EPI==4) ? 0.f : bias[col];
      #pragma unroll
      for (int r=0;r<4;r++){
        const int row = m0 + wm + i*16 + lq*4 + r;
        float v = acc[i][j][r] + bv;
        if constexpr (EPI==7){
          if (col < 2048) ((u16*)C)[(size_t)row*2048 + col] = f2bf(v);
          else            ((u16*)C2)[(size_t)(col-2048)*Mdim + row] = f2bf(v);
        } else if constexpr (EPI==4){
          ((u16*)C)[(size_t)col*Mdim + row] = f2bf(v);
        } else {
          ((u16*)C)[(size_t)row*Nn + col] = f2bf(v);
        }
      }
    }
  }
}

// =================== fused proj+LN + ffn+mish + dual-LN ===================
__global__ __launch_bounds__(256) void projffn_k(
    const u16* __restrict__ vals, const u16* __restrict__ fwT,
    const float* __restrict__ fb, const u16* __restrict__ ffnWT,
    const float* __restrict__ fnb,
    const float* __restrict__ g1, const float* __restrict__ b1,
    const float* __restrict__ g2, const float* __restrict__ b2,
    float* __restrict__ x_io, u16* __restrict__ xn_io)
{
  constexpr int BM = 32, BK = 128, LDK = BK + 8;
  __shared__ u16 As[BM*LDK];        // proj A tiles; then xn2 (bf16)
  __shared__ u16 Bs[EE*LDK];        // fwT tiles; then ffnWT
  __shared__ float sred[BM*8];
  const int tid = threadIdx.x;
  const int wv = tid>>6, lane = tid&63;
  const int lm = lane&15, lq = lane>>4;
  const int m0 = blockIdx.x*BM;
  const int wn = wv*32;             // 4 waves x 32 cols

  f32x4 acc[2][2];
  #pragma unroll
  for (int i=0;i<2;i++)
    #pragma unroll
    for (int j=0;j<2;j++) acc[i][j] = (f32x4){0.f,0.f,0.f,0.f};

  // ---- phase A: proj GEMM, K=1024 ----
  for (int k0=0; k0<EHH; k0+=BK){
    #pragma unroll
    for (int c = tid; c < BM*BK/8; c += 256){
      const int r = c>>4, kg = c&15;
      *(float4*)&As[r*LDK + kg*8] = *(const float4*)(vals + (size_t)(m0+r)*EHH + k0 + kg*8);
    }
    #pragma unroll
    for (int c = tid; c < EE*BK/8; c += 256){
      const int r = c>>4, kg = c&15;
      *(float4*)&Bs[r*LDK + kg*8] = *(const float4*)(fwT + (size_t)r*EHH + k0 + kg*8);
    }
    __syncthreads();
    #pragma unroll
    for (int kk=0; kk<BK/32; kk++){
      bf16x8 af[2], bfr[2];
      #pragma unroll
      for (int i=0;i<2;i++)
        af[i] = *(const bf16x8*)&As[(i*16 + lm)*LDK + kk*32 + lq*8];
      #pragma unroll
      for (int j=0;j<2;j++)
        bfr[j] = *(const bf16x8*)&Bs[(wn + j*16 + lm)*LDK + kk*32 + lq*8];
      #pragma unroll
      for (int i=0;i<2;i++)
        #pragma unroll
        for (int j=0;j<2;j++)
          acc[i][j] = __builtin_amdgcn_mfma_f32_16x16x32_bf16(af[i], bfr[j], acc[i][j], 0, 0, 0);
    }
    __syncthreads();
  }

  // ---- phase A epilogue: vout = acc + fb + x ; LN stats ----
  float vout[2][2][4];
  float ps[2][4], qs[2][4];
  #pragma unroll
  for (int i=0;i<2;i++)
    #pragma unroll
    for (int r=0;r<4;r++){ ps[i][r]=0.f; qs[i][r]=0.f; }
  #pragma unroll
  for (int i=0;i<2;i++){
    #pragma unroll
    for (int j=0;j<2;j++){
      const int col = wn + j*16 + lm;
      const float bv = fb[col];
      #pragma unroll
      for (int r=0;r<4;r++){
        const int row = m0 + i*16 + lq*4 + r;
        const float v = acc[i][j][r] + bv + x_io[(size_t)row*EE + col];
        vout[i][j][r] = v;
        ps[i][r] += v; qs[i][r] += v*v;
      }
    }
  }
  #pragma unroll
  for (int i=0;i<2;i++)
    #pragma unroll
    for (int r=0;r<4;r++){
      float s = ps[i][r], q = qs[i][r];
      s += __shfl_xor(s,1); s += __shfl_xor(s,2); s += __shfl_xor(s,4); s += __shfl_xor(s,8);
      q += __shfl_xor(q,1); q += __shfl_xor(q,2); q += __shfl_xor(q,4); q += __shfl_xor(q,8);
      if (lm==0){
        const int row = i*16 + lq*4 + r;
        sred[row*4 + wv] = s;
        sred[BM*4 + row*4 + wv] = q;
      }
    }
  __syncthreads();
  // xn2 -> As (bf16), and stage ffnWT -> Bs
  #pragma unroll
  for (int i=0;i<2;i++)
    #pragma unroll
    for (int r=0;r<4;r++){
      const int row = i*16 + lq*4 + r;
      const float s = sred[row*4+0]+sred[row*4+1]+sred[row*4+2]+sred[row*4+3];
      const float q = sred[BM*4+row*4+0]+sred[BM*4+row*4+1]+sred[BM*4+row*4+2]+sred[BM*4+row*4+3];
      const float mean = s*(1.0f/128.0f);
      const float var  = q*(1.0f/128.0f) - mean*mean;
      const float rstd = rsqrtf(var + 1e-5f);
      #pragma unroll
      for (int j=0;j<2;j++){
        const int col = wn + j*16 + lm;
        const float xnv = (vout[i][j][r]-mean)*rstd*g1[col] + b1[col];
        As[row*LDK + col] = f2bf(xnv);
      }
    }
  #pragma unroll
  for (int c = tid; c < EE*EE/8; c += 256){
    const int r = c>>4, kg = c&15;
    *(float4*)&Bs[r*LDK + kg*8] = *(const float4*)(ffnWT + (size_t)r*EE + kg*8);
  }
  __syncthreads();

  // ---- phase B: ffn GEMM, K=128 from LDS ----
  f32x4 fa[2][2];
  #pragma unroll
  for (int i=0;i<2;i++)
    #pragma unroll
    for (int j=0;j<2;j++) fa[i][j] = (f32x4){0.f,0.f,0.f,0.f};
  #pragma unroll
  for (int kk=0; kk<4; kk++){
    bf16x8 af[2], bfr[2];
    #pragma unroll
    for (int i=0;i<2;i++)
      af[i] = *(const bf16x8*)&As[(i*16 + lm)*LDK + kk*32 + lq*8];
    #pragma unroll
    for (int j=0;j<2;j++)
      bfr[j] = *(const bf16x8*)&Bs[(wn + j*16 + lm)*LDK + kk*32 + lq*8];
    #pragma unroll
    for (int i=0;i<2;i++)
      #pragma unroll
      for (int j=0;j<2;j++)
        fa[i][j] = __builtin_amdgcn_mfma_f32_16x16x32_bf16(af[i], bfr[j], fa[i][j], 0, 0, 0);
  }

  // ---- phase C: t = vout + mish(fa + fnb); dual row-LN ----
  float tv[2][2][4];
  #pragma unroll
  for (int i=0;i<2;i++)
    #pragma unroll
    for (int r=0;r<4;r++){ ps[i][r]=0.f; qs[i][r]=0.f; }
  #pragma unroll
  for (int i=0;i<2;i++){
    #pragma unroll
    for (int j=0;j<2;j++){
      const int col = wn + j*16 + lm;
      const float bv = fnb[col];
      #pragma unroll
      for (int r=0;r<4;r++){
        const float v = fa[i][j][r] + bv;
        const float E = __expf(v);
        const float uu = E*E + 2.f*E;
        const float mi = (v > 20.f) ? v : v*(uu/(uu+2.f));
        const float t = vout[i][j][r] + mi;
        tv[i][j][r] = t;
        ps[i][r] += t; qs[i][r] += t*t;
      }
    }
  }
  #pragma unroll
  for (int i=0;i<2;i++)
    #pragma unroll
    for (int r=0;r<4;r++){
      float s = ps[i][r], q = qs[i][r];
      s += __shfl_xor(s,1); s += __shfl_xor(s,2); s += __shfl_xor(s,4); s += __shfl_xor(s,8);
      q += __shfl_xor(q,1); q += __shfl_xor(q,2); q += __shfl_xor(q,4); q += __shfl_xor(q,8);
      if (lm==0){
        const int row = i*16 + lq*4 + r;
        sred[row*4 + wv] = s;
        sred[BM*4 + row*4 + wv] = q;
      }
    }
  __syncthreads();
  float xv[2][2][4];
  float ps2[2][4], qs2[2][4];
  #pragma unroll
  for (int i=0;i<2;i++)
    #pragma unroll
    for (int r=0;r<4;r++){
      const int row = i*16 + lq*4 + r;
      const float s = sred[row*4+0]+sred[row*4+1]+sred[row*4+2]+sred[row*4+3];
      const float q = sred[BM*4+row*4+0]+sred[BM*4+row*4+1]+sred[BM*4+row*4+2]+sred[BM*4+row*4+3];
      const float mean = s*(1.0f/128.0f);
      const float var  = q*(1.0f/128.0f) - mean*mean;
      const float rstd = rsqrtf(var + 1e-5f);
      float s2 = 0.f, q2 = 0.f;
      #pragma unroll
      for (int j=0;j<2;j++){
        const int col = wn + j*16 + lm;
        const float xnv = (tv[i][j][r]-mean)*rstd*g1[col] + b1[col];
        x_io[(size_t)(m0+row)*EE + col] = xnv;
        xv[i][j][r] = xnv;
        s2 += xnv; q2 += xnv*xnv;
      }
      ps2[i][r] = s2; qs2[i][r] = q2;
    }
  __syncthreads();
  #pragma unroll
  for (int i=0;i<2;i++)
    #pragma unroll
    for (int r=0;r<4;r++){
      float s = ps2[i][r], q = qs2[i][r];
      s += __shfl_xor(s,1); s += __shfl_xor(s,2); s += __shfl_xor(s,4); s += __shfl_xor(s,8);
      q += __shfl_xor(q,1); q += __shfl_xor(q,2); q += __shfl_xor(q,4); q += __shfl_xor(q,8);
      if (lm==0){
        const int row = i*16 + lq*4 + r;
        sred[row*4 + wv] = s;
        sred[BM*4 + row*4 + wv] = q;
      }
    }
  __syncthreads();
  #pragma unroll
  for (int i=0;i<2;i++)
    #pragma unroll
    for (int r=0;r<4;r++){
      const int row = i*16 + lq*4 + r;
      const float s = sred[row*4+0]+sred[row*4+1]+sred[row*4+2]+sred[row*4+3];
      const float q = sred[BM*4+row*4+0]+sred[BM*4+row*4+1]+sred[BM*4+row*4+2]+sred[BM*4+row*4+3];
      const float mean = s*(1.0f/128.0f);
      const float var  = q*(1.0f/128.0f) - mean*mean;
      const float rstd = rsqrtf(var + 1e-5f);
      #pragma unroll
      for (int j=0;j<2;j++){
        const int col = wn + j*16 + lm;
        const float xnv = (xv[i][j][r]-mean)*rstd*g2[col] + b2[col];
        xn_io[(size_t)(m0+row)*EE + col] = f2bf(xnv);
      }
    }
}

// =================== MFMA flash attention (XCD-local grid: bl,h,qt) ===================
// qkc: [tok][h*256 + (q:0..127 | k:128..255)] bf16, tok chunk-local.
// vTc: [h*128+d][tok] bf16 (pre-transposed V), tok chunk-local.
__global__ __launch_bounds__(256) void attn_mf_k(
    const u16* __restrict__ qkc, const u16* __restrict__ vTc,
    const float* __restrict__ w, u16* __restrict__ vals_c, int b0)
{
  const int bl = blockIdx.x;   // id%8 = bl -> one XCD per batch
  const int h  = blockIdx.y;
  const int qt = blockIdx.z;
  const int tid = threadIdx.x;
  const int wv = tid>>6, lane = tid&63;
  const int lm = lane&15, lq = lane>>4;

  __shared__ u16 Qs[64][136];
  __shared__ u16 Ks[64][136];
  __shared__ u16 Vts[128][72];
  __shared__ u16 Ps[64][72];
  __shared__ float wt[64], qwt[64];

  const size_t rs = 2048;
  const u16* qk = qkc + (size_t)bl*SEQ*rs + (size_t)h*256;
  const u16* vb = vTc + (size_t)h*128*CTOK + (size_t)bl*SEQ;
  const int q0 = qt*64;

  #pragma unroll
  for (int it=0; it<4; it++){
    const int fi = it*256 + tid;
    const int r = fi >> 4, g = fi & 15;
    *(float4*)&Qs[r][g*8] = *(const float4*)(qk + (size_t)(q0+r)*rs + g*8);
  }
  if (tid < 64) qwt[tid] = w[(b0+bl)*SEQ + q0 + tid];
  __syncthreads();

  float kq[4];
  #pragma unroll
  for (int r=0;r<4;r++) kq[r] = qwt[wv*16 + lq*4 + r];

  f32x4 oacc[8];
  #pragma unroll
  for (int j=0;j<8;j++) oacc[j] = (f32x4){0.f,0.f,0.f,0.f};
  float mrow[4], lrow[4];
  #pragma unroll
  for (int r=0;r<4;r++){ mrow[r]=-INFINITY; lrow[r]=0.f; }
  const float scale = 0.08838834764831845f;  // 1/sqrt(128)

  for (int kt=0; kt<8; kt++){
    __syncthreads();
    #pragma unroll
    for (int it=0; it<4; it++){
      const int fi = it*256 + tid;
      const int r = fi >> 4, g = fi & 15;
      *(float4*)&Ks[r][g*8] = *(const float4*)(qk + (size_t)(kt*64+r)*rs + 128 + g*8);
    }
    #pragma unroll
    for (int it=0; it<4; it++){
      const int fi = it*256 + tid;
      const int d = fi >> 3, g = fi & 7;
      *(float4*)&Vts[d][g*8] = *(const float4*)(vb + (size_t)d*CTOK + kt*64 + g*8);
    }
    if (tid < 64) wt[tid] = w[(b0+bl)*SEQ + kt*64 + tid];
    __syncthreads();

    f32x4 sacc[4];
    #pragma unroll
    for (int j=0;j<4;j++) sacc[j] = (f32x4){0.f,0.f,0.f,0.f};
    __builtin_amdgcn_s_setprio(1);
    #pragma unroll
    for (int kk=0; kk<4; kk++){
      const bf16x8 af = *(const bf16x8*)&Qs[wv*16+lm][kk*32+lq*8];
      #pragma unroll
      for (int j=0;j<4;j++){
        const bf16x8 bf = *(const bf16x8*)&Ks[j*16+lm][kk*32+lq*8];
        sacc[j] = __builtin_amdgcn_mfma_f32_16x16x32_bf16(af, bf, sacc[j], 0, 0, 0);
      }
    }
    __builtin_amdgcn_s_setprio(0);
    float wkj[4], s[4][4];
    #pragma unroll
    for (int j=0;j<4;j++) wkj[j] = wt[j*16+lm];
    #pragma unroll
    for (int j=0;j<4;j++)
      #pragma unroll
      for (int r=0;r<4;r++){
        const bool keep = (kq[r] > 0.f) && (wkj[j] > 0.f);
        s[j][r] = keep ? sacc[j][r]*scale : -9.0e15f;
      }
    float alpha[4];
    #pragma unroll
    for (int r=0;r<4;r++){
      float rm = fmaxf(fmaxf(s[0][r], s[1][r]), fmaxf(s[2][r], s[3][r]));
      rm = fmaxf(rm, __shfl_xor(rm, 1));
      rm = fmaxf(rm, __shfl_xor(rm, 2));
      rm = fmaxf(rm, __shfl_xor(rm, 4));
      rm = fmaxf(rm, __shfl_xor(rm, 8));
      const float newm = fmaxf(mrow[r], rm);
      alpha[r] = __expf(mrow[r] - newm);
      float ls = 0.f;
      #pragma unroll
      for (int j=0;j<4;j++){
        const float pv = wkj[j]*__expf(s[j][r]-newm);
        s[j][r] = pv; ls += pv;
      }
      ls += __shfl_xor(ls, 1);
      ls += __shfl_xor(ls, 2);
      ls += __shfl_xor(ls, 4);
      ls += __shfl_xor(ls, 8);
      lrow[r] = lrow[r]*alpha[r] + ls;
      mrow[r] = newm;
    }
    #pragma unroll
    for (int j=0;j<4;j++)
      #pragma unroll
      for (int r=0;r<4;r++)
        Ps[wv*16 + lq*4 + r][j*16+lm] = f2bf(s[j][r]);
    #pragma unroll
    for (int j=0;j<8;j++)
      #pragma unroll
      for (int r=0;r<4;r++) oacc[j][r] *= alpha[r];
    __syncthreads();   // R19: restored (cross-wave P-scatter/PV-read contention)

    __builtin_amdgcn_s_setprio(1);
    #pragma unroll
    for (int kk=0; kk<2; kk++){
      const bf16x8 pf = *(const bf16x8*)&Ps[wv*16+lm][kk*32+lq*8];
      #pragma unroll
      for (int j=0;j<8;j++){
        const bf16x8 vf = *(const bf16x8*)&Vts[j*16+lm][kk*32+lq*8];
        oacc[j] = __builtin_amdgcn_mfma_f32_16x16x32_bf16(pf, vf, oacc[j], 0, 0, 0);
      }
    }
    __builtin_amdgcn_s_setprio(0);
  }
  #pragma unroll
  for (int r=0;r<4;r++){
    const float inv = 1.0f / lrow[r];
    u16* orow = vals_c + ((size_t)(bl*SEQ + q0 + wv*16 + lq*4 + r))*EHH + h*EE;
    #pragma unroll
    for (int j=0;j<8;j++) orow[j*16+lm] = f2bf(oacc[j][r]*inv);
  }
}

// =================== fused pool: weighted sum + LN + head (4-way split) ===================
__global__ __launch_bounds__(512) void pool_k(
    const float* __restrict__ x, const float* __restrict__ x_init,
    const float* __restrict__ w, const float* __restrict__ g2,
    const float* __restrict__ b2, const float* __restrict__ head_W,
    const float* __restrict__ head_b, float* __restrict__ out)
{
  const int b = blockIdx.x;
  const int tid = threadIdx.x;
  const int e = tid & 127, seg = tid >> 7;
  __shared__ float red[512];
  float acc = 0.f;
  const int n0 = seg*128;
  #pragma unroll 4
  for (int n=n0;n<n0+128;n++){
    const int tok = b*SEQ + n;
    const size_t idx = (size_t)tok*EE + e;
    acc = fmaf(w[tok], x[idx]+x_init[idx], acc);
  }
  red[tid] = acc;
  __syncthreads();
  const float a = (red[e]+red[128+e])+(red[256+e]+red[384+e]);
  __syncthreads();
  if (tid < 128) red[tid] = a;
  __syncthreads();
  for (int s=64;s>0;s>>=1){ if(tid<s) red[tid]+=red[tid+s]; __syncthreads(); }
  const float mean = red[0]*(1.0f/128.0f);
  __syncthreads();
  const float d = a-mean;
  if (tid < 128) red[tid] = d*d;
  __syncthreads();
  for (int s=64;s>0;s>>=1){ if(tid<s) red[tid]+=red[tid+s]; __syncthreads(); }
  const float var = red[0]*(1.0f/128.0f);
  const float p = d*rsqrtf(var+1e-5f)*g2[e]+b2[e];
  __syncthreads();
  if (tid < 128) red[tid] = p*head_W[e];
  __syncthreads();
  for (int s=64;s>0;s>>=1){ if(tid<s) red[tid]+=red[tid+s]; __syncthreads(); }
  if (tid==0) out[b] = red[0] + head_b[0];
}

// =================== launch ===================
extern "C" void kernel_launch(void* const* d_in, const int* in_sizes, int n_in,
                              void* d_out, int out_size, void* d_ws, size_t ws_size,
                              hipStream_t stream)
{
  const float* str_fea   = (const float*)d_in[0];
  const int*   comp_fea  = (const int*)  d_in[1];
  // d_in[2] cell_fea unused by reference
  const float* atom_table= (const float*)d_in[3];
  const float* comp_W    = (const float*)d_in[4];
  const float* comp_b    = (const float*)d_in[5];
  const float* pdd_W     = (const float*)d_in[6];
  const float* pdd_b     = (const float*)d_in[7];
  const float* enc_ln_g  = (const float*)d_in[8];
  const float* enc_ln_b  = (const float*)d_in[9];
  const float* qkv_W     = (const float*)d_in[10];
  const float* qkv_b     = (const float*)d_in[11];
  const float* o_W       = (const float*)d_in[12];
  const float* o_b       = (const float*)d_in[13];
  const float* out_W     = (const float*)d_in[14];
  const float* out_b     = (const float*)d_in[15];
  const float* ffn_W     = (const float*)d_in[16];
  const float* ffn_b     = (const float*)d_in[17];
  const float* ln2_g     = (const float*)d_in[18];
  const float* ln2_b     = (const float*)d_in[19];
  const float* head_W    = (const float*)d_in[20];
  const float* head_b    = (const float*)d_in[21];
  float* out = (float*)d_out;

  // ---- diagnostic 1: input layout model ----
  bool sizes_ok = (n_in >= 22);
  if (sizes_ok){
    sizes_ok = in_sizes[0]==BB*SEQ*KF && in_sizes[1]==NTOK &&
               in_sizes[3]==NATOM*ADIM && in_sizes[4]==ADIM*EE &&
               in_sizes[10]==LL*EE*3*EHH && in_sizes[12]==LL*EHH*EHH &&
               in_sizes[14]==LL*EHH*EE   && in_sizes[16]==LL*EE*EE &&
               in_sizes[20]==EE;
  }
  if (!sizes_ok){
    sentinel_k<<<(out_size+63)/64,64,0,stream>>>(out, 99999.0f, out_size);
    return;
  }

  // ---- workspace layout (~90 MB; <= 109.7 MB proven) ----
  char* p = (char*)d_ws;
  size_t off = 0;
  auto alloc = [&](size_t bytes)->void*{
    off = (off + 255) & ~(size_t)255;
    void* r = p + off; off += bytes; return r;
  };
  float* w        = (float*)alloc((size_t)NTOK*4);
  float* x        = (float*)alloc((size_t)NTOK*EE*4);
  float* x_init   = (float*)alloc((size_t)NTOK*EE*4);
  u16*   xn_bf    = (u16*)  alloc((size_t)NTOK*EE*2);
  u16*   qkc      = (u16*)  alloc((size_t)CTOK*2048*2);   // 16.8 MB chunk (Q|K)
  u16*   vTc      = (u16*)  alloc((size_t)EHH*CTOK*2);    // 8.4 MB chunk (V^T)
  u16*   vals_bf  = (u16*)  alloc((size_t)NTOK*EHH*2);    // 33.6 MB
  u16*   qkvWT_a  = (u16*)  alloc((size_t)LL*3*EHH*EE*2); // 2.36 MB (reordered)
  float* rqkv_b   = (float*)alloc((size_t)LL*3*EHH*4);    // reordered bias
  u16*   fwT_a    = (u16*)  alloc((size_t)LL*EE*EHH*2);   // 0.79 MB
  u16*   ffnWT_a  = (u16*)  alloc((size_t)LL*EE*EE*2);
  u16*   oWb_a    = (u16*)  alloc((size_t)LL*EHH*EHH*2);  // 6.29 MB
  u16*   outWT_a  = (u16*)  alloc((size_t)LL*EE*EHH*2);
  float* fb_a     = (float*)alloc((size_t)LL*EE*4);
  float* atom_emb = (float*)alloc((size_t)NATOM*EE*4);

  // ---- diagnostic 2: workspace size ----
  if (off > ws_size){
    sentinel_k<<<(out_size+63)/64,64,0,stream>>>(out, 12345.0f, out_size);
    return;
  }

  // ---- hoisted weight prep (merged; includes atomemb + fuse_b roles) ----
  prep_k<<<14030,256,0,stream>>>(qkv_W, qkvWT_a, ffn_W, ffnWT_a,
                                 out_W, outWT_a, o_W, oWb_a, qkv_b, rqkv_b,
                                 atom_table, comp_W, comp_b, pdd_b, atom_emb,
                                 o_b, out_b, fb_a);
  // fwT = (o_W @ out_W)^T per layer (EPI4 transposed store), grid.z = layers
  mgemm_k<4,32,64,128><<<dim3(EE/64, EHH/32, LL),256,0,stream>>>(
      oWb_a, outWT_a, nullptr, fwT_a, EE, EHH, EHH, nullptr,
      (size_t)EHH*EHH, (size_t)EE*EHH, (size_t)EE*EHH*2);

  embed_ln_k<<<NTOK/64,1024,0,stream>>>(str_fea, comp_fea, atom_emb, pdd_W,
                                        enc_ln_g, enc_ln_b, x, x_init, w, xn_bf);

  for (int i=0;i<LL;i++){
    const float* gi = enc_ln_g + i*EE;
    const float* bi = enc_ln_b + i*EE;
    for (int cb=0; cb<NCHUNK; cb++){
      const int t0 = cb*CTOK;
      const int b0 = cb*CB;
      // QKV with router epilogue: Q|K -> qkc (stride 2048), V -> vTc (transposed)
      mgemm_k<7,128,128,64><<<dim3(3*EHH/128, CTOK/128),256,0,stream>>>(
          xn_bf + (size_t)t0*EE, qkvWT_a + (size_t)i*3*EHH*EE,
          rqkv_b + (size_t)i*3*EHH,
          qkc, 3*EHH, EE, CTOK, vTc, 0, 0, 0);
      attn_mf_k<<<dim3(CB, HH, SEQ/64),256,0,stream>>>(
          qkc, vTc, w, vals_bf + (size_t)t0*EHH, b0);
    }
    // proj + resid + LN + ffn + mish + dual-LN, all in one kernel
    const float* gn = (i<LL-1) ? enc_ln_g + (i+1)*EE : gi;
    const float* bn = (i<LL-1) ? enc_ln_b + (i+1)*EE : bi;
    projffn_k<<<NTOK/32,256,0,stream>>>(
        vals_bf, fwT_a + (size_t)i*EE*EHH, fb_a + (size_t)i*EE,
        ffnWT_a + (size_t)i*EE*EE, ffn_b + (size_t)i*EE,
        gi, bi, gn, bn, x, xn_bf);
  }
  pool_k<<<BB,512,0,stream>>>(x, x_init, w, ln2_g, ln2_b, head_W, head_b, out);
}

// Round 6
// 920.969 us; speedup vs baseline: 1.1226x; 1.1226x over previous
//
#include <hip/hip_runtime.h>
#include <math.h>

#define DI __device__ __forceinline__

// ---- problem constants ----
#define BB 32
#define SEQ 512
#define KF 101
#define EE 128
#define HH 8
#define EHH 1024
#define LL 3
#define ADIM 200
#define NATOM 119
#define NTOK (BB*SEQ)   // 16384
#define CB 8            // batches per chunk
#define NCHUNK (BB/CB)  // 4
#define CTOK (CB*SEQ)   // 4096 tokens per chunk

// R20: R19's embed_ln spilled (VGPR capped 64 @1024thr -> 450MB scratch
// traffic, 104us). Fix: 512thr blocks + __launch_bounds__(512,4) -> 128
// VGPR cap, no spill, same math. Pool re-split (fused pool ran 33.6MB
// read on 32 blocks = 12.5% of CUs): pool1 256 blocks + pool2.
// Attn barrier + prep merge unchanged from R19.

typedef unsigned short u16;
typedef __attribute__((ext_vector_type(8))) short bf16x8;
typedef __attribute__((ext_vector_type(4))) float f32x4;

DI float bf2f(u16 s){ union{unsigned int u; float f;} x; x.u = ((unsigned int)s)<<16; return x.f; }
DI u16 f2bf(float f){
  union{float f; unsigned int u;} x; x.f = f;
  unsigned int u = x.u;
  u += 0x7fffu + ((u>>16)&1u);           // RNE
  return (u16)(u>>16);
}
DI float rdl(float v, int l){
  return __int_as_float(__builtin_amdgcn_readlane(__float_as_int(v), l));
}

// =================== sentinel ===================
__global__ void sentinel_k(float* out, float v, int n){
  int i = blockIdx.x*64 + threadIdx.x;
  if (i < n) out[i] = v;
}

// =================== embed + layer-0 LN (32 tokens/block, 8 waves) ===================
// x = atom_emb[idx] + str[1:]@pdd_W ; xn = LN(x, g0, b0)
// Wave handles 4 tokens; pdd loads (float2, conflict-free) shared across
// tokens; str broadcast via v_readlane from 2 VGPRs. 128-VGPR budget.
__global__ __launch_bounds__(512, 4) void embed_ln_k(
    const float* __restrict__ str_fea, const int* __restrict__ comp_fea,
    const float* __restrict__ atom_emb, const float* __restrict__ pdd_W,
    const float* __restrict__ g, const float* __restrict__ bta,
    float* __restrict__ x, float* __restrict__ x_init, float* __restrict__ w,
    u16* __restrict__ xn)
{
  const int t0 = blockIdx.x*32;
  const int tid = threadIdx.x;
  const int wv = tid>>6, lane = tid&63;
  __shared__ float2 sPdd[100*64];      // [j][pair] = pdd_W[j][2p..2p+1], 51.2 KB
  for (int k2=tid; k2<100*64; k2+=512)
    sPdd[k2] = ((const float2*)pdd_W)[k2];

  // per-wave: 4 tokens; str row in 2 VGPRs (lanes 0..63 hold str[0..63],
  // lanes 0..36 hold str[64..100] in sv1)
  float sv0[4], sv1[4];
  int idx[4];
  #pragma unroll
  for (int tk=0; tk<4; ++tk){
    const int t = t0 + wv*4 + tk;
    const float* sr0 = str_fea + (size_t)t*KF;
    sv0[tk] = sr0[lane];
    sv1[tk] = (lane+64 < KF) ? sr0[lane+64] : 0.f;
    idx[tk] = comp_fea[t];
  }
  __syncthreads();

  float a0[4],a1[4],a2[4],a3[4],c0[4],c1[4],c2[4],c3[4];
  #pragma unroll
  for (int tk=0; tk<4; ++tk){
    const float2 ae = ((const float2*)(atom_emb + (size_t)idx[tk]*EE))[lane];
    a0[tk]=ae.x; a1[tk]=0.f; a2[tk]=0.f; a3[tk]=0.f;
    c0[tk]=ae.y; c1[tk]=0.f; c2[tk]=0.f; c3[tk]=0.f;
  }
  #pragma unroll 5
  for (int j=0; j<100; j+=4){
    const float2 w0 = sPdd[(j  )*64 + lane];
    const float2 w1 = sPdd[(j+1)*64 + lane];
    const float2 w2 = sPdd[(j+2)*64 + lane];
    const float2 w3 = sPdd[(j+3)*64 + lane];
    #pragma unroll
    for (int tk=0; tk<4; ++tk){
      const float s1 = (1+j<64) ? rdl(sv0[tk],1+j) : rdl(sv1[tk],1+j-64);
      const float s2 = (2+j<64) ? rdl(sv0[tk],2+j) : rdl(sv1[tk],2+j-64);
      const float s3 = (3+j<64) ? rdl(sv0[tk],3+j) : rdl(sv1[tk],3+j-64);
      const float s4 = (4+j<64) ? rdl(sv0[tk],4+j) : rdl(sv1[tk],4+j-64);
      a0[tk] = fmaf(s1, w0.x, a0[tk]);  c0[tk] = fmaf(s1, w0.y, c0[tk]);
      a1[tk] = fmaf(s2, w1.x, a1[tk]);  c1[tk] = fmaf(s2, w1.y, c1[tk]);
      a2[tk] = fmaf(s3, w2.x, a2[tk]);  c2[tk] = fmaf(s3, w2.y, c2[tk]);
      a3[tk] = fmaf(s4, w3.x, a3[tk]);  c3[tk] = fmaf(s4, w3.y, c3[tk]);
    }
  }
  const float2 gg = ((const float2*)g)[lane];
  const float2 bb = ((const float2*)bta)[lane];
  #pragma unroll
  for (int tk=0; tk<4; ++tk){
    const int t = t0 + wv*4 + tk;
    const float vx = (a0[tk]+a1[tk])+(a2[tk]+a3[tk]);
    const float vy = (c0[tk]+c1[tk])+(c2[tk]+c3[tk]);
    ((float2*)(x      + (size_t)t*EE))[lane] = make_float2(vx, vy);
    ((float2*)(x_init + (size_t)t*EE))[lane] = make_float2(vx, vy);
    if (lane==0) w[t] = sv0[tk];
    // LN (identical order to old ln_k)
    float s = vx + vy;
    #pragma unroll
    for (int off=32; off; off>>=1) s += __shfl_xor(s, off);
    const float mean = s*(1.0f/128.0f);
    const float d0 = vx-mean, d1 = vy-mean;
    float q = d0*d0 + d1*d1;
    #pragma unroll
    for (int off=32; off; off>>=1) q += __shfl_xor(q, off);
    const float rstd = rsqrtf(q*(1.0f/128.0f) + 1e-5f);
    u16* o = xn + (size_t)t*EE + lane*2;
    o[0] = f2bf(d0*rstd*gg.x + bb.x);
    o[1] = f2bf(d1*rstd*gg.y + bb.y);
  }
}

// =================== merged weight prep (+atomemb +fuse_b roles) ===================
DI void trans32(const float* __restrict__ W, u16* __restrict__ WT,
                int Nn, int Kk, int srcCol0, int n0, int k0, int tid,
                u16 (&tile)[32][33])
{
  const int lr = tid>>5, lc = tid&31;
  #pragma unroll
  for (int i=0;i<4;i++)
    tile[lr+i*8][lc] = f2bf(W[(size_t)(k0+lr+i*8)*Nn + srcCol0 + lc]);
  __syncthreads();
  #pragma unroll
  for (int i=0;i<4;i++)
    WT[(size_t)(n0+lr+i*8)*Kk + k0 + lc] = tile[lc][lr+i*8];
}

// roles: [0,1152) qkvT | [1152,1200) ffnT | [1200,1584) outWT |
//        [1584,13872) oW cconv | [13872,13908) qkv bias reorder |
//        [13908,14027) atomemb | [14027,14030) fuse_b
__global__ __launch_bounds__(256) void prep_k(
    const float* __restrict__ qkv_W, u16* __restrict__ qkvWT,
    const float* __restrict__ ffn_W, u16* __restrict__ ffnWT,
    const float* __restrict__ out_W, u16* __restrict__ outWT,
    const float* __restrict__ o_W,  u16* __restrict__ oWb,
    const float* __restrict__ qkv_b, float* __restrict__ rqkv_b,
    const float* __restrict__ atom_table, const float* __restrict__ comp_W,
    const float* __restrict__ comp_b, const float* __restrict__ pdd_b,
    float* __restrict__ atom_emb,
    const float* __restrict__ o_b, const float* __restrict__ out_b,
    float* __restrict__ fb)
{
  __shared__ u16 tile[32][33];
  __shared__ float sbuf[456];          // atomemb: sAtom[200]+red[256]; fuse_b: red[256]
  int bid = blockIdx.x;
  const int tid = threadIdx.x;
  if (bid < 1152){
    const int xb = bid%96, yb = (bid/96)%4, zb = bid/384;
    const int n0 = xb*32, k0 = yb*32;
    int c0;
    if (n0 < 2048) c0 = (n0>>8)*384 + (n0&255);
    else { const int m0 = n0-2048; c0 = (m0>>7)*384 + 256 + (m0&127); }
    trans32(qkv_W + (size_t)zb*EE*3*EHH, qkvWT + (size_t)zb*3*EHH*EE,
            3*EHH, EE, c0, n0, k0, tid, tile);
    return;
  }
  bid -= 1152;
  if (bid < 48){
    const int xb = bid%4, yb = (bid/4)%4, zb = bid/16;
    trans32(ffn_W + (size_t)zb*EE*EE, ffnWT + (size_t)zb*EE*EE,
            EE, EE, xb*32, xb*32, yb*32, tid, tile);
    return;
  }
  bid -= 48;
  if (bid < 384){
    const int xb = bid%4, yb = (bid/4)%32, zb = bid/128;
    trans32(out_W + (size_t)zb*EHH*EE, outWT + (size_t)zb*EE*EHH,
            EE, EHH, xb*32, xb*32, yb*32, tid, tile);
    return;
  }
  bid -= 384;
  if (bid < 12288){
    const int i = bid*256 + tid;
    oWb[i] = f2bf(o_W[i]);
    return;
  }
  bid -= 12288;
  if (bid < 36){
    const int l = bid/12;
    const int n = (bid%12)*256 + tid;
    int c;
    if (n < 2048) c = (n>>8)*384 + (n&255);
    else { const int m = n-2048; c = (m>>7)*384 + 256 + (m&127); }
    rqkv_b[(size_t)l*3*EHH + n] = qkv_b[(size_t)l*3*EHH + c];
    return;
  }
  bid -= 36;
  if (bid < NATOM){
    // atom embedding: atom_emb[a] = comp_b + pdd_b + atom_table[a]@comp_W
    const int a = bid;
    const int e = tid & 127, half = tid >> 7;
    float* sAtom = sbuf;
    float* red   = sbuf + 200;
    for (int d=tid; d<ADIM; d+=256) sAtom[d] = atom_table[a*ADIM+d];
    __syncthreads();
    float acc = half ? 0.f : (comp_b[e] + pdd_b[e]);
    const int d0 = half*100;
    #pragma unroll 4
    for (int d=d0; d<d0+100; d++) acc = fmaf(sAtom[d], comp_W[d*EE+e], acc);
    red[tid] = acc;
    __syncthreads();
    if (half==0) atom_emb[a*EE+e] = red[e] + red[128+e];
    return;
  }
  bid -= NATOM;
  {
    // fb = o_b@out_W + out_b (2-way k-split)
    const int ly = bid;
    const float* ob = o_b + (size_t)ly*EHH;
    const float* oW = out_W + (size_t)ly*EHH*EE;
    const int n = tid & 127, seg = tid >> 7;
    float acc = 0.f;
    const int kb = seg*512;
    #pragma unroll 4
    for (int k2=kb; k2<kb+512; ++k2) acc = fmaf(ob[k2], oW[(size_t)k2*EE+n], acc);
    float* red = sbuf + 200;
    red[tid] = acc;
    __syncthreads();
    if (seg==0)
      fb[(size_t)ly*EE + n] = out_b[(size_t)ly*EE + n] + (red[n] + red[128+n]);
  }
}

// =================== MFMA bf16 GEMM (layer-batched via z strides) ===================
// A: M x Kk bf16 row-major. BT: Nn x Kk bf16 (pre-transposed B).
// EPI 0: store bf16; 4: bf16 transposed store (no bias);
// EPI 7 (QKV router): col<2048 -> ((u16*)C)[row*2048+col];
//                     col>=2048 -> ((u16*)C2)[(col-2048)*Mdim+row] (V^T).
template<int EPI, int BM, int BN, int BK>
__global__ __launch_bounds__(256) void mgemm_k(
    const u16* __restrict__ A, const u16* __restrict__ BT,
    const float* __restrict__ bias, void* __restrict__ Cv,
    int Nn, int Kk, int Mdim, void* __restrict__ C2,
    size_t sA, size_t sBT, size_t sCb)
{
  const int lz = blockIdx.z;
  A  += (size_t)lz*sA;
  BT += (size_t)lz*sBT;
  void* C = (void*)((char*)Cv + (size_t)lz*sCb);

  constexpr int LDK = BK + 8;
  __shared__ u16 As[BM*LDK];
  __shared__ u16 Bs[BN*LDK];
  const int tid = threadIdx.x;
  const int m0 = blockIdx.y*BM, n0 = blockIdx.x*BN;
  constexpr int WMN = (BM>=128)?2:1;
  constexpr int WNN = 4/WMN;
  constexpr int WM = BM/WMN;
  constexpr int WN = BN/WNN;
  constexpr int FM = WM/16, FN = WN/16;
  const int wv = tid>>6, lane = tid&63;
  const int wm = (wv/WNN)*WM;
  const int wn = (wv%WNN)*WN;
  const int lm = lane&15, lq = lane>>4;

  f32x4 acc[FM][FN];
  #pragma unroll
  for (int i=0;i<FM;i++)
    #pragma unroll
    for (int j=0;j<FN;j++) acc[i][j] = (f32x4){0.f,0.f,0.f,0.f};

  constexpr int ACH = BM*BK/8;
  constexpr int BCH = BN*BK/8;

  for (int k0=0; k0<Kk; k0+=BK){
    #pragma unroll
    for (int c = tid; c < ACH; c += 256){
      const int r = c/(BK/8), kg = c - r*(BK/8);
      const float4 v = *(const float4*)(A + (size_t)(m0+r)*Kk + k0 + kg*8);
      *(float4*)&As[r*LDK + kg*8] = v;
    }
    #pragma unroll
    for (int c = tid; c < BCH; c += 256){
      const int r = c/(BK/8), kg = c - r*(BK/8);
      const float4 v = *(const float4*)(BT + (size_t)(n0+r)*Kk + k0 + kg*8);
      *(float4*)&Bs[r*LDK + kg*8] = v;
    }
    __syncthreads();
    #pragma unroll
    for (int kk=0; kk<BK/32; kk++){
      bf16x8 af[FM], bfr[FN];
      #pragma unroll
      for (int i=0;i<FM;i++)
        af[i] = *(const bf16x8*)&As[(wm + i*16 + lm)*LDK + kk*32 + lq*8];
      #pragma unroll
      for (int j=0;j<FN;j++)
        bfr[j] = *(const bf16x8*)&Bs[(wn + j*16 + lm)*LDK + kk*32 + lq*8];
      #pragma unroll
      for (int i=0;i<FM;i++)
        #pragma unroll
        for (int j=0;j<FN;j++)
          acc[i][j] = __builtin_amdgcn_mfma_f32_16x16x32_bf16(af[i], bfr[j], acc[i][j], 0, 0, 0);
    }
    __syncthreads();
  }
  #pragma unroll
  for (int i=0;i<FM;i++){
    #pragma unroll
    for (int j=0;j<FN;j++){
      const int col = n0 + wn + j*16 + lm;
      const float bv = (EPI==4) ? 0.f : bias[col];
      #pragma unroll
      for (int r=0;r<4;r++){
        const int row = m0 + wm + i*16 + lq*4 + r;
        float v = acc[i][j][r] + bv;
        if constexpr (EPI==7){
          if (col < 2048) ((u16*)C)[(size_t)row*2048 + col] = f2bf(v);
          else            ((u16*)C2)[(size_t)(col-2048)*Mdim + row] = f2bf(v);
        } else if constexpr (EPI==4){
          ((u16*)C)[(size_t)col*Mdim + row] = f2bf(v);
        } else {
          ((u16*)C)[(size_t)row*Nn + col] = f2bf(v);
        }
      }
    }
  }
}

// =================== fused proj+LN + ffn+mish + dual-LN ===================
__global__ __launch_bounds__(256) void projffn_k(
    const u16* __restrict__ vals, const u16* __restrict__ fwT,
    const float* __restrict__ fb, const u16* __restrict__ ffnWT,
    const float* __restrict__ fnb,
    const float* __restrict__ g1, const float* __restrict__ b1,
    const float* __restrict__ g2, const float* __restrict__ b2,
    float* __restrict__ x_io, u16* __restrict__ xn_io)
{
  constexpr int BM = 32, BK = 128, LDK = BK + 8;
  __shared__ u16 As[BM*LDK];        // proj A tiles; then xn2 (bf16)
  __shared__ u16 Bs[EE*LDK];        // fwT tiles; then ffnWT
  __shared__ float sred[BM*8];
  const int tid = threadIdx.x;
  const int wv = tid>>6, lane = tid&63;
  const int lm = lane&15, lq = lane>>4;
  const int m0 = blockIdx.x*BM;
  const int wn = wv*32;             // 4 waves x 32 cols

  f32x4 acc[2][2];
  #pragma unroll
  for (int i=0;i<2;i++)
    #pragma unroll
    for (int j=0;j<2;j++) acc[i][j] = (f32x4){0.f,0.f,0.f,0.f};

  // ---- phase A: proj GEMM, K=1024 ----
  for (int k0=0; k0<EHH; k0+=BK){
    #pragma unroll
    for (int c = tid; c < BM*BK/8; c += 256){
      const int r = c>>4, kg = c&15;
      *(float4*)&As[r*LDK + kg*8] = *(const float4*)(vals + (size_t)(m0+r)*EHH + k0 + kg*8);
    }
    #pragma unroll
    for (int c = tid; c < EE*BK/8; c += 256){
      const int r = c>>4, kg = c&15;
      *(float4*)&Bs[r*LDK + kg*8] = *(const float4*)(fwT + (size_t)r*EHH + k0 + kg*8);
    }
    __syncthreads();
    #pragma unroll
    for (int kk=0; kk<BK/32; kk++){
      bf16x8 af[2], bfr[2];
      #pragma unroll
      for (int i=0;i<2;i++)
        af[i] = *(const bf16x8*)&As[(i*16 + lm)*LDK + kk*32 + lq*8];
      #pragma unroll
      for (int j=0;j<2;j++)
        bfr[j] = *(const bf16x8*)&Bs[(wn + j*16 + lm)*LDK + kk*32 + lq*8];
      #pragma unroll
      for (int i=0;i<2;i++)
        #pragma unroll
        for (int j=0;j<2;j++)
          acc[i][j] = __builtin_amdgcn_mfma_f32_16x16x32_bf16(af[i], bfr[j], acc[i][j], 0, 0, 0);
    }
    __syncthreads();
  }

  // ---- phase A epilogue: vout = acc + fb + x ; LN stats ----
  float vout[2][2][4];
  float ps[2][4], qs[2][4];
  #pragma unroll
  for (int i=0;i<2;i++)
    #pragma unroll
    for (int r=0;r<4;r++){ ps[i][r]=0.f; qs[i][r]=0.f; }
  #pragma unroll
  for (int i=0;i<2;i++){
    #pragma unroll
    for (int j=0;j<2;j++){
      const int col = wn + j*16 + lm;
      const float bv = fb[col];
      #pragma unroll
      for (int r=0;r<4;r++){
        const int row = m0 + i*16 + lq*4 + r;
        const float v = acc[i][j][r] + bv + x_io[(size_t)row*EE + col];
        vout[i][j][r] = v;
        ps[i][r] += v; qs[i][r] += v*v;
      }
    }
  }
  #pragma unroll
  for (int i=0;i<2;i++)
    #pragma unroll
    for (int r=0;r<4;r++){
      float s = ps[i][r], q = qs[i][r];
      s += __shfl_xor(s,1); s += __shfl_xor(s,2); s += __shfl_xor(s,4); s += __shfl_xor(s,8);
      q += __shfl_xor(q,1); q += __shfl_xor(q,2); q += __shfl_xor(q,4); q += __shfl_xor(q,8);
      if (lm==0){
        const int row = i*16 + lq*4 + r;
        sred[row*4 + wv] = s;
        sred[BM*4 + row*4 + wv] = q;
      }
    }
  __syncthreads();
  // xn2 -> As (bf16), and stage ffnWT -> Bs
  #pragma unroll
  for (int i=0;i<2;i++)
    #pragma unroll
    for (int r=0;r<4;r++){
      const int row = i*16 + lq*4 + r;
      const float s = sred[row*4+0]+sred[row*4+1]+sred[row*4+2]+sred[row*4+3];
      const float q = sred[BM*4+row*4+0]+sred[BM*4+row*4+1]+sred[BM*4+row*4+2]+sred[BM*4+row*4+3];
      const float mean = s*(1.0f/128.0f);
      const float var  = q*(1.0f/128.0f) - mean*mean;
      const float rstd = rsqrtf(var + 1e-5f);
      #pragma unroll
      for (int j=0;j<2;j++){
        const int col = wn + j*16 + lm;
        const float xnv = (vout[i][j][r]-mean)*rstd*g1[col] + b1[col];
        As[row*LDK + col] = f2bf(xnv);
      }
    }
  #pragma unroll
  for (int c = tid; c < EE*EE/8; c += 256){
    const int r = c>>4, kg = c&15;
    *(float4*)&Bs[r*LDK + kg*8] = *(const float4*)(ffnWT + (size_t)r*EE + kg*8);
  }
  __syncthreads();

  // ---- phase B: ffn GEMM, K=128 from LDS ----
  f32x4 fa[2][2];
  #pragma unroll
  for (int i=0;i<2;i++)
    #pragma unroll
    for (int j=0;j<2;j++) fa[i][j] = (f32x4){0.f,0.f,0.f,0.f};
  #pragma unroll
  for (int kk=0; kk<4; kk++){
    bf16x8 af[2], bfr[2];
    #pragma unroll
    for (int i=0;i<2;i++)
      af[i] = *(const bf16x8*)&As[(i*16 + lm)*LDK + kk*32 + lq*8];
    #pragma unroll
    for (int j=0;j<2;j++)
      bfr[j] = *(const bf16x8*)&Bs[(wn + j*16 + lm)*LDK + kk*32 + lq*8];
    #pragma unroll
    for (int i=0;i<2;i++)
      #pragma unroll
      for (int j=0;j<2;j++)
        fa[i][j] = __builtin_amdgcn_mfma_f32_16x16x32_bf16(af[i], bfr[j], fa[i][j], 0, 0, 0);
  }

  // ---- phase C: t = vout + mish(fa + fnb); dual row-LN ----
  float tv[2][2][4];
  #pragma unroll
  for (int i=0;i<2;i++)
    #pragma unroll
    for (int r=0;r<4;r++){ ps[i][r]=0.f; qs[i][r]=0.f; }
  #pragma unroll
  for (int i=0;i<2;i++){
    #pragma unroll
    for (int j=0;j<2;j++){
      const int col = wn + j*16 + lm;
      const float bv = fnb[col];
      #pragma unroll
      for (int r=0;r<4;r++){
        const float v = fa[i][j][r] + bv;
        const float E = __expf(v);
        const float uu = E*E + 2.f*E;
        const float mi = (v > 20.f) ? v : v*(uu/(uu+2.f));
        const float t = vout[i][j][r] + mi;
        tv[i][j][r] = t;
        ps[i][r] += t; qs[i][r] += t*t;
      }
    }
  }
  #pragma unroll
  for (int i=0;i<2;i++)
    #pragma unroll
    for (int r=0;r<4;r++){
      float s = ps[i][r], q = qs[i][r];
      s += __shfl_xor(s,1); s += __shfl_xor(s,2); s += __shfl_xor(s,4); s += __shfl_xor(s,8);
      q += __shfl_xor(q,1); q += __shfl_xor(q,2); q += __shfl_xor(q,4); q += __shfl_xor(q,8);
      if (lm==0){
        const int row = i*16 + lq*4 + r;
        sred[row*4 + wv] = s;
        sred[BM*4 + row*4 + wv] = q;
      }
    }
  __syncthreads();
  float xv[2][2][4];
  float ps2[2][4], qs2[2][4];
  #pragma unroll
  for (int i=0;i<2;i++)
    #pragma unroll
    for (int r=0;r<4;r++){
      const int row = i*16 + lq*4 + r;
      const float s = sred[row*4+0]+sred[row*4+1]+sred[row*4+2]+sred[row*4+3];
      const float q = sred[BM*4+row*4+0]+sred[BM*4+row*4+1]+sred[BM*4+row*4+2]+sred[BM*4+row*4+3];
      const float mean = s*(1.0f/128.0f);
      const float var  = q*(1.0f/128.0f) - mean*mean;
      const float rstd = rsqrtf(var + 1e-5f);
      float s2 = 0.f, q2 = 0.f;
      #pragma unroll
      for (int j=0;j<2;j++){
        const int col = wn + j*16 + lm;
        const float xnv = (tv[i][j][r]-mean)*rstd*g1[col] + b1[col];
        x_io[(size_t)(m0+row)*EE + col] = xnv;
        xv[i][j][r] = xnv;
        s2 += xnv; q2 += xnv*xnv;
      }
      ps2[i][r] = s2; qs2[i][r] = q2;
    }
  __syncthreads();
  #pragma unroll
  for (int i=0;i<2;i++)
    #pragma unroll
    for (int r=0;r<4;r++){
      float s = ps2[i][r], q = qs2[i][r];
      s += __shfl_xor(s,1); s += __shfl_xor(s,2); s += __shfl_xor(s,4); s += __shfl_xor(s,8);
      q += __shfl_xor(q,1); q += __shfl_xor(q,2); q += __shfl_xor(q,4); q += __shfl_xor(q,8);
      if (lm==0){
        const int row = i*16 + lq*4 + r;
        sred[row*4 + wv] = s;
        sred[BM*4 + row*4 + wv] = q;
      }
    }
  __syncthreads();
  #pragma unroll
  for (int i=0;i<2;i++)
    #pragma unroll
    for (int r=0;r<4;r++){
      const int row = i*16 + lq*4 + r;
      const float s = sred[row*4+0]+sred[row*4+1]+sred[row*4+2]+sred[row*4+3];
      const float q = sred[BM*4+row*4+0]+sred[BM*4+row*4+1]+sred[BM*4+row*4+2]+sred[BM*4+row*4+3];
      const float mean = s*(1.0f/128.0f);
      const float var  = q*(1.0f/128.0f) - mean*mean;
      const float rstd = rsqrtf(var + 1e-5f);
      #pragma unroll
      for (int j=0;j<2;j++){
        const int col = wn + j*16 + lm;
        const float xnv = (xv[i][j][r]-mean)*rstd*g2[col] + b2[col];
        xn_io[(size_t)(m0+row)*EE + col] = f2bf(xnv);
      }
    }
}

// =================== MFMA flash attention (XCD-local grid: bl,h,qt) ===================
// qkc: [tok][h*256 + (q:0..127 | k:128..255)] bf16, tok chunk-local.
// vTc: [h*128+d][tok] bf16 (pre-transposed V), tok chunk-local.
__global__ __launch_bounds__(256) void attn_mf_k(
    const u16* __restrict__ qkc, const u16* __restrict__ vTc,
    const float* __restrict__ w, u16* __restrict__ vals_c, int b0)
{
  const int bl = blockIdx.x;   // id%8 = bl -> one XCD per batch
  const int h  = blockIdx.y;
  const int qt = blockIdx.z;
  const int tid = threadIdx.x;
  const int wv = tid>>6, lane = tid&63;
  const int lm = lane&15, lq = lane>>4;

  __shared__ u16 Qs[64][136];
  __shared__ u16 Ks[64][136];
  __shared__ u16 Vts[128][72];
  __shared__ u16 Ps[64][72];
  __shared__ float wt[64], qwt[64];

  const size_t rs = 2048;
  const u16* qk = qkc + (size_t)bl*SEQ*rs + (size_t)h*256;
  const u16* vb = vTc + (size_t)h*128*CTOK + (size_t)bl*SEQ;
  const int q0 = qt*64;

  #pragma unroll
  for (int it=0; it<4; it++){
    const int fi = it*256 + tid;
    const int r = fi >> 4, g = fi & 15;
    *(float4*)&Qs[r][g*8] = *(const float4*)(qk + (size_t)(q0+r)*rs + g*8);
  }
  if (tid < 64) qwt[tid] = w[(b0+bl)*SEQ + q0 + tid];
  __syncthreads();

  float kq[4];
  #pragma unroll
  for (int r=0;r<4;r++) kq[r] = qwt[wv*16 + lq*4 + r];

  f32x4 oacc[8];
  #pragma unroll
  for (int j=0;j<8;j++) oacc[j] = (f32x4){0.f,0.f,0.f,0.f};
  float mrow[4], lrow[4];
  #pragma unroll
  for (int r=0;r<4;r++){ mrow[r]=-INFINITY; lrow[r]=0.f; }
  const float scale = 0.08838834764831845f;  // 1/sqrt(128)

  for (int kt=0; kt<8; kt++){
    __syncthreads();
    #pragma unroll
    for (int it=0; it<4; it++){
      const int fi = it*256 + tid;
      const int r = fi >> 4, g = fi & 15;
      *(float4*)&Ks[r][g*8] = *(const float4*)(qk + (size_t)(kt*64+r)*rs + 128 + g*8);
    }
    #pragma unroll
    for (int it=0; it<4; it++){
      const int fi = it*256 + tid;
      const int d = fi >> 3, g = fi & 7;
      *(float4*)&Vts[d][g*8] = *(const float4*)(vb + (size_t)d*CTOK + kt*64 + g*8);
    }
    if (tid < 64) wt[tid] = w[(b0+bl)*SEQ + kt*64 + tid];
    __syncthreads();

    f32x4 sacc[4];
    #pragma unroll
    for (int j=0;j<4;j++) sacc[j] = (f32x4){0.f,0.f,0.f,0.f};
    __builtin_amdgcn_s_setprio(1);
    #pragma unroll
    for (int kk=0; kk<4; kk++){
      const bf16x8 af = *(const bf16x8*)&Qs[wv*16+lm][kk*32+lq*8];
      #pragma unroll
      for (int j=0;j<4;j++){
        const bf16x8 bf = *(const bf16x8*)&Ks[j*16+lm][kk*32+lq*8];
        sacc[j] = __builtin_amdgcn_mfma_f32_16x16x32_bf16(af, bf, sacc[j], 0, 0, 0);
      }
    }
    __builtin_amdgcn_s_setprio(0);
    float wkj[4], s[4][4];
    #pragma unroll
    for (int j=0;j<4;j++) wkj[j] = wt[j*16+lm];
    #pragma unroll
    for (int j=0;j<4;j++)
      #pragma unroll
      for (int r=0;r<4;r++){
        const bool keep = (kq[r] > 0.f) && (wkj[j] > 0.f);
        s[j][r] = keep ? sacc[j][r]*scale : -9.0e15f;
      }
    float alpha[4];
    #pragma unroll
    for (int r=0;r<4;r++){
      float rm = fmaxf(fmaxf(s[0][r], s[1][r]), fmaxf(s[2][r], s[3][r]));
      rm = fmaxf(rm, __shfl_xor(rm, 1));
      rm = fmaxf(rm, __shfl_xor(rm, 2));
      rm = fmaxf(rm, __shfl_xor(rm, 4));
      rm = fmaxf(rm, __shfl_xor(rm, 8));
      const float newm = fmaxf(mrow[r], rm);
      alpha[r] = __expf(mrow[r] - newm);
      float ls = 0.f;
      #pragma unroll
      for (int j=0;j<4;j++){
        const float pv = wkj[j]*__expf(s[j][r]-newm);
        s[j][r] = pv; ls += pv;
      }
      ls += __shfl_xor(ls, 1);
      ls += __shfl_xor(ls, 2);
      ls += __shfl_xor(ls, 4);
      ls += __shfl_xor(ls, 8);
      lrow[r] = lrow[r]*alpha[r] + ls;
      mrow[r] = newm;
    }
    #pragma unroll
    for (int j=0;j<4;j++)
      #pragma unroll
      for (int r=0;r<4;r++)
        Ps[wv*16 + lq*4 + r][j*16+lm] = f2bf(s[j][r]);
    #pragma unroll
    for (int j=0;j<8;j++)
      #pragma unroll
      for (int r=0;r<4;r++) oacc[j][r] *= alpha[r];
    __syncthreads();   // keep: removing it caused a pathological 30ms mode (R18)

    __builtin_amdgcn_s_setprio(1);
    #pragma unroll
    for (int kk=0; kk<2; kk++){
      const bf16x8 pf = *(const bf16x8*)&Ps[wv*16+lm][kk*32+lq*8];
      #pragma unroll
      for (int j=0;j<8;j++){
        const bf16x8 vf = *(const bf16x8*)&Vts[j*16+lm][kk*32+lq*8];
        oacc[j] = __builtin_amdgcn_mfma_f32_16x16x32_bf16(pf, vf, oacc[j], 0, 0, 0);
      }
    }
    __builtin_amdgcn_s_setprio(0);
  }
  #pragma unroll
  for (int r=0;r<4;r++){
    const float inv = 1.0f / lrow[r];
    u16* orow = vals_c + ((size_t)(bl*SEQ + q0 + wv*16 + lq*4 + r))*EHH + h*EE;
    #pragma unroll
    for (int j=0;j<8;j++) orow[j*16+lm] = f2bf(oacc[j][r]*inv);
  }
}

// =================== pool phase 1: partial weighted sums (256 blocks) ===================
__global__ __launch_bounds__(128) void pool1_k(
    const float* __restrict__ x, const float* __restrict__ x_init,
    const float* __restrict__ w, float* __restrict__ part)
{
  const int bc = blockIdx.x;          // b*8 + c
  const int b = bc >> 3, c = bc & 7;
  const int e = threadIdx.x;
  float acc = 0.f;
  const int n0 = c*64;
  #pragma unroll 4
  for (int n=0;n<64;n++){
    const int tok = b*SEQ + n0 + n;
    const size_t idx = (size_t)tok*EE + e;
    acc = fmaf(w[tok], x[idx]+x_init[idx], acc);
  }
  part[(size_t)bc*EE + e] = acc;
}

// =================== pool phase 2: sum parts + LN + head ===================
__global__ __launch_bounds__(128) void pool2_k(
    const float* __restrict__ part, const float* __restrict__ g2,
    const float* __restrict__ b2, const float* __restrict__ head_W,
    const float* __restrict__ head_b, float* __restrict__ out)
{
  const int b = blockIdx.x;
  const int e = threadIdx.x;
  __shared__ float red[128];
  float acc = 0.f;
  #pragma unroll
  for (int c=0;c<8;c++) acc += part[(size_t)(b*8+c)*EE+e];
  red[e]=acc; __syncthreads();
  for (int s=64;s>0;s>>=1){ if(e<s) red[e]+=red[e+s]; __syncthreads(); }
  const float mean = red[0]*(1.0f/128.0f);
  __syncthreads();
  const float d = acc-mean;
  red[e]=d*d; __syncthreads();
  for (int s=64;s>0;s>>=1){ if(e<s) red[e]+=red[e+s]; __syncthreads(); }
  const float var = red[0]*(1.0f/128.0f);
  const float p = d*rsqrtf(var+1e-5f)*g2[e]+b2[e];
  __syncthreads();
  red[e] = p*head_W[e]; __syncthreads();
  for (int s=64;s>0;s>>=1){ if(e<s) red[e]+=red[e+s]; __syncthreads(); }
  if (e==0) out[b] = red[0] + head_b[0];
}

// =================== launch ===================
extern "C" void kernel_launch(void* const* d_in, const int* in_sizes, int n_in,
                              void* d_out, int out_size, void* d_ws, size_t ws_size,
                              hipStream_t stream)
{
  const float* str_fea   = (const float*)d_in[0];
  const int*   comp_fea  = (const int*)  d_in[1];
  // d_in[2] cell_fea unused by reference
  const float* atom_table= (const float*)d_in[3];
  const float* comp_W    = (const float*)d_in[4];
  const float* comp_b    = (const float*)d_in[5];
  const float* pdd_W     = (const float*)d_in[6];
  const float* pdd_b     = (const float*)d_in[7];
  const float* enc_ln_g  = (const float*)d_in[8];
  const float* enc_ln_b  = (const float*)d_in[9];
  const float* qkv_W     = (const float*)d_in[10];
  const float* qkv_b     = (const float*)d_in[11];
  const float* o_W       = (const float*)d_in[12];
  const float* o_b       = (const float*)d_in[13];
  const float* out_W     = (const float*)d_in[14];
  const float* out_b     = (const float*)d_in[15];
  const float* ffn_W     = (const float*)d_in[16];
  const float* ffn_b     = (const float*)d_in[17];
  const float* ln2_g     = (const float*)d_in[18];
  const float* ln2_b     = (const float*)d_in[19];
  const float* head_W    = (const float*)d_in[20];
  const float* head_b    = (const float*)d_in[21];
  float* out = (float*)d_out;

  // ---- diagnostic 1: input layout model ----
  bool sizes_ok = (n_in >= 22);
  if (sizes_ok){
    sizes_ok = in_sizes[0]==BB*SEQ*KF && in_sizes[1]==NTOK &&
               in_sizes[3]==NATOM*ADIM && in_sizes[4]==ADIM*EE &&
               in_sizes[10]==LL*EE*3*EHH && in_sizes[12]==LL*EHH*EHH &&
               in_sizes[14]==LL*EHH*EE   && in_sizes[16]==LL*EE*EE &&
               in_sizes[20]==EE;
  }
  if (!sizes_ok){
    sentinel_k<<<(out_size+63)/64,64,0,stream>>>(out, 99999.0f, out_size);
    return;
  }

  // ---- workspace layout (~90 MB; <= 109.7 MB proven) ----
  char* p = (char*)d_ws;
  size_t off = 0;
  auto alloc = [&](size_t bytes)->void*{
    off = (off + 255) & ~(size_t)255;
    void* r = p + off; off += bytes; return r;
  };
  float* w        = (float*)alloc((size_t)NTOK*4);
  float* x        = (float*)alloc((size_t)NTOK*EE*4);
  float* x_init   = (float*)alloc((size_t)NTOK*EE*4);
  u16*   xn_bf    = (u16*)  alloc((size_t)NTOK*EE*2);
  u16*   qkc      = (u16*)  alloc((size_t)CTOK*2048*2);   // 16.8 MB chunk (Q|K)
  u16*   vTc      = (u16*)  alloc((size_t)EHH*CTOK*2);    // 8.4 MB chunk (V^T)
  u16*   vals_bf  = (u16*)  alloc((size_t)NTOK*EHH*2);    // 33.6 MB
  u16*   qkvWT_a  = (u16*)  alloc((size_t)LL*3*EHH*EE*2); // 2.36 MB (reordered)
  float* rqkv_b   = (float*)alloc((size_t)LL*3*EHH*4);    // reordered bias
  u16*   fwT_a    = (u16*)  alloc((size_t)LL*EE*EHH*2);   // 0.79 MB
  u16*   ffnWT_a  = (u16*)  alloc((size_t)LL*EE*EE*2);
  u16*   oWb_a    = (u16*)  alloc((size_t)LL*EHH*EHH*2);  // 6.29 MB
  u16*   outWT_a  = (u16*)  alloc((size_t)LL*EE*EHH*2);
  float* fb_a     = (float*)alloc((size_t)LL*EE*4);
  float* atom_emb = (float*)alloc((size_t)NATOM*EE*4);
  float* part     = (float*)alloc((size_t)BB*8*EE*4);

  // ---- diagnostic 2: workspace size ----
  if (off > ws_size){
    sentinel_k<<<(out_size+63)/64,64,0,stream>>>(out, 12345.0f, out_size);
    return;
  }

  // ---- hoisted weight prep (merged; includes atomemb + fuse_b roles) ----
  prep_k<<<14030,256,0,stream>>>(qkv_W, qkvWT_a, ffn_W, ffnWT_a,
                                 out_W, outWT_a, o_W, oWb_a, qkv_b, rqkv_b,
                                 atom_table, comp_W, comp_b, pdd_b, atom_emb,
                                 o_b, out_b, fb_a);
  // fwT = (o_W @ out_W)^T per layer (EPI4 transposed store), grid.z = layers
  mgemm_k<4,32,64,128><<<dim3(EE/64, EHH/32, LL),256,0,stream>>>(
      oWb_a, outWT_a, nullptr, fwT_a, EE, EHH, EHH, nullptr,
      (size_t)EHH*EHH, (size_t)EE*EHH, (size_t)EE*EHH*2);

  embed_ln_k<<<NTOK/32,512,0,stream>>>(str_fea, comp_fea, atom_emb, pdd_W,
                                       enc_ln_g, enc_ln_b, x, x_init, w, xn_bf);

  for (int i=0;i<LL;i++){
    const float* gi = enc_ln_g + i*EE;
    const float* bi = enc_ln_b + i*EE;
    for (int cb=0; cb<NCHUNK; cb++){
      const int t0 = cb*CTOK;
      const int b0 = cb*CB;
      // QKV with router epilogue: Q|K -> qkc (stride 2048), V -> vTc (transposed)
      mgemm_k<7,128,128,64><<<dim3(3*EHH/128, CTOK/128),256,0,stream>>>(
          xn_bf + (size_t)t0*EE, qkvWT_a + (size_t)i*3*EHH*EE,
          rqkv_b + (size_t)i*3*EHH,
          qkc, 3*EHH, EE, CTOK, vTc, 0, 0, 0);
      attn_mf_k<<<dim3(CB, HH, SEQ/64),256,0,stream>>>(
          qkc, vTc, w, vals_bf + (size_t)t0*EHH, b0);
    }
    // proj + resid + LN + ffn + mish + dual-LN, all in one kernel
    const float* gn = (i<LL-1) ? enc_ln_g + (i+1)*EE : gi;
    const float* bn = (i<LL-1) ? enc_ln_b + (i+1)*EE : bi;
    projffn_k<<<NTOK/32,256,0,stream>>>(
        vals_bf, fwT_a + (size_t)i*EE*EHH, fb_a + (size_t)i*EE,
        ffnWT_a + (size_t)i*EE*EE, ffn_b + (size_t)i*EE,
        gi, bi, gn, bn, x, xn_bf);
  }
  pool1_k<<<BB*8,128,0,stream>>>(x, x_init, w, part);
  pool2_k<<<BB,128,0,stream>>>(part, ln2_g, ln2_b, head_W, head_b, out);
}

// Round 8
// 886.851 us; speedup vs baseline: 1.1658x; 1.0385x over previous
//
#include <hip/hip_runtime.h>
#include <math.h>

#define DI __device__ __forceinline__

// ---- problem constants ----
#define BB 32
#define SEQ 512
#define KF 101
#define EE 128
#define HH 8
#define EHH 1024
#define LL 3
#define ADIM 200
#define NATOM 119
#define NTOK (BB*SEQ)   // 16384
#define CB 8            // batches per chunk
#define NCHUNK (BB/CB)  // 4
#define CTOK (CB*SEQ)   // 4096 tokens per chunk

// R22 = R21 resubmit (infra "container failed twice", same as R3->R4;
// no defect found on audit). R21: prep_k serial-tail fix: cconv role
// removed (mgemm AF32 flag converts o_W f32->bf16 in staging; bitwise
// identical fwT), fuse_b -> 24 partial blocks (final sum folded into
// projffn bias, deterministic), atomemb 4-acc ILP, slow roles first.

typedef unsigned short u16;
typedef __attribute__((ext_vector_type(8))) short bf16x8;
typedef __attribute__((ext_vector_type(4))) float f32x4;

DI float bf2f(u16 s){ union{unsigned int u; float f;} x; x.u = ((unsigned int)s)<<16; return x.f; }
DI u16 f2bf(float f){
  union{float f; unsigned int u;} x; x.f = f;
  unsigned int u = x.u;
  u += 0x7fffu + ((u>>16)&1u);           // RNE
  return (u16)(u>>16);
}
DI float rdl(float v, int l){
  return __int_as_float(__builtin_amdgcn_readlane(__float_as_int(v), l));
}

// =================== sentinel ===================
__global__ void sentinel_k(float* out, float v, int n){
  int i = blockIdx.x*64 + threadIdx.x;
  if (i < n) out[i] = v;
}

// =================== embed + layer-0 LN (32 tokens/block, 8 waves) ===================
__global__ __launch_bounds__(512, 4) void embed_ln_k(
    const float* __restrict__ str_fea, const int* __restrict__ comp_fea,
    const float* __restrict__ atom_emb, const float* __restrict__ pdd_W,
    const float* __restrict__ g, const float* __restrict__ bta,
    float* __restrict__ x, float* __restrict__ x_init, float* __restrict__ w,
    u16* __restrict__ xn)
{
  const int t0 = blockIdx.x*32;
  const int tid = threadIdx.x;
  const int wv = tid>>6, lane = tid&63;
  __shared__ float2 sPdd[100*64];      // 51.2 KB
  for (int k2=tid; k2<100*64; k2+=512)
    sPdd[k2] = ((const float2*)pdd_W)[k2];

  float sv0[4], sv1[4];
  int idx[4];
  #pragma unroll
  for (int tk=0; tk<4; ++tk){
    const int t = t0 + wv*4 + tk;
    const float* sr0 = str_fea + (size_t)t*KF;
    sv0[tk] = sr0[lane];
    sv1[tk] = (lane+64 < KF) ? sr0[lane+64] : 0.f;
    idx[tk] = comp_fea[t];
  }
  __syncthreads();

  float a0[4],a1[4],a2[4],a3[4],c0[4],c1[4],c2[4],c3[4];
  #pragma unroll
  for (int tk=0; tk<4; ++tk){
    const float2 ae = ((const float2*)(atom_emb + (size_t)idx[tk]*EE))[lane];
    a0[tk]=ae.x; a1[tk]=0.f; a2[tk]=0.f; a3[tk]=0.f;
    c0[tk]=ae.y; c1[tk]=0.f; c2[tk]=0.f; c3[tk]=0.f;
  }
  #pragma unroll 5
  for (int j=0; j<100; j+=4){
    const float2 w0 = sPdd[(j  )*64 + lane];
    const float2 w1 = sPdd[(j+1)*64 + lane];
    const float2 w2 = sPdd[(j+2)*64 + lane];
    const float2 w3 = sPdd[(j+3)*64 + lane];
    #pragma unroll
    for (int tk=0; tk<4; ++tk){
      const float s1 = (1+j<64) ? rdl(sv0[tk],1+j) : rdl(sv1[tk],1+j-64);
      const float s2 = (2+j<64) ? rdl(sv0[tk],2+j) : rdl(sv1[tk],2+j-64);
      const float s3 = (3+j<64) ? rdl(sv0[tk],3+j) : rdl(sv1[tk],3+j-64);
      const float s4 = (4+j<64) ? rdl(sv0[tk],4+j) : rdl(sv1[tk],4+j-64);
      a0[tk] = fmaf(s1, w0.x, a0[tk]);  c0[tk] = fmaf(s1, w0.y, c0[tk]);
      a1[tk] = fmaf(s2, w1.x, a1[tk]);  c1[tk] = fmaf(s2, w1.y, c1[tk]);
      a2[tk] = fmaf(s3, w2.x, a2[tk]);  c2[tk] = fmaf(s3, w2.y, c2[tk]);
      a3[tk] = fmaf(s4, w3.x, a3[tk]);  c3[tk] = fmaf(s4, w3.y, c3[tk]);
    }
  }
  const float2 gg = ((const float2*)g)[lane];
  const float2 bb = ((const float2*)bta)[lane];
  #pragma unroll
  for (int tk=0; tk<4; ++tk){
    const int t = t0 + wv*4 + tk;
    const float vx = (a0[tk]+a1[tk])+(a2[tk]+a3[tk]);
    const float vy = (c0[tk]+c1[tk])+(c2[tk]+c3[tk]);
    ((float2*)(x      + (size_t)t*EE))[lane] = make_float2(vx, vy);
    ((float2*)(x_init + (size_t)t*EE))[lane] = make_float2(vx, vy);
    if (lane==0) w[t] = sv0[tk];
    float s = vx + vy;
    #pragma unroll
    for (int off=32; off; off>>=1) s += __shfl_xor(s, off);
    const float mean = s*(1.0f/128.0f);
    const float d0 = vx-mean, d1 = vy-mean;
    float q = d0*d0 + d1*d1;
    #pragma unroll
    for (int off=32; off; off>>=1) q += __shfl_xor(q, off);
    const float rstd = rsqrtf(q*(1.0f/128.0f) + 1e-5f);
    u16* o = xn + (size_t)t*EE + lane*2;
    o[0] = f2bf(d0*rstd*gg.x + bb.x);
    o[1] = f2bf(d1*rstd*gg.y + bb.y);
  }
}

// =================== merged weight prep ===================
DI void trans32(const float* __restrict__ W, u16* __restrict__ WT,
                int Nn, int Kk, int srcCol0, int n0, int k0, int tid,
                u16 (&tile)[32][33])
{
  const int lr = tid>>5, lc = tid&31;
  #pragma unroll
  for (int i=0;i<4;i++)
    tile[lr+i*8][lc] = f2bf(W[(size_t)(k0+lr+i*8)*Nn + srcCol0 + lc]);
  __syncthreads();
  #pragma unroll
  for (int i=0;i<4;i++)
    WT[(size_t)(n0+lr+i*8)*Kk + k0 + lc] = tile[lc][lr+i*8];
}

// roles (slow serial roles FIRST so their chains overlap the fast blocks):
// [0,119) atomemb | [119,143) fuse_b partials | [143,1295) qkvT |
// [1295,1343) ffnT | [1343,1727) outWT | [1727,1763) qkv bias reorder
__global__ __launch_bounds__(256) void prep_k(
    const float* __restrict__ qkv_W, u16* __restrict__ qkvWT,
    const float* __restrict__ ffn_W, u16* __restrict__ ffnWT,
    const float* __restrict__ out_W, u16* __restrict__ outWT,
    const float* __restrict__ qkv_b, float* __restrict__ rqkv_b,
    const float* __restrict__ atom_table, const float* __restrict__ comp_W,
    const float* __restrict__ comp_b, const float* __restrict__ pdd_b,
    float* __restrict__ atom_emb,
    const float* __restrict__ o_b, float* __restrict__ fbp)
{
  __shared__ u16 tile[32][33];
  __shared__ float sbuf[456];
  int bid = blockIdx.x;
  const int tid = threadIdx.x;
  if (bid < NATOM){
    // atom embedding: atom_emb[a] = comp_b + pdd_b + atom_table[a]@comp_W
    const int a = bid;
    const int e = tid & 127, half = tid >> 7;
    float* sAtom = sbuf;
    float* red   = sbuf + 200;
    for (int d=tid; d<ADIM; d+=256) sAtom[d] = atom_table[a*ADIM+d];
    __syncthreads();
    const int d0 = half*100;
    float b0 = half ? 0.f : (comp_b[e] + pdd_b[e]);
    float b1 = 0.f, b2 = 0.f, b3 = 0.f;
    #pragma unroll 5
    for (int d=d0; d<d0+100; d+=4){
      b0 = fmaf(sAtom[d  ], comp_W[(d  )*EE+e], b0);
      b1 = fmaf(sAtom[d+1], comp_W[(d+1)*EE+e], b1);
      b2 = fmaf(sAtom[d+2], comp_W[(d+2)*EE+e], b2);
      b3 = fmaf(sAtom[d+3], comp_W[(d+3)*EE+e], b3);
    }
    red[tid] = (b0+b1)+(b2+b3);
    __syncthreads();
    if (half==0) atom_emb[a*EE+e] = red[e] + red[128+e];
    return;
  }
  bid -= NATOM;
  if (bid < 24){
    // fuse_b partials: fbp[ly][s][n] = sum_{k in s-slice} o_b[k]*out_W[k][n]
    const int ly = bid >> 3, s = bid & 7;
    const float* ob = o_b + (size_t)ly*EHH;
    const float* oW = out_W + (size_t)ly*EHH*EE;
    const int n = tid & 127, h2 = tid >> 7;
    const int kb = s*128 + h2*64;
    float b0=0.f,b1=0.f,b2=0.f,b3=0.f;
    #pragma unroll 4
    for (int k2=kb; k2<kb+64; k2+=4){
      b0 = fmaf(ob[k2  ], oW[(size_t)(k2  )*EE+n], b0);
      b1 = fmaf(ob[k2+1], oW[(size_t)(k2+1)*EE+n], b1);
      b2 = fmaf(ob[k2+2], oW[(size_t)(k2+2)*EE+n], b2);
      b3 = fmaf(ob[k2+3], oW[(size_t)(k2+3)*EE+n], b3);
    }
    float* red = sbuf;
    red[tid] = (b0+b1)+(b2+b3);
    __syncthreads();
    if (h2==0) fbp[((size_t)ly*8 + s)*EE + n] = red[n] + red[128+n];
    return;
  }
  bid -= 24;
  if (bid < 1152){
    const int xb = bid%96, yb = (bid/96)%4, zb = bid/384;
    const int n0 = xb*32, k0 = yb*32;
    int c0;
    if (n0 < 2048) c0 = (n0>>8)*384 + (n0&255);
    else { const int m0 = n0-2048; c0 = (m0>>7)*384 + 256 + (m0&127); }
    trans32(qkv_W + (size_t)zb*EE*3*EHH, qkvWT + (size_t)zb*3*EHH*EE,
            3*EHH, EE, c0, n0, k0, tid, tile);
    return;
  }
  bid -= 1152;
  if (bid < 48){
    const int xb = bid%4, yb = (bid/4)%4, zb = bid/16;
    trans32(ffn_W + (size_t)zb*EE*EE, ffnWT + (size_t)zb*EE*EE,
            EE, EE, xb*32, xb*32, yb*32, tid, tile);
    return;
  }
  bid -= 48;
  if (bid < 384){
    const int xb = bid%4, yb = (bid/4)%32, zb = bid/128;
    trans32(out_W + (size_t)zb*EHH*EE, outWT + (size_t)zb*EE*EHH,
            EE, EHH, xb*32, xb*32, yb*32, tid, tile);
    return;
  }
  bid -= 384;
  {
    const int l = bid/12;
    const int n = (bid%12)*256 + tid;
    int c;
    if (n < 2048) c = (n>>8)*384 + (n&255);
    else { const int m = n-2048; c = (m>>7)*384 + 256 + (m&127); }
    rqkv_b[(size_t)l*3*EHH + n] = qkv_b[(size_t)l*3*EHH + c];
  }
}

// =================== MFMA bf16 GEMM (layer-batched via z strides) ===================
// A: M x Kk row-major (bf16, or f32 when AF32 — converted in staging).
// BT: Nn x Kk bf16 (pre-transposed B).
// EPI 0: store bf16; 4: bf16 transposed store (no bias);
// EPI 7 (QKV router): col<2048 -> C[row*2048+col]; col>=2048 -> C2 V^T.
template<int EPI, int BM, int BN, int BK, int AF32>
__global__ __launch_bounds__(256) void mgemm_k(
    const void* __restrict__ Av, const u16* __restrict__ BT,
    const float* __restrict__ bias, void* __restrict__ Cv,
    int Nn, int Kk, int Mdim, void* __restrict__ C2,
    size_t sA, size_t sBT, size_t sCb)
{
  const int lz = blockIdx.z;
  BT += (size_t)lz*sBT;
  void* C = (void*)((char*)Cv + (size_t)lz*sCb);

  constexpr int LDK = BK + 8;
  __shared__ u16 As[BM*LDK];
  __shared__ u16 Bs[BN*LDK];
  const int tid = threadIdx.x;
  const int m0 = blockIdx.y*BM, n0 = blockIdx.x*BN;
  constexpr int WMN = (BM>=128)?2:1;
  constexpr int WNN = 4/WMN;
  constexpr int WM = BM/WMN;
  constexpr int WN = BN/WNN;
  constexpr int FM = WM/16, FN = WN/16;
  const int wv = tid>>6, lane = tid&63;
  const int wm = (wv/WNN)*WM;
  const int wn = (wv%WNN)*WN;
  const int lm = lane&15, lq = lane>>4;

  f32x4 acc[FM][FN];
  #pragma unroll
  for (int i=0;i<FM;i++)
    #pragma unroll
    for (int j=0;j<FN;j++) acc[i][j] = (f32x4){0.f,0.f,0.f,0.f};

  constexpr int BCH = BN*BK/8;

  for (int k0=0; k0<Kk; k0+=BK){
    if constexpr (AF32){
      const float* A = (const float*)Av + (size_t)lz*sA;
      #pragma unroll
      for (int c = tid; c < BM*BK/4; c += 256){
        const int r = c/(BK/4), kg = c - r*(BK/4);
        const float4 v = *(const float4*)(A + (size_t)(m0+r)*Kk + k0 + kg*4);
        union { u16 u[4]; unsigned long long ll; } t;
        t.u[0]=f2bf(v.x); t.u[1]=f2bf(v.y); t.u[2]=f2bf(v.z); t.u[3]=f2bf(v.w);
        *(unsigned long long*)&As[r*LDK + kg*4] = t.ll;
      }
    } else {
      const u16* A = (const u16*)Av + (size_t)lz*sA;
      #pragma unroll
      for (int c = tid; c < BM*BK/8; c += 256){
        const int r = c/(BK/8), kg = c - r*(BK/8);
        const float4 v = *(const float4*)(A + (size_t)(m0+r)*Kk + k0 + kg*8);
        *(float4*)&As[r*LDK + kg*8] = v;
      }
    }
    #pragma unroll
    for (int c = tid; c < BCH; c += 256){
      const int r = c/(BK/8), kg = c - r*(BK/8);
      const float4 v = *(const float4*)(BT + (size_t)(n0+r)*Kk + k0 + kg*8);
      *(float4*)&Bs[r*LDK + kg*8] = v;
    }
    __syncthreads();
    #pragma unroll
    for (int kk=0; kk<BK/32; kk++){
      bf16x8 af[FM], bfr[FN];
      #pragma unroll
      for (int i=0;i<FM;i++)
        af[i] = *(const bf16x8*)&As[(wm + i*16 + lm)*LDK + kk*32 + lq*8];
      #pragma unroll
      for (int j=0;j<FN;j++)
        bfr[j] = *(const bf16x8*)&Bs[(wn + j*16 + lm)*LDK + kk*32 + lq*8];
      #pragma unroll
      for (int i=0;i<FM;i++)
        #pragma unroll
        for (int j=0;j<FN;j++)
          acc[i][j] = __builtin_amdgcn_mfma_f32_16x16x32_bf16(af[i], bfr[j], acc[i][j], 0, 0, 0);
    }
    __syncthreads();
  }
  #pragma unroll
  for (int i=0;i<FM;i++){
    #pragma unroll
    for (int j=0;j<FN;j++){
      const int col = n0 + wn + j*16 + lm;
      const float bv = (EPI==4) ? 0.f : bias[col];
      #pragma unroll
      for (int r=0;r<4;r++){
        const int row = m0 + wm + i*16 + lq*4 + r;
        float v = acc[i][j][r] + bv;
        if constexpr (EPI==7){
          if (col < 2048) ((u16*)C)[(size_t)row*2048 + col] = f2bf(v);
          else            ((u16*)C2)[(size_t)(col-2048)*Mdim + row] = f2bf(v);
        } else if constexpr (EPI==4){
          ((u16*)C)[(size_t)col*Mdim + row] = f2bf(v);
        } else {
          ((u16*)C)[(size_t)row*Nn + col] = f2bf(v);
        }
      }
    }
  }
}

// =================== fused proj+LN + ffn+mish + dual-LN ===================
__global__ __launch_bounds__(256) void projffn_k(
    const u16* __restrict__ vals, const u16* __restrict__ fwT,
    const float* __restrict__ fbp, const float* __restrict__ outb,
    const u16* __restrict__ ffnWT, const float* __restrict__ fnb,
    const float* __restrict__ g1, const float* __restrict__ b1,
    const float* __restrict__ g2, const float* __restrict__ b2,
    float* __restrict__ x_io, u16* __restrict__ xn_io)
{
  constexpr int BM = 32, BK = 128, LDK = BK + 8;
  __shared__ u16 As[BM*LDK];        // proj A tiles; then xn2 (bf16)
  __shared__ u16 Bs[EE*LDK];        // fwT tiles; then ffnWT
  __shared__ float sred[BM*8];
  const int tid = threadIdx.x;
  const int wv = tid>>6, lane = tid&63;
  const int lm = lane&15, lq = lane>>4;
  const int m0 = blockIdx.x*BM;
  const int wn = wv*32;             // 4 waves x 32 cols

  f32x4 acc[2][2];
  #pragma unroll
  for (int i=0;i<2;i++)
    #pragma unroll
    for (int j=0;j<2;j++) acc[i][j] = (f32x4){0.f,0.f,0.f,0.f};

  // ---- phase A: proj GEMM, K=1024 ----
  for (int k0=0; k0<EHH; k0+=BK){
    #pragma unroll
    for (int c = tid; c < BM*BK/8; c += 256){
      const int r = c>>4, kg = c&15;
      *(float4*)&As[r*LDK + kg*8] = *(const float4*)(vals + (size_t)(m0+r)*EHH + k0 + kg*8);
    }
    #pragma unroll
    for (int c = tid; c < EE*BK/8; c += 256){
      const int r = c>>4, kg = c&15;
      *(float4*)&Bs[r*LDK + kg*8] = *(const float4*)(fwT + (size_t)r*EHH + k0 + kg*8);
    }
    __syncthreads();
    #pragma unroll
    for (int kk=0; kk<BK/32; kk++){
      bf16x8 af[2], bfr[2];
      #pragma unroll
      for (int i=0;i<2;i++)
        af[i] = *(const bf16x8*)&As[(i*16 + lm)*LDK + kk*32 + lq*8];
      #pragma unroll
      for (int j=0;j<2;j++)
        bfr[j] = *(const bf16x8*)&Bs[(wn + j*16 + lm)*LDK + kk*32 + lq*8];
      #pragma unroll
      for (int i=0;i<2;i++)
        #pragma unroll
        for (int j=0;j<2;j++)
          acc[i][j] = __builtin_amdgcn_mfma_f32_16x16x32_bf16(af[i], bfr[j], acc[i][j], 0, 0, 0);
    }
    __syncthreads();
  }

  // ---- phase A epilogue: vout = acc + fb + x ; LN stats ----
  float vout[2][2][4];
  float ps[2][4], qs[2][4];
  #pragma unroll
  for (int i=0;i<2;i++)
    #pragma unroll
    for (int r=0;r<4;r++){ ps[i][r]=0.f; qs[i][r]=0.f; }
  #pragma unroll
  for (int i=0;i<2;i++){
    #pragma unroll
    for (int j=0;j<2;j++){
      const int col = wn + j*16 + lm;
      const float bv = outb[col]
        + ((fbp[0*EE+col]+fbp[1*EE+col])+(fbp[2*EE+col]+fbp[3*EE+col]))
        + ((fbp[4*EE+col]+fbp[5*EE+col])+(fbp[6*EE+col]+fbp[7*EE+col]));
      #pragma unroll
      for (int r=0;r<4;r++){
        const int row = m0 + i*16 + lq*4 + r;
        const float v = acc[i][j][r] + bv + x_io[(size_t)row*EE + col];
        vout[i][j][r] = v;
        ps[i][r] += v; qs[i][r] += v*v;
      }
    }
  }
  #pragma unroll
  for (int i=0;i<2;i++)
    #pragma unroll
    for (int r=0;r<4;r++){
      float s = ps[i][r], q = qs[i][r];
      s += __shfl_xor(s,1); s += __shfl_xor(s,2); s += __shfl_xor(s,4); s += __shfl_xor(s,8);
      q += __shfl_xor(q,1); q += __shfl_xor(q,2); q += __shfl_xor(q,4); q += __shfl_xor(q,8);
      if (lm==0){
        const int row = i*16 + lq*4 + r;
        sred[row*4 + wv] = s;
        sred[BM*4 + row*4 + wv] = q;
      }
    }
  __syncthreads();
  // xn2 -> As (bf16), and stage ffnWT -> Bs
  #pragma unroll
  for (int i=0;i<2;i++)
    #pragma unroll
    for (int r=0;r<4;r++){
      const int row = i*16 + lq*4 + r;
      const float s = sred[row*4+0]+sred[row*4+1]+sred[row*4+2]+sred[row*4+3];
      const float q = sred[BM*4+row*4+0]+sred[BM*4+row*4+1]+sred[BM*4+row*4+2]+sred[BM*4+row*4+3];
      const float mean = s*(1.0f/128.0f);
      const float var  = q*(1.0f/128.0f) - mean*mean;
      const float rstd = rsqrtf(var + 1e-5f);
      #pragma unroll
      for (int j=0;j<2;j++){
        const int col = wn + j*16 + lm;
        const float xnv = (vout[i][j][r]-mean)*rstd*g1[col] + b1[col];
        As[row*LDK + col] = f2bf(xnv);
      }
    }
  #pragma unroll
  for (int c = tid; c < EE*EE/8; c += 256){
    const int r = c>>4, kg = c&15;
    *(float4*)&Bs[r*LDK + kg*8] = *(const float4*)(ffnWT + (size_t)r*EE + kg*8);
  }
  __syncthreads();

  // ---- phase B: ffn GEMM, K=128 from LDS ----
  f32x4 fa[2][2];
  #pragma unroll
  for (int i=0;i<2;i++)
    #pragma unroll
    for (int j=0;j<2;j++) fa[i][j] = (f32x4){0.f,0.f,0.f,0.f};
  #pragma unroll
  for (int kk=0; kk<4; kk++){
    bf16x8 af[2], bfr[2];
    #pragma unroll
    for (int i=0;i<2;i++)
      af[i] = *(const bf16x8*)&As[(i*16 + lm)*LDK + kk*32 + lq*8];
    #pragma unroll
    for (int j=0;j<2;j++)
      bfr[j] = *(const bf16x8*)&Bs[(wn + j*16 + lm)*LDK + kk*32 + lq*8];
    #pragma unroll
    for (int i=0;i<2;i++)
      #pragma unroll
      for (int j=0;j<2;j++)
        fa[i][j] = __builtin_amdgcn_mfma_f32_16x16x32_bf16(af[i], bfr[j], fa[i][j], 0, 0, 0);
  }

  // ---- phase C: t = vout + mish(fa + fnb); dual row-LN ----
  float tv[2][2][4];
  #pragma unroll
  for (int i=0;i<2;i++)
    #pragma unroll
    for (int r=0;r<4;r++){ ps[i][r]=0.f; qs[i][r]=0.f; }
  #pragma unroll
  for (int i=0;i<2;i++){
    #pragma unroll
    for (int j=0;j<2;j++){
      const int col = wn + j*16 + lm;
      const float bv = fnb[col];
      #pragma unroll
      for (int r=0;r<4;r++){
        const float v = fa[i][j][r] + bv;
        const float E = __expf(v);
        const float uu = E*E + 2.f*E;
        const float mi = (v > 20.f) ? v : v*(uu/(uu+2.f));
        const float t = vout[i][j][r] + mi;
        tv[i][j][r] = t;
        ps[i][r] += t; qs[i][r] += t*t;
      }
    }
  }
  #pragma unroll
  for (int i=0;i<2;i++)
    #pragma unroll
    for (int r=0;r<4;r++){
      float s = ps[i][r], q = qs[i][r];
      s += __shfl_xor(s,1); s += __shfl_xor(s,2); s += __shfl_xor(s,4); s += __shfl_xor(s,8);
      q += __shfl_xor(q,1); q += __shfl_xor(q,2); q += __shfl_xor(q,4); q += __shfl_xor(q,8);
      if (lm==0){
        const int row = i*16 + lq*4 + r;
        sred[row*4 + wv] = s;
        sred[BM*4 + row*4 + wv] = q;
      }
    }
  __syncthreads();
  float xv[2][2][4];
  float ps2[2][4], qs2[2][4];
  #pragma unroll
  for (int i=0;i<2;i++)
    #pragma unroll
    for (int r=0;r<4;r++){
      const int row = i*16 + lq*4 + r;
      const float s = sred[row*4+0]+sred[row*4+1]+sred[row*4+2]+sred[row*4+3];
      const float q = sred[BM*4+row*4+0]+sred[BM*4+row*4+1]+sred[BM*4+row*4+2]+sred[BM*4+row*4+3];
      const float mean = s*(1.0f/128.0f);
      const float var  = q*(1.0f/128.0f) - mean*mean;
      const float rstd = rsqrtf(var + 1e-5f);
      float s2 = 0.f, q2 = 0.f;
      #pragma unroll
      for (int j=0;j<2;j++){
        const int col = wn + j*16 + lm;
        const float xnv = (tv[i][j][r]-mean)*rstd*g1[col] + b1[col];
        x_io[(size_t)(m0+row)*EE + col] = xnv;
        xv[i][j][r] = xnv;
        s2 += xnv; q2 += xnv*xnv;
      }
      ps2[i][r] = s2; qs2[i][r] = q2;
    }
  __syncthreads();
  #pragma unroll
  for (int i=0;i<2;i++)
    #pragma unroll
    for (int r=0;r<4;r++){
      float s = ps2[i][r], q = qs2[i][r];
      s += __shfl_xor(s,1); s += __shfl_xor(s,2); s += __shfl_xor(s,4); s += __shfl_xor(s,8);
      q += __shfl_xor(q,1); q += __shfl_xor(q,2); q += __shfl_xor(q,4); q += __shfl_xor(q,8);
      if (lm==0){
        const int row = i*16 + lq*4 + r;
        sred[row*4 + wv] = s;
        sred[BM*4 + row*4 + wv] = q;
      }
    }
  __syncthreads();
  #pragma unroll
  for (int i=0;i<2;i++)
    #pragma unroll
    for (int r=0;r<4;r++){
      const int row = i*16 + lq*4 + r;
      const float s = sred[row*4+0]+sred[row*4+1]+sred[row*4+2]+sred[row*4+3];
      const float q = sred[BM*4+row*4+0]+sred[BM*4+row*4+1]+sred[BM*4+row*4+2]+sred[BM*4+row*4+3];
      const float mean = s*(1.0f/128.0f);
      const float var  = q*(1.0f/128.0f) - mean*mean;
      const float rstd = rsqrtf(var + 1e-5f);
      #pragma unroll
      for (int j=0;j<2;j++){
        const int col = wn + j*16 + lm;
        const float xnv = (xv[i][j][r]-mean)*rstd*g2[col] + b2[col];
        xn_io[(size_t)(m0+row)*EE + col] = f2bf(xnv);
      }
    }
}

// =================== MFMA flash attention (XCD-local grid: bl,h,qt) ===================
__global__ __launch_bounds__(256) void attn_mf_k(
    const u16* __restrict__ qkc, const u16* __restrict__ vTc,
    const float* __restrict__ w, u16* __restrict__ vals_c, int b0)
{
  const int bl = blockIdx.x;   // id%8 = bl -> one XCD per batch
  const int h  = blockIdx.y;
  const int qt = blockIdx.z;
  const int tid = threadIdx.x;
  const int wv = tid>>6, lane = tid&63;
  const int lm = lane&15, lq = lane>>4;

  __shared__ u16 Qs[64][136];
  __shared__ u16 Ks[64][136];
  __shared__ u16 Vts[128][72];
  __shared__ u16 Ps[64][72];
  __shared__ float wt[64], qwt[64];

  const size_t rs = 2048;
  const u16* qk = qkc + (size_t)bl*SEQ*rs + (size_t)h*256;
  const u16* vb = vTc + (size_t)h*128*CTOK + (size_t)bl*SEQ;
  const int q0 = qt*64;

  #pragma unroll
  for (int it=0; it<4; it++){
    const int fi = it*256 + tid;
    const int r = fi >> 4, g = fi & 15;
    *(float4*)&Qs[r][g*8] = *(const float4*)(qk + (size_t)(q0+r)*rs + g*8);
  }
  if (tid < 64) qwt[tid] = w[(b0+bl)*SEQ + q0 + tid];
  __syncthreads();

  float kq[4];
  #pragma unroll
  for (int r=0;r<4;r++) kq[r] = qwt[wv*16 + lq*4 + r];

  f32x4 oacc[8];
  #pragma unroll
  for (int j=0;j<8;j++) oacc[j] = (f32x4){0.f,0.f,0.f,0.f};
  float mrow[4], lrow[4];
  #pragma unroll
  for (int r=0;r<4;r++){ mrow[r]=-INFINITY; lrow[r]=0.f; }
  const float scale = 0.08838834764831845f;  // 1/sqrt(128)

  for (int kt=0; kt<8; kt++){
    __syncthreads();
    #pragma unroll
    for (int it=0; it<4; it++){
      const int fi = it*256 + tid;
      const int r = fi >> 4, g = fi & 15;
      *(float4*)&Ks[r][g*8] = *(const float4*)(qk + (size_t)(kt*64+r)*rs + 128 + g*8);
    }
    #pragma unroll
    for (int it=0; it<4; it++){
      const int fi = it*256 + tid;
      const int d = fi >> 3, g = fi & 7;
      *(float4*)&Vts[d][g*8] = *(const float4*)(vb + (size_t)d*CTOK + kt*64 + g*8);
    }
    if (tid < 64) wt[tid] = w[(b0+bl)*SEQ + kt*64 + tid];
    __syncthreads();

    f32x4 sacc[4];
    #pragma unroll
    for (int j=0;j<4;j++) sacc[j] = (f32x4){0.f,0.f,0.f,0.f};
    __builtin_amdgcn_s_setprio(1);
    #pragma unroll
    for (int kk=0; kk<4; kk++){
      const bf16x8 af = *(const bf16x8*)&Qs[wv*16+lm][kk*32+lq*8];
      #pragma unroll
      for (int j=0;j<4;j++){
        const bf16x8 bf = *(const bf16x8*)&Ks[j*16+lm][kk*32+lq*8];
        sacc[j] = __builtin_amdgcn_mfma_f32_16x16x32_bf16(af, bf, sacc[j], 0, 0, 0);
      }
    }
    __builtin_amdgcn_s_setprio(0);
    float wkj[4], s[4][4];
    #pragma unroll
    for (int j=0;j<4;j++) wkj[j] = wt[j*16+lm];
    #pragma unroll
    for (int j=0;j<4;j++)
      #pragma unroll
      for (int r=0;r<4;r++){
        const bool keep = (kq[r] > 0.f) && (wkj[j] > 0.f);
        s[j][r] = keep ? sacc[j][r]*scale : -9.0e15f;
      }
    float alpha[4];
    #pragma unroll
    for (int r=0;r<4;r++){
      float rm = fmaxf(fmaxf(s[0][r], s[1][r]), fmaxf(s[2][r], s[3][r]));
      rm = fmaxf(rm, __shfl_xor(rm, 1));
      rm = fmaxf(rm, __shfl_xor(rm, 2));
      rm = fmaxf(rm, __shfl_xor(rm, 4));
      rm = fmaxf(rm, __shfl_xor(rm, 8));
      const float newm = fmaxf(mrow[r], rm);
      alpha[r] = __expf(mrow[r] - newm);
      float ls = 0.f;
      #pragma unroll
      for (int j=0;j<4;j++){
        const float pv = wkj[j]*__expf(s[j][r]-newm);
        s[j][r] = pv; ls += pv;
      }
      ls += __shfl_xor(ls, 1);
      ls += __shfl_xor(ls, 2);
      ls += __shfl_xor(ls, 4);
      ls += __shfl_xor(ls, 8);
      lrow[r] = lrow[r]*alpha[r] + ls;
      mrow[r] = newm;
    }
    #pragma unroll
    for (int j=0;j<4;j++)
      #pragma unroll
      for (int r=0;r<4;r++)
        Ps[wv*16 + lq*4 + r][j*16+lm] = f2bf(s[j][r]);
    #pragma unroll
    for (int j=0;j<8;j++)
      #pragma unroll
      for (int r=0;r<4;r++) oacc[j][r] *= alpha[r];
    __syncthreads();   // keep: removing it caused a pathological 30ms mode (R18)

    __builtin_amdgcn_s_setprio(1);
    #pragma unroll
    for (int kk=0; kk<2; kk++){
      const bf16x8 pf = *(const bf16x8*)&Ps[wv*16+lm][kk*32+lq*8];
      #pragma unroll
      for (int j=0;j<8;j++){
        const bf16x8 vf = *(const bf16x8*)&Vts[j*16+lm][kk*32+lq*8];
        oacc[j] = __builtin_amdgcn_mfma_f32_16x16x32_bf16(pf, vf, oacc[j], 0, 0, 0);
      }
    }
    __builtin_amdgcn_s_setprio(0);
  }
  #pragma unroll
  for (int r=0;r<4;r++){
    const float inv = 1.0f / lrow[r];
    u16* orow = vals_c + ((size_t)(bl*SEQ + q0 + wv*16 + lq*4 + r))*EHH + h*EE;
    #pragma unroll
    for (int j=0;j<8;j++) orow[j*16+lm] = f2bf(oacc[j][r]*inv);
  }
}

// =================== pool phase 1: partial weighted sums (256 blocks) ===================
__global__ __launch_bounds__(128) void pool1_k(
    const float* __restrict__ x, const float* __restrict__ x_init,
    const float* __restrict__ w, float* __restrict__ part)
{
  const int bc = blockIdx.x;          // b*8 + c
  const int b = bc >> 3, c = bc & 7;
  const int e = threadIdx.x;
  float acc = 0.f;
  const int n0 = c*64;
  #pragma unroll 4
  for (int n=0;n<64;n++){
    const int tok = b*SEQ + n0 + n;
    const size_t idx = (size_t)tok*EE + e;
    acc = fmaf(w[tok], x[idx]+x_init[idx], acc);
  }
  part[(size_t)bc*EE + e] = acc;
}

// =================== pool phase 2: sum parts + LN + head ===================
__global__ __launch_bounds__(128) void pool2_k(
    const float* __restrict__ part, const float* __restrict__ g2,
    const float* __restrict__ b2, const float* __restrict__ head_W,
    const float* __restrict__ head_b, float* __restrict__ out)
{
  const int b = blockIdx.x;
  const int e = threadIdx.x;
  __shared__ float red[128];
  float acc = 0.f;
  #pragma unroll
  for (int c=0;c<8;c++) acc += part[(size_t)(b*8+c)*EE+e];
  red[e]=acc; __syncthreads();
  for (int s=64;s>0;s>>=1){ if(e<s) red[e]+=red[e+s]; __syncthreads(); }
  const float mean = red[0]*(1.0f/128.0f);
  __syncthreads();
  const float d = acc-mean;
  red[e]=d*d; __syncthreads();
  for (int s=64;s>0;s>>=1){ if(e<s) red[e]+=red[e+s]; __syncthreads(); }
  const float var = red[0]*(1.0f/128.0f);
  const float p = d*rsqrtf(var+1e-5f)*g2[e]+b2[e];
  __syncthreads();
  red[e] = p*head_W[e]; __syncthreads();
  for (int s=64;s>0;s>>=1){ if(e<s) red[e]+=red[e+s]; __syncthreads(); }
  if (e==0) out[b] = red[0] + head_b[0];
}

// =================== launch ===================
extern "C" void kernel_launch(void* const* d_in, const int* in_sizes, int n_in,
                              void* d_out, int out_size, void* d_ws, size_t ws_size,
                              hipStream_t stream)
{
  const float* str_fea   = (const float*)d_in[0];
  const int*   comp_fea  = (const int*)  d_in[1];
  // d_in[2] cell_fea unused by reference
  const float* atom_table= (const float*)d_in[3];
  const float* comp_W    = (const float*)d_in[4];
  const float* comp_b    = (const float*)d_in[5];
  const float* pdd_W     = (const float*)d_in[6];
  const float* pdd_b     = (const float*)d_in[7];
  const float* enc_ln_g  = (const float*)d_in[8];
  const float* enc_ln_b  = (const float*)d_in[9];
  const float* qkv_W     = (const float*)d_in[10];
  const float* qkv_b     = (const float*)d_in[11];
  const float* o_W       = (const float*)d_in[12];
  const float* o_b       = (const float*)d_in[13];
  const float* out_W     = (const float*)d_in[14];
  const float* out_b     = (const float*)d_in[15];
  const float* ffn_W     = (const float*)d_in[16];
  const float* ffn_b     = (const float*)d_in[17];
  const float* ln2_g     = (const float*)d_in[18];
  const float* ln2_b     = (const float*)d_in[19];
  const float* head_W    = (const float*)d_in[20];
  const float* head_b    = (const float*)d_in[21];
  float* out = (float*)d_out;

  // ---- diagnostic 1: input layout model ----
  bool sizes_ok = (n_in >= 22);
  if (sizes_ok){
    sizes_ok = in_sizes[0]==BB*SEQ*KF && in_sizes[1]==NTOK &&
               in_sizes[3]==NATOM*ADIM && in_sizes[4]==ADIM*EE &&
               in_sizes[10]==LL*EE*3*EHH && in_sizes[12]==LL*EHH*EHH &&
               in_sizes[14]==LL*EHH*EE   && in_sizes[16]==LL*EE*EE &&
               in_sizes[20]==EE;
  }
  if (!sizes_ok){
    sentinel_k<<<(out_size+63)/64,64,0,stream>>>(out, 99999.0f, out_size);
    return;
  }

  // ---- workspace layout (~84 MB; <= 109.7 MB proven) ----
  char* p = (char*)d_ws;
  size_t off = 0;
  auto alloc = [&](size_t bytes)->void*{
    off = (off + 255) & ~(size_t)255;
    void* r = p + off; off += bytes; return r;
  };
  float* w        = (float*)alloc((size_t)NTOK*4);
  float* x        = (float*)alloc((size_t)NTOK*EE*4);
  float* x_init   = (float*)alloc((size_t)NTOK*EE*4);
  u16*   xn_bf    = (u16*)  alloc((size_t)NTOK*EE*2);
  u16*   qkc      = (u16*)  alloc((size_t)CTOK*2048*2);   // 16.8 MB chunk (Q|K)
  u16*   vTc      = (u16*)  alloc((size_t)EHH*CTOK*2);    // 8.4 MB chunk (V^T)
  u16*   vals_bf  = (u16*)  alloc((size_t)NTOK*EHH*2);    // 33.6 MB
  u16*   qkvWT_a  = (u16*)  alloc((size_t)LL*3*EHH*EE*2); // 2.36 MB (reordered)
  float* rqkv_b   = (float*)alloc((size_t)LL*3*EHH*4);    // reordered bias
  u16*   fwT_a    = (u16*)  alloc((size_t)LL*EE*EHH*2);   // 0.79 MB
  u16*   ffnWT_a  = (u16*)  alloc((size_t)LL*EE*EE*2);
  u16*   outWT_a  = (u16*)  alloc((size_t)LL*EE*EHH*2);
  float* fbp_a    = (float*)alloc((size_t)LL*8*EE*4);     // fuse_b partials
  float* atom_emb = (float*)alloc((size_t)NATOM*EE*4);
  float* part     = (float*)alloc((size_t)BB*8*EE*4);

  // ---- diagnostic 2: workspace size ----
  if (off > ws_size){
    sentinel_k<<<(out_size+63)/64,64,0,stream>>>(out, 12345.0f, out_size);
    return;
  }

  // ---- hoisted weight prep (merged; serial roles first) ----
  prep_k<<<1763,256,0,stream>>>(qkv_W, qkvWT_a, ffn_W, ffnWT_a,
                                out_W, outWT_a, qkv_b, rqkv_b,
                                atom_table, comp_W, comp_b, pdd_b, atom_emb,
                                o_b, fbp_a);
  // fwT = (o_W @ out_W)^T per layer; A = o_W f32 converted in staging
  mgemm_k<4,32,64,128,1><<<dim3(EE/64, EHH/32, LL),256,0,stream>>>(
      o_W, outWT_a, nullptr, fwT_a, EE, EHH, EHH, nullptr,
      (size_t)EHH*EHH, (size_t)EE*EHH, (size_t)EE*EHH*2);

  embed_ln_k<<<NTOK/32,512,0,stream>>>(str_fea, comp_fea, atom_emb, pdd_W,
                                       enc_ln_g, enc_ln_b, x, x_init, w, xn_bf);

  for (int i=0;i<LL;i++){
    const float* gi = enc_ln_g + i*EE;
    const float* bi = enc_ln_b + i*EE;
    for (int cb=0; cb<NCHUNK; cb++){
      const int t0 = cb*CTOK;
      const int b0 = cb*CB;
      // QKV with router epilogue: Q|K -> qkc (stride 2048), V -> vTc (transposed)
      mgemm_k<7,128,128,64,0><<<dim3(3*EHH/128, CTOK/128),256,0,stream>>>(
          xn_bf + (size_t)t0*EE, qkvWT_a + (size_t)i*3*EHH*EE,
          rqkv_b + (size_t)i*3*EHH,
          qkc, 3*EHH, EE, CTOK, vTc, 0, 0, 0);
      attn_mf_k<<<dim3(CB, HH, SEQ/64),256,0,stream>>>(
          qkc, vTc, w, vals_bf + (size_t)t0*EHH, b0);
    }
    // proj + resid + LN + ffn + mish + dual-LN, all in one kernel
    const float* gn = (i<LL-1) ? enc_ln_g + (i+1)*EE : gi;
    const float* bn = (i<LL-1) ? enc_ln_b + (i+1)*EE : bi;
    projffn_k<<<NTOK/32,256,0,stream>>>(
        vals_bf, fwT_a + (size_t)i*EE*EHH,
        fbp_a + (size_t)i*8*EE, out_b + (size_t)i*EE,
        ffnWT_a + (size_t)i*EE*EE, ffn_b + (size_t)i*EE,
        gi, bi, gn, bn, x, xn_bf);
  }
  pool1_k<<<BB*8,128,0,stream>>>(x, x_init, w, part);
  pool2_k<<<BB,128,0,stream>>>(part, ln2_g, ln2_b, head_W, head_b, out);
}

// Round 9
// 880.624 us; speedup vs baseline: 1.1740x; 1.0071x over previous
//
#include <hip/hip_runtime.h>
#include <math.h>

#define DI __device__ __forceinline__

// ---- problem constants ----
#define BB 32
#define SEQ 512
#define KF 101
#define EE 128
#define HH 8
#define EHH 1024
#define LL 3
#define ADIM 200
#define NATOM 119
#define NTOK (BB*SEQ)   // 16384
#define CB 8            // batches per chunk
#define NCHUNK (BB/CB)  // 4
#define CTOK (CB*SEQ)   // 4096 tokens per chunk

// R23: attention = ~54% of runtime, latency-bound at 2 blocks/CU (63KB
// LDS). Q moved LDS->16 VGPRs (fragments constant across kt; same
// addresses = bitwise operands) -> 45.6KB LDS -> 3 blocks/CU, 3
// waves/SIMD. x_init eliminated: embed_ln computes per-block partial
// pooled sums (epart); pool1 reads only x. absmax unchanged.

typedef unsigned short u16;
typedef __attribute__((ext_vector_type(8))) short bf16x8;
typedef __attribute__((ext_vector_type(4))) float f32x4;

DI float bf2f(u16 s){ union{unsigned int u; float f;} x; x.u = ((unsigned int)s)<<16; return x.f; }
DI u16 f2bf(float f){
  union{float f; unsigned int u;} x; x.f = f;
  unsigned int u = x.u;
  u += 0x7fffu + ((u>>16)&1u);           // RNE
  return (u16)(u>>16);
}
DI float rdl(float v, int l){
  return __int_as_float(__builtin_amdgcn_readlane(__float_as_int(v), l));
}

// =================== sentinel ===================
__global__ void sentinel_k(float* out, float v, int n){
  int i = blockIdx.x*64 + threadIdx.x;
  if (i < n) out[i] = v;
}

// =================== embed + layer-0 LN (32 tokens/block, 8 waves) ===================
// x = atom_emb[idx] + str[1:]@pdd_W ; xn = LN(x); epart = per-block sum w*x
__global__ __launch_bounds__(512, 4) void embed_ln_k(
    const float* __restrict__ str_fea, const int* __restrict__ comp_fea,
    const float* __restrict__ atom_emb, const float* __restrict__ pdd_W,
    const float* __restrict__ g, const float* __restrict__ bta,
    float* __restrict__ x, float* __restrict__ w,
    u16* __restrict__ xn, float* __restrict__ epart)
{
  const int t0 = blockIdx.x*32;
  const int tid = threadIdx.x;
  const int wv = tid>>6, lane = tid&63;
  __shared__ float2 sPdd[100*64];      // 51.2 KB
  __shared__ float sEp[8][128];        // 4 KB
  for (int k2=tid; k2<100*64; k2+=512)
    sPdd[k2] = ((const float2*)pdd_W)[k2];

  float sv0[4], sv1[4];
  int idx[4];
  #pragma unroll
  for (int tk=0; tk<4; ++tk){
    const int t = t0 + wv*4 + tk;
    const float* sr0 = str_fea + (size_t)t*KF;
    sv0[tk] = sr0[lane];
    sv1[tk] = (lane+64 < KF) ? sr0[lane+64] : 0.f;
    idx[tk] = comp_fea[t];
  }
  __syncthreads();

  float a0[4],a1[4],a2[4],a3[4],c0[4],c1[4],c2[4],c3[4];
  #pragma unroll
  for (int tk=0; tk<4; ++tk){
    const float2 ae = ((const float2*)(atom_emb + (size_t)idx[tk]*EE))[lane];
    a0[tk]=ae.x; a1[tk]=0.f; a2[tk]=0.f; a3[tk]=0.f;
    c0[tk]=ae.y; c1[tk]=0.f; c2[tk]=0.f; c3[tk]=0.f;
  }
  #pragma unroll 5
  for (int j=0; j<100; j+=4){
    const float2 w0 = sPdd[(j  )*64 + lane];
    const float2 w1 = sPdd[(j+1)*64 + lane];
    const float2 w2 = sPdd[(j+2)*64 + lane];
    const float2 w3 = sPdd[(j+3)*64 + lane];
    #pragma unroll
    for (int tk=0; tk<4; ++tk){
      const float s1 = (1+j<64) ? rdl(sv0[tk],1+j) : rdl(sv1[tk],1+j-64);
      const float s2 = (2+j<64) ? rdl(sv0[tk],2+j) : rdl(sv1[tk],2+j-64);
      const float s3 = (3+j<64) ? rdl(sv0[tk],3+j) : rdl(sv1[tk],3+j-64);
      const float s4 = (4+j<64) ? rdl(sv0[tk],4+j) : rdl(sv1[tk],4+j-64);
      a0[tk] = fmaf(s1, w0.x, a0[tk]);  c0[tk] = fmaf(s1, w0.y, c0[tk]);
      a1[tk] = fmaf(s2, w1.x, a1[tk]);  c1[tk] = fmaf(s2, w1.y, c1[tk]);
      a2[tk] = fmaf(s3, w2.x, a2[tk]);  c2[tk] = fmaf(s3, w2.y, c2[tk]);
      a3[tk] = fmaf(s4, w3.x, a3[tk]);  c3[tk] = fmaf(s4, w3.y, c3[tk]);
    }
  }
  const float2 gg = ((const float2*)g)[lane];
  const float2 bb = ((const float2*)bta)[lane];
  const int e0 = lane*2;
  float ep0 = 0.f, ep1 = 0.f;
  #pragma unroll
  for (int tk=0; tk<4; ++tk){
    const int t = t0 + wv*4 + tk;
    const float vx = (a0[tk]+a1[tk])+(a2[tk]+a3[tk]);
    const float vy = (c0[tk]+c1[tk])+(c2[tk]+c3[tk]);
    ((float2*)(x + (size_t)t*EE))[lane] = make_float2(vx, vy);
    const float wt_ = rdl(sv0[tk], 0);
    if (lane==0) w[t] = sv0[tk];
    ep0 = fmaf(wt_, vx, ep0);
    ep1 = fmaf(wt_, vy, ep1);
    float s = vx + vy;
    #pragma unroll
    for (int off=32; off; off>>=1) s += __shfl_xor(s, off);
    const float mean = s*(1.0f/128.0f);
    const float d0 = vx-mean, d1 = vy-mean;
    float q = d0*d0 + d1*d1;
    #pragma unroll
    for (int off=32; off; off>>=1) q += __shfl_xor(q, off);
    const float rstd = rsqrtf(q*(1.0f/128.0f) + 1e-5f);
    u16* o = xn + (size_t)t*EE + e0;
    o[0] = f2bf(d0*rstd*gg.x + bb.x);
    o[1] = f2bf(d1*rstd*gg.y + bb.y);
  }
  sEp[wv][e0]   = ep0;
  sEp[wv][e0+1] = ep1;
  __syncthreads();
  if (tid < 128){
    float s = 0.f;
    #pragma unroll
    for (int v=0; v<8; ++v) s += sEp[v][tid];
    epart[(size_t)blockIdx.x*EE + tid] = s;
  }
}

// =================== merged weight prep ===================
DI void trans32(const float* __restrict__ W, u16* __restrict__ WT,
                int Nn, int Kk, int srcCol0, int n0, int k0, int tid,
                u16 (&tile)[32][33])
{
  const int lr = tid>>5, lc = tid&31;
  #pragma unroll
  for (int i=0;i<4;i++)
    tile[lr+i*8][lc] = f2bf(W[(size_t)(k0+lr+i*8)*Nn + srcCol0 + lc]);
  __syncthreads();
  #pragma unroll
  for (int i=0;i<4;i++)
    WT[(size_t)(n0+lr+i*8)*Kk + k0 + lc] = tile[lc][lr+i*8];
}

// roles (slow serial roles FIRST so their chains overlap the fast blocks):
// [0,119) atomemb | [119,143) fuse_b partials | [143,1295) qkvT |
// [1295,1343) ffnT | [1343,1727) outWT | [1727,1763) qkv bias reorder
__global__ __launch_bounds__(256) void prep_k(
    const float* __restrict__ qkv_W, u16* __restrict__ qkvWT,
    const float* __restrict__ ffn_W, u16* __restrict__ ffnWT,
    const float* __restrict__ out_W, u16* __restrict__ outWT,
    const float* __restrict__ qkv_b, float* __restrict__ rqkv_b,
    const float* __restrict__ atom_table, const float* __restrict__ comp_W,
    const float* __restrict__ comp_b, const float* __restrict__ pdd_b,
    float* __restrict__ atom_emb,
    const float* __restrict__ o_b, float* __restrict__ fbp)
{
  __shared__ u16 tile[32][33];
  __shared__ float sbuf[456];
  int bid = blockIdx.x;
  const int tid = threadIdx.x;
  if (bid < NATOM){
    // atom embedding: atom_emb[a] = comp_b + pdd_b + atom_table[a]@comp_W
    const int a = bid;
    const int e = tid & 127, half = tid >> 7;
    float* sAtom = sbuf;
    float* red   = sbuf + 200;
    for (int d=tid; d<ADIM; d+=256) sAtom[d] = atom_table[a*ADIM+d];
    __syncthreads();
    const int d0 = half*100;
    float b0 = half ? 0.f : (comp_b[e] + pdd_b[e]);
    float b1 = 0.f, b2 = 0.f, b3 = 0.f;
    #pragma unroll 5
    for (int d=d0; d<d0+100; d+=4){
      b0 = fmaf(sAtom[d  ], comp_W[(d  )*EE+e], b0);
      b1 = fmaf(sAtom[d+1], comp_W[(d+1)*EE+e], b1);
      b2 = fmaf(sAtom[d+2], comp_W[(d+2)*EE+e], b2);
      b3 = fmaf(sAtom[d+3], comp_W[(d+3)*EE+e], b3);
    }
    red[tid] = (b0+b1)+(b2+b3);
    __syncthreads();
    if (half==0) atom_emb[a*EE+e] = red[e] + red[128+e];
    return;
  }
  bid -= NATOM;
  if (bid < 24){
    // fuse_b partials: fbp[ly][s][n] = sum_{k in s-slice} o_b[k]*out_W[k][n]
    const int ly = bid >> 3, s = bid & 7;
    const float* ob = o_b + (size_t)ly*EHH;
    const float* oW = out_W + (size_t)ly*EHH*EE;
    const int n = tid & 127, h2 = tid >> 7;
    const int kb = s*128 + h2*64;
    float b0=0.f,b1=0.f,b2=0.f,b3=0.f;
    #pragma unroll 4
    for (int k2=kb; k2<kb+64; k2+=4){
      b0 = fmaf(ob[k2  ], oW[(size_t)(k2  )*EE+n], b0);
      b1 = fmaf(ob[k2+1], oW[(size_t)(k2+1)*EE+n], b1);
      b2 = fmaf(ob[k2+2], oW[(size_t)(k2+2)*EE+n], b2);
      b3 = fmaf(ob[k2+3], oW[(size_t)(k2+3)*EE+n], b3);
    }
    float* red = sbuf;
    red[tid] = (b0+b1)+(b2+b3);
    __syncthreads();
    if (h2==0) fbp[((size_t)ly*8 + s)*EE + n] = red[n] + red[128+n];
    return;
  }
  bid -= 24;
  if (bid < 1152){
    const int xb = bid%96, yb = (bid/96)%4, zb = bid/384;
    const int n0 = xb*32, k0 = yb*32;
    int c0;
    if (n0 < 2048) c0 = (n0>>8)*384 + (n0&255);
    else { const int m0 = n0-2048; c0 = (m0>>7)*384 + 256 + (m0&127); }
    trans32(qkv_W + (size_t)zb*EE*3*EHH, qkvWT + (size_t)zb*3*EHH*EE,
            3*EHH, EE, c0, n0, k0, tid, tile);
    return;
  }
  bid -= 1152;
  if (bid < 48){
    const int xb = bid%4, yb = (bid/4)%4, zb = bid/16;
    trans32(ffn_W + (size_t)zb*EE*EE, ffnWT + (size_t)zb*EE*EE,
            EE, EE, xb*32, xb*32, yb*32, tid, tile);
    return;
  }
  bid -= 48;
  if (bid < 384){
    const int xb = bid%4, yb = (bid/4)%32, zb = bid/128;
    trans32(out_W + (size_t)zb*EHH*EE, outWT + (size_t)zb*EE*EHH,
            EE, EHH, xb*32, xb*32, yb*32, tid, tile);
    return;
  }
  bid -= 384;
  {
    const int l = bid/12;
    const int n = (bid%12)*256 + tid;
    int c;
    if (n < 2048) c = (n>>8)*384 + (n&255);
    else { const int m = n-2048; c = (m>>7)*384 + 256 + (m&127); }
    rqkv_b[(size_t)l*3*EHH + n] = qkv_b[(size_t)l*3*EHH + c];
  }
}

// =================== MFMA bf16 GEMM (layer-batched via z strides) ===================
// A: M x Kk row-major (bf16, or f32 when AF32 — converted in staging).
// BT: Nn x Kk bf16 (pre-transposed B).
// EPI 0: store bf16; 4: bf16 transposed store (no bias);
// EPI 7 (QKV router): col<2048 -> C[row*2048+col]; col>=2048 -> C2 V^T.
template<int EPI, int BM, int BN, int BK, int AF32>
__global__ __launch_bounds__(256) void mgemm_k(
    const void* __restrict__ Av, const u16* __restrict__ BT,
    const float* __restrict__ bias, void* __restrict__ Cv,
    int Nn, int Kk, int Mdim, void* __restrict__ C2,
    size_t sA, size_t sBT, size_t sCb)
{
  const int lz = blockIdx.z;
  BT += (size_t)lz*sBT;
  void* C = (void*)((char*)Cv + (size_t)lz*sCb);

  constexpr int LDK = BK + 8;
  __shared__ u16 As[BM*LDK];
  __shared__ u16 Bs[BN*LDK];
  const int tid = threadIdx.x;
  const int m0 = blockIdx.y*BM, n0 = blockIdx.x*BN;
  constexpr int WMN = (BM>=128)?2:1;
  constexpr int WNN = 4/WMN;
  constexpr int WM = BM/WMN;
  constexpr int WN = BN/WNN;
  constexpr int FM = WM/16, FN = WN/16;
  const int wv = tid>>6, lane = tid&63;
  const int wm = (wv/WNN)*WM;
  const int wn = (wv%WNN)*WN;
  const int lm = lane&15, lq = lane>>4;

  f32x4 acc[FM][FN];
  #pragma unroll
  for (int i=0;i<FM;i++)
    #pragma unroll
    for (int j=0;j<FN;j++) acc[i][j] = (f32x4){0.f,0.f,0.f,0.f};

  constexpr int BCH = BN*BK/8;

  for (int k0=0; k0<Kk; k0+=BK){
    if constexpr (AF32){
      const float* A = (const float*)Av + (size_t)lz*sA;
      #pragma unroll
      for (int c = tid; c < BM*BK/4; c += 256){
        const int r = c/(BK/4), kg = c - r*(BK/4);
        const float4 v = *(const float4*)(A + (size_t)(m0+r)*Kk + k0 + kg*4);
        union { u16 u[4]; unsigned long long ll; } t;
        t.u[0]=f2bf(v.x); t.u[1]=f2bf(v.y); t.u[2]=f2bf(v.z); t.u[3]=f2bf(v.w);
        *(unsigned long long*)&As[r*LDK + kg*4] = t.ll;
      }
    } else {
      const u16* A = (const u16*)Av + (size_t)lz*sA;
      #pragma unroll
      for (int c = tid; c < BM*BK/8; c += 256){
        const int r = c/(BK/8), kg = c - r*(BK/8);
        const float4 v = *(const float4*)(A + (size_t)(m0+r)*Kk + k0 + kg*8);
        *(float4*)&As[r*LDK + kg*8] = v;
      }
    }
    #pragma unroll
    for (int c = tid; c < BCH; c += 256){
      const int r = c/(BK/8), kg = c - r*(BK/8);
      const float4 v = *(const float4*)(BT + (size_t)(n0+r)*Kk + k0 + kg*8);
      *(float4*)&Bs[r*LDK + kg*8] = v;
    }
    __syncthreads();
    #pragma unroll
    for (int kk=0; kk<BK/32; kk++){
      bf16x8 af[FM], bfr[FN];
      #pragma unroll
      for (int i=0;i<FM;i++)
        af[i] = *(const bf16x8*)&As[(wm + i*16 + lm)*LDK + kk*32 + lq*8];
      #pragma unroll
      for (int j=0;j<FN;j++)
        bfr[j] = *(const bf16x8*)&Bs[(wn + j*16 + lm)*LDK + kk*32 + lq*8];
      #pragma unroll
      for (int i=0;i<FM;i++)
        #pragma unroll
        for (int j=0;j<FN;j++)
          acc[i][j] = __builtin_amdgcn_mfma_f32_16x16x32_bf16(af[i], bfr[j], acc[i][j], 0, 0, 0);
    }
    __syncthreads();
  }
  #pragma unroll
  for (int i=0;i<FM;i++){
    #pragma unroll
    for (int j=0;j<FN;j++){
      const int col = n0 + wn + j*16 + lm;
      const float bv = (EPI==4) ? 0.f : bias[col];
      #pragma unroll
      for (int r=0;r<4;r++){
        const int row = m0 + wm + i*16 + lq*4 + r;
        float v = acc[i][j][r] + bv;
        if constexpr (EPI==7){
          if (col < 2048) ((u16*)C)[(size_t)row*2048 + col] = f2bf(v);
          else            ((u16*)C2)[(size_t)(col-2048)*Mdim + row] = f2bf(v);
        } else if constexpr (EPI==4){
          ((u16*)C)[(size_t)col*Mdim + row] = f2bf(v);
        } else {
          ((u16*)C)[(size_t)row*Nn + col] = f2bf(v);
        }
      }
    }
  }
}

// =================== fused proj+LN + ffn+mish + dual-LN ===================
__global__ __launch_bounds__(256) void projffn_k(
    const u16* __restrict__ vals, const u16* __restrict__ fwT,
    const float* __restrict__ fbp, const float* __restrict__ outb,
    const u16* __restrict__ ffnWT, const float* __restrict__ fnb,
    const float* __restrict__ g1, const float* __restrict__ b1,
    const float* __restrict__ g2, const float* __restrict__ b2,
    float* __restrict__ x_io, u16* __restrict__ xn_io)
{
  constexpr int BM = 32, BK = 128, LDK = BK + 8;
  __shared__ u16 As[BM*LDK];        // proj A tiles; then xn2 (bf16)
  __shared__ u16 Bs[EE*LDK];        // fwT tiles; then ffnWT
  __shared__ float sred[BM*8];
  const int tid = threadIdx.x;
  const int wv = tid>>6, lane = tid&63;
  const int lm = lane&15, lq = lane>>4;
  const int m0 = blockIdx.x*BM;
  const int wn = wv*32;             // 4 waves x 32 cols

  f32x4 acc[2][2];
  #pragma unroll
  for (int i=0;i<2;i++)
    #pragma unroll
    for (int j=0;j<2;j++) acc[i][j] = (f32x4){0.f,0.f,0.f,0.f};

  // ---- phase A: proj GEMM, K=1024 ----
  for (int k0=0; k0<EHH; k0+=BK){
    #pragma unroll
    for (int c = tid; c < BM*BK/8; c += 256){
      const int r = c>>4, kg = c&15;
      *(float4*)&As[r*LDK + kg*8] = *(const float4*)(vals + (size_t)(m0+r)*EHH + k0 + kg*8);
    }
    #pragma unroll
    for (int c = tid; c < EE*BK/8; c += 256){
      const int r = c>>4, kg = c&15;
      *(float4*)&Bs[r*LDK + kg*8] = *(const float4*)(fwT + (size_t)r*EHH + k0 + kg*8);
    }
    __syncthreads();
    #pragma unroll
    for (int kk=0; kk<BK/32; kk++){
      bf16x8 af[2], bfr[2];
      #pragma unroll
      for (int i=0;i<2;i++)
        af[i] = *(const bf16x8*)&As[(i*16 + lm)*LDK + kk*32 + lq*8];
      #pragma unroll
      for (int j=0;j<2;j++)
        bfr[j] = *(const bf16x8*)&Bs[(wn + j*16 + lm)*LDK + kk*32 + lq*8];
      #pragma unroll
      for (int i=0;i<2;i++)
        #pragma unroll
        for (int j=0;j<2;j++)
          acc[i][j] = __builtin_amdgcn_mfma_f32_16x16x32_bf16(af[i], bfr[j], acc[i][j], 0, 0, 0);
    }
    __syncthreads();
  }

  // ---- phase A epilogue: vout = acc + fb + x ; LN stats ----
  float vout[2][2][4];
  float ps[2][4], qs[2][4];
  #pragma unroll
  for (int i=0;i<2;i++)
    #pragma unroll
    for (int r=0;r<4;r++){ ps[i][r]=0.f; qs[i][r]=0.f; }
  #pragma unroll
  for (int i=0;i<2;i++){
    #pragma unroll
    for (int j=0;j<2;j++){
      const int col = wn + j*16 + lm;
      const float bv = outb[col]
        + ((fbp[0*EE+col]+fbp[1*EE+col])+(fbp[2*EE+col]+fbp[3*EE+col]))
        + ((fbp[4*EE+col]+fbp[5*EE+col])+(fbp[6*EE+col]+fbp[7*EE+col]));
      #pragma unroll
      for (int r=0;r<4;r++){
        const int row = m0 + i*16 + lq*4 + r;
        const float v = acc[i][j][r] + bv + x_io[(size_t)row*EE + col];
        vout[i][j][r] = v;
        ps[i][r] += v; qs[i][r] += v*v;
      }
    }
  }
  #pragma unroll
  for (int i=0;i<2;i++)
    #pragma unroll
    for (int r=0;r<4;r++){
      float s = ps[i][r], q = qs[i][r];
      s += __shfl_xor(s,1); s += __shfl_xor(s,2); s += __shfl_xor(s,4); s += __shfl_xor(s,8);
      q += __shfl_xor(q,1); q += __shfl_xor(q,2); q += __shfl_xor(q,4); q += __shfl_xor(q,8);
      if (lm==0){
        const int row = i*16 + lq*4 + r;
        sred[row*4 + wv] = s;
        sred[BM*4 + row*4 + wv] = q;
      }
    }
  __syncthreads();
  // xn2 -> As (bf16), and stage ffnWT -> Bs
  #pragma unroll
  for (int i=0;i<2;i++)
    #pragma unroll
    for (int r=0;r<4;r++){
      const int row = i*16 + lq*4 + r;
      const float s = sred[row*4+0]+sred[row*4+1]+sred[row*4+2]+sred[row*4+3];
      const float q = sred[BM*4+row*4+0]+sred[BM*4+row*4+1]+sred[BM*4+row*4+2]+sred[BM*4+row*4+3];
      const float mean = s*(1.0f/128.0f);
      const float var  = q*(1.0f/128.0f) - mean*mean;
      const float rstd = rsqrtf(var + 1e-5f);
      #pragma unroll
      for (int j=0;j<2;j++){
        const int col = wn + j*16 + lm;
        const float xnv = (vout[i][j][r]-mean)*rstd*g1[col] + b1[col];
        As[row*LDK + col] = f2bf(xnv);
      }
    }
  #pragma unroll
  for (int c = tid; c < EE*EE/8; c += 256){
    const int r = c>>4, kg = c&15;
    *(float4*)&Bs[r*LDK + kg*8] = *(const float4*)(ffnWT + (size_t)r*EE + kg*8);
  }
  __syncthreads();

  // ---- phase B: ffn GEMM, K=128 from LDS ----
  f32x4 fa[2][2];
  #pragma unroll
  for (int i=0;i<2;i++)
    #pragma unroll
    for (int j=0;j<2;j++) fa[i][j] = (f32x4){0.f,0.f,0.f,0.f};
  #pragma unroll
  for (int kk=0; kk<4; kk++){
    bf16x8 af[2], bfr[2];
    #pragma unroll
    for (int i=0;i<2;i++)
      af[i] = *(const bf16x8*)&As[(i*16 + lm)*LDK + kk*32 + lq*8];
    #pragma unroll
    for (int j=0;j<2;j++)
      bfr[j] = *(const bf16x8*)&Bs[(wn + j*16 + lm)*LDK + kk*32 + lq*8];
    #pragma unroll
    for (int i=0;i<2;i++)
      #pragma unroll
      for (int j=0;j<2;j++)
        fa[i][j] = __builtin_amdgcn_mfma_f32_16x16x32_bf16(af[i], bfr[j], fa[i][j], 0, 0, 0);
  }

  // ---- phase C: t = vout + mish(fa + fnb); dual row-LN ----
  float tv[2][2][4];
  #pragma unroll
  for (int i=0;i<2;i++)
    #pragma unroll
    for (int r=0;r<4;r++){ ps[i][r]=0.f; qs[i][r]=0.f; }
  #pragma unroll
  for (int i=0;i<2;i++){
    #pragma unroll
    for (int j=0;j<2;j++){
      const int col = wn + j*16 + lm;
      const float bv = fnb[col];
      #pragma unroll
      for (int r=0;r<4;r++){
        const float v = fa[i][j][r] + bv;
        const float E = __expf(v);
        const float uu = E*E + 2.f*E;
        const float mi = (v > 20.f) ? v : v*(uu/(uu+2.f));
        const float t = vout[i][j][r] + mi;
        tv[i][j][r] = t;
        ps[i][r] += t; qs[i][r] += t*t;
      }
    }
  }
  #pragma unroll
  for (int i=0;i<2;i++)
    #pragma unroll
    for (int r=0;r<4;r++){
      float s = ps[i][r], q = qs[i][r];
      s += __shfl_xor(s,1); s += __shfl_xor(s,2); s += __shfl_xor(s,4); s += __shfl_xor(s,8);
      q += __shfl_xor(q,1); q += __shfl_xor(q,2); q += __shfl_xor(q,4); q += __shfl_xor(q,8);
      if (lm==0){
        const int row = i*16 + lq*4 + r;
        sred[row*4 + wv] = s;
        sred[BM*4 + row*4 + wv] = q;
      }
    }
  __syncthreads();
  float xv[2][2][4];
  float ps2[2][4], qs2[2][4];
  #pragma unroll
  for (int i=0;i<2;i++)
    #pragma unroll
    for (int r=0;r<4;r++){
      const int row = i*16 + lq*4 + r;
      const float s = sred[row*4+0]+sred[row*4+1]+sred[row*4+2]+sred[row*4+3];
      const float q = sred[BM*4+row*4+0]+sred[BM*4+row*4+1]+sred[BM*4+row*4+2]+sred[BM*4+row*4+3];
      const float mean = s*(1.0f/128.0f);
      const float var  = q*(1.0f/128.0f) - mean*mean;
      const float rstd = rsqrtf(var + 1e-5f);
      float s2 = 0.f, q2 = 0.f;
      #pragma unroll
      for (int j=0;j<2;j++){
        const int col = wn + j*16 + lm;
        const float xnv = (tv[i][j][r]-mean)*rstd*g1[col] + b1[col];
        x_io[(size_t)(m0+row)*EE + col] = xnv;
        xv[i][j][r] = xnv;
        s2 += xnv; q2 += xnv*xnv;
      }
      ps2[i][r] = s2; qs2[i][r] = q2;
    }
  __syncthreads();
  #pragma unroll
  for (int i=0;i<2;i++)
    #pragma unroll
    for (int r=0;r<4;r++){
      float s = ps2[i][r], q = qs2[i][r];
      s += __shfl_xor(s,1); s += __shfl_xor(s,2); s += __shfl_xor(s,4); s += __shfl_xor(s,8);
      q += __shfl_xor(q,1); q += __shfl_xor(q,2); q += __shfl_xor(q,4); q += __shfl_xor(q,8);
      if (lm==0){
        const int row = i*16 + lq*4 + r;
        sred[row*4 + wv] = s;
        sred[BM*4 + row*4 + wv] = q;
      }
    }
  __syncthreads();
  #pragma unroll
  for (int i=0;i<2;i++)
    #pragma unroll
    for (int r=0;r<4;r++){
      const int row = i*16 + lq*4 + r;
      const float s = sred[row*4+0]+sred[row*4+1]+sred[row*4+2]+sred[row*4+3];
      const float q = sred[BM*4+row*4+0]+sred[BM*4+row*4+1]+sred[BM*4+row*4+2]+sred[BM*4+row*4+3];
      const float mean = s*(1.0f/128.0f);
      const float var  = q*(1.0f/128.0f) - mean*mean;
      const float rstd = rsqrtf(var + 1e-5f);
      #pragma unroll
      for (int j=0;j<2;j++){
        const int col = wn + j*16 + lm;
        const float xnv = (xv[i][j][r]-mean)*rstd*g2[col] + b2[col];
        xn_io[(size_t)(m0+row)*EE + col] = f2bf(xnv);
      }
    }
}

// =================== MFMA flash attention (XCD-local grid: bl,h,qt) ===================
// qkc: [tok][h*256 + (q:0..127 | k:128..255)] bf16, tok chunk-local.
// vTc: [h*128+d][tok] bf16 (pre-transposed V), tok chunk-local.
// Q held in 16 VGPRs (same addresses as old LDS staging = bitwise).
__global__ __launch_bounds__(256) void attn_mf_k(
    const u16* __restrict__ qkc, const u16* __restrict__ vTc,
    const float* __restrict__ w, u16* __restrict__ vals_c, int b0)
{
  const int bl = blockIdx.x;   // id%8 = bl -> one XCD per batch
  const int h  = blockIdx.y;
  const int qt = blockIdx.z;
  const int tid = threadIdx.x;
  const int wv = tid>>6, lane = tid&63;
  const int lm = lane&15, lq = lane>>4;

  __shared__ u16 Ks[64][136];
  __shared__ u16 Vts[128][72];
  __shared__ u16 Ps[64][72];
  __shared__ float wt[64], qwt[64];

  const size_t rs = 2048;
  const u16* qk = qkc + (size_t)bl*SEQ*rs + (size_t)h*256;
  const u16* vb = vTc + (size_t)h*128*CTOK + (size_t)bl*SEQ;
  const int q0 = qt*64;

  // Q fragments in registers (constant across all kt)
  bf16x8 qf[4];
  #pragma unroll
  for (int kk=0; kk<4; kk++)
    qf[kk] = *(const bf16x8*)(qk + (size_t)(q0 + wv*16 + lm)*rs + kk*32 + lq*8);
  if (tid < 64) qwt[tid] = w[(b0+bl)*SEQ + q0 + tid];
  __syncthreads();

  float kq[4];
  #pragma unroll
  for (int r=0;r<4;r++) kq[r] = qwt[wv*16 + lq*4 + r];

  f32x4 oacc[8];
  #pragma unroll
  for (int j=0;j<8;j++) oacc[j] = (f32x4){0.f,0.f,0.f,0.f};
  float mrow[4], lrow[4];
  #pragma unroll
  for (int r=0;r<4;r++){ mrow[r]=-INFINITY; lrow[r]=0.f; }
  const float scale = 0.08838834764831845f;  // 1/sqrt(128)

  for (int kt=0; kt<8; kt++){
    __syncthreads();
    #pragma unroll
    for (int it=0; it<4; it++){
      const int fi = it*256 + tid;
      const int r = fi >> 4, g = fi & 15;
      *(float4*)&Ks[r][g*8] = *(const float4*)(qk + (size_t)(kt*64+r)*rs + 128 + g*8);
    }
    #pragma unroll
    for (int it=0; it<4; it++){
      const int fi = it*256 + tid;
      const int d = fi >> 3, g = fi & 7;
      *(float4*)&Vts[d][g*8] = *(const float4*)(vb + (size_t)d*CTOK + kt*64 + g*8);
    }
    if (tid < 64) wt[tid] = w[(b0+bl)*SEQ + kt*64 + tid];
    __syncthreads();

    f32x4 sacc[4];
    #pragma unroll
    for (int j=0;j<4;j++) sacc[j] = (f32x4){0.f,0.f,0.f,0.f};
    __builtin_amdgcn_s_setprio(1);
    #pragma unroll
    for (int kk=0; kk<4; kk++){
      const bf16x8 af = qf[kk];
      #pragma unroll
      for (int j=0;j<4;j++){
        const bf16x8 bf = *(const bf16x8*)&Ks[j*16+lm][kk*32+lq*8];
        sacc[j] = __builtin_amdgcn_mfma_f32_16x16x32_bf16(af, bf, sacc[j], 0, 0, 0);
      }
    }
    __builtin_amdgcn_s_setprio(0);
    float wkj[4], s[4][4];
    #pragma unroll
    for (int j=0;j<4;j++) wkj[j] = wt[j*16+lm];
    #pragma unroll
    for (int j=0;j<4;j++)
      #pragma unroll
      for (int r=0;r<4;r++){
        const bool keep = (kq[r] > 0.f) && (wkj[j] > 0.f);
        s[j][r] = keep ? sacc[j][r]*scale : -9.0e15f;
      }
    float alpha[4];
    #pragma unroll
    for (int r=0;r<4;r++){
      float rm = fmaxf(fmaxf(s[0][r], s[1][r]), fmaxf(s[2][r], s[3][r]));
      rm = fmaxf(rm, __shfl_xor(rm, 1));
      rm = fmaxf(rm, __shfl_xor(rm, 2));
      rm = fmaxf(rm, __shfl_xor(rm, 4));
      rm = fmaxf(rm, __shfl_xor(rm, 8));
      const float newm = fmaxf(mrow[r], rm);
      alpha[r] = __expf(mrow[r] - newm);
      float ls = 0.f;
      #pragma unroll
      for (int j=0;j<4;j++){
        const float pv = wkj[j]*__expf(s[j][r]-newm);
        s[j][r] = pv; ls += pv;
      }
      ls += __shfl_xor(ls, 1);
      ls += __shfl_xor(ls, 2);
      ls += __shfl_xor(ls, 4);
      ls += __shfl_xor(ls, 8);
      lrow[r] = lrow[r]*alpha[r] + ls;
      mrow[r] = newm;
    }
    #pragma unroll
    for (int j=0;j<4;j++)
      #pragma unroll
      for (int r=0;r<4;r++)
        Ps[wv*16 + lq*4 + r][j*16+lm] = f2bf(s[j][r]);
    #pragma unroll
    for (int j=0;j<8;j++)
      #pragma unroll
      for (int r=0;r<4;r++) oacc[j][r] *= alpha[r];
    __syncthreads();   // keep: removing it caused a pathological 30ms mode (R18)

    __builtin_amdgcn_s_setprio(1);
    #pragma unroll
    for (int kk=0; kk<2; kk++){
      const bf16x8 pf = *(const bf16x8*)&Ps[wv*16+lm][kk*32+lq*8];
      #pragma unroll
      for (int j=0;j<8;j++){
        const bf16x8 vf = *(const bf16x8*)&Vts[j*16+lm][kk*32+lq*8];
        oacc[j] = __builtin_amdgcn_mfma_f32_16x16x32_bf16(pf, vf, oacc[j], 0, 0, 0);
      }
    }
    __builtin_amdgcn_s_setprio(0);
  }
  #pragma unroll
  for (int r=0;r<4;r++){
    const float inv = 1.0f / lrow[r];
    u16* orow = vals_c + ((size_t)(bl*SEQ + q0 + wv*16 + lq*4 + r))*EHH + h*EE;
    #pragma unroll
    for (int j=0;j<8;j++) orow[j*16+lm] = f2bf(oacc[j][r]*inv);
  }
}

// =================== pool phase 1: partial weighted sums (256 blocks) ===================
__global__ __launch_bounds__(128) void pool1_k(
    const float* __restrict__ x, const float* __restrict__ w,
    float* __restrict__ part)
{
  const int bc = blockIdx.x;          // b*8 + c
  const int b = bc >> 3, c = bc & 7;
  const int e = threadIdx.x;
  float acc = 0.f;
  const int n0 = c*64;
  #pragma unroll 4
  for (int n=0;n<64;n++){
    const int tok = b*SEQ + n0 + n;
    acc = fmaf(w[tok], x[(size_t)tok*EE + e], acc);
  }
  part[(size_t)bc*EE + e] = acc;
}

// =================== pool phase 2: sum parts + eparts + LN + head ===================
__global__ __launch_bounds__(128) void pool2_k(
    const float* __restrict__ part, const float* __restrict__ epart,
    const float* __restrict__ g2, const float* __restrict__ b2,
    const float* __restrict__ head_W, const float* __restrict__ head_b,
    float* __restrict__ out)
{
  const int b = blockIdx.x;
  const int e = threadIdx.x;
  __shared__ float red[128];
  float acc = 0.f;
  #pragma unroll
  for (int c=0;c<8;c++) acc += part[(size_t)(b*8+c)*EE+e];
  #pragma unroll
  for (int k=0;k<16;k++) acc += epart[(size_t)(b*16+k)*EE+e];
  red[e]=acc; __syncthreads();
  for (int s=64;s>0;s>>=1){ if(e<s) red[e]+=red[e+s]; __syncthreads(); }
  const float mean = red[0]*(1.0f/128.0f);
  __syncthreads();
  const float d = acc-mean;
  red[e]=d*d; __syncthreads();
  for (int s=64;s>0;s>>=1){ if(e<s) red[e]+=red[e+s]; __syncthreads(); }
  const float var = red[0]*(1.0f/128.0f);
  const float p = d*rsqrtf(var+1e-5f)*g2[e]+b2[e];
  __syncthreads();
  red[e] = p*head_W[e]; __syncthreads();
  for (int s=64;s>0;s>>=1){ if(e<s) red[e]+=red[e+s]; __syncthreads(); }
  if (e==0) out[b] = red[0] + head_b[0];
}

// =================== launch ===================
extern "C" void kernel_launch(void* const* d_in, const int* in_sizes, int n_in,
                              void* d_out, int out_size, void* d_ws, size_t ws_size,
                              hipStream_t stream)
{
  const float* str_fea   = (const float*)d_in[0];
  const int*   comp_fea  = (const int*)  d_in[1];
  // d_in[2] cell_fea unused by reference
  const float* atom_table= (const float*)d_in[3];
  const float* comp_W    = (const float*)d_in[4];
  const float* comp_b    = (const float*)d_in[5];
  const float* pdd_W     = (const float*)d_in[6];
  const float* pdd_b     = (const float*)d_in[7];
  const float* enc_ln_g  = (const float*)d_in[8];
  const float* enc_ln_b  = (const float*)d_in[9];
  const float* qkv_W     = (const float*)d_in[10];
  const float* qkv_b     = (const float*)d_in[11];
  const float* o_W       = (const float*)d_in[12];
  const float* o_b       = (const float*)d_in[13];
  const float* out_W     = (const float*)d_in[14];
  const float* out_b     = (const float*)d_in[15];
  const float* ffn_W     = (const float*)d_in[16];
  const float* ffn_b     = (const float*)d_in[17];
  const float* ln2_g     = (const float*)d_in[18];
  const float* ln2_b     = (const float*)d_in[19];
  const float* head_W    = (const float*)d_in[20];
  const float* head_b    = (const float*)d_in[21];
  float* out = (float*)d_out;

  // ---- diagnostic 1: input layout model ----
  bool sizes_ok = (n_in >= 22);
  if (sizes_ok){
    sizes_ok = in_sizes[0]==BB*SEQ*KF && in_sizes[1]==NTOK &&
               in_sizes[3]==NATOM*ADIM && in_sizes[4]==ADIM*EE &&
               in_sizes[10]==LL*EE*3*EHH && in_sizes[12]==LL*EHH*EHH &&
               in_sizes[14]==LL*EHH*EE   && in_sizes[16]==LL*EE*EE &&
               in_sizes[20]==EE;
  }
  if (!sizes_ok){
    sentinel_k<<<(out_size+63)/64,64,0,stream>>>(out, 99999.0f, out_size);
    return;
  }

  // ---- workspace layout (~76 MB; <= 109.7 MB proven) ----
  char* p = (char*)d_ws;
  size_t off = 0;
  auto alloc = [&](size_t bytes)->void*{
    off = (off + 255) & ~(size_t)255;
    void* r = p + off; off += bytes; return r;
  };
  float* w        = (float*)alloc((size_t)NTOK*4);
  float* x        = (float*)alloc((size_t)NTOK*EE*4);
  u16*   xn_bf    = (u16*)  alloc((size_t)NTOK*EE*2);
  u16*   qkc      = (u16*)  alloc((size_t)CTOK*2048*2);   // 16.8 MB chunk (Q|K)
  u16*   vTc      = (u16*)  alloc((size_t)EHH*CTOK*2);    // 8.4 MB chunk (V^T)
  u16*   vals_bf  = (u16*)  alloc((size_t)NTOK*EHH*2);    // 33.6 MB
  u16*   qkvWT_a  = (u16*)  alloc((size_t)LL*3*EHH*EE*2); // 2.36 MB (reordered)
  float* rqkv_b   = (float*)alloc((size_t)LL*3*EHH*4);    // reordered bias
  u16*   fwT_a    = (u16*)  alloc((size_t)LL*EE*EHH*2);   // 0.79 MB
  u16*   ffnWT_a  = (u16*)  alloc((size_t)LL*EE*EE*2);
  u16*   outWT_a  = (u16*)  alloc((size_t)LL*EE*EHH*2);
  float* fbp_a    = (float*)alloc((size_t)LL*8*EE*4);     // fuse_b partials
  float* atom_emb = (float*)alloc((size_t)NATOM*EE*4);
  float* part     = (float*)alloc((size_t)BB*8*EE*4);
  float* epart    = (float*)alloc((size_t)(NTOK/32)*EE*4); // embed pooled partials

  // ---- diagnostic 2: workspace size ----
  if (off > ws_size){
    sentinel_k<<<(out_size+63)/64,64,0,stream>>>(out, 12345.0f, out_size);
    return;
  }

  // ---- hoisted weight prep (merged; serial roles first) ----
  prep_k<<<1763,256,0,stream>>>(qkv_W, qkvWT_a, ffn_W, ffnWT_a,
                                out_W, outWT_a, qkv_b, rqkv_b,
                                atom_table, comp_W, comp_b, pdd_b, atom_emb,
                                o_b, fbp_a);
  // fwT = (o_W @ out_W)^T per layer; A = o_W f32 converted in staging
  mgemm_k<4,32,64,128,1><<<dim3(EE/64, EHH/32, LL),256,0,stream>>>(
      o_W, outWT_a, nullptr, fwT_a, EE, EHH, EHH, nullptr,
      (size_t)EHH*EHH, (size_t)EE*EHH, (size_t)EE*EHH*2);

  embed_ln_k<<<NTOK/32,512,0,stream>>>(str_fea, comp_fea, atom_emb, pdd_W,
                                       enc_ln_g, enc_ln_b, x, w, xn_bf, epart);

  for (int i=0;i<LL;i++){
    const float* gi = enc_ln_g + i*EE;
    const float* bi = enc_ln_b + i*EE;
    for (int cb=0; cb<NCHUNK; cb++){
      const int t0 = cb*CTOK;
      const int b0 = cb*CB;
      // QKV with router epilogue: Q|K -> qkc (stride 2048), V -> vTc (transposed)
      mgemm_k<7,128,128,64,0><<<dim3(3*EHH/128, CTOK/128),256,0,stream>>>(
          xn_bf + (size_t)t0*EE, qkvWT_a + (size_t)i*3*EHH*EE,
          rqkv_b + (size_t)i*3*EHH,
          qkc, 3*EHH, EE, CTOK, vTc, 0, 0, 0);
      attn_mf_k<<<dim3(CB, HH, SEQ/64),256,0,stream>>>(
          qkc, vTc, w, vals_bf + (size_t)t0*EHH, b0);
    }
    // proj + resid + LN + ffn + mish + dual-LN, all in one kernel
    const float* gn = (i<LL-1) ? enc_ln_g + (i+1)*EE : gi;
    const float* bn = (i<LL-1) ? enc_ln_b + (i+1)*EE : bi;
    projffn_k<<<NTOK/32,256,0,stream>>>(
        vals_bf, fwT_a + (size_t)i*EE*EHH,
        fbp_a + (size_t)i*8*EE, out_b + (size_t)i*EE,
        ffnWT_a + (size_t)i*EE*EE, ffn_b + (size_t)i*EE,
        gi, bi, gn, bn, x, xn_bf);
  }
  pool1_k<<<BB*8,128,0,stream>>>(x, w, part);
  pool2_k<<<BB,128,0,stream>>>(part, epart, ln2_g, ln2_b, head_W, head_b, out);
}

// Round 10
// 860.773 us; speedup vs baseline: 1.2011x; 1.0231x over previous
//
#include <hip/hip_runtime.h>
#include <math.h>

#define DI __device__ __forceinline__

// ---- problem constants ----
#define BB 32
#define SEQ 512
#define KF 101
#define EE 128
#define HH 8
#define EHH 1024
#define LL 3
#define ADIM 200
#define NATOM 119
#define NTOK (BB*SEQ)   // 16384
#define CB 16           // batches per chunk (R24: 8->16)
#define NCHUNK (BB/CB)  // 2
#define CTOK (CB*SEQ)   // 8192 tokens per chunk

// R24: R23 post-mortem - attn occupancy fix gave only -6us => attention
// is ~240us barrier-paced, not the 480us assumed; runtime is a serial
// sum of ~32 medium dispatches (HBM floor ~78us => structure-bound).
// Levers: CB 8->16 (24->12 QKV/attn launches, 2x grids; workspace
// ~101.6MB < 109.7 proven; bitwise identical), pool1 fused into
// last-layer projffn (pp per-block partials; pool2 sums pp+epart).

typedef unsigned short u16;
typedef __attribute__((ext_vector_type(8))) short bf16x8;
typedef __attribute__((ext_vector_type(4))) float f32x4;

DI float bf2f(u16 s){ union{unsigned int u; float f;} x; x.u = ((unsigned int)s)<<16; return x.f; }
DI u16 f2bf(float f){
  union{float f; unsigned int u;} x; x.f = f;
  unsigned int u = x.u;
  u += 0x7fffu + ((u>>16)&1u);           // RNE
  return (u16)(u>>16);
}
DI float rdl(float v, int l){
  return __int_as_float(__builtin_amdgcn_readlane(__float_as_int(v), l));
}

// =================== sentinel ===================
__global__ void sentinel_k(float* out, float v, int n){
  int i = blockIdx.x*64 + threadIdx.x;
  if (i < n) out[i] = v;
}

// =================== embed + layer-0 LN (32 tokens/block, 8 waves) ===================
// x = atom_emb[idx] + str[1:]@pdd_W ; xn = LN(x); epart = per-block sum w*x
__global__ __launch_bounds__(512, 4) void embed_ln_k(
    const float* __restrict__ str_fea, const int* __restrict__ comp_fea,
    const float* __restrict__ atom_emb, const float* __restrict__ pdd_W,
    const float* __restrict__ g, const float* __restrict__ bta,
    float* __restrict__ x, float* __restrict__ w,
    u16* __restrict__ xn, float* __restrict__ epart)
{
  const int t0 = blockIdx.x*32;
  const int tid = threadIdx.x;
  const int wv = tid>>6, lane = tid&63;
  __shared__ float2 sPdd[100*64];      // 51.2 KB
  __shared__ float sEp[8][128];        // 4 KB
  for (int k2=tid; k2<100*64; k2+=512)
    sPdd[k2] = ((const float2*)pdd_W)[k2];

  float sv0[4], sv1[4];
  int idx[4];
  #pragma unroll
  for (int tk=0; tk<4; ++tk){
    const int t = t0 + wv*4 + tk;
    const float* sr0 = str_fea + (size_t)t*KF;
    sv0[tk] = sr0[lane];
    sv1[tk] = (lane+64 < KF) ? sr0[lane+64] : 0.f;
    idx[tk] = comp_fea[t];
  }
  __syncthreads();

  float a0[4],a1[4],a2[4],a3[4],c0[4],c1[4],c2[4],c3[4];
  #pragma unroll
  for (int tk=0; tk<4; ++tk){
    const float2 ae = ((const float2*)(atom_emb + (size_t)idx[tk]*EE))[lane];
    a0[tk]=ae.x; a1[tk]=0.f; a2[tk]=0.f; a3[tk]=0.f;
    c0[tk]=ae.y; c1[tk]=0.f; c2[tk]=0.f; c3[tk]=0.f;
  }
  #pragma unroll 5
  for (int j=0; j<100; j+=4){
    const float2 w0 = sPdd[(j  )*64 + lane];
    const float2 w1 = sPdd[(j+1)*64 + lane];
    const float2 w2 = sPdd[(j+2)*64 + lane];
    const float2 w3 = sPdd[(j+3)*64 + lane];
    #pragma unroll
    for (int tk=0; tk<4; ++tk){
      const float s1 = (1+j<64) ? rdl(sv0[tk],1+j) : rdl(sv1[tk],1+j-64);
      const float s2 = (2+j<64) ? rdl(sv0[tk],2+j) : rdl(sv1[tk],2+j-64);
      const float s3 = (3+j<64) ? rdl(sv0[tk],3+j) : rdl(sv1[tk],3+j-64);
      const float s4 = (4+j<64) ? rdl(sv0[tk],4+j) : rdl(sv1[tk],4+j-64);
      a0[tk] = fmaf(s1, w0.x, a0[tk]);  c0[tk] = fmaf(s1, w0.y, c0[tk]);
      a1[tk] = fmaf(s2, w1.x, a1[tk]);  c1[tk] = fmaf(s2, w1.y, c1[tk]);
      a2[tk] = fmaf(s3, w2.x, a2[tk]);  c2[tk] = fmaf(s3, w2.y, c2[tk]);
      a3[tk] = fmaf(s4, w3.x, a3[tk]);  c3[tk] = fmaf(s4, w3.y, c3[tk]);
    }
  }
  const float2 gg = ((const float2*)g)[lane];
  const float2 bb = ((const float2*)bta)[lane];
  const int e0 = lane*2;
  float ep0 = 0.f, ep1 = 0.f;
  #pragma unroll
  for (int tk=0; tk<4; ++tk){
    const int t = t0 + wv*4 + tk;
    const float vx = (a0[tk]+a1[tk])+(a2[tk]+a3[tk]);
    const float vy = (c0[tk]+c1[tk])+(c2[tk]+c3[tk]);
    ((float2*)(x + (size_t)t*EE))[lane] = make_float2(vx, vy);
    const float wt_ = rdl(sv0[tk], 0);
    if (lane==0) w[t] = sv0[tk];
    ep0 = fmaf(wt_, vx, ep0);
    ep1 = fmaf(wt_, vy, ep1);
    float s = vx + vy;
    #pragma unroll
    for (int off=32; off; off>>=1) s += __shfl_xor(s, off);
    const float mean = s*(1.0f/128.0f);
    const float d0 = vx-mean, d1 = vy-mean;
    float q = d0*d0 + d1*d1;
    #pragma unroll
    for (int off=32; off; off>>=1) q += __shfl_xor(q, off);
    const float rstd = rsqrtf(q*(1.0f/128.0f) + 1e-5f);
    u16* o = xn + (size_t)t*EE + e0;
    o[0] = f2bf(d0*rstd*gg.x + bb.x);
    o[1] = f2bf(d1*rstd*gg.y + bb.y);
  }
  sEp[wv][e0]   = ep0;
  sEp[wv][e0+1] = ep1;
  __syncthreads();
  if (tid < 128){
    float s = 0.f;
    #pragma unroll
    for (int v=0; v<8; ++v) s += sEp[v][tid];
    epart[(size_t)blockIdx.x*EE + tid] = s;
  }
}

// =================== merged weight prep ===================
DI void trans32(const float* __restrict__ W, u16* __restrict__ WT,
                int Nn, int Kk, int srcCol0, int n0, int k0, int tid,
                u16 (&tile)[32][33])
{
  const int lr = tid>>5, lc = tid&31;
  #pragma unroll
  for (int i=0;i<4;i++)
    tile[lr+i*8][lc] = f2bf(W[(size_t)(k0+lr+i*8)*Nn + srcCol0 + lc]);
  __syncthreads();
  #pragma unroll
  for (int i=0;i<4;i++)
    WT[(size_t)(n0+lr+i*8)*Kk + k0 + lc] = tile[lc][lr+i*8];
}

// roles (slow serial roles FIRST so their chains overlap the fast blocks):
// [0,119) atomemb | [119,143) fuse_b partials | [143,1295) qkvT |
// [1295,1343) ffnT | [1343,1727) outWT | [1727,1763) qkv bias reorder
__global__ __launch_bounds__(256) void prep_k(
    const float* __restrict__ qkv_W, u16* __restrict__ qkvWT,
    const float* __restrict__ ffn_W, u16* __restrict__ ffnWT,
    const float* __restrict__ out_W, u16* __restrict__ outWT,
    const float* __restrict__ qkv_b, float* __restrict__ rqkv_b,
    const float* __restrict__ atom_table, const float* __restrict__ comp_W,
    const float* __restrict__ comp_b, const float* __restrict__ pdd_b,
    float* __restrict__ atom_emb,
    const float* __restrict__ o_b, float* __restrict__ fbp)
{
  __shared__ u16 tile[32][33];
  __shared__ float sbuf[456];
  int bid = blockIdx.x;
  const int tid = threadIdx.x;
  if (bid < NATOM){
    // atom embedding: atom_emb[a] = comp_b + pdd_b + atom_table[a]@comp_W
    const int a = bid;
    const int e = tid & 127, half = tid >> 7;
    float* sAtom = sbuf;
    float* red   = sbuf + 200;
    for (int d=tid; d<ADIM; d+=256) sAtom[d] = atom_table[a*ADIM+d];
    __syncthreads();
    const int d0 = half*100;
    float b0 = half ? 0.f : (comp_b[e] + pdd_b[e]);
    float b1 = 0.f, b2 = 0.f, b3 = 0.f;
    #pragma unroll 5
    for (int d=d0; d<d0+100; d+=4){
      b0 = fmaf(sAtom[d  ], comp_W[(d  )*EE+e], b0);
      b1 = fmaf(sAtom[d+1], comp_W[(d+1)*EE+e], b1);
      b2 = fmaf(sAtom[d+2], comp_W[(d+2)*EE+e], b2);
      b3 = fmaf(sAtom[d+3], comp_W[(d+3)*EE+e], b3);
    }
    red[tid] = (b0+b1)+(b2+b3);
    __syncthreads();
    if (half==0) atom_emb[a*EE+e] = red[e] + red[128+e];
    return;
  }
  bid -= NATOM;
  if (bid < 24){
    // fuse_b partials: fbp[ly][s][n] = sum_{k in s-slice} o_b[k]*out_W[k][n]
    const int ly = bid >> 3, s = bid & 7;
    const float* ob = o_b + (size_t)ly*EHH;
    const float* oW = out_W + (size_t)ly*EHH*EE;
    const int n = tid & 127, h2 = tid >> 7;
    const int kb = s*128 + h2*64;
    float b0=0.f,b1=0.f,b2=0.f,b3=0.f;
    #pragma unroll 4
    for (int k2=kb; k2<kb+64; k2+=4){
      b0 = fmaf(ob[k2  ], oW[(size_t)(k2  )*EE+n], b0);
      b1 = fmaf(ob[k2+1], oW[(size_t)(k2+1)*EE+n], b1);
      b2 = fmaf(ob[k2+2], oW[(size_t)(k2+2)*EE+n], b2);
      b3 = fmaf(ob[k2+3], oW[(size_t)(k2+3)*EE+n], b3);
    }
    float* red = sbuf;
    red[tid] = (b0+b1)+(b2+b3);
    __syncthreads();
    if (h2==0) fbp[((size_t)ly*8 + s)*EE + n] = red[n] + red[128+n];
    return;
  }
  bid -= 24;
  if (bid < 1152){
    const int xb = bid%96, yb = (bid/96)%4, zb = bid/384;
    const int n0 = xb*32, k0 = yb*32;
    int c0;
    if (n0 < 2048) c0 = (n0>>8)*384 + (n0&255);
    else { const int m0 = n0-2048; c0 = (m0>>7)*384 + 256 + (m0&127); }
    trans32(qkv_W + (size_t)zb*EE*3*EHH, qkvWT + (size_t)zb*3*EHH*EE,
            3*EHH, EE, c0, n0, k0, tid, tile);
    return;
  }
  bid -= 1152;
  if (bid < 48){
    const int xb = bid%4, yb = (bid/4)%4, zb = bid/16;
    trans32(ffn_W + (size_t)zb*EE*EE, ffnWT + (size_t)zb*EE*EE,
            EE, EE, xb*32, xb*32, yb*32, tid, tile);
    return;
  }
  bid -= 48;
  if (bid < 384){
    const int xb = bid%4, yb = (bid/4)%32, zb = bid/128;
    trans32(out_W + (size_t)zb*EHH*EE, outWT + (size_t)zb*EE*EHH,
            EE, EHH, xb*32, xb*32, yb*32, tid, tile);
    return;
  }
  bid -= 384;
  {
    const int l = bid/12;
    const int n = (bid%12)*256 + tid;
    int c;
    if (n < 2048) c = (n>>8)*384 + (n&255);
    else { const int m = n-2048; c = (m>>7)*384 + 256 + (m&127); }
    rqkv_b[(size_t)l*3*EHH + n] = qkv_b[(size_t)l*3*EHH + c];
  }
}

// =================== MFMA bf16 GEMM (layer-batched via z strides) ===================
// A: M x Kk row-major (bf16, or f32 when AF32 — converted in staging).
// BT: Nn x Kk bf16 (pre-transposed B).
// EPI 0: store bf16; 4: bf16 transposed store (no bias);
// EPI 7 (QKV router): col<2048 -> C[row*2048+col]; col>=2048 -> C2 V^T.
template<int EPI, int BM, int BN, int BK, int AF32>
__global__ __launch_bounds__(256) void mgemm_k(
    const void* __restrict__ Av, const u16* __restrict__ BT,
    const float* __restrict__ bias, void* __restrict__ Cv,
    int Nn, int Kk, int Mdim, void* __restrict__ C2,
    size_t sA, size_t sBT, size_t sCb)
{
  const int lz = blockIdx.z;
  BT += (size_t)lz*sBT;
  void* C = (void*)((char*)Cv + (size_t)lz*sCb);

  constexpr int LDK = BK + 8;
  __shared__ u16 As[BM*LDK];
  __shared__ u16 Bs[BN*LDK];
  const int tid = threadIdx.x;
  const int m0 = blockIdx.y*BM, n0 = blockIdx.x*BN;
  constexpr int WMN = (BM>=128)?2:1;
  constexpr int WNN = 4/WMN;
  constexpr int WM = BM/WMN;
  constexpr int WN = BN/WNN;
  constexpr int FM = WM/16, FN = WN/16;
  const int wv = tid>>6, lane = tid&63;
  const int wm = (wv/WNN)*WM;
  const int wn = (wv%WNN)*WN;
  const int lm = lane&15, lq = lane>>4;

  f32x4 acc[FM][FN];
  #pragma unroll
  for (int i=0;i<FM;i++)
    #pragma unroll
    for (int j=0;j<FN;j++) acc[i][j] = (f32x4){0.f,0.f,0.f,0.f};

  constexpr int BCH = BN*BK/8;

  for (int k0=0; k0<Kk; k0+=BK){
    if constexpr (AF32){
      const float* A = (const float*)Av + (size_t)lz*sA;
      #pragma unroll
      for (int c = tid; c < BM*BK/4; c += 256){
        const int r = c/(BK/4), kg = c - r*(BK/4);
        const float4 v = *(const float4*)(A + (size_t)(m0+r)*Kk + k0 + kg*4);
        union { u16 u[4]; unsigned long long ll; } t;
        t.u[0]=f2bf(v.x); t.u[1]=f2bf(v.y); t.u[2]=f2bf(v.z); t.u[3]=f2bf(v.w);
        *(unsigned long long*)&As[r*LDK + kg*4] = t.ll;
      }
    } else {
      const u16* A = (const u16*)Av + (size_t)lz*sA;
      #pragma unroll
      for (int c = tid; c < BM*BK/8; c += 256){
        const int r = c/(BK/8), kg = c - r*(BK/8);
        const float4 v = *(const float4*)(A + (size_t)(m0+r)*Kk + k0 + kg*8);
        *(float4*)&As[r*LDK + kg*8] = v;
      }
    }
    #pragma unroll
    for (int c = tid; c < BCH; c += 256){
      const int r = c/(BK/8), kg = c - r*(BK/8);
      const float4 v = *(const float4*)(BT + (size_t)(n0+r)*Kk + k0 + kg*8);
      *(float4*)&Bs[r*LDK + kg*8] = v;
    }
    __syncthreads();
    #pragma unroll
    for (int kk=0; kk<BK/32; kk++){
      bf16x8 af[FM], bfr[FN];
      #pragma unroll
      for (int i=0;i<FM;i++)
        af[i] = *(const bf16x8*)&As[(wm + i*16 + lm)*LDK + kk*32 + lq*8];
      #pragma unroll
      for (int j=0;j<FN;j++)
        bfr[j] = *(const bf16x8*)&Bs[(wn + j*16 + lm)*LDK + kk*32 + lq*8];
      #pragma unroll
      for (int i=0;i<FM;i++)
        #pragma unroll
        for (int j=0;j<FN;j++)
          acc[i][j] = __builtin_amdgcn_mfma_f32_16x16x32_bf16(af[i], bfr[j], acc[i][j], 0, 0, 0);
    }
    __syncthreads();
  }
  #pragma unroll
  for (int i=0;i<FM;i++){
    #pragma unroll
    for (int j=0;j<FN;j++){
      const int col = n0 + wn + j*16 + lm;
      const float bv = (EPI==4) ? 0.f : bias[col];
      #pragma unroll
      for (int r=0;r<4;r++){
        const int row = m0 + wm + i*16 + lq*4 + r;
        float v = acc[i][j][r] + bv;
        if constexpr (EPI==7){
          if (col < 2048) ((u16*)C)[(size_t)row*2048 + col] = f2bf(v);
          else            ((u16*)C2)[(size_t)(col-2048)*Mdim + row] = f2bf(v);
        } else if constexpr (EPI==4){
          ((u16*)C)[(size_t)col*Mdim + row] = f2bf(v);
        } else {
          ((u16*)C)[(size_t)row*Nn + col] = f2bf(v);
        }
      }
    }
  }
}

// =================== fused proj+LN + ffn+mish + dual-LN (+pool partial) ===================
__global__ __launch_bounds__(256) void projffn_k(
    const u16* __restrict__ vals, const u16* __restrict__ fwT,
    const float* __restrict__ fbp, const float* __restrict__ outb,
    const u16* __restrict__ ffnWT, const float* __restrict__ fnb,
    const float* __restrict__ g1, const float* __restrict__ b1,
    const float* __restrict__ g2, const float* __restrict__ b2,
    float* __restrict__ x_io, u16* __restrict__ xn_io,
    const float* __restrict__ w, float* __restrict__ pp)
{
  constexpr int BM = 32, BK = 128, LDK = BK + 8;
  __shared__ u16 As[BM*LDK];        // proj A tiles; then xn2 (bf16)
  __shared__ u16 Bs[EE*LDK];        // fwT tiles; then ffnWT
  __shared__ float sred[BM*8];
  const int tid = threadIdx.x;
  const int wv = tid>>6, lane = tid&63;
  const int lm = lane&15, lq = lane>>4;
  const int m0 = blockIdx.x*BM;
  const int wn = wv*32;             // 4 waves x 32 cols

  f32x4 acc[2][2];
  #pragma unroll
  for (int i=0;i<2;i++)
    #pragma unroll
    for (int j=0;j<2;j++) acc[i][j] = (f32x4){0.f,0.f,0.f,0.f};

  // ---- phase A: proj GEMM, K=1024 ----
  for (int k0=0; k0<EHH; k0+=BK){
    #pragma unroll
    for (int c = tid; c < BM*BK/8; c += 256){
      const int r = c>>4, kg = c&15;
      *(float4*)&As[r*LDK + kg*8] = *(const float4*)(vals + (size_t)(m0+r)*EHH + k0 + kg*8);
    }
    #pragma unroll
    for (int c = tid; c < EE*BK/8; c += 256){
      const int r = c>>4, kg = c&15;
      *(float4*)&Bs[r*LDK + kg*8] = *(const float4*)(fwT + (size_t)r*EHH + k0 + kg*8);
    }
    __syncthreads();
    #pragma unroll
    for (int kk=0; kk<BK/32; kk++){
      bf16x8 af[2], bfr[2];
      #pragma unroll
      for (int i=0;i<2;i++)
        af[i] = *(const bf16x8*)&As[(i*16 + lm)*LDK + kk*32 + lq*8];
      #pragma unroll
      for (int j=0;j<2;j++)
        bfr[j] = *(const bf16x8*)&Bs[(wn + j*16 + lm)*LDK + kk*32 + lq*8];
      #pragma unroll
      for (int i=0;i<2;i++)
        #pragma unroll
        for (int j=0;j<2;j++)
          acc[i][j] = __builtin_amdgcn_mfma_f32_16x16x32_bf16(af[i], bfr[j], acc[i][j], 0, 0, 0);
    }
    __syncthreads();
  }

  // ---- phase A epilogue: vout = acc + fb + x ; LN stats ----
  float vout[2][2][4];
  float ps[2][4], qs[2][4];
  #pragma unroll
  for (int i=0;i<2;i++)
    #pragma unroll
    for (int r=0;r<4;r++){ ps[i][r]=0.f; qs[i][r]=0.f; }
  #pragma unroll
  for (int i=0;i<2;i++){
    #pragma unroll
    for (int j=0;j<2;j++){
      const int col = wn + j*16 + lm;
      const float bv = outb[col]
        + ((fbp[0*EE+col]+fbp[1*EE+col])+(fbp[2*EE+col]+fbp[3*EE+col]))
        + ((fbp[4*EE+col]+fbp[5*EE+col])+(fbp[6*EE+col]+fbp[7*EE+col]));
      #pragma unroll
      for (int r=0;r<4;r++){
        const int row = m0 + i*16 + lq*4 + r;
        const float v = acc[i][j][r] + bv + x_io[(size_t)row*EE + col];
        vout[i][j][r] = v;
        ps[i][r] += v; qs[i][r] += v*v;
      }
    }
  }
  #pragma unroll
  for (int i=0;i<2;i++)
    #pragma unroll
    for (int r=0;r<4;r++){
      float s = ps[i][r], q = qs[i][r];
      s += __shfl_xor(s,1); s += __shfl_xor(s,2); s += __shfl_xor(s,4); s += __shfl_xor(s,8);
      q += __shfl_xor(q,1); q += __shfl_xor(q,2); q += __shfl_xor(q,4); q += __shfl_xor(q,8);
      if (lm==0){
        const int row = i*16 + lq*4 + r;
        sred[row*4 + wv] = s;
        sred[BM*4 + row*4 + wv] = q;
      }
    }
  __syncthreads();
  // xn2 -> As (bf16), and stage ffnWT -> Bs
  #pragma unroll
  for (int i=0;i<2;i++)
    #pragma unroll
    for (int r=0;r<4;r++){
      const int row = i*16 + lq*4 + r;
      const float s = sred[row*4+0]+sred[row*4+1]+sred[row*4+2]+sred[row*4+3];
      const float q = sred[BM*4+row*4+0]+sred[BM*4+row*4+1]+sred[BM*4+row*4+2]+sred[BM*4+row*4+3];
      const float mean = s*(1.0f/128.0f);
      const float var  = q*(1.0f/128.0f) - mean*mean;
      const float rstd = rsqrtf(var + 1e-5f);
      #pragma unroll
      for (int j=0;j<2;j++){
        const int col = wn + j*16 + lm;
        const float xnv = (vout[i][j][r]-mean)*rstd*g1[col] + b1[col];
        As[row*LDK + col] = f2bf(xnv);
      }
    }
  #pragma unroll
  for (int c = tid; c < EE*EE/8; c += 256){
    const int r = c>>4, kg = c&15;
    *(float4*)&Bs[r*LDK + kg*8] = *(const float4*)(ffnWT + (size_t)r*EE + kg*8);
  }
  __syncthreads();

  // ---- phase B: ffn GEMM, K=128 from LDS ----
  f32x4 fa[2][2];
  #pragma unroll
  for (int i=0;i<2;i++)
    #pragma unroll
    for (int j=0;j<2;j++) fa[i][j] = (f32x4){0.f,0.f,0.f,0.f};
  #pragma unroll
  for (int kk=0; kk<4; kk++){
    bf16x8 af[2], bfr[2];
    #pragma unroll
    for (int i=0;i<2;i++)
      af[i] = *(const bf16x8*)&As[(i*16 + lm)*LDK + kk*32 + lq*8];
    #pragma unroll
    for (int j=0;j<2;j++)
      bfr[j] = *(const bf16x8*)&Bs[(wn + j*16 + lm)*LDK + kk*32 + lq*8];
    #pragma unroll
    for (int i=0;i<2;i++)
      #pragma unroll
      for (int j=0;j<2;j++)
        fa[i][j] = __builtin_amdgcn_mfma_f32_16x16x32_bf16(af[i], bfr[j], fa[i][j], 0, 0, 0);
  }

  // ---- phase C: t = vout + mish(fa + fnb); dual row-LN ----
  float tv[2][2][4];
  #pragma unroll
  for (int i=0;i<2;i++)
    #pragma unroll
    for (int r=0;r<4;r++){ ps[i][r]=0.f; qs[i][r]=0.f; }
  #pragma unroll
  for (int i=0;i<2;i++){
    #pragma unroll
    for (int j=0;j<2;j++){
      const int col = wn + j*16 + lm;
      const float bv = fnb[col];
      #pragma unroll
      for (int r=0;r<4;r++){
        const float v = fa[i][j][r] + bv;
        const float E = __expf(v);
        const float uu = E*E + 2.f*E;
        const float mi = (v > 20.f) ? v : v*(uu/(uu+2.f));
        const float t = vout[i][j][r] + mi;
        tv[i][j][r] = t;
        ps[i][r] += t; qs[i][r] += t*t;
      }
    }
  }
  #pragma unroll
  for (int i=0;i<2;i++)
    #pragma unroll
    for (int r=0;r<4;r++){
      float s = ps[i][r], q = qs[i][r];
      s += __shfl_xor(s,1); s += __shfl_xor(s,2); s += __shfl_xor(s,4); s += __shfl_xor(s,8);
      q += __shfl_xor(q,1); q += __shfl_xor(q,2); q += __shfl_xor(q,4); q += __shfl_xor(q,8);
      if (lm==0){
        const int row = i*16 + lq*4 + r;
        sred[row*4 + wv] = s;
        sred[BM*4 + row*4 + wv] = q;
      }
    }
  __syncthreads();
  float xv[2][2][4];
  float ps2[2][4], qs2[2][4];
  #pragma unroll
  for (int i=0;i<2;i++)
    #pragma unroll
    for (int r=0;r<4;r++){
      const int row = i*16 + lq*4 + r;
      const float s = sred[row*4+0]+sred[row*4+1]+sred[row*4+2]+sred[row*4+3];
      const float q = sred[BM*4+row*4+0]+sred[BM*4+row*4+1]+sred[BM*4+row*4+2]+sred[BM*4+row*4+3];
      const float mean = s*(1.0f/128.0f);
      const float var  = q*(1.0f/128.0f) - mean*mean;
      const float rstd = rsqrtf(var + 1e-5f);
      float s2 = 0.f, q2 = 0.f;
      #pragma unroll
      for (int j=0;j<2;j++){
        const int col = wn + j*16 + lm;
        const float xnv = (tv[i][j][r]-mean)*rstd*g1[col] + b1[col];
        x_io[(size_t)(m0+row)*EE + col] = xnv;
        xv[i][j][r] = xnv;
        s2 += xnv; q2 += xnv*xnv;
      }
      ps2[i][r] = s2; qs2[i][r] = q2;
    }
  // fused pool partial (last layer): pp[block][col] = sum_rows w[row]*x[row][col]
  if (pp){
    float pz[2] = {0.f, 0.f};
    #pragma unroll
    for (int i=0;i<2;i++)
      #pragma unroll
      for (int r=0;r<4;r++){
        const float wr = w[m0 + i*16 + lq*4 + r];
        pz[0] = fmaf(wr, xv[i][0][r], pz[0]);
        pz[1] = fmaf(wr, xv[i][1][r], pz[1]);
      }
    #pragma unroll
    for (int j=0;j<2;j++){
      pz[j] += __shfl_xor(pz[j], 16);
      pz[j] += __shfl_xor(pz[j], 32);
      if (lq==0) pp[(size_t)blockIdx.x*EE + wn + j*16 + lm] = pz[j];
    }
  }
  __syncthreads();
  #pragma unroll
  for (int i=0;i<2;i++)
    #pragma unroll
    for (int r=0;r<4;r++){
      float s = ps2[i][r], q = qs2[i][r];
      s += __shfl_xor(s,1); s += __shfl_xor(s,2); s += __shfl_xor(s,4); s += __shfl_xor(s,8);
      q += __shfl_xor(q,1); q += __shfl_xor(q,2); q += __shfl_xor(q,4); q += __shfl_xor(q,8);
      if (lm==0){
        const int row = i*16 + lq*4 + r;
        sred[row*4 + wv] = s;
        sred[BM*4 + row*4 + wv] = q;
      }
    }
  __syncthreads();
  #pragma unroll
  for (int i=0;i<2;i++)
    #pragma unroll
    for (int r=0;r<4;r++){
      const int row = i*16 + lq*4 + r;
      const float s = sred[row*4+0]+sred[row*4+1]+sred[row*4+2]+sred[row*4+3];
      const float q = sred[BM*4+row*4+0]+sred[BM*4+row*4+1]+sred[BM*4+row*4+2]+sred[BM*4+row*4+3];
      const float mean = s*(1.0f/128.0f);
      const float var  = q*(1.0f/128.0f) - mean*mean;
      const float rstd = rsqrtf(var + 1e-5f);
      #pragma unroll
      for (int j=0;j<2;j++){
        const int col = wn + j*16 + lm;
        const float xnv = (xv[i][j][r]-mean)*rstd*g2[col] + b2[col];
        xn_io[(size_t)(m0+row)*EE + col] = f2bf(xnv);
      }
    }
}

// =================== MFMA flash attention (XCD-local grid: bl,h,qt) ===================
// qkc: [tok][h*256 + (q:0..127 | k:128..255)] bf16, tok chunk-local.
// vTc: [h*128+d][tok] bf16 (pre-transposed V), tok chunk-local.
// Q held in 16 VGPRs (same addresses as old LDS staging = bitwise).
__global__ __launch_bounds__(256) void attn_mf_k(
    const u16* __restrict__ qkc, const u16* __restrict__ vTc,
    const float* __restrict__ w, u16* __restrict__ vals_c, int b0)
{
  const int bl = blockIdx.x;   // id%8 -> XCD-local batch groups
  const int h  = blockIdx.y;
  const int qt = blockIdx.z;
  const int tid = threadIdx.x;
  const int wv = tid>>6, lane = tid&63;
  const int lm = lane&15, lq = lane>>4;

  __shared__ u16 Ks[64][136];
  __shared__ u16 Vts[128][72];
  __shared__ u16 Ps[64][72];
  __shared__ float wt[64], qwt[64];

  const size_t rs = 2048;
  const u16* qk = qkc + (size_t)bl*SEQ*rs + (size_t)h*256;
  const u16* vb = vTc + (size_t)h*128*CTOK + (size_t)bl*SEQ;
  const int q0 = qt*64;

  // Q fragments in registers (constant across all kt)
  bf16x8 qf[4];
  #pragma unroll
  for (int kk=0; kk<4; kk++)
    qf[kk] = *(const bf16x8*)(qk + (size_t)(q0 + wv*16 + lm)*rs + kk*32 + lq*8);
  if (tid < 64) qwt[tid] = w[(b0+bl)*SEQ + q0 + tid];
  __syncthreads();

  float kq[4];
  #pragma unroll
  for (int r=0;r<4;r++) kq[r] = qwt[wv*16 + lq*4 + r];

  f32x4 oacc[8];
  #pragma unroll
  for (int j=0;j<8;j++) oacc[j] = (f32x4){0.f,0.f,0.f,0.f};
  float mrow[4], lrow[4];
  #pragma unroll
  for (int r=0;r<4;r++){ mrow[r]=-INFINITY; lrow[r]=0.f; }
  const float scale = 0.08838834764831845f;  // 1/sqrt(128)

  for (int kt=0; kt<8; kt++){
    __syncthreads();
    #pragma unroll
    for (int it=0; it<4; it++){
      const int fi = it*256 + tid;
      const int r = fi >> 4, g = fi & 15;
      *(float4*)&Ks[r][g*8] = *(const float4*)(qk + (size_t)(kt*64+r)*rs + 128 + g*8);
    }
    #pragma unroll
    for (int it=0; it<4; it++){
      const int fi = it*256 + tid;
      const int d = fi >> 3, g = fi & 7;
      *(float4*)&Vts[d][g*8] = *(const float4*)(vb + (size_t)d*CTOK + kt*64 + g*8);
    }
    if (tid < 64) wt[tid] = w[(b0+bl)*SEQ + kt*64 + tid];
    __syncthreads();

    f32x4 sacc[4];
    #pragma unroll
    for (int j=0;j<4;j++) sacc[j] = (f32x4){0.f,0.f,0.f,0.f};
    __builtin_amdgcn_s_setprio(1);
    #pragma unroll
    for (int kk=0; kk<4; kk++){
      const bf16x8 af = qf[kk];
      #pragma unroll
      for (int j=0;j<4;j++){
        const bf16x8 bf = *(const bf16x8*)&Ks[j*16+lm][kk*32+lq*8];
        sacc[j] = __builtin_amdgcn_mfma_f32_16x16x32_bf16(af, bf, sacc[j], 0, 0, 0);
      }
    }
    __builtin_amdgcn_s_setprio(0);
    float wkj[4], s[4][4];
    #pragma unroll
    for (int j=0;j<4;j++) wkj[j] = wt[j*16+lm];
    #pragma unroll
    for (int j=0;j<4;j++)
      #pragma unroll
      for (int r=0;r<4;r++){
        const bool keep = (kq[r] > 0.f) && (wkj[j] > 0.f);
        s[j][r] = keep ? sacc[j][r]*scale : -9.0e15f;
      }
    float alpha[4];
    #pragma unroll
    for (int r=0;r<4;r++){
      float rm = fmaxf(fmaxf(s[0][r], s[1][r]), fmaxf(s[2][r], s[3][r]));
      rm = fmaxf(rm, __shfl_xor(rm, 1));
      rm = fmaxf(rm, __shfl_xor(rm, 2));
      rm = fmaxf(rm, __shfl_xor(rm, 4));
      rm = fmaxf(rm, __shfl_xor(rm, 8));
      const float newm = fmaxf(mrow[r], rm);
      alpha[r] = __expf(mrow[r] - newm);
      float ls = 0.f;
      #pragma unroll
      for (int j=0;j<4;j++){
        const float pv = wkj[j]*__expf(s[j][r]-newm);
        s[j][r] = pv; ls += pv;
      }
      ls += __shfl_xor(ls, 1);
      ls += __shfl_xor(ls, 2);
      ls += __shfl_xor(ls, 4);
      ls += __shfl_xor(ls, 8);
      lrow[r] = lrow[r]*alpha[r] + ls;
      mrow[r] = newm;
    }
    #pragma unroll
    for (int j=0;j<4;j++)
      #pragma unroll
      for (int r=0;r<4;r++)
        Ps[wv*16 + lq*4 + r][j*16+lm] = f2bf(s[j][r]);
    #pragma unroll
    for (int j=0;j<8;j++)
      #pragma unroll
      for (int r=0;r<4;r++) oacc[j][r] *= alpha[r];
    __syncthreads();   // keep: removing it caused a pathological 30ms mode (R18)

    __builtin_amdgcn_s_setprio(1);
    #pragma unroll
    for (int kk=0; kk<2; kk++){
      const bf16x8 pf = *(const bf16x8*)&Ps[wv*16+lm][kk*32+lq*8];
      #pragma unroll
      for (int j=0;j<8;j++){
        const bf16x8 vf = *(const bf16x8*)&Vts[j*16+lm][kk*32+lq*8];
        oacc[j] = __builtin_amdgcn_mfma_f32_16x16x32_bf16(pf, vf, oacc[j], 0, 0, 0);
      }
    }
    __builtin_amdgcn_s_setprio(0);
  }
  #pragma unroll
  for (int r=0;r<4;r++){
    const float inv = 1.0f / lrow[r];
    u16* orow = vals_c + ((size_t)(bl*SEQ + q0 + wv*16 + lq*4 + r))*EHH + h*EE;
    #pragma unroll
    for (int j=0;j<8;j++) orow[j*16+lm] = f2bf(oacc[j][r]*inv);
  }
}

// =================== pool phase 2: sum pp + eparts + LN + head ===================
__global__ __launch_bounds__(128) void pool2_k(
    const float* __restrict__ pp, const float* __restrict__ epart,
    const float* __restrict__ g2, const float* __restrict__ b2,
    const float* __restrict__ head_W, const float* __restrict__ head_b,
    float* __restrict__ out)
{
  const int b = blockIdx.x;
  const int e = threadIdx.x;
  __shared__ float red[128];
  float acc = 0.f;
  #pragma unroll
  for (int k=0;k<16;k++) acc += pp[(size_t)(b*16+k)*EE+e];
  #pragma unroll
  for (int k=0;k<16;k++) acc += epart[(size_t)(b*16+k)*EE+e];
  red[e]=acc; __syncthreads();
  for (int s=64;s>0;s>>=1){ if(e<s) red[e]+=red[e+s]; __syncthreads(); }
  const float mean = red[0]*(1.0f/128.0f);
  __syncthreads();
  const float d = acc-mean;
  red[e]=d*d; __syncthreads();
  for (int s=64;s>0;s>>=1){ if(e<s) red[e]+=red[e+s]; __syncthreads(); }
  const float var = red[0]*(1.0f/128.0f);
  const float p = d*rsqrtf(var+1e-5f)*g2[e]+b2[e];
  __syncthreads();
  red[e] = p*head_W[e]; __syncthreads();
  for (int s=64;s>0;s>>=1){ if(e<s) red[e]+=red[e+s]; __syncthreads(); }
  if (e==0) out[b] = red[0] + head_b[0];
}

// =================== launch ===================
extern "C" void kernel_launch(void* const* d_in, const int* in_sizes, int n_in,
                              void* d_out, int out_size, void* d_ws, size_t ws_size,
                              hipStream_t stream)
{
  const float* str_fea   = (const float*)d_in[0];
  const int*   comp_fea  = (const int*)  d_in[1];
  // d_in[2] cell_fea unused by reference
  const float* atom_table= (const float*)d_in[3];
  const float* comp_W    = (const float*)d_in[4];
  const float* comp_b    = (const float*)d_in[5];
  const float* pdd_W     = (const float*)d_in[6];
  const float* pdd_b     = (const float*)d_in[7];
  const float* enc_ln_g  = (const float*)d_in[8];
  const float* enc_ln_b  = (const float*)d_in[9];
  const float* qkv_W     = (const float*)d_in[10];
  const float* qkv_b     = (const float*)d_in[11];
  const float* o_W       = (const float*)d_in[12];
  const float* o_b       = (const float*)d_in[13];
  const float* out_W     = (const float*)d_in[14];
  const float* out_b     = (const float*)d_in[15];
  const float* ffn_W     = (const float*)d_in[16];
  const float* ffn_b     = (const float*)d_in[17];
  const float* ln2_g     = (const float*)d_in[18];
  const float* ln2_b     = (const float*)d_in[19];
  const float* head_W    = (const float*)d_in[20];
  const float* head_b    = (const float*)d_in[21];
  float* out = (float*)d_out;

  // ---- diagnostic 1: input layout model ----
  bool sizes_ok = (n_in >= 22);
  if (sizes_ok){
    sizes_ok = in_sizes[0]==BB*SEQ*KF && in_sizes[1]==NTOK &&
               in_sizes[3]==NATOM*ADIM && in_sizes[4]==ADIM*EE &&
               in_sizes[10]==LL*EE*3*EHH && in_sizes[12]==LL*EHH*EHH &&
               in_sizes[14]==LL*EHH*EE   && in_sizes[16]==LL*EE*EE &&
               in_sizes[20]==EE;
  }
  if (!sizes_ok){
    sentinel_k<<<(out_size+63)/64,64,0,stream>>>(out, 99999.0f, out_size);
    return;
  }

  // ---- workspace layout (~101.6 MB; <= 109.7 MB proven) ----
  char* p = (char*)d_ws;
  size_t off = 0;
  auto alloc = [&](size_t bytes)->void*{
    off = (off + 255) & ~(size_t)255;
    void* r = p + off; off += bytes; return r;
  };
  float* w        = (float*)alloc((size_t)NTOK*4);
  float* x        = (float*)alloc((size_t)NTOK*EE*4);
  u16*   xn_bf    = (u16*)  alloc((size_t)NTOK*EE*2);
  u16*   qkc      = (u16*)  alloc((size_t)CTOK*2048*2);   // 33.6 MB chunk (Q|K)
  u16*   vTc      = (u16*)  alloc((size_t)EHH*CTOK*2);    // 16.8 MB chunk (V^T)
  u16*   vals_bf  = (u16*)  alloc((size_t)NTOK*EHH*2);    // 33.6 MB
  u16*   qkvWT_a  = (u16*)  alloc((size_t)LL*3*EHH*EE*2); // 2.36 MB (reordered)
  float* rqkv_b   = (float*)alloc((size_t)LL*3*EHH*4);    // reordered bias
  u16*   fwT_a    = (u16*)  alloc((size_t)LL*EE*EHH*2);   // 0.79 MB
  u16*   ffnWT_a  = (u16*)  alloc((size_t)LL*EE*EE*2);
  u16*   outWT_a  = (u16*)  alloc((size_t)LL*EE*EHH*2);
  float* fbp_a    = (float*)alloc((size_t)LL*8*EE*4);     // fuse_b partials
  float* atom_emb = (float*)alloc((size_t)NATOM*EE*4);
  float* epart    = (float*)alloc((size_t)(NTOK/32)*EE*4); // embed pooled partials
  float* pp       = (float*)alloc((size_t)(NTOK/32)*EE*4); // projffn pooled partials

  // ---- diagnostic 2: workspace size ----
  if (off > ws_size){
    sentinel_k<<<(out_size+63)/64,64,0,stream>>>(out, 12345.0f, out_size);
    return;
  }

  // ---- hoisted weight prep (merged; serial roles first) ----
  prep_k<<<1763,256,0,stream>>>(qkv_W, qkvWT_a, ffn_W, ffnWT_a,
                                out_W, outWT_a, qkv_b, rqkv_b,
                                atom_table, comp_W, comp_b, pdd_b, atom_emb,
                                o_b, fbp_a);
  // fwT = (o_W @ out_W)^T per layer; A = o_W f32 converted in staging
  mgemm_k<4,32,64,128,1><<<dim3(EE/64, EHH/32, LL),256,0,stream>>>(
      o_W, outWT_a, nullptr, fwT_a, EE, EHH, EHH, nullptr,
      (size_t)EHH*EHH, (size_t)EE*EHH, (size_t)EE*EHH*2);

  embed_ln_k<<<NTOK/32,512,0,stream>>>(str_fea, comp_fea, atom_emb, pdd_W,
                                       enc_ln_g, enc_ln_b, x, w, xn_bf, epart);

  for (int i=0;i<LL;i++){
    const float* gi = enc_ln_g + i*EE;
    const float* bi = enc_ln_b + i*EE;
    for (int cb=0; cb<NCHUNK; cb++){
      const int t0 = cb*CTOK;
      const int b0 = cb*CB;
      // QKV with router epilogue: Q|K -> qkc (stride 2048), V -> vTc (transposed)
      mgemm_k<7,128,128,64,0><<<dim3(3*EHH/128, CTOK/128),256,0,stream>>>(
          xn_bf + (size_t)t0*EE, qkvWT_a + (size_t)i*3*EHH*EE,
          rqkv_b + (size_t)i*3*EHH,
          qkc, 3*EHH, EE, CTOK, vTc, 0, 0, 0);
      attn_mf_k<<<dim3(CB, HH, SEQ/64),256,0,stream>>>(
          qkc, vTc, w, vals_bf + (size_t)t0*EHH, b0);
    }
    // proj + resid + LN + ffn + mish + dual-LN (+pool partial on last layer)
    const float* gn = (i<LL-1) ? enc_ln_g + (i+1)*EE : gi;
    const float* bn = (i<LL-1) ? enc_ln_b + (i+1)*EE : bi;
    projffn_k<<<NTOK/32,256,0,stream>>>(
        vals_bf, fwT_a + (size_t)i*EE*EHH,
        fbp_a + (size_t)i*8*EE, out_b + (size_t)i*EE,
        ffnWT_a + (size_t)i*EE*EE, ffn_b + (size_t)i*EE,
        gi, bi, gn, bn, x, xn_bf,
        w, (i==LL-1) ? pp : nullptr);
  }
  pool2_k<<<BB,128,0,stream>>>(pp, epart, ln2_g, ln2_b, head_W, head_b, out);
}

// Round 11
// 794.956 us; speedup vs baseline: 1.3006x; 1.0828x over previous
//
#include <hip/hip_runtime.h>
#include <math.h>

#define DI __device__ __forceinline__

// ---- problem constants ----
#define BB 32
#define SEQ 512
#define KF 101
#define EE 128
#define HH 8
#define EHH 1024
#define LL 3
#define ADIM 200
#define NATOM 119
#define NTOK (BB*SEQ)   // 16384
#define CB 16           // batches per chunk
#define NCHUNK (BB/CB)  // 2
#define CTOK (CB*SEQ)   // 8192 tokens per chunk

// R25: attention counters (62us x6, MfmaUtil 10.6%, VALU 34%, occ 22%,
// 4.45M bank-conflict cy) => latency/sync-bound. Swapped-operand QK^T
// (mfma(K,Q): bitwise transpose; lane owns a q-row) -> in-lane softmax
// (2 shfl_xor vs 16), P kept in registers (pk u32 pairs + 8 shfl + 4
// sel per kk feed PV's B-fragment), PV also swapped (Vts frag read
// unchanged). Ps LDS gone (-9.2KB -> 35.5KB, 4 blocks/CU), mid-barrier
// gone (3->2/kt), output packed 8B stores. O bitwise identical; lrow
// sum reassociated ~1e-7.

typedef unsigned short u16;
typedef __attribute__((ext_vector_type(8))) short bf16x8;
typedef __attribute__((ext_vector_type(4))) float f32x4;

DI float bf2f(u16 s){ union{unsigned int u; float f;} x; x.u = ((unsigned int)s)<<16; return x.f; }
DI u16 f2bf(float f){
  union{float f; unsigned int u;} x; x.f = f;
  unsigned int u = x.u;
  u += 0x7fffu + ((u>>16)&1u);           // RNE
  return (u16)(u>>16);
}
DI unsigned int f2bf2(float lo, float hi){
  return (unsigned int)f2bf(lo) | ((unsigned int)f2bf(hi)<<16);
}
DI float rdl(float v, int l){
  return __int_as_float(__builtin_amdgcn_readlane(__float_as_int(v), l));
}

// =================== sentinel ===================
__global__ void sentinel_k(float* out, float v, int n){
  int i = blockIdx.x*64 + threadIdx.x;
  if (i < n) out[i] = v;
}

// =================== embed + layer-0 LN (32 tokens/block, 8 waves) ===================
// x = atom_emb[idx] + str[1:]@pdd_W ; xn = LN(x); epart = per-block sum w*x
__global__ __launch_bounds__(512, 4) void embed_ln_k(
    const float* __restrict__ str_fea, const int* __restrict__ comp_fea,
    const float* __restrict__ atom_emb, const float* __restrict__ pdd_W,
    const float* __restrict__ g, const float* __restrict__ bta,
    float* __restrict__ x, float* __restrict__ w,
    u16* __restrict__ xn, float* __restrict__ epart)
{
  const int t0 = blockIdx.x*32;
  const int tid = threadIdx.x;
  const int wv = tid>>6, lane = tid&63;
  __shared__ float2 sPdd[100*64];      // 51.2 KB
  __shared__ float sEp[8][128];        // 4 KB
  for (int k2=tid; k2<100*64; k2+=512)
    sPdd[k2] = ((const float2*)pdd_W)[k2];

  float sv0[4], sv1[4];
  int idx[4];
  #pragma unroll
  for (int tk=0; tk<4; ++tk){
    const int t = t0 + wv*4 + tk;
    const float* sr0 = str_fea + (size_t)t*KF;
    sv0[tk] = sr0[lane];
    sv1[tk] = (lane+64 < KF) ? sr0[lane+64] : 0.f;
    idx[tk] = comp_fea[t];
  }
  __syncthreads();

  float a0[4],a1[4],a2[4],a3[4],c0[4],c1[4],c2[4],c3[4];
  #pragma unroll
  for (int tk=0; tk<4; ++tk){
    const float2 ae = ((const float2*)(atom_emb + (size_t)idx[tk]*EE))[lane];
    a0[tk]=ae.x; a1[tk]=0.f; a2[tk]=0.f; a3[tk]=0.f;
    c0[tk]=ae.y; c1[tk]=0.f; c2[tk]=0.f; c3[tk]=0.f;
  }
  #pragma unroll 5
  for (int j=0; j<100; j+=4){
    const float2 w0 = sPdd[(j  )*64 + lane];
    const float2 w1 = sPdd[(j+1)*64 + lane];
    const float2 w2 = sPdd[(j+2)*64 + lane];
    const float2 w3 = sPdd[(j+3)*64 + lane];
    #pragma unroll
    for (int tk=0; tk<4; ++tk){
      const float s1 = (1+j<64) ? rdl(sv0[tk],1+j) : rdl(sv1[tk],1+j-64);
      const float s2 = (2+j<64) ? rdl(sv0[tk],2+j) : rdl(sv1[tk],2+j-64);
      const float s3 = (3+j<64) ? rdl(sv0[tk],3+j) : rdl(sv1[tk],3+j-64);
      const float s4 = (4+j<64) ? rdl(sv0[tk],4+j) : rdl(sv1[tk],4+j-64);
      a0[tk] = fmaf(s1, w0.x, a0[tk]);  c0[tk] = fmaf(s1, w0.y, c0[tk]);
      a1[tk] = fmaf(s2, w1.x, a1[tk]);  c1[tk] = fmaf(s2, w1.y, c1[tk]);
      a2[tk] = fmaf(s3, w2.x, a2[tk]);  c2[tk] = fmaf(s3, w2.y, c2[tk]);
      a3[tk] = fmaf(s4, w3.x, a3[tk]);  c3[tk] = fmaf(s4, w3.y, c3[tk]);
    }
  }
  const float2 gg = ((const float2*)g)[lane];
  const float2 bb = ((const float2*)bta)[lane];
  const int e0 = lane*2;
  float ep0 = 0.f, ep1 = 0.f;
  #pragma unroll
  for (int tk=0; tk<4; ++tk){
    const int t = t0 + wv*4 + tk;
    const float vx = (a0[tk]+a1[tk])+(a2[tk]+a3[tk]);
    const float vy = (c0[tk]+c1[tk])+(c2[tk]+c3[tk]);
    ((float2*)(x + (size_t)t*EE))[lane] = make_float2(vx, vy);
    const float wt_ = rdl(sv0[tk], 0);
    if (lane==0) w[t] = sv0[tk];
    ep0 = fmaf(wt_, vx, ep0);
    ep1 = fmaf(wt_, vy, ep1);
    float s = vx + vy;
    #pragma unroll
    for (int off=32; off; off>>=1) s += __shfl_xor(s, off);
    const float mean = s*(1.0f/128.0f);
    const float d0 = vx-mean, d1 = vy-mean;
    float q = d0*d0 + d1*d1;
    #pragma unroll
    for (int off=32; off; off>>=1) q += __shfl_xor(q, off);
    const float rstd = rsqrtf(q*(1.0f/128.0f) + 1e-5f);
    u16* o = xn + (size_t)t*EE + e0;
    o[0] = f2bf(d0*rstd*gg.x + bb.x);
    o[1] = f2bf(d1*rstd*gg.y + bb.y);
  }
  sEp[wv][e0]   = ep0;
  sEp[wv][e0+1] = ep1;
  __syncthreads();
  if (tid < 128){
    float s = 0.f;
    #pragma unroll
    for (int v=0; v<8; ++v) s += sEp[v][tid];
    epart[(size_t)blockIdx.x*EE + tid] = s;
  }
}

// =================== merged weight prep ===================
DI void trans32(const float* __restrict__ W, u16* __restrict__ WT,
                int Nn, int Kk, int srcCol0, int n0, int k0, int tid,
                u16 (&tile)[32][33])
{
  const int lr = tid>>5, lc = tid&31;
  #pragma unroll
  for (int i=0;i<4;i++)
    tile[lr+i*8][lc] = f2bf(W[(size_t)(k0+lr+i*8)*Nn + srcCol0 + lc]);
  __syncthreads();
  #pragma unroll
  for (int i=0;i<4;i++)
    WT[(size_t)(n0+lr+i*8)*Kk + k0 + lc] = tile[lc][lr+i*8];
}

// roles (slow serial roles FIRST so their chains overlap the fast blocks):
// [0,119) atomemb | [119,143) fuse_b partials | [143,1295) qkvT |
// [1295,1343) ffnT | [1343,1727) outWT | [1727,1763) qkv bias reorder
__global__ __launch_bounds__(256) void prep_k(
    const float* __restrict__ qkv_W, u16* __restrict__ qkvWT,
    const float* __restrict__ ffn_W, u16* __restrict__ ffnWT,
    const float* __restrict__ out_W, u16* __restrict__ outWT,
    const float* __restrict__ qkv_b, float* __restrict__ rqkv_b,
    const float* __restrict__ atom_table, const float* __restrict__ comp_W,
    const float* __restrict__ comp_b, const float* __restrict__ pdd_b,
    float* __restrict__ atom_emb,
    const float* __restrict__ o_b, float* __restrict__ fbp)
{
  __shared__ u16 tile[32][33];
  __shared__ float sbuf[456];
  int bid = blockIdx.x;
  const int tid = threadIdx.x;
  if (bid < NATOM){
    // atom embedding: atom_emb[a] = comp_b + pdd_b + atom_table[a]@comp_W
    const int a = bid;
    const int e = tid & 127, half = tid >> 7;
    float* sAtom = sbuf;
    float* red   = sbuf + 200;
    for (int d=tid; d<ADIM; d+=256) sAtom[d] = atom_table[a*ADIM+d];
    __syncthreads();
    const int d0 = half*100;
    float b0 = half ? 0.f : (comp_b[e] + pdd_b[e]);
    float b1 = 0.f, b2 = 0.f, b3 = 0.f;
    #pragma unroll 5
    for (int d=d0; d<d0+100; d+=4){
      b0 = fmaf(sAtom[d  ], comp_W[(d  )*EE+e], b0);
      b1 = fmaf(sAtom[d+1], comp_W[(d+1)*EE+e], b1);
      b2 = fmaf(sAtom[d+2], comp_W[(d+2)*EE+e], b2);
      b3 = fmaf(sAtom[d+3], comp_W[(d+3)*EE+e], b3);
    }
    red[tid] = (b0+b1)+(b2+b3);
    __syncthreads();
    if (half==0) atom_emb[a*EE+e] = red[e] + red[128+e];
    return;
  }
  bid -= NATOM;
  if (bid < 24){
    // fuse_b partials: fbp[ly][s][n] = sum_{k in s-slice} o_b[k]*out_W[k][n]
    const int ly = bid >> 3, s = bid & 7;
    const float* ob = o_b + (size_t)ly*EHH;
    const float* oW = out_W + (size_t)ly*EHH*EE;
    const int n = tid & 127, h2 = tid >> 7;
    const int kb = s*128 + h2*64;
    float b0=0.f,b1=0.f,b2=0.f,b3=0.f;
    #pragma unroll 4
    for (int k2=kb; k2<kb+64; k2+=4){
      b0 = fmaf(ob[k2  ], oW[(size_t)(k2  )*EE+n], b0);
      b1 = fmaf(ob[k2+1], oW[(size_t)(k2+1)*EE+n], b1);
      b2 = fmaf(ob[k2+2], oW[(size_t)(k2+2)*EE+n], b2);
      b3 = fmaf(ob[k2+3], oW[(size_t)(k2+3)*EE+n], b3);
    }
    float* red = sbuf;
    red[tid] = (b0+b1)+(b2+b3);
    __syncthreads();
    if (h2==0) fbp[((size_t)ly*8 + s)*EE + n] = red[n] + red[128+n];
    return;
  }
  bid -= 24;
  if (bid < 1152){
    const int xb = bid%96, yb = (bid/96)%4, zb = bid/384;
    const int n0 = xb*32, k0 = yb*32;
    int c0;
    if (n0 < 2048) c0 = (n0>>8)*384 + (n0&255);
    else { const int m0 = n0-2048; c0 = (m0>>7)*384 + 256 + (m0&127); }
    trans32(qkv_W + (size_t)zb*EE*3*EHH, qkvWT + (size_t)zb*3*EHH*EE,
            3*EHH, EE, c0, n0, k0, tid, tile);
    return;
  }
  bid -= 1152;
  if (bid < 48){
    const int xb = bid%4, yb = (bid/4)%4, zb = bid/16;
    trans32(ffn_W + (size_t)zb*EE*EE, ffnWT + (size_t)zb*EE*EE,
            EE, EE, xb*32, xb*32, yb*32, tid, tile);
    return;
  }
  bid -= 48;
  if (bid < 384){
    const int xb = bid%4, yb = (bid/4)%32, zb = bid/128;
    trans32(out_W + (size_t)zb*EHH*EE, outWT + (size_t)zb*EE*EHH,
            EE, EHH, xb*32, xb*32, yb*32, tid, tile);
    return;
  }
  bid -= 384;
  {
    const int l = bid/12;
    const int n = (bid%12)*256 + tid;
    int c;
    if (n < 2048) c = (n>>8)*384 + (n&255);
    else { const int m = n-2048; c = (m>>7)*384 + 256 + (m&127); }
    rqkv_b[(size_t)l*3*EHH + n] = qkv_b[(size_t)l*3*EHH + c];
  }
}

// =================== MFMA bf16 GEMM (layer-batched via z strides) ===================
// A: M x Kk row-major (bf16, or f32 when AF32 — converted in staging).
// BT: Nn x Kk bf16 (pre-transposed B).
// EPI 0: store bf16; 4: bf16 transposed store (no bias);
// EPI 7 (QKV router): col<2048 -> C[row*2048+col]; col>=2048 -> C2 V^T.
template<int EPI, int BM, int BN, int BK, int AF32>
__global__ __launch_bounds__(256) void mgemm_k(
    const void* __restrict__ Av, const u16* __restrict__ BT,
    const float* __restrict__ bias, void* __restrict__ Cv,
    int Nn, int Kk, int Mdim, void* __restrict__ C2,
    size_t sA, size_t sBT, size_t sCb)
{
  const int lz = blockIdx.z;
  BT += (size_t)lz*sBT;
  void* C = (void*)((char*)Cv + (size_t)lz*sCb);

  constexpr int LDK = BK + 8;
  __shared__ u16 As[BM*LDK];
  __shared__ u16 Bs[BN*LDK];
  const int tid = threadIdx.x;
  const int m0 = blockIdx.y*BM, n0 = blockIdx.x*BN;
  constexpr int WMN = (BM>=128)?2:1;
  constexpr int WNN = 4/WMN;
  constexpr int WM = BM/WMN;
  constexpr int WN = BN/WNN;
  constexpr int FM = WM/16, FN = WN/16;
  const int wv = tid>>6, lane = tid&63;
  const int wm = (wv/WNN)*WM;
  const int wn = (wv%WNN)*WN;
  const int lm = lane&15, lq = lane>>4;

  f32x4 acc[FM][FN];
  #pragma unroll
  for (int i=0;i<FM;i++)
    #pragma unroll
    for (int j=0;j<FN;j++) acc[i][j] = (f32x4){0.f,0.f,0.f,0.f};

  constexpr int BCH = BN*BK/8;

  for (int k0=0; k0<Kk; k0+=BK){
    if constexpr (AF32){
      const float* A = (const float*)Av + (size_t)lz*sA;
      #pragma unroll
      for (int c = tid; c < BM*BK/4; c += 256){
        const int r = c/(BK/4), kg = c - r*(BK/4);
        const float4 v = *(const float4*)(A + (size_t)(m0+r)*Kk + k0 + kg*4);
        union { u16 u[4]; unsigned long long ll; } t;
        t.u[0]=f2bf(v.x); t.u[1]=f2bf(v.y); t.u[2]=f2bf(v.z); t.u[3]=f2bf(v.w);
        *(unsigned long long*)&As[r*LDK + kg*4] = t.ll;
      }
    } else {
      const u16* A = (const u16*)Av + (size_t)lz*sA;
      #pragma unroll
      for (int c = tid; c < BM*BK/8; c += 256){
        const int r = c/(BK/8), kg = c - r*(BK/8);
        const float4 v = *(const float4*)(A + (size_t)(m0+r)*Kk + k0 + kg*8);
        *(float4*)&As[r*LDK + kg*8] = v;
      }
    }
    #pragma unroll
    for (int c = tid; c < BCH; c += 256){
      const int r = c/(BK/8), kg = c - r*(BK/8);
      const float4 v = *(const float4*)(BT + (size_t)(n0+r)*Kk + k0 + kg*8);
      *(float4*)&Bs[r*LDK + kg*8] = v;
    }
    __syncthreads();
    #pragma unroll
    for (int kk=0; kk<BK/32; kk++){
      bf16x8 af[FM], bfr[FN];
      #pragma unroll
      for (int i=0;i<FM;i++)
        af[i] = *(const bf16x8*)&As[(wm + i*16 + lm)*LDK + kk*32 + lq*8];
      #pragma unroll
      for (int j=0;j<FN;j++)
        bfr[j] = *(const bf16x8*)&Bs[(wn + j*16 + lm)*LDK + kk*32 + lq*8];
      #pragma unroll
      for (int i=0;i<FM;i++)
        #pragma unroll
        for (int j=0;j<FN;j++)
          acc[i][j] = __builtin_amdgcn_mfma_f32_16x16x32_bf16(af[i], bfr[j], acc[i][j], 0, 0, 0);
    }
    __syncthreads();
  }
  #pragma unroll
  for (int i=0;i<FM;i++){
    #pragma unroll
    for (int j=0;j<FN;j++){
      const int col = n0 + wn + j*16 + lm;
      const float bv = (EPI==4) ? 0.f : bias[col];
      #pragma unroll
      for (int r=0;r<4;r++){
        const int row = m0 + wm + i*16 + lq*4 + r;
        float v = acc[i][j][r] + bv;
        if constexpr (EPI==7){
          if (col < 2048) ((u16*)C)[(size_t)row*2048 + col] = f2bf(v);
          else            ((u16*)C2)[(size_t)(col-2048)*Mdim + row] = f2bf(v);
        } else if constexpr (EPI==4){
          ((u16*)C)[(size_t)col*Mdim + row] = f2bf(v);
        } else {
          ((u16*)C)[(size_t)row*Nn + col] = f2bf(v);
        }
      }
    }
  }
}

// =================== fused proj+LN + ffn+mish + dual-LN (+pool partial) ===================
__global__ __launch_bounds__(256) void projffn_k(
    const u16* __restrict__ vals, const u16* __restrict__ fwT,
    const float* __restrict__ fbp, const float* __restrict__ outb,
    const u16* __restrict__ ffnWT, const float* __restrict__ fnb,
    const float* __restrict__ g1, const float* __restrict__ b1,
    const float* __restrict__ g2, const float* __restrict__ b2,
    float* __restrict__ x_io, u16* __restrict__ xn_io,
    const float* __restrict__ w, float* __restrict__ pp)
{
  constexpr int BM = 32, BK = 128, LDK = BK + 8;
  __shared__ u16 As[BM*LDK];        // proj A tiles; then xn2 (bf16)
  __shared__ u16 Bs[EE*LDK];        // fwT tiles; then ffnWT
  __shared__ float sred[BM*8];
  const int tid = threadIdx.x;
  const int wv = tid>>6, lane = tid&63;
  const int lm = lane&15, lq = lane>>4;
  const int m0 = blockIdx.x*BM;
  const int wn = wv*32;             // 4 waves x 32 cols

  f32x4 acc[2][2];
  #pragma unroll
  for (int i=0;i<2;i++)
    #pragma unroll
    for (int j=0;j<2;j++) acc[i][j] = (f32x4){0.f,0.f,0.f,0.f};

  // ---- phase A: proj GEMM, K=1024 ----
  for (int k0=0; k0<EHH; k0+=BK){
    #pragma unroll
    for (int c = tid; c < BM*BK/8; c += 256){
      const int r = c>>4, kg = c&15;
      *(float4*)&As[r*LDK + kg*8] = *(const float4*)(vals + (size_t)(m0+r)*EHH + k0 + kg*8);
    }
    #pragma unroll
    for (int c = tid; c < EE*BK/8; c += 256){
      const int r = c>>4, kg = c&15;
      *(float4*)&Bs[r*LDK + kg*8] = *(const float4*)(fwT + (size_t)r*EHH + k0 + kg*8);
    }
    __syncthreads();
    #pragma unroll
    for (int kk=0; kk<BK/32; kk++){
      bf16x8 af[2], bfr[2];
      #pragma unroll
      for (int i=0;i<2;i++)
        af[i] = *(const bf16x8*)&As[(i*16 + lm)*LDK + kk*32 + lq*8];
      #pragma unroll
      for (int j=0;j<2;j++)
        bfr[j] = *(const bf16x8*)&Bs[(wn + j*16 + lm)*LDK + kk*32 + lq*8];
      #pragma unroll
      for (int i=0;i<2;i++)
        #pragma unroll
        for (int j=0;j<2;j++)
          acc[i][j] = __builtin_amdgcn_mfma_f32_16x16x32_bf16(af[i], bfr[j], acc[i][j], 0, 0, 0);
    }
    __syncthreads();
  }

  // ---- phase A epilogue: vout = acc + fb + x ; LN stats ----
  float vout[2][2][4];
  float ps[2][4], qs[2][4];
  #pragma unroll
  for (int i=0;i<2;i++)
    #pragma unroll
    for (int r=0;r<4;r++){ ps[i][r]=0.f; qs[i][r]=0.f; }
  #pragma unroll
  for (int i=0;i<2;i++){
    #pragma unroll
    for (int j=0;j<2;j++){
      const int col = wn + j*16 + lm;
      const float bv = outb[col]
        + ((fbp[0*EE+col]+fbp[1*EE+col])+(fbp[2*EE+col]+fbp[3*EE+col]))
        + ((fbp[4*EE+col]+fbp[5*EE+col])+(fbp[6*EE+col]+fbp[7*EE+col]));
      #pragma unroll
      for (int r=0;r<4;r++){
        const int row = m0 + i*16 + lq*4 + r;
        const float v = acc[i][j][r] + bv + x_io[(size_t)row*EE + col];
        vout[i][j][r] = v;
        ps[i][r] += v; qs[i][r] += v*v;
      }
    }
  }
  #pragma unroll
  for (int i=0;i<2;i++)
    #pragma unroll
    for (int r=0;r<4;r++){
      float s = ps[i][r], q = qs[i][r];
      s += __shfl_xor(s,1); s += __shfl_xor(s,2); s += __shfl_xor(s,4); s += __shfl_xor(s,8);
      q += __shfl_xor(q,1); q += __shfl_xor(q,2); q += __shfl_xor(q,4); q += __shfl_xor(q,8);
      if (lm==0){
        const int row = i*16 + lq*4 + r;
        sred[row*4 + wv] = s;
        sred[BM*4 + row*4 + wv] = q;
      }
    }
  __syncthreads();
  // xn2 -> As (bf16), and stage ffnWT -> Bs
  #pragma unroll
  for (int i=0;i<2;i++)
    #pragma unroll
    for (int r=0;r<4;r++){
      const int row = i*16 + lq*4 + r;
      const float s = sred[row*4+0]+sred[row*4+1]+sred[row*4+2]+sred[row*4+3];
      const float q = sred[BM*4+row*4+0]+sred[BM*4+row*4+1]+sred[BM*4+row*4+2]+sred[BM*4+row*4+3];
      const float mean = s*(1.0f/128.0f);
      const float var  = q*(1.0f/128.0f) - mean*mean;
      const float rstd = rsqrtf(var + 1e-5f);
      #pragma unroll
      for (int j=0;j<2;j++){
        const int col = wn + j*16 + lm;
        const float xnv = (vout[i][j][r]-mean)*rstd*g1[col] + b1[col];
        As[row*LDK + col] = f2bf(xnv);
      }
    }
  #pragma unroll
  for (int c = tid; c < EE*EE/8; c += 256){
    const int r = c>>4, kg = c&15;
    *(float4*)&Bs[r*LDK + kg*8] = *(const float4*)(ffnWT + (size_t)r*EE + kg*8);
  }
  __syncthreads();

  // ---- phase B: ffn GEMM, K=128 from LDS ----
  f32x4 fa[2][2];
  #pragma unroll
  for (int i=0;i<2;i++)
    #pragma unroll
    for (int j=0;j<2;j++) fa[i][j] = (f32x4){0.f,0.f,0.f,0.f};
  #pragma unroll
  for (int kk=0; kk<4; kk++){
    bf16x8 af[2], bfr[2];
    #pragma unroll
    for (int i=0;i<2;i++)
      af[i] = *(const bf16x8*)&As[(i*16 + lm)*LDK + kk*32 + lq*8];
    #pragma unroll
    for (int j=0;j<2;j++)
      bfr[j] = *(const bf16x8*)&Bs[(wn + j*16 + lm)*LDK + kk*32 + lq*8];
    #pragma unroll
    for (int i=0;i<2;i++)
      #pragma unroll
      for (int j=0;j<2;j++)
        fa[i][j] = __builtin_amdgcn_mfma_f32_16x16x32_bf16(af[i], bfr[j], fa[i][j], 0, 0, 0);
  }

  // ---- phase C: t = vout + mish(fa + fnb); dual row-LN ----
  float tv[2][2][4];
  #pragma unroll
  for (int i=0;i<2;i++)
    #pragma unroll
    for (int r=0;r<4;r++){ ps[i][r]=0.f; qs[i][r]=0.f; }
  #pragma unroll
  for (int i=0;i<2;i++){
    #pragma unroll
    for (int j=0;j<2;j++){
      const int col = wn + j*16 + lm;
      const float bv = fnb[col];
      #pragma unroll
      for (int r=0;r<4;r++){
        const float v = fa[i][j][r] + bv;
        const float E = __expf(v);
        const float uu = E*E + 2.f*E;
        const float mi = (v > 20.f) ? v : v*(uu/(uu+2.f));
        const float t = vout[i][j][r] + mi;
        tv[i][j][r] = t;
        ps[i][r] += t; qs[i][r] += t*t;
      }
    }
  }
  #pragma unroll
  for (int i=0;i<2;i++)
    #pragma unroll
    for (int r=0;r<4;r++){
      float s = ps[i][r], q = qs[i][r];
      s += __shfl_xor(s,1); s += __shfl_xor(s,2); s += __shfl_xor(s,4); s += __shfl_xor(s,8);
      q += __shfl_xor(q,1); q += __shfl_xor(q,2); q += __shfl_xor(q,4); q += __shfl_xor(q,8);
      if (lm==0){
        const int row = i*16 + lq*4 + r;
        sred[row*4 + wv] = s;
        sred[BM*4 + row*4 + wv] = q;
      }
    }
  __syncthreads();
  float xv[2][2][4];
  float ps2[2][4], qs2[2][4];
  #pragma unroll
  for (int i=0;i<2;i++)
    #pragma unroll
    for (int r=0;r<4;r++){
      const int row = i*16 + lq*4 + r;
      const float s = sred[row*4+0]+sred[row*4+1]+sred[row*4+2]+sred[row*4+3];
      const float q = sred[BM*4+row*4+0]+sred[BM*4+row*4+1]+sred[BM*4+row*4+2]+sred[BM*4+row*4+3];
      const float mean = s*(1.0f/128.0f);
      const float var  = q*(1.0f/128.0f) - mean*mean;
      const float rstd = rsqrtf(var + 1e-5f);
      float s2 = 0.f, q2 = 0.f;
      #pragma unroll
      for (int j=0;j<2;j++){
        const int col = wn + j*16 + lm;
        const float xnv = (tv[i][j][r]-mean)*rstd*g1[col] + b1[col];
        x_io[(size_t)(m0+row)*EE + col] = xnv;
        xv[i][j][r] = xnv;
        s2 += xnv; q2 += xnv*xnv;
      }
      ps2[i][r] = s2; qs2[i][r] = q2;
    }
  // fused pool partial (last layer): pp[block][col] = sum_rows w[row]*x[row][col]
  if (pp){
    float pz[2] = {0.f, 0.f};
    #pragma unroll
    for (int i=0;i<2;i++)
      #pragma unroll
      for (int r=0;r<4;r++){
        const float wr = w[m0 + i*16 + lq*4 + r];
        pz[0] = fmaf(wr, xv[i][0][r], pz[0]);
        pz[1] = fmaf(wr, xv[i][1][r], pz[1]);
      }
    #pragma unroll
    for (int j=0;j<2;j++){
      pz[j] += __shfl_xor(pz[j], 16);
      pz[j] += __shfl_xor(pz[j], 32);
      if (lq==0) pp[(size_t)blockIdx.x*EE + wn + j*16 + lm] = pz[j];
    }
  }
  __syncthreads();
  #pragma unroll
  for (int i=0;i<2;i++)
    #pragma unroll
    for (int r=0;r<4;r++){
      float s = ps2[i][r], q = qs2[i][r];
      s += __shfl_xor(s,1); s += __shfl_xor(s,2); s += __shfl_xor(s,4); s += __shfl_xor(s,8);
      q += __shfl_xor(q,1); q += __shfl_xor(q,2); q += __shfl_xor(q,4); q += __shfl_xor(q,8);
      if (lm==0){
        const int row = i*16 + lq*4 + r;
        sred[row*4 + wv] = s;
        sred[BM*4 + row*4 + wv] = q;
      }
    }
  __syncthreads();
  #pragma unroll
  for (int i=0;i<2;i++)
    #pragma unroll
    for (int r=0;r<4;r++){
      const int row = i*16 + lq*4 + r;
      const float s = sred[row*4+0]+sred[row*4+1]+sred[row*4+2]+sred[row*4+3];
      const float q = sred[BM*4+row*4+0]+sred[BM*4+row*4+1]+sred[BM*4+row*4+2]+sred[BM*4+row*4+3];
      const float mean = s*(1.0f/128.0f);
      const float var  = q*(1.0f/128.0f) - mean*mean;
      const float rstd = rsqrtf(var + 1e-5f);
      #pragma unroll
      for (int j=0;j<2;j++){
        const int col = wn + j*16 + lm;
        const float xnv = (xv[i][j][r]-mean)*rstd*g2[col] + b2[col];
        xn_io[(size_t)(m0+row)*EE + col] = f2bf(xnv);
      }
    }
}

// =================== MFMA flash attention (swapped operands, in-reg P) ===================
// qkc: [tok][h*256 + (q:0..127 | k:128..255)] bf16, tok chunk-local.
// vTc: [h*128+d][tok] bf16 (pre-transposed V), tok chunk-local.
// QK^T computed as mfma(K,Q): lane (lm,lq) holds S[k=16j+4lq+r][q=wv*16+lm]
// -> softmax per-lane (q = lm), P redistributed to PV B-fragments via
// shfl; PV as mfma(Vt,P): oacc[d-local][q]. No Ps LDS, 2 barriers/kt.
__global__ __launch_bounds__(256, 4) void attn_mf_k(
    const u16* __restrict__ qkc, const u16* __restrict__ vTc,
    const float* __restrict__ w, u16* __restrict__ vals_c, int b0)
{
  const int bl = blockIdx.x;   // id%8 -> XCD-local batch groups
  const int h  = blockIdx.y;
  const int qt = blockIdx.z;
  const int tid = threadIdx.x;
  const int wv = tid>>6, lane = tid&63;
  const int lm = lane&15, lq = lane>>4;

  __shared__ u16 Ks[64][136];
  __shared__ u16 Vts[128][72];
  __shared__ float wt[64], qwt[64];

  const size_t rs = 2048;
  const u16* qk = qkc + (size_t)bl*SEQ*rs + (size_t)h*256;
  const u16* vb = vTc + (size_t)h*128*CTOK + (size_t)bl*SEQ;
  const int q0 = qt*64;

  // Q fragments in registers (constant across all kt)
  bf16x8 qf[4];
  #pragma unroll
  for (int kk=0; kk<4; kk++)
    qf[kk] = *(const bf16x8*)(qk + (size_t)(q0 + wv*16 + lm)*rs + kk*32 + lq*8);
  if (tid < 64) qwt[tid] = w[(b0+bl)*SEQ + q0 + tid];
  __syncthreads();
  const float qw = qwt[wv*16 + lm];   // this lane's q-row weight

  f32x4 oacc[8];
  #pragma unroll
  for (int j=0;j<8;j++) oacc[j] = (f32x4){0.f,0.f,0.f,0.f};
  float mrow = -INFINITY, lrow = 0.f;
  const float scale = 0.08838834764831845f;  // 1/sqrt(128)

  const int srcA = ((lq&1)<<1)*16 + lm;   // source lane for P elems 0..3
  const int srcB = srcA + 16;             // source lane for P elems 4..7
  const bool selhi = (lq>>1) != 0;

  for (int kt=0; kt<8; kt++){
    __syncthreads();
    #pragma unroll
    for (int it=0; it<4; it++){
      const int fi = it*256 + tid;
      const int r = fi >> 4, g = fi & 15;
      *(float4*)&Ks[r][g*8] = *(const float4*)(qk + (size_t)(kt*64+r)*rs + 128 + g*8);
    }
    #pragma unroll
    for (int it=0; it<4; it++){
      const int fi = it*256 + tid;
      const int d = fi >> 3, g = fi & 7;
      *(float4*)&Vts[d][g*8] = *(const float4*)(vb + (size_t)d*CTOK + kt*64 + g*8);
    }
    if (tid < 64) wt[tid] = w[(b0+bl)*SEQ + kt*64 + tid];
    __syncthreads();

    // QK^T swapped: sacc[j] = D[k-local][q], A = K rows, B = Q rows
    f32x4 sacc[4];
    #pragma unroll
    for (int j=0;j<4;j++) sacc[j] = (f32x4){0.f,0.f,0.f,0.f};
    __builtin_amdgcn_s_setprio(1);
    #pragma unroll
    for (int kk=0; kk<4; kk++){
      const bf16x8 bfq = qf[kk];
      #pragma unroll
      for (int j=0;j<4;j++){
        const bf16x8 afk = *(const bf16x8*)&Ks[j*16+lm][kk*32+lq*8];
        sacc[j] = __builtin_amdgcn_mfma_f32_16x16x32_bf16(afk, bfq, sacc[j], 0, 0, 0);
      }
    }
    __builtin_amdgcn_s_setprio(0);

    // lane (lm,lq) holds S[k=16j+4lq+r][q=wv*16+lm]
    float s[4][4], wk[4][4];
    const bool qpos = qw > 0.f;
    #pragma unroll
    for (int j=0;j<4;j++)
      #pragma unroll
      for (int r=0;r<4;r++){
        wk[j][r] = wt[j*16 + lq*4 + r];
        const bool keep = qpos && (wk[j][r] > 0.f);
        s[j][r] = keep ? sacc[j][r]*scale : -9.0e15f;
      }
    // per-q (per-lane) max over 16 + cross-lq
    float rm = s[0][0];
    #pragma unroll
    for (int j=0;j<4;j++)
      #pragma unroll
      for (int r=0;r<4;r++) if (j|r) rm = fmaxf(rm, s[j][r]);
    rm = fmaxf(rm, __shfl_xor(rm, 16));
    rm = fmaxf(rm, __shfl_xor(rm, 32));
    const float newm = fmaxf(mrow, rm);
    const float alpha = __expf(mrow - newm);
    float ls = 0.f;
    int pk[4][2];
    #pragma unroll
    for (int j=0;j<4;j++){
      const float p0 = wk[j][0]*__expf(s[j][0]-newm);
      const float p1 = wk[j][1]*__expf(s[j][1]-newm);
      const float p2 = wk[j][2]*__expf(s[j][2]-newm);
      const float p3 = wk[j][3]*__expf(s[j][3]-newm);
      ls += ((p0+p1)+(p2+p3));
      pk[j][0] = (int)f2bf2(p0, p1);
      pk[j][1] = (int)f2bf2(p2, p3);
    }
    ls += __shfl_xor(ls, 16);
    ls += __shfl_xor(ls, 32);
    lrow = lrow*alpha + ls;
    mrow = newm;
    #pragma unroll
    for (int j=0;j<8;j++)
      #pragma unroll
      for (int r=0;r<4;r++) oacc[j][r] *= alpha;

    // PV swapped: B-fragment for lane = P[q=wv*16+lm][k=kk*32+lq*8..+7]
    __builtin_amdgcn_s_setprio(1);
    #pragma unroll
    for (int kk=0; kk<2; kk++){
      const int j0 = 2*kk, j1 = 2*kk+1;
      const int a00 = __shfl(pk[j0][0], srcA), a01 = __shfl(pk[j0][1], srcA);
      const int b00 = __shfl(pk[j0][0], srcB), b01 = __shfl(pk[j0][1], srcB);
      const int a10 = __shfl(pk[j1][0], srcA), a11 = __shfl(pk[j1][1], srcA);
      const int b10 = __shfl(pk[j1][0], srcB), b11 = __shfl(pk[j1][1], srcB);
      union { int i[4]; bf16x8 v; } pf;
      pf.i[0] = selhi ? a10 : a00;
      pf.i[1] = selhi ? a11 : a01;
      pf.i[2] = selhi ? b10 : b00;
      pf.i[3] = selhi ? b11 : b01;
      #pragma unroll
      for (int j=0;j<8;j++){
        const bf16x8 vf = *(const bf16x8*)&Vts[j*16+lm][kk*32+lq*8];
        oacc[j] = __builtin_amdgcn_mfma_f32_16x16x32_bf16(vf, pf.v, oacc[j], 0, 0, 0);
      }
    }
    __builtin_amdgcn_s_setprio(0);
  }
  // output: lane holds O[d=16j+4lq+r][q=wv*16+lm]; pack 4 u16 -> 8B stores
  const float inv = 1.0f / lrow;
  u16* orow = vals_c + ((size_t)(bl*SEQ + q0 + wv*16 + lm))*EHH + h*EE;
  #pragma unroll
  for (int j=0;j<8;j++){
    uint2 pkd;
    pkd.x = f2bf2(oacc[j][0]*inv, oacc[j][1]*inv);
    pkd.y = f2bf2(oacc[j][2]*inv, oacc[j][3]*inv);
    *(uint2*)(orow + j*16 + lq*4) = pkd;
  }
}

// =================== pool phase 2: sum pp + eparts + LN + head ===================
__global__ __launch_bounds__(128) void pool2_k(
    const float* __restrict__ pp, const float* __restrict__ epart,
    const float* __restrict__ g2, const float* __restrict__ b2,
    const float* __restrict__ head_W, const float* __restrict__ head_b,
    float* __restrict__ out)
{
  const int b = blockIdx.x;
  const int e = threadIdx.x;
  __shared__ float red[128];
  float acc = 0.f;
  #pragma unroll
  for (int k=0;k<16;k++) acc += pp[(size_t)(b*16+k)*EE+e];
  #pragma unroll
  for (int k=0;k<16;k++) acc += epart[(size_t)(b*16+k)*EE+e];
  red[e]=acc; __syncthreads();
  for (int s=64;s>0;s>>=1){ if(e<s) red[e]+=red[e+s]; __syncthreads(); }
  const float mean = red[0]*(1.0f/128.0f);
  __syncthreads();
  const float d = acc-mean;
  red[e]=d*d; __syncthreads();
  for (int s=64;s>0;s>>=1){ if(e<s) red[e]+=red[e+s]; __syncthreads(); }
  const float var = red[0]*(1.0f/128.0f);
  const float p = d*rsqrtf(var+1e-5f)*g2[e]+b2[e];
  __syncthreads();
  red[e] = p*head_W[e]; __syncthreads();
  for (int s=64;s>0;s>>=1){ if(e<s) red[e]+=red[e+s]; __syncthreads(); }
  if (e==0) out[b] = red[0] + head_b[0];
}

// =================== launch ===================
extern "C" void kernel_launch(void* const* d_in, const int* in_sizes, int n_in,
                              void* d_out, int out_size, void* d_ws, size_t ws_size,
                              hipStream_t stream)
{
  const float* str_fea   = (const float*)d_in[0];
  const int*   comp_fea  = (const int*)  d_in[1];
  // d_in[2] cell_fea unused by reference
  const float* atom_table= (const float*)d_in[3];
  const float* comp_W    = (const float*)d_in[4];
  const float* comp_b    = (const float*)d_in[5];
  const float* pdd_W     = (const float*)d_in[6];
  const float* pdd_b     = (const float*)d_in[7];
  const float* enc_ln_g  = (const float*)d_in[8];
  const float* enc_ln_b  = (const float*)d_in[9];
  const float* qkv_W     = (const float*)d_in[10];
  const float* qkv_b     = (const float*)d_in[11];
  const float* o_W       = (const float*)d_in[12];
  const float* o_b       = (const float*)d_in[13];
  const float* out_W     = (const float*)d_in[14];
  const float* out_b     = (const float*)d_in[15];
  const float* ffn_W     = (const float*)d_in[16];
  const float* ffn_b     = (const float*)d_in[17];
  const float* ln2_g     = (const float*)d_in[18];
  const float* ln2_b     = (const float*)d_in[19];
  const float* head_W    = (const float*)d_in[20];
  const float* head_b    = (const float*)d_in[21];
  float* out = (float*)d_out;

  // ---- diagnostic 1: input layout model ----
  bool sizes_ok = (n_in >= 22);
  if (sizes_ok){
    sizes_ok = in_sizes[0]==BB*SEQ*KF && in_sizes[1]==NTOK &&
               in_sizes[3]==NATOM*ADIM && in_sizes[4]==ADIM*EE &&
               in_sizes[10]==LL*EE*3*EHH && in_sizes[12]==LL*EHH*EHH &&
               in_sizes[14]==LL*EHH*EE   && in_sizes[16]==LL*EE*EE &&
               in_sizes[20]==EE;
  }
  if (!sizes_ok){
    sentinel_k<<<(out_size+63)/64,64,0,stream>>>(out, 99999.0f, out_size);
    return;
  }

  // ---- workspace layout (~101.6 MB; <= 109.7 MB proven) ----
  char* p = (char*)d_ws;
  size_t off = 0;
  auto alloc = [&](size_t bytes)->void*{
    off = (off + 255) & ~(size_t)255;
    void* r = p + off; off += bytes; return r;
  };
  float* w        = (float*)alloc((size_t)NTOK*4);
  float* x        = (float*)alloc((size_t)NTOK*EE*4);
  u16*   xn_bf    = (u16*)  alloc((size_t)NTOK*EE*2);
  u16*   qkc      = (u16*)  alloc((size_t)CTOK*2048*2);   // 33.6 MB chunk (Q|K)
  u16*   vTc      = (u16*)  alloc((size_t)EHH*CTOK*2);    // 16.8 MB chunk (V^T)
  u16*   vals_bf  = (u16*)  alloc((size_t)NTOK*EHH*2);    // 33.6 MB
  u16*   qkvWT_a  = (u16*)  alloc((size_t)LL*3*EHH*EE*2); // 2.36 MB (reordered)
  float* rqkv_b   = (float*)alloc((size_t)LL*3*EHH*4);    // reordered bias
  u16*   fwT_a    = (u16*)  alloc((size_t)LL*EE*EHH*2);   // 0.79 MB
  u16*   ffnWT_a  = (u16*)  alloc((size_t)LL*EE*EE*2);
  u16*   outWT_a  = (u16*)  alloc((size_t)LL*EE*EHH*2);
  float* fbp_a    = (float*)alloc((size_t)LL*8*EE*4);     // fuse_b partials
  float* atom_emb = (float*)alloc((size_t)NATOM*EE*4);
  float* epart    = (float*)alloc((size_t)(NTOK/32)*EE*4); // embed pooled partials
  float* pp       = (float*)alloc((size_t)(NTOK/32)*EE*4); // projffn pooled partials

  // ---- diagnostic 2: workspace size ----
  if (off > ws_size){
    sentinel_k<<<(out_size+63)/64,64,0,stream>>>(out, 12345.0f, out_size);
    return;
  }

  // ---- hoisted weight prep (merged; serial roles first) ----
  prep_k<<<1763,256,0,stream>>>(qkv_W, qkvWT_a, ffn_W, ffnWT_a,
                                out_W, outWT_a, qkv_b, rqkv_b,
                                atom_table, comp_W, comp_b, pdd_b, atom_emb,
                                o_b, fbp_a);
  // fwT = (o_W @ out_W)^T per layer; A = o_W f32 converted in staging
  mgemm_k<4,32,64,128,1><<<dim3(EE/64, EHH/32, LL),256,0,stream>>>(
      o_W, outWT_a, nullptr, fwT_a, EE, EHH, EHH, nullptr,
      (size_t)EHH*EHH, (size_t)EE*EHH, (size_t)EE*EHH*2);

  embed_ln_k<<<NTOK/32,512,0,stream>>>(str_fea, comp_fea, atom_emb, pdd_W,
                                       enc_ln_g, enc_ln_b, x, w, xn_bf, epart);

  for (int i=0;i<LL;i++){
    const float* gi = enc_ln_g + i*EE;
    const float* bi = enc_ln_b + i*EE;
    for (int cb=0; cb<NCHUNK; cb++){
      const int t0 = cb*CTOK;
      const int b0 = cb*CB;
      // QKV with router epilogue: Q|K -> qkc (stride 2048), V -> vTc (transposed)
      mgemm_k<7,128,128,64,0><<<dim3(3*EHH/128, CTOK/128),256,0,stream>>>(
          xn_bf + (size_t)t0*EE, qkvWT_a + (size_t)i*3*EHH*EE,
          rqkv_b + (size_t)i*3*EHH,
          qkc, 3*EHH, EE, CTOK, vTc, 0, 0, 0);
      attn_mf_k<<<dim3(CB, HH, SEQ/64),256,0,stream>>>(
          qkc, vTc, w, vals_bf + (size_t)t0*EHH, b0);
    }
    // proj + resid + LN + ffn + mish + dual-LN (+pool partial on last layer)
    const float* gn = (i<LL-1) ? enc_ln_g + (i+1)*EE : gi;
    const float* bn = (i<LL-1) ? enc_ln_b + (i+1)*EE : bi;
    projffn_k<<<NTOK/32,256,0,stream>>>(
        vals_bf, fwT_a + (size_t)i*EE*EHH,
        fbp_a + (size_t)i*8*EE, out_b + (size_t)i*EE,
        ffnWT_a + (size_t)i*EE*EE, ffn_b + (size_t)i*EE,
        gi, bi, gn, bn, x, xn_bf,
        w, (i==LL-1) ? pp : nullptr);
  }
  pool2_k<<<BB,128,0,stream>>>(pp, epart, ln2_g, ln2_b, head_W, head_b, out);
}

// Round 12
// 776.766 us; speedup vs baseline: 1.3310x; 1.0234x over previous
//
#include <hip/hip_runtime.h>
#include <math.h>

#define DI __device__ __forceinline__

// ---- problem constants ----
#define BB 32
#define SEQ 512
#define KF 101
#define EE 128
#define HH 8
#define EHH 1024
#define LL 3
#define ADIM 200
#define NATOM 119
#define NTOK (BB*SEQ)   // 16384
#define CB 16           // batches per chunk
#define NCHUNK (BB/CB)  // 2
#define CTOK (CB*SEQ)   // 8192 tokens per chunk

// R26: QKV GEMM was the top cost (52us x6, MfmaUtil 4%, occ 18%):
// epilogue issued 64 scattered 2B stores/thread. Fix: orientation-matched
// packed stores - Q|K region computes mfma SWAPPED (bitwise-identical
// values, R25-validated trick) so lanes hold 4 consecutive cols -> one
// 8B store into qkc; V region keeps original orientation (4 consecutive
// token rows contiguous in vT) -> one 8B store. 64 -> 16 store
// instructions/thread. Block-uniform branch on n0. Rest = R25.

typedef unsigned short u16;
typedef __attribute__((ext_vector_type(8))) short bf16x8;
typedef __attribute__((ext_vector_type(4))) float f32x4;

DI float bf2f(u16 s){ union{unsigned int u; float f;} x; x.u = ((unsigned int)s)<<16; return x.f; }
DI u16 f2bf(float f){
  union{float f; unsigned int u;} x; x.f = f;
  unsigned int u = x.u;
  u += 0x7fffu + ((u>>16)&1u);           // RNE
  return (u16)(u>>16);
}
DI unsigned int f2bf2(float lo, float hi){
  return (unsigned int)f2bf(lo) | ((unsigned int)f2bf(hi)<<16);
}
DI float rdl(float v, int l){
  return __int_as_float(__builtin_amdgcn_readlane(__float_as_int(v), l));
}

// =================== sentinel ===================
__global__ void sentinel_k(float* out, float v, int n){
  int i = blockIdx.x*64 + threadIdx.x;
  if (i < n) out[i] = v;
}

// =================== embed + layer-0 LN (32 tokens/block, 8 waves) ===================
// x = atom_emb[idx] + str[1:]@pdd_W ; xn = LN(x); epart = per-block sum w*x
__global__ __launch_bounds__(512, 4) void embed_ln_k(
    const float* __restrict__ str_fea, const int* __restrict__ comp_fea,
    const float* __restrict__ atom_emb, const float* __restrict__ pdd_W,
    const float* __restrict__ g, const float* __restrict__ bta,
    float* __restrict__ x, float* __restrict__ w,
    u16* __restrict__ xn, float* __restrict__ epart)
{
  const int t0 = blockIdx.x*32;
  const int tid = threadIdx.x;
  const int wv = tid>>6, lane = tid&63;
  __shared__ float2 sPdd[100*64];      // 51.2 KB
  __shared__ float sEp[8][128];        // 4 KB
  for (int k2=tid; k2<100*64; k2+=512)
    sPdd[k2] = ((const float2*)pdd_W)[k2];

  float sv0[4], sv1[4];
  int idx[4];
  #pragma unroll
  for (int tk=0; tk<4; ++tk){
    const int t = t0 + wv*4 + tk;
    const float* sr0 = str_fea + (size_t)t*KF;
    sv0[tk] = sr0[lane];
    sv1[tk] = (lane+64 < KF) ? sr0[lane+64] : 0.f;
    idx[tk] = comp_fea[t];
  }
  __syncthreads();

  float a0[4],a1[4],a2[4],a3[4],c0[4],c1[4],c2[4],c3[4];
  #pragma unroll
  for (int tk=0; tk<4; ++tk){
    const float2 ae = ((const float2*)(atom_emb + (size_t)idx[tk]*EE))[lane];
    a0[tk]=ae.x; a1[tk]=0.f; a2[tk]=0.f; a3[tk]=0.f;
    c0[tk]=ae.y; c1[tk]=0.f; c2[tk]=0.f; c3[tk]=0.f;
  }
  #pragma unroll 5
  for (int j=0; j<100; j+=4){
    const float2 w0 = sPdd[(j  )*64 + lane];
    const float2 w1 = sPdd[(j+1)*64 + lane];
    const float2 w2 = sPdd[(j+2)*64 + lane];
    const float2 w3 = sPdd[(j+3)*64 + lane];
    #pragma unroll
    for (int tk=0; tk<4; ++tk){
      const float s1 = (1+j<64) ? rdl(sv0[tk],1+j) : rdl(sv1[tk],1+j-64);
      const float s2 = (2+j<64) ? rdl(sv0[tk],2+j) : rdl(sv1[tk],2+j-64);
      const float s3 = (3+j<64) ? rdl(sv0[tk],3+j) : rdl(sv1[tk],3+j-64);
      const float s4 = (4+j<64) ? rdl(sv0[tk],4+j) : rdl(sv1[tk],4+j-64);
      a0[tk] = fmaf(s1, w0.x, a0[tk]);  c0[tk] = fmaf(s1, w0.y, c0[tk]);
      a1[tk] = fmaf(s2, w1.x, a1[tk]);  c1[tk] = fmaf(s2, w1.y, c1[tk]);
      a2[tk] = fmaf(s3, w2.x, a2[tk]);  c2[tk] = fmaf(s3, w2.y, c2[tk]);
      a3[tk] = fmaf(s4, w3.x, a3[tk]);  c3[tk] = fmaf(s4, w3.y, c3[tk]);
    }
  }
  const float2 gg = ((const float2*)g)[lane];
  const float2 bb = ((const float2*)bta)[lane];
  const int e0 = lane*2;
  float ep0 = 0.f, ep1 = 0.f;
  #pragma unroll
  for (int tk=0; tk<4; ++tk){
    const int t = t0 + wv*4 + tk;
    const float vx = (a0[tk]+a1[tk])+(a2[tk]+a3[tk]);
    const float vy = (c0[tk]+c1[tk])+(c2[tk]+c3[tk]);
    ((float2*)(x + (size_t)t*EE))[lane] = make_float2(vx, vy);
    const float wt_ = rdl(sv0[tk], 0);
    if (lane==0) w[t] = sv0[tk];
    ep0 = fmaf(wt_, vx, ep0);
    ep1 = fmaf(wt_, vy, ep1);
    float s = vx + vy;
    #pragma unroll
    for (int off=32; off; off>>=1) s += __shfl_xor(s, off);
    const float mean = s*(1.0f/128.0f);
    const float d0 = vx-mean, d1 = vy-mean;
    float q = d0*d0 + d1*d1;
    #pragma unroll
    for (int off=32; off; off>>=1) q += __shfl_xor(q, off);
    const float rstd = rsqrtf(q*(1.0f/128.0f) + 1e-5f);
    u16* o = xn + (size_t)t*EE + e0;
    o[0] = f2bf(d0*rstd*gg.x + bb.x);
    o[1] = f2bf(d1*rstd*gg.y + bb.y);
  }
  sEp[wv][e0]   = ep0;
  sEp[wv][e0+1] = ep1;
  __syncthreads();
  if (tid < 128){
    float s = 0.f;
    #pragma unroll
    for (int v=0; v<8; ++v) s += sEp[v][tid];
    epart[(size_t)blockIdx.x*EE + tid] = s;
  }
}

// =================== merged weight prep ===================
DI void trans32(const float* __restrict__ W, u16* __restrict__ WT,
                int Nn, int Kk, int srcCol0, int n0, int k0, int tid,
                u16 (&tile)[32][33])
{
  const int lr = tid>>5, lc = tid&31;
  #pragma unroll
  for (int i=0;i<4;i++)
    tile[lr+i*8][lc] = f2bf(W[(size_t)(k0+lr+i*8)*Nn + srcCol0 + lc]);
  __syncthreads();
  #pragma unroll
  for (int i=0;i<4;i++)
    WT[(size_t)(n0+lr+i*8)*Kk + k0 + lc] = tile[lc][lr+i*8];
}

// roles (slow serial roles FIRST so their chains overlap the fast blocks):
// [0,119) atomemb | [119,143) fuse_b partials | [143,1295) qkvT |
// [1295,1343) ffnT | [1343,1727) outWT | [1727,1763) qkv bias reorder
__global__ __launch_bounds__(256) void prep_k(
    const float* __restrict__ qkv_W, u16* __restrict__ qkvWT,
    const float* __restrict__ ffn_W, u16* __restrict__ ffnWT,
    const float* __restrict__ out_W, u16* __restrict__ outWT,
    const float* __restrict__ qkv_b, float* __restrict__ rqkv_b,
    const float* __restrict__ atom_table, const float* __restrict__ comp_W,
    const float* __restrict__ comp_b, const float* __restrict__ pdd_b,
    float* __restrict__ atom_emb,
    const float* __restrict__ o_b, float* __restrict__ fbp)
{
  __shared__ u16 tile[32][33];
  __shared__ float sbuf[456];
  int bid = blockIdx.x;
  const int tid = threadIdx.x;
  if (bid < NATOM){
    // atom embedding: atom_emb[a] = comp_b + pdd_b + atom_table[a]@comp_W
    const int a = bid;
    const int e = tid & 127, half = tid >> 7;
    float* sAtom = sbuf;
    float* red   = sbuf + 200;
    for (int d=tid; d<ADIM; d+=256) sAtom[d] = atom_table[a*ADIM+d];
    __syncthreads();
    const int d0 = half*100;
    float b0 = half ? 0.f : (comp_b[e] + pdd_b[e]);
    float b1 = 0.f, b2 = 0.f, b3 = 0.f;
    #pragma unroll 5
    for (int d=d0; d<d0+100; d+=4){
      b0 = fmaf(sAtom[d  ], comp_W[(d  )*EE+e], b0);
      b1 = fmaf(sAtom[d+1], comp_W[(d+1)*EE+e], b1);
      b2 = fmaf(sAtom[d+2], comp_W[(d+2)*EE+e], b2);
      b3 = fmaf(sAtom[d+3], comp_W[(d+3)*EE+e], b3);
    }
    red[tid] = (b0+b1)+(b2+b3);
    __syncthreads();
    if (half==0) atom_emb[a*EE+e] = red[e] + red[128+e];
    return;
  }
  bid -= NATOM;
  if (bid < 24){
    // fuse_b partials: fbp[ly][s][n] = sum_{k in s-slice} o_b[k]*out_W[k][n]
    const int ly = bid >> 3, s = bid & 7;
    const float* ob = o_b + (size_t)ly*EHH;
    const float* oW = out_W + (size_t)ly*EHH*EE;
    const int n = tid & 127, h2 = tid >> 7;
    const int kb = s*128 + h2*64;
    float b0=0.f,b1=0.f,b2=0.f,b3=0.f;
    #pragma unroll 4
    for (int k2=kb; k2<kb+64; k2+=4){
      b0 = fmaf(ob[k2  ], oW[(size_t)(k2  )*EE+n], b0);
      b1 = fmaf(ob[k2+1], oW[(size_t)(k2+1)*EE+n], b1);
      b2 = fmaf(ob[k2+2], oW[(size_t)(k2+2)*EE+n], b2);
      b3 = fmaf(ob[k2+3], oW[(size_t)(k2+3)*EE+n], b3);
    }
    float* red = sbuf;
    red[tid] = (b0+b1)+(b2+b3);
    __syncthreads();
    if (h2==0) fbp[((size_t)ly*8 + s)*EE + n] = red[n] + red[128+n];
    return;
  }
  bid -= 24;
  if (bid < 1152){
    const int xb = bid%96, yb = (bid/96)%4, zb = bid/384;
    const int n0 = xb*32, k0 = yb*32;
    int c0;
    if (n0 < 2048) c0 = (n0>>8)*384 + (n0&255);
    else { const int m0 = n0-2048; c0 = (m0>>7)*384 + 256 + (m0&127); }
    trans32(qkv_W + (size_t)zb*EE*3*EHH, qkvWT + (size_t)zb*3*EHH*EE,
            3*EHH, EE, c0, n0, k0, tid, tile);
    return;
  }
  bid -= 1152;
  if (bid < 48){
    const int xb = bid%4, yb = (bid/4)%4, zb = bid/16;
    trans32(ffn_W + (size_t)zb*EE*EE, ffnWT + (size_t)zb*EE*EE,
            EE, EE, xb*32, xb*32, yb*32, tid, tile);
    return;
  }
  bid -= 48;
  if (bid < 384){
    const int xb = bid%4, yb = (bid/4)%32, zb = bid/128;
    trans32(out_W + (size_t)zb*EHH*EE, outWT + (size_t)zb*EE*EHH,
            EE, EHH, xb*32, xb*32, yb*32, tid, tile);
    return;
  }
  bid -= 384;
  {
    const int l = bid/12;
    const int n = (bid%12)*256 + tid;
    int c;
    if (n < 2048) c = (n>>8)*384 + (n&255);
    else { const int m = n-2048; c = (m>>7)*384 + 256 + (m&127); }
    rqkv_b[(size_t)l*3*EHH + n] = qkv_b[(size_t)l*3*EHH + c];
  }
}

// =================== MFMA bf16 GEMM (layer-batched via z strides) ===================
// A: M x Kk row-major (bf16, or f32 when AF32 — converted in staging).
// BT: Nn x Kk bf16 (pre-transposed B).
// EPI 4: bf16 transposed store (no bias);
// EPI 7 (QKV router): n0<2048 -> SWAPPED mfma (lane holds 4 consecutive
//   cols; bitwise-identical values) + packed 8B stores into C;
//   n0>=2048 -> original orientation (4 consecutive token rows) + packed
//   8B stores into C2 (V^T rows).
template<int EPI, int BM, int BN, int BK, int AF32>
__global__ __launch_bounds__(256) void mgemm_k(
    const void* __restrict__ Av, const u16* __restrict__ BT,
    const float* __restrict__ bias, void* __restrict__ Cv,
    int Nn, int Kk, int Mdim, void* __restrict__ C2,
    size_t sA, size_t sBT, size_t sCb)
{
  const int lz = blockIdx.z;
  BT += (size_t)lz*sBT;
  void* C = (void*)((char*)Cv + (size_t)lz*sCb);

  constexpr int LDK = BK + 8;
  __shared__ u16 As[BM*LDK];
  __shared__ u16 Bs[BN*LDK];
  const int tid = threadIdx.x;
  const int m0 = blockIdx.y*BM, n0 = blockIdx.x*BN;
  constexpr int WMN = (BM>=128)?2:1;
  constexpr int WNN = 4/WMN;
  constexpr int WM = BM/WMN;
  constexpr int WN = BN/WNN;
  constexpr int FM = WM/16, FN = WN/16;
  const int wv = tid>>6, lane = tid&63;
  const int wm = (wv/WNN)*WM;
  const int wn = (wv%WNN)*WN;
  const int lm = lane&15, lq = lane>>4;
  const bool swp = (EPI==7) && (n0 < 2048);

  f32x4 acc[FM][FN];
  #pragma unroll
  for (int i=0;i<FM;i++)
    #pragma unroll
    for (int j=0;j<FN;j++) acc[i][j] = (f32x4){0.f,0.f,0.f,0.f};

  constexpr int BCH = BN*BK/8;

  for (int k0=0; k0<Kk; k0+=BK){
    if constexpr (AF32){
      const float* A = (const float*)Av + (size_t)lz*sA;
      #pragma unroll
      for (int c = tid; c < BM*BK/4; c += 256){
        const int r = c/(BK/4), kg = c - r*(BK/4);
        const float4 v = *(const float4*)(A + (size_t)(m0+r)*Kk + k0 + kg*4);
        union { u16 u[4]; unsigned long long ll; } t;
        t.u[0]=f2bf(v.x); t.u[1]=f2bf(v.y); t.u[2]=f2bf(v.z); t.u[3]=f2bf(v.w);
        *(unsigned long long*)&As[r*LDK + kg*4] = t.ll;
      }
    } else {
      const u16* A = (const u16*)Av + (size_t)lz*sA;
      #pragma unroll
      for (int c = tid; c < BM*BK/8; c += 256){
        const int r = c/(BK/8), kg = c - r*(BK/8);
        const float4 v = *(const float4*)(A + (size_t)(m0+r)*Kk + k0 + kg*8);
        *(float4*)&As[r*LDK + kg*8] = v;
      }
    }
    #pragma unroll
    for (int c = tid; c < BCH; c += 256){
      const int r = c/(BK/8), kg = c - r*(BK/8);
      const float4 v = *(const float4*)(BT + (size_t)(n0+r)*Kk + k0 + kg*8);
      *(float4*)&Bs[r*LDK + kg*8] = v;
    }
    __syncthreads();
    #pragma unroll
    for (int kk=0; kk<BK/32; kk++){
      bf16x8 af[FM], bfr[FN];
      #pragma unroll
      for (int i=0;i<FM;i++)
        af[i] = *(const bf16x8*)&As[(wm + i*16 + lm)*LDK + kk*32 + lq*8];
      #pragma unroll
      for (int j=0;j<FN;j++)
        bfr[j] = *(const bf16x8*)&Bs[(wn + j*16 + lm)*LDK + kk*32 + lq*8];
      if (swp){
        #pragma unroll
        for (int i=0;i<FM;i++)
          #pragma unroll
          for (int j=0;j<FN;j++)
            acc[i][j] = __builtin_amdgcn_mfma_f32_16x16x32_bf16(bfr[j], af[i], acc[i][j], 0, 0, 0);
      } else {
        #pragma unroll
        for (int i=0;i<FM;i++)
          #pragma unroll
          for (int j=0;j<FN;j++)
            acc[i][j] = __builtin_amdgcn_mfma_f32_16x16x32_bf16(af[i], bfr[j], acc[i][j], 0, 0, 0);
      }
    }
    __syncthreads();
  }
  if constexpr (EPI==7){
    if (swp){
      // lane holds C[m = m0+wm+i*16+lm][cols colb..colb+3]
      #pragma unroll
      for (int i=0;i<FM;i++){
        const int m = m0 + wm + i*16 + lm;
        #pragma unroll
        for (int j=0;j<FN;j++){
          const int colb = n0 + wn + j*16 + lq*4;
          const float4 bv4 = *(const float4*)&bias[colb];
          uint2 pkd;
          pkd.x = f2bf2(acc[i][j][0]+bv4.x, acc[i][j][1]+bv4.y);
          pkd.y = f2bf2(acc[i][j][2]+bv4.z, acc[i][j][3]+bv4.w);
          *(uint2*)((u16*)C + (size_t)m*2048 + colb) = pkd;
        }
      }
    } else {
      // lane holds C[rows row0..row0+3][col] -> contiguous in vT[col-2048][tok]
      #pragma unroll
      for (int i=0;i<FM;i++){
        const int row0 = m0 + wm + i*16 + lq*4;
        #pragma unroll
        for (int j=0;j<FN;j++){
          const int col = n0 + wn + j*16 + lm;
          const float bv = bias[col];
          uint2 pkd;
          pkd.x = f2bf2(acc[i][j][0]+bv, acc[i][j][1]+bv);
          pkd.y = f2bf2(acc[i][j][2]+bv, acc[i][j][3]+bv);
          *(uint2*)((u16*)C2 + (size_t)(col-2048)*Mdim + row0) = pkd;
        }
      }
    }
  } else {
    #pragma unroll
    for (int i=0;i<FM;i++){
      #pragma unroll
      for (int j=0;j<FN;j++){
        const int col = n0 + wn + j*16 + lm;
        const float bv = (EPI==4) ? 0.f : bias[col];
        #pragma unroll
        for (int r=0;r<4;r++){
          const int row = m0 + wm + i*16 + lq*4 + r;
          float v = acc[i][j][r] + bv;
          if constexpr (EPI==4){
            ((u16*)C)[(size_t)col*Mdim + row] = f2bf(v);
          } else {
            ((u16*)C)[(size_t)row*Nn + col] = f2bf(v);
          }
        }
      }
    }
  }
}

// =================== fused proj+LN + ffn+mish + dual-LN (+pool partial) ===================
__global__ __launch_bounds__(256) void projffn_k(
    const u16* __restrict__ vals, const u16* __restrict__ fwT,
    const float* __restrict__ fbp, const float* __restrict__ outb,
    const u16* __restrict__ ffnWT, const float* __restrict__ fnb,
    const float* __restrict__ g1, const float* __restrict__ b1,
    const float* __restrict__ g2, const float* __restrict__ b2,
    float* __restrict__ x_io, u16* __restrict__ xn_io,
    const float* __restrict__ w, float* __restrict__ pp)
{
  constexpr int BM = 32, BK = 128, LDK = BK + 8;
  __shared__ u16 As[BM*LDK];        // proj A tiles; then xn2 (bf16)
  __shared__ u16 Bs[EE*LDK];        // fwT tiles; then ffnWT
  __shared__ float sred[BM*8];
  const int tid = threadIdx.x;
  const int wv = tid>>6, lane = tid&63;
  const int lm = lane&15, lq = lane>>4;
  const int m0 = blockIdx.x*BM;
  const int wn = wv*32;             // 4 waves x 32 cols

  f32x4 acc[2][2];
  #pragma unroll
  for (int i=0;i<2;i++)
    #pragma unroll
    for (int j=0;j<2;j++) acc[i][j] = (f32x4){0.f,0.f,0.f,0.f};

  // ---- phase A: proj GEMM, K=1024 ----
  for (int k0=0; k0<EHH; k0+=BK){
    #pragma unroll
    for (int c = tid; c < BM*BK/8; c += 256){
      const int r = c>>4, kg = c&15;
      *(float4*)&As[r*LDK + kg*8] = *(const float4*)(vals + (size_t)(m0+r)*EHH + k0 + kg*8);
    }
    #pragma unroll
    for (int c = tid; c < EE*BK/8; c += 256){
      const int r = c>>4, kg = c&15;
      *(float4*)&Bs[r*LDK + kg*8] = *(const float4*)(fwT + (size_t)r*EHH + k0 + kg*8);
    }
    __syncthreads();
    #pragma unroll
    for (int kk=0; kk<BK/32; kk++){
      bf16x8 af[2], bfr[2];
      #pragma unroll
      for (int i=0;i<2;i++)
        af[i] = *(const bf16x8*)&As[(i*16 + lm)*LDK + kk*32 + lq*8];
      #pragma unroll
      for (int j=0;j<2;j++)
        bfr[j] = *(const bf16x8*)&Bs[(wn + j*16 + lm)*LDK + kk*32 + lq*8];
      #pragma unroll
      for (int i=0;i<2;i++)
        #pragma unroll
        for (int j=0;j<2;j++)
          acc[i][j] = __builtin_amdgcn_mfma_f32_16x16x32_bf16(af[i], bfr[j], acc[i][j], 0, 0, 0);
    }
    __syncthreads();
  }

  // ---- phase A epilogue: vout = acc + fb + x ; LN stats ----
  float vout[2][2][4];
  float ps[2][4], qs[2][4];
  #pragma unroll
  for (int i=0;i<2;i++)
    #pragma unroll
    for (int r=0;r<4;r++){ ps[i][r]=0.f; qs[i][r]=0.f; }
  #pragma unroll
  for (int i=0;i<2;i++){
    #pragma unroll
    for (int j=0;j<2;j++){
      const int col = wn + j*16 + lm;
      const float bv = outb[col]
        + ((fbp[0*EE+col]+fbp[1*EE+col])+(fbp[2*EE+col]+fbp[3*EE+col]))
        + ((fbp[4*EE+col]+fbp[5*EE+col])+(fbp[6*EE+col]+fbp[7*EE+col]));
      #pragma unroll
      for (int r=0;r<4;r++){
        const int row = m0 + i*16 + lq*4 + r;
        const float v = acc[i][j][r] + bv + x_io[(size_t)row*EE + col];
        vout[i][j][r] = v;
        ps[i][r] += v; qs[i][r] += v*v;
      }
    }
  }
  #pragma unroll
  for (int i=0;i<2;i++)
    #pragma unroll
    for (int r=0;r<4;r++){
      float s = ps[i][r], q = qs[i][r];
      s += __shfl_xor(s,1); s += __shfl_xor(s,2); s += __shfl_xor(s,4); s += __shfl_xor(s,8);
      q += __shfl_xor(q,1); q += __shfl_xor(q,2); q += __shfl_xor(q,4); q += __shfl_xor(q,8);
      if (lm==0){
        const int row = i*16 + lq*4 + r;
        sred[row*4 + wv] = s;
        sred[BM*4 + row*4 + wv] = q;
      }
    }
  __syncthreads();
  // xn2 -> As (bf16), and stage ffnWT -> Bs
  #pragma unroll
  for (int i=0;i<2;i++)
    #pragma unroll
    for (int r=0;r<4;r++){
      const int row = i*16 + lq*4 + r;
      const float s = sred[row*4+0]+sred[row*4+1]+sred[row*4+2]+sred[row*4+3];
      const float q = sred[BM*4+row*4+0]+sred[BM*4+row*4+1]+sred[BM*4+row*4+2]+sred[BM*4+row*4+3];
      const float mean = s*(1.0f/128.0f);
      const float var  = q*(1.0f/128.0f) - mean*mean;
      const float rstd = rsqrtf(var + 1e-5f);
      #pragma unroll
      for (int j=0;j<2;j++){
        const int col = wn + j*16 + lm;
        const float xnv = (vout[i][j][r]-mean)*rstd*g1[col] + b1[col];
        As[row*LDK + col] = f2bf(xnv);
      }
    }
  #pragma unroll
  for (int c = tid; c < EE*EE/8; c += 256){
    const int r = c>>4, kg = c&15;
    *(float4*)&Bs[r*LDK + kg*8] = *(const float4*)(ffnWT + (size_t)r*EE + kg*8);
  }
  __syncthreads();

  // ---- phase B: ffn GEMM, K=128 from LDS ----
  f32x4 fa[2][2];
  #pragma unroll
  for (int i=0;i<2;i++)
    #pragma unroll
    for (int j=0;j<2;j++) fa[i][j] = (f32x4){0.f,0.f,0.f,0.f};
  #pragma unroll
  for (int kk=0; kk<4; kk++){
    bf16x8 af[2], bfr[2];
    #pragma unroll
    for (int i=0;i<2;i++)
      af[i] = *(const bf16x8*)&As[(i*16 + lm)*LDK + kk*32 + lq*8];
    #pragma unroll
    for (int j=0;j<2;j++)
      bfr[j] = *(const bf16x8*)&Bs[(wn + j*16 + lm)*LDK + kk*32 + lq*8];
    #pragma unroll
    for (int i=0;i<2;i++)
      #pragma unroll
      for (int j=0;j<2;j++)
        fa[i][j] = __builtin_amdgcn_mfma_f32_16x16x32_bf16(af[i], bfr[j], fa[i][j], 0, 0, 0);
  }

  // ---- phase C: t = vout + mish(fa + fnb); dual row-LN ----
  float tv[2][2][4];
  #pragma unroll
  for (int i=0;i<2;i++)
    #pragma unroll
    for (int r=0;r<4;r++){ ps[i][r]=0.f; qs[i][r]=0.f; }
  #pragma unroll
  for (int i=0;i<2;i++){
    #pragma unroll
    for (int j=0;j<2;j++){
      const int col = wn + j*16 + lm;
      const float bv = fnb[col];
      #pragma unroll
      for (int r=0;r<4;r++){
        const float v = fa[i][j][r] + bv;
        const float E = __expf(v);
        const float uu = E*E + 2.f*E;
        const float mi = (v > 20.f) ? v : v*(uu/(uu+2.f));
        const float t = vout[i][j][r] + mi;
        tv[i][j][r] = t;
        ps[i][r] += t; qs[i][r] += t*t;
      }
    }
  }
  #pragma unroll
  for (int i=0;i<2;i++)
    #pragma unroll
    for (int r=0;r<4;r++){
      float s = ps[i][r], q = qs[i][r];
      s += __shfl_xor(s,1); s += __shfl_xor(s,2); s += __shfl_xor(s,4); s += __shfl_xor(s,8);
      q += __shfl_xor(q,1); q += __shfl_xor(q,2); q += __shfl_xor(q,4); q += __shfl_xor(q,8);
      if (lm==0){
        const int row = i*16 + lq*4 + r;
        sred[row*4 + wv] = s;
        sred[BM*4 + row*4 + wv] = q;
      }
    }
  __syncthreads();
  float xv[2][2][4];
  float ps2[2][4], qs2[2][4];
  #pragma unroll
  for (int i=0;i<2;i++)
    #pragma unroll
    for (int r=0;r<4;r++){
      const int row = i*16 + lq*4 + r;
      const float s = sred[row*4+0]+sred[row*4+1]+sred[row*4+2]+sred[row*4+3];
      const float q = sred[BM*4+row*4+0]+sred[BM*4+row*4+1]+sred[BM*4+row*4+2]+sred[BM*4+row*4+3];
      const float mean = s*(1.0f/128.0f);
      const float var  = q*(1.0f/128.0f) - mean*mean;
      const float rstd = rsqrtf(var + 1e-5f);
      float s2 = 0.f, q2 = 0.f;
      #pragma unroll
      for (int j=0;j<2;j++){
        const int col = wn + j*16 + lm;
        const float xnv = (tv[i][j][r]-mean)*rstd*g1[col] + b1[col];
        x_io[(size_t)(m0+row)*EE + col] = xnv;
        xv[i][j][r] = xnv;
        s2 += xnv; q2 += xnv*xnv;
      }
      ps2[i][r] = s2; qs2[i][r] = q2;
    }
  // fused pool partial (last layer): pp[block][col] = sum_rows w[row]*x[row][col]
  if (pp){
    float pz[2] = {0.f, 0.f};
    #pragma unroll
    for (int i=0;i<2;i++)
      #pragma unroll
      for (int r=0;r<4;r++){
        const float wr = w[m0 + i*16 + lq*4 + r];
        pz[0] = fmaf(wr, xv[i][0][r], pz[0]);
        pz[1] = fmaf(wr, xv[i][1][r], pz[1]);
      }
    #pragma unroll
    for (int j=0;j<2;j++){
      pz[j] += __shfl_xor(pz[j], 16);
      pz[j] += __shfl_xor(pz[j], 32);
      if (lq==0) pp[(size_t)blockIdx.x*EE + wn + j*16 + lm] = pz[j];
    }
  }
  __syncthreads();
  #pragma unroll
  for (int i=0;i<2;i++)
    #pragma unroll
    for (int r=0;r<4;r++){
      float s = ps2[i][r], q = qs2[i][r];
      s += __shfl_xor(s,1); s += __shfl_xor(s,2); s += __shfl_xor(s,4); s += __shfl_xor(s,8);
      q += __shfl_xor(q,1); q += __shfl_xor(q,2); q += __shfl_xor(q,4); q += __shfl_xor(q,8);
      if (lm==0){
        const int row = i*16 + lq*4 + r;
        sred[row*4 + wv] = s;
        sred[BM*4 + row*4 + wv] = q;
      }
    }
  __syncthreads();
  #pragma unroll
  for (int i=0;i<2;i++)
    #pragma unroll
    for (int r=0;r<4;r++){
      const int row = i*16 + lq*4 + r;
      const float s = sred[row*4+0]+sred[row*4+1]+sred[row*4+2]+sred[row*4+3];
      const float q = sred[BM*4+row*4+0]+sred[BM*4+row*4+1]+sred[BM*4+row*4+2]+sred[BM*4+row*4+3];
      const float mean = s*(1.0f/128.0f);
      const float var  = q*(1.0f/128.0f) - mean*mean;
      const float rstd = rsqrtf(var + 1e-5f);
      #pragma unroll
      for (int j=0;j<2;j++){
        const int col = wn + j*16 + lm;
        const float xnv = (xv[i][j][r]-mean)*rstd*g2[col] + b2[col];
        xn_io[(size_t)(m0+row)*EE + col] = f2bf(xnv);
      }
    }
}

// =================== MFMA flash attention (swapped operands, in-reg P) ===================
// qkc: [tok][h*256 + (q:0..127 | k:128..255)] bf16, tok chunk-local.
// vTc: [h*128+d][tok] bf16 (pre-transposed V), tok chunk-local.
__global__ __launch_bounds__(256, 4) void attn_mf_k(
    const u16* __restrict__ qkc, const u16* __restrict__ vTc,
    const float* __restrict__ w, u16* __restrict__ vals_c, int b0)
{
  const int bl = blockIdx.x;   // id%8 -> XCD-local batch groups
  const int h  = blockIdx.y;
  const int qt = blockIdx.z;
  const int tid = threadIdx.x;
  const int wv = tid>>6, lane = tid&63;
  const int lm = lane&15, lq = lane>>4;

  __shared__ u16 Ks[64][136];
  __shared__ u16 Vts[128][72];
  __shared__ float wt[64], qwt[64];

  const size_t rs = 2048;
  const u16* qk = qkc + (size_t)bl*SEQ*rs + (size_t)h*256;
  const u16* vb = vTc + (size_t)h*128*CTOK + (size_t)bl*SEQ;
  const int q0 = qt*64;

  // Q fragments in registers (constant across all kt)
  bf16x8 qf[4];
  #pragma unroll
  for (int kk=0; kk<4; kk++)
    qf[kk] = *(const bf16x8*)(qk + (size_t)(q0 + wv*16 + lm)*rs + kk*32 + lq*8);
  if (tid < 64) qwt[tid] = w[(b0+bl)*SEQ + q0 + tid];
  __syncthreads();
  const float qw = qwt[wv*16 + lm];   // this lane's q-row weight

  f32x4 oacc[8];
  #pragma unroll
  for (int j=0;j<8;j++) oacc[j] = (f32x4){0.f,0.f,0.f,0.f};
  float mrow = -INFINITY, lrow = 0.f;
  const float scale = 0.08838834764831845f;  // 1/sqrt(128)

  const int srcA = ((lq&1)<<1)*16 + lm;   // source lane for P elems 0..3
  const int srcB = srcA + 16;             // source lane for P elems 4..7
  const bool selhi = (lq>>1) != 0;

  for (int kt=0; kt<8; kt++){
    __syncthreads();
    #pragma unroll
    for (int it=0; it<4; it++){
      const int fi = it*256 + tid;
      const int r = fi >> 4, g = fi & 15;
      *(float4*)&Ks[r][g*8] = *(const float4*)(qk + (size_t)(kt*64+r)*rs + 128 + g*8);
    }
    #pragma unroll
    for (int it=0; it<4; it++){
      const int fi = it*256 + tid;
      const int d = fi >> 3, g = fi & 7;
      *(float4*)&Vts[d][g*8] = *(const float4*)(vb + (size_t)d*CTOK + kt*64 + g*8);
    }
    if (tid < 64) wt[tid] = w[(b0+bl)*SEQ + kt*64 + tid];
    __syncthreads();

    // QK^T swapped: sacc[j] = D[k-local][q], A = K rows, B = Q rows
    f32x4 sacc[4];
    #pragma unroll
    for (int j=0;j<4;j++) sacc[j] = (f32x4){0.f,0.f,0.f,0.f};
    __builtin_amdgcn_s_setprio(1);
    #pragma unroll
    for (int kk=0; kk<4; kk++){
      const bf16x8 bfq = qf[kk];
      #pragma unroll
      for (int j=0;j<4;j++){
        const bf16x8 afk = *(const bf16x8*)&Ks[j*16+lm][kk*32+lq*8];
        sacc[j] = __builtin_amdgcn_mfma_f32_16x16x32_bf16(afk, bfq, sacc[j], 0, 0, 0);
      }
    }
    __builtin_amdgcn_s_setprio(0);

    // lane (lm,lq) holds S[k=16j+4lq+r][q=wv*16+lm]
    float s[4][4], wk[4][4];
    const bool qpos = qw > 0.f;
    #pragma unroll
    for (int j=0;j<4;j++)
      #pragma unroll
      for (int r=0;r<4;r++){
        wk[j][r] = wt[j*16 + lq*4 + r];
        const bool keep = qpos && (wk[j][r] > 0.f);
        s[j][r] = keep ? sacc[j][r]*scale : -9.0e15f;
      }
    // per-q (per-lane) max over 16 + cross-lq
    float rm = s[0][0];
    #pragma unroll
    for (int j=0;j<4;j++)
      #pragma unroll
      for (int r=0;r<4;r++) if (j|r) rm = fmaxf(rm, s[j][r]);
    rm = fmaxf(rm, __shfl_xor(rm, 16));
    rm = fmaxf(rm, __shfl_xor(rm, 32));
    const float newm = fmaxf(mrow, rm);
    const float alpha = __expf(mrow - newm);
    float ls = 0.f;
    int pk[4][2];
    #pragma unroll
    for (int j=0;j<4;j++){
      const float p0 = wk[j][0]*__expf(s[j][0]-newm);
      const float p1 = wk[j][1]*__expf(s[j][1]-newm);
      const float p2 = wk[j][2]*__expf(s[j][2]-newm);
      const float p3 = wk[j][3]*__expf(s[j][3]-newm);
      ls += ((p0+p1)+(p2+p3));
      pk[j][0] = (int)f2bf2(p0, p1);
      pk[j][1] = (int)f2bf2(p2, p3);
    }
    ls += __shfl_xor(ls, 16);
    ls += __shfl_xor(ls, 32);
    lrow = lrow*alpha + ls;
    mrow = newm;
    #pragma unroll
    for (int j=0;j<8;j++)
      #pragma unroll
      for (int r=0;r<4;r++) oacc[j][r] *= alpha;

    // PV swapped: B-fragment for lane = P[q=wv*16+lm][k=kk*32+lq*8..+7]
    __builtin_amdgcn_s_setprio(1);
    #pragma unroll
    for (int kk=0; kk<2; kk++){
      const int j0 = 2*kk, j1 = 2*kk+1;
      const int a00 = __shfl(pk[j0][0], srcA), a01 = __shfl(pk[j0][1], srcA);
      const int b00 = __shfl(pk[j0][0], srcB), b01 = __shfl(pk[j0][1], srcB);
      const int a10 = __shfl(pk[j1][0], srcA), a11 = __shfl(pk[j1][1], srcA);
      const int b10 = __shfl(pk[j1][0], srcB), b11 = __shfl(pk[j1][1], srcB);
      union { int i[4]; bf16x8 v; } pf;
      pf.i[0] = selhi ? a10 : a00;
      pf.i[1] = selhi ? a11 : a01;
      pf.i[2] = selhi ? b10 : b00;
      pf.i[3] = selhi ? b11 : b01;
      #pragma unroll
      for (int j=0;j<8;j++){
        const bf16x8 vf = *(const bf16x8*)&Vts[j*16+lm][kk*32+lq*8];
        oacc[j] = __builtin_amdgcn_mfma_f32_16x16x32_bf16(vf, pf.v, oacc[j], 0, 0, 0);
      }
    }
    __builtin_amdgcn_s_setprio(0);
  }
  // output: lane holds O[d=16j+4lq+r][q=wv*16+lm]; pack 4 u16 -> 8B stores
  const float inv = 1.0f / lrow;
  u16* orow = vals_c + ((size_t)(bl*SEQ + q0 + wv*16 + lm))*EHH + h*EE;
  #pragma unroll
  for (int j=0;j<8;j++){
    uint2 pkd;
    pkd.x = f2bf2(oacc[j][0]*inv, oacc[j][1]*inv);
    pkd.y = f2bf2(oacc[j][2]*inv, oacc[j][3]*inv);
    *(uint2*)(orow + j*16 + lq*4) = pkd;
  }
}

// =================== pool phase 2: sum pp + eparts + LN + head ===================
__global__ __launch_bounds__(128) void pool2_k(
    const float* __restrict__ pp, const float* __restrict__ epart,
    const float* __restrict__ g2, const float* __restrict__ b2,
    const float* __restrict__ head_W, const float* __restrict__ head_b,
    float* __restrict__ out)
{
  const int b = blockIdx.x;
  const int e = threadIdx.x;
  __shared__ float red[128];
  float acc = 0.f;
  #pragma unroll
  for (int k=0;k<16;k++) acc += pp[(size_t)(b*16+k)*EE+e];
  #pragma unroll
  for (int k=0;k<16;k++) acc += epart[(size_t)(b*16+k)*EE+e];
  red[e]=acc; __syncthreads();
  for (int s=64;s>0;s>>=1){ if(e<s) red[e]+=red[e+s]; __syncthreads(); }
  const float mean = red[0]*(1.0f/128.0f);
  __syncthreads();
  const float d = acc-mean;
  red[e]=d*d; __syncthreads();
  for (int s=64;s>0;s>>=1){ if(e<s) red[e]+=red[e+s]; __syncthreads(); }
  const float var = red[0]*(1.0f/128.0f);
  const float p = d*rsqrtf(var+1e-5f)*g2[e]+b2[e];
  __syncthreads();
  red[e] = p*head_W[e]; __syncthreads();
  for (int s=64;s>0;s>>=1){ if(e<s) red[e]+=red[e+s]; __syncthreads(); }
  if (e==0) out[b] = red[0] + head_b[0];
}

// =================== launch ===================
extern "C" void kernel_launch(void* const* d_in, const int* in_sizes, int n_in,
                              void* d_out, int out_size, void* d_ws, size_t ws_size,
                              hipStream_t stream)
{
  const float* str_fea   = (const float*)d_in[0];
  const int*   comp_fea  = (const int*)  d_in[1];
  // d_in[2] cell_fea unused by reference
  const float* atom_table= (const float*)d_in[3];
  const float* comp_W    = (const float*)d_in[4];
  const float* comp_b    = (const float*)d_in[5];
  const float* pdd_W     = (const float*)d_in[6];
  const float* pdd_b     = (const float*)d_in[7];
  const float* enc_ln_g  = (const float*)d_in[8];
  const float* enc_ln_b  = (const float*)d_in[9];
  const float* qkv_W     = (const float*)d_in[10];
  const float* qkv_b     = (const float*)d_in[11];
  const float* o_W       = (const float*)d_in[12];
  const float* o_b       = (const float*)d_in[13];
  const float* out_W     = (const float*)d_in[14];
  const float* out_b     = (const float*)d_in[15];
  const float* ffn_W     = (const float*)d_in[16];
  const float* ffn_b     = (const float*)d_in[17];
  const float* ln2_g     = (const float*)d_in[18];
  const float* ln2_b     = (const float*)d_in[19];
  const float* head_W    = (const float*)d_in[20];
  const float* head_b    = (const float*)d_in[21];
  float* out = (float*)d_out;

  // ---- diagnostic 1: input layout model ----
  bool sizes_ok = (n_in >= 22);
  if (sizes_ok){
    sizes_ok = in_sizes[0]==BB*SEQ*KF && in_sizes[1]==NTOK &&
               in_sizes[3]==NATOM*ADIM && in_sizes[4]==ADIM*EE &&
               in_sizes[10]==LL*EE*3*EHH && in_sizes[12]==LL*EHH*EHH &&
               in_sizes[14]==LL*EHH*EE   && in_sizes[16]==LL*EE*EE &&
               in_sizes[20]==EE;
  }
  if (!sizes_ok){
    sentinel_k<<<(out_size+63)/64,64,0,stream>>>(out, 99999.0f, out_size);
    return;
  }

  // ---- workspace layout (~101.6 MB; <= 109.7 MB proven) ----
  char* p = (char*)d_ws;
  size_t off = 0;
  auto alloc = [&](size_t bytes)->void*{
    off = (off + 255) & ~(size_t)255;
    void* r = p + off; off += bytes; return r;
  };
  float* w        = (float*)alloc((size_t)NTOK*4);
  float* x        = (float*)alloc((size_t)NTOK*EE*4);
  u16*   xn_bf    = (u16*)  alloc((size_t)NTOK*EE*2);
  u16*   qkc      = (u16*)  alloc((size_t)CTOK*2048*2);   // 33.6 MB chunk (Q|K)
  u16*   vTc      = (u16*)  alloc((size_t)EHH*CTOK*2);    // 16.8 MB chunk (V^T)
  u16*   vals_bf  = (u16*)  alloc((size_t)NTOK*EHH*2);    // 33.6 MB
  u16*   qkvWT_a  = (u16*)  alloc((size_t)LL*3*EHH*EE*2); // 2.36 MB (reordered)
  float* rqkv_b   = (float*)alloc((size_t)LL*3*EHH*4);    // reordered bias
  u16*   fwT_a    = (u16*)  alloc((size_t)LL*EE*EHH*2);   // 0.79 MB
  u16*   ffnWT_a  = (u16*)  alloc((size_t)LL*EE*EE*2);
  u16*   outWT_a  = (u16*)  alloc((size_t)LL*EE*EHH*2);
  float* fbp_a    = (float*)alloc((size_t)LL*8*EE*4);     // fuse_b partials
  float* atom_emb = (float*)alloc((size_t)NATOM*EE*4);
  float* epart    = (float*)alloc((size_t)(NTOK/32)*EE*4); // embed pooled partials
  float* pp       = (float*)alloc((size_t)(NTOK/32)*EE*4); // projffn pooled partials

  // ---- diagnostic 2: workspace size ----
  if (off > ws_size){
    sentinel_k<<<(out_size+63)/64,64,0,stream>>>(out, 12345.0f, out_size);
    return;
  }

  // ---- hoisted weight prep (merged; serial roles first) ----
  prep_k<<<1763,256,0,stream>>>(qkv_W, qkvWT_a, ffn_W, ffnWT_a,
                                out_W, outWT_a, qkv_b, rqkv_b,
                                atom_table, comp_W, comp_b, pdd_b, atom_emb,
                                o_b, fbp_a);
  // fwT = (o_W @ out_W)^T per layer; A = o_W f32 converted in staging
  mgemm_k<4,32,64,128,1><<<dim3(EE/64, EHH/32, LL),256,0,stream>>>(
      o_W, outWT_a, nullptr, fwT_a, EE, EHH, EHH, nullptr,
      (size_t)EHH*EHH, (size_t)EE*EHH, (size_t)EE*EHH*2);

  embed_ln_k<<<NTOK/32,512,0,stream>>>(str_fea, comp_fea, atom_emb, pdd_W,
                                       enc_ln_g, enc_ln_b, x, w, xn_bf, epart);

  for (int i=0;i<LL;i++){
    const float* gi = enc_ln_g + i*EE;
    const float* bi = enc_ln_b + i*EE;
    for (int cb=0; cb<NCHUNK; cb++){
      const int t0 = cb*CTOK;
      const int b0 = cb*CB;
      // QKV with router epilogue: Q|K -> qkc (stride 2048), V -> vTc (transposed)
      mgemm_k<7,128,128,64,0><<<dim3(3*EHH/128, CTOK/128),256,0,stream>>>(
          xn_bf + (size_t)t0*EE, qkvWT_a + (size_t)i*3*EHH*EE,
          rqkv_b + (size_t)i*3*EHH,
          qkc, 3*EHH, EE, CTOK, vTc, 0, 0, 0);
      attn_mf_k<<<dim3(CB, HH, SEQ/64),256,0,stream>>>(
          qkc, vTc, w, vals_bf + (size_t)t0*EHH, b0);
    }
    // proj + resid + LN + ffn + mish + dual-LN (+pool partial on last layer)
    const float* gn = (i<LL-1) ? enc_ln_g + (i+1)*EE : gi;
    const float* bn = (i<LL-1) ? enc_ln_b + (i+1)*EE : bi;
    projffn_k<<<NTOK/32,256,0,stream>>>(
        vals_bf, fwT_a + (size_t)i*EE*EHH,
        fbp_a + (size_t)i*8*EE, out_b + (size_t)i*EE,
        ffnWT_a + (size_t)i*EE*EE, ffn_b + (size_t)i*EE,
        gi, bi, gn, bn, x, xn_bf,
        w, (i==LL-1) ? pp : nullptr);
  }
  pool2_k<<<BB,128,0,stream>>>(pp, epart, ln2_g, ln2_b, head_W, head_b, out);
}

// Round 13
// 716.779 us; speedup vs baseline: 1.4424x; 1.0837x over previous
//
#include <hip/hip_runtime.h>
#include <math.h>

#define DI __device__ __forceinline__

// ---- problem constants ----
#define BB 32
#define SEQ 512
#define KF 101
#define EE 128
#define HH 8
#define EHH 1024
#define LL 3
#define ADIM 200
#define NATOM 119
#define NTOK (BB*SEQ)   // 16384
#define CB 16           // batches per chunk
#define NCHUNK (BB/CB)  // 2
#define CTOK (CB*SEQ)   // 8192 tokens per chunk

// R27: QKV GEMM stuck at 51us (MfmaUtil 4.4%, 2 K-steps, barrier-drain
// dominated; R26's store packing worked - WRITE 49MB = exact - but VGPR
// 80->132 halved occupancy, net 0). Fix: dedicated barrier-free LDS-free
// qkv_k - fragments loaded DIRECT from global (A/B panels L2-resident;
// LDS only gave 2x cross-wave reuse at the cost of 2 barriers/step).
// kk=0..3 double-buffered in regs, fully unrolled (compile-time idx),
// zero __syncthreads. K/iter order identical -> bitwise. R26 packed
// epilogue kept. mgemm_k template retained for prep EPI4 only.

typedef unsigned short u16;
typedef __attribute__((ext_vector_type(8))) short bf16x8;
typedef __attribute__((ext_vector_type(4))) float f32x4;

DI float bf2f(u16 s){ union{unsigned int u; float f;} x; x.u = ((unsigned int)s)<<16; return x.f; }
DI u16 f2bf(float f){
  union{float f; unsigned int u;} x; x.f = f;
  unsigned int u = x.u;
  u += 0x7fffu + ((u>>16)&1u);           // RNE
  return (u16)(u>>16);
}
DI unsigned int f2bf2(float lo, float hi){
  return (unsigned int)f2bf(lo) | ((unsigned int)f2bf(hi)<<16);
}
DI float rdl(float v, int l){
  return __int_as_float(__builtin_amdgcn_readlane(__float_as_int(v), l));
}

// =================== sentinel ===================
__global__ void sentinel_k(float* out, float v, int n){
  int i = blockIdx.x*64 + threadIdx.x;
  if (i < n) out[i] = v;
}

// =================== embed + layer-0 LN (32 tokens/block, 8 waves) ===================
// x = atom_emb[idx] + str[1:]@pdd_W ; xn = LN(x); epart = per-block sum w*x
__global__ __launch_bounds__(512, 4) void embed_ln_k(
    const float* __restrict__ str_fea, const int* __restrict__ comp_fea,
    const float* __restrict__ atom_emb, const float* __restrict__ pdd_W,
    const float* __restrict__ g, const float* __restrict__ bta,
    float* __restrict__ x, float* __restrict__ w,
    u16* __restrict__ xn, float* __restrict__ epart)
{
  const int t0 = blockIdx.x*32;
  const int tid = threadIdx.x;
  const int wv = tid>>6, lane = tid&63;
  __shared__ float2 sPdd[100*64];      // 51.2 KB
  __shared__ float sEp[8][128];        // 4 KB
  for (int k2=tid; k2<100*64; k2+=512)
    sPdd[k2] = ((const float2*)pdd_W)[k2];

  float sv0[4], sv1[4];
  int idx[4];
  #pragma unroll
  for (int tk=0; tk<4; ++tk){
    const int t = t0 + wv*4 + tk;
    const float* sr0 = str_fea + (size_t)t*KF;
    sv0[tk] = sr0[lane];
    sv1[tk] = (lane+64 < KF) ? sr0[lane+64] : 0.f;
    idx[tk] = comp_fea[t];
  }
  __syncthreads();

  float a0[4],a1[4],a2[4],a3[4],c0[4],c1[4],c2[4],c3[4];
  #pragma unroll
  for (int tk=0; tk<4; ++tk){
    const float2 ae = ((const float2*)(atom_emb + (size_t)idx[tk]*EE))[lane];
    a0[tk]=ae.x; a1[tk]=0.f; a2[tk]=0.f; a3[tk]=0.f;
    c0[tk]=ae.y; c1[tk]=0.f; c2[tk]=0.f; c3[tk]=0.f;
  }
  #pragma unroll 5
  for (int j=0; j<100; j+=4){
    const float2 w0 = sPdd[(j  )*64 + lane];
    const float2 w1 = sPdd[(j+1)*64 + lane];
    const float2 w2 = sPdd[(j+2)*64 + lane];
    const float2 w3 = sPdd[(j+3)*64 + lane];
    #pragma unroll
    for (int tk=0; tk<4; ++tk){
      const float s1 = (1+j<64) ? rdl(sv0[tk],1+j) : rdl(sv1[tk],1+j-64);
      const float s2 = (2+j<64) ? rdl(sv0[tk],2+j) : rdl(sv1[tk],2+j-64);
      const float s3 = (3+j<64) ? rdl(sv0[tk],3+j) : rdl(sv1[tk],3+j-64);
      const float s4 = (4+j<64) ? rdl(sv0[tk],4+j) : rdl(sv1[tk],4+j-64);
      a0[tk] = fmaf(s1, w0.x, a0[tk]);  c0[tk] = fmaf(s1, w0.y, c0[tk]);
      a1[tk] = fmaf(s2, w1.x, a1[tk]);  c1[tk] = fmaf(s2, w1.y, c1[tk]);
      a2[tk] = fmaf(s3, w2.x, a2[tk]);  c2[tk] = fmaf(s3, w2.y, c2[tk]);
      a3[tk] = fmaf(s4, w3.x, a3[tk]);  c3[tk] = fmaf(s4, w3.y, c3[tk]);
    }
  }
  const float2 gg = ((const float2*)g)[lane];
  const float2 bb = ((const float2*)bta)[lane];
  const int e0 = lane*2;
  float ep0 = 0.f, ep1 = 0.f;
  #pragma unroll
  for (int tk=0; tk<4; ++tk){
    const int t = t0 + wv*4 + tk;
    const float vx = (a0[tk]+a1[tk])+(a2[tk]+a3[tk]);
    const float vy = (c0[tk]+c1[tk])+(c2[tk]+c3[tk]);
    ((float2*)(x + (size_t)t*EE))[lane] = make_float2(vx, vy);
    const float wt_ = rdl(sv0[tk], 0);
    if (lane==0) w[t] = sv0[tk];
    ep0 = fmaf(wt_, vx, ep0);
    ep1 = fmaf(wt_, vy, ep1);
    float s = vx + vy;
    #pragma unroll
    for (int off=32; off; off>>=1) s += __shfl_xor(s, off);
    const float mean = s*(1.0f/128.0f);
    const float d0 = vx-mean, d1 = vy-mean;
    float q = d0*d0 + d1*d1;
    #pragma unroll
    for (int off=32; off; off>>=1) q += __shfl_xor(q, off);
    const float rstd = rsqrtf(q*(1.0f/128.0f) + 1e-5f);
    u16* o = xn + (size_t)t*EE + e0;
    o[0] = f2bf(d0*rstd*gg.x + bb.x);
    o[1] = f2bf(d1*rstd*gg.y + bb.y);
  }
  sEp[wv][e0]   = ep0;
  sEp[wv][e0+1] = ep1;
  __syncthreads();
  if (tid < 128){
    float s = 0.f;
    #pragma unroll
    for (int v=0; v<8; ++v) s += sEp[v][tid];
    epart[(size_t)blockIdx.x*EE + tid] = s;
  }
}

// =================== merged weight prep ===================
DI void trans32(const float* __restrict__ W, u16* __restrict__ WT,
                int Nn, int Kk, int srcCol0, int n0, int k0, int tid,
                u16 (&tile)[32][33])
{
  const int lr = tid>>5, lc = tid&31;
  #pragma unroll
  for (int i=0;i<4;i++)
    tile[lr+i*8][lc] = f2bf(W[(size_t)(k0+lr+i*8)*Nn + srcCol0 + lc]);
  __syncthreads();
  #pragma unroll
  for (int i=0;i<4;i++)
    WT[(size_t)(n0+lr+i*8)*Kk + k0 + lc] = tile[lc][lr+i*8];
}

// roles (slow serial roles FIRST so their chains overlap the fast blocks):
// [0,119) atomemb | [119,143) fuse_b partials | [143,1295) qkvT |
// [1295,1343) ffnT | [1343,1727) outWT | [1727,1763) qkv bias reorder
__global__ __launch_bounds__(256) void prep_k(
    const float* __restrict__ qkv_W, u16* __restrict__ qkvWT,
    const float* __restrict__ ffn_W, u16* __restrict__ ffnWT,
    const float* __restrict__ out_W, u16* __restrict__ outWT,
    const float* __restrict__ qkv_b, float* __restrict__ rqkv_b,
    const float* __restrict__ atom_table, const float* __restrict__ comp_W,
    const float* __restrict__ comp_b, const float* __restrict__ pdd_b,
    float* __restrict__ atom_emb,
    const float* __restrict__ o_b, float* __restrict__ fbp)
{
  __shared__ u16 tile[32][33];
  __shared__ float sbuf[456];
  int bid = blockIdx.x;
  const int tid = threadIdx.x;
  if (bid < NATOM){
    // atom embedding: atom_emb[a] = comp_b + pdd_b + atom_table[a]@comp_W
    const int a = bid;
    const int e = tid & 127, half = tid >> 7;
    float* sAtom = sbuf;
    float* red   = sbuf + 200;
    for (int d=tid; d<ADIM; d+=256) sAtom[d] = atom_table[a*ADIM+d];
    __syncthreads();
    const int d0 = half*100;
    float b0 = half ? 0.f : (comp_b[e] + pdd_b[e]);
    float b1 = 0.f, b2 = 0.f, b3 = 0.f;
    #pragma unroll 5
    for (int d=d0; d<d0+100; d+=4){
      b0 = fmaf(sAtom[d  ], comp_W[(d  )*EE+e], b0);
      b1 = fmaf(sAtom[d+1], comp_W[(d+1)*EE+e], b1);
      b2 = fmaf(sAtom[d+2], comp_W[(d+2)*EE+e], b2);
      b3 = fmaf(sAtom[d+3], comp_W[(d+3)*EE+e], b3);
    }
    red[tid] = (b0+b1)+(b2+b3);
    __syncthreads();
    if (half==0) atom_emb[a*EE+e] = red[e] + red[128+e];
    return;
  }
  bid -= NATOM;
  if (bid < 24){
    // fuse_b partials: fbp[ly][s][n] = sum_{k in s-slice} o_b[k]*out_W[k][n]
    const int ly = bid >> 3, s = bid & 7;
    const float* ob = o_b + (size_t)ly*EHH;
    const float* oW = out_W + (size_t)ly*EHH*EE;
    const int n = tid & 127, h2 = tid >> 7;
    const int kb = s*128 + h2*64;
    float b0=0.f,b1=0.f,b2=0.f,b3=0.f;
    #pragma unroll 4
    for (int k2=kb; k2<kb+64; k2+=4){
      b0 = fmaf(ob[k2  ], oW[(size_t)(k2  )*EE+n], b0);
      b1 = fmaf(ob[k2+1], oW[(size_t)(k2+1)*EE+n], b1);
      b2 = fmaf(ob[k2+2], oW[(size_t)(k2+2)*EE+n], b2);
      b3 = fmaf(ob[k2+3], oW[(size_t)(k2+3)*EE+n], b3);
    }
    float* red = sbuf;
    red[tid] = (b0+b1)+(b2+b3);
    __syncthreads();
    if (h2==0) fbp[((size_t)ly*8 + s)*EE + n] = red[n] + red[128+n];
    return;
  }
  bid -= 24;
  if (bid < 1152){
    const int xb = bid%96, yb = (bid/96)%4, zb = bid/384;
    const int n0 = xb*32, k0 = yb*32;
    int c0;
    if (n0 < 2048) c0 = (n0>>8)*384 + (n0&255);
    else { const int m0 = n0-2048; c0 = (m0>>7)*384 + 256 + (m0&127); }
    trans32(qkv_W + (size_t)zb*EE*3*EHH, qkvWT + (size_t)zb*3*EHH*EE,
            3*EHH, EE, c0, n0, k0, tid, tile);
    return;
  }
  bid -= 1152;
  if (bid < 48){
    const int xb = bid%4, yb = (bid/4)%4, zb = bid/16;
    trans32(ffn_W + (size_t)zb*EE*EE, ffnWT + (size_t)zb*EE*EE,
            EE, EE, xb*32, xb*32, yb*32, tid, tile);
    return;
  }
  bid -= 48;
  if (bid < 384){
    const int xb = bid%4, yb = (bid/4)%32, zb = bid/128;
    trans32(out_W + (size_t)zb*EHH*EE, outWT + (size_t)zb*EE*EHH,
            EE, EHH, xb*32, xb*32, yb*32, tid, tile);
    return;
  }
  bid -= 384;
  {
    const int l = bid/12;
    const int n = (bid%12)*256 + tid;
    int c;
    if (n < 2048) c = (n>>8)*384 + (n&255);
    else { const int m = n-2048; c = (m>>7)*384 + 256 + (m&127); }
    rqkv_b[(size_t)l*3*EHH + n] = qkv_b[(size_t)l*3*EHH + c];
  }
}

// =================== MFMA bf16 GEMM (prep fwT only; layer-batched) ===================
// A: M x Kk row-major (f32 when AF32 — converted in staging).
// BT: Nn x Kk bf16. EPI 4: bf16 transposed store (no bias).
template<int EPI, int BM, int BN, int BK, int AF32>
__global__ __launch_bounds__(256) void mgemm_k(
    const void* __restrict__ Av, const u16* __restrict__ BT,
    const float* __restrict__ bias, void* __restrict__ Cv,
    int Nn, int Kk, int Mdim, void* __restrict__ C2,
    size_t sA, size_t sBT, size_t sCb)
{
  const int lz = blockIdx.z;
  BT += (size_t)lz*sBT;
  void* C = (void*)((char*)Cv + (size_t)lz*sCb);

  constexpr int LDK = BK + 8;
  __shared__ u16 As[BM*LDK];
  __shared__ u16 Bs[BN*LDK];
  const int tid = threadIdx.x;
  const int m0 = blockIdx.y*BM, n0 = blockIdx.x*BN;
  constexpr int WMN = (BM>=128)?2:1;
  constexpr int WNN = 4/WMN;
  constexpr int WM = BM/WMN;
  constexpr int WN = BN/WNN;
  constexpr int FM = WM/16, FN = WN/16;
  const int wv = tid>>6, lane = tid&63;
  const int wm = (wv/WNN)*WM;
  const int wn = (wv%WNN)*WN;
  const int lm = lane&15, lq = lane>>4;

  f32x4 acc[FM][FN];
  #pragma unroll
  for (int i=0;i<FM;i++)
    #pragma unroll
    for (int j=0;j<FN;j++) acc[i][j] = (f32x4){0.f,0.f,0.f,0.f};

  constexpr int BCH = BN*BK/8;

  for (int k0=0; k0<Kk; k0+=BK){
    if constexpr (AF32){
      const float* A = (const float*)Av + (size_t)lz*sA;
      #pragma unroll
      for (int c = tid; c < BM*BK/4; c += 256){
        const int r = c/(BK/4), kg = c - r*(BK/4);
        const float4 v = *(const float4*)(A + (size_t)(m0+r)*Kk + k0 + kg*4);
        union { u16 u[4]; unsigned long long ll; } t;
        t.u[0]=f2bf(v.x); t.u[1]=f2bf(v.y); t.u[2]=f2bf(v.z); t.u[3]=f2bf(v.w);
        *(unsigned long long*)&As[r*LDK + kg*4] = t.ll;
      }
    } else {
      const u16* A = (const u16*)Av + (size_t)lz*sA;
      #pragma unroll
      for (int c = tid; c < BM*BK/8; c += 256){
        const int r = c/(BK/8), kg = c - r*(BK/8);
        const float4 v = *(const float4*)(A + (size_t)(m0+r)*Kk + k0 + kg*8);
        *(float4*)&As[r*LDK + kg*8] = v;
      }
    }
    #pragma unroll
    for (int c = tid; c < BCH; c += 256){
      const int r = c/(BK/8), kg = c - r*(BK/8);
      const float4 v = *(const float4*)(BT + (size_t)(n0+r)*Kk + k0 + kg*8);
      *(float4*)&Bs[r*LDK + kg*8] = v;
    }
    __syncthreads();
    #pragma unroll
    for (int kk=0; kk<BK/32; kk++){
      bf16x8 af[FM], bfr[FN];
      #pragma unroll
      for (int i=0;i<FM;i++)
        af[i] = *(const bf16x8*)&As[(wm + i*16 + lm)*LDK + kk*32 + lq*8];
      #pragma unroll
      for (int j=0;j<FN;j++)
        bfr[j] = *(const bf16x8*)&Bs[(wn + j*16 + lm)*LDK + kk*32 + lq*8];
      #pragma unroll
      for (int i=0;i<FM;i++)
        #pragma unroll
        for (int j=0;j<FN;j++)
          acc[i][j] = __builtin_amdgcn_mfma_f32_16x16x32_bf16(af[i], bfr[j], acc[i][j], 0, 0, 0);
    }
    __syncthreads();
  }
  #pragma unroll
  for (int i=0;i<FM;i++){
    #pragma unroll
    for (int j=0;j<FN;j++){
      const int col = n0 + wn + j*16 + lm;
      const float bv = (EPI==4) ? 0.f : bias[col];
      #pragma unroll
      for (int r=0;r<4;r++){
        const int row = m0 + wm + i*16 + lq*4 + r;
        float v = acc[i][j][r] + bv;
        if constexpr (EPI==4){
          ((u16*)C)[(size_t)col*Mdim + row] = f2bf(v);
        } else {
          ((u16*)C)[(size_t)row*Nn + col] = f2bf(v);
        }
      }
    }
  }
}

// =================== QKV GEMM: barrier-free, LDS-free, reg-direct ===================
// A: xn chunk [CTOK][128] bf16; BT: qkvWT layer [3072][128] bf16.
// Fragments loaded direct from global (L2-resident), kk double-buffered.
// n0<2048 (Q|K): SWAPPED mfma -> packed 8B stores into qkc[m][col];
// n0>=2048 (V): normal -> packed 8B stores into vTc[col-2048][tok].
// K-order (kk 0..3) and i,j order identical to the old LDS path -> bitwise.
__global__ __launch_bounds__(256) void qkv_k(
    const u16* __restrict__ A, const u16* __restrict__ BT,
    const float* __restrict__ bias, u16* __restrict__ qkc,
    u16* __restrict__ vTc, int Mdim)
{
  const int n0 = blockIdx.x*128, m0 = blockIdx.y*128;
  const int tid = threadIdx.x;
  const int wv = tid>>6, lane = tid&63;
  const int lm = lane&15, lq = lane>>4;
  const int wm = (wv>>1)*64, wn = (wv&1)*64;   // WMN=2, WNN=2
  const bool swp = (n0 < 2048);

  const u16* Ab = A  + (size_t)(m0+wm+lm)*EE + lq*8;
  const u16* Bb = BT + (size_t)(n0+wn+lm)*EE + lq*8;

  f32x4 acc[4][4];
  #pragma unroll
  for (int i=0;i<4;i++)
    #pragma unroll
    for (int j=0;j<4;j++) acc[i][j] = (f32x4){0.f,0.f,0.f,0.f};

  bf16x8 afb[2][4], bfb[2][4];
  #pragma unroll
  for (int i=0;i<4;i++){
    afb[0][i] = *(const bf16x8*)(Ab + (size_t)i*16*EE);
    bfb[0][i] = *(const bf16x8*)(Bb + (size_t)i*16*EE);
  }
  #pragma unroll
  for (int kk=0; kk<4; kk++){
    const int cur = kk&1, nxt = cur^1;
    if (kk<3){
      #pragma unroll
      for (int i=0;i<4;i++){
        afb[nxt][i] = *(const bf16x8*)(Ab + (size_t)i*16*EE + (kk+1)*32);
        bfb[nxt][i] = *(const bf16x8*)(Bb + (size_t)i*16*EE + (kk+1)*32);
      }
    }
    if (swp){
      #pragma unroll
      for (int i=0;i<4;i++)
        #pragma unroll
        for (int j=0;j<4;j++)
          acc[i][j] = __builtin_amdgcn_mfma_f32_16x16x32_bf16(bfb[cur][j], afb[cur][i], acc[i][j], 0, 0, 0);
    } else {
      #pragma unroll
      for (int i=0;i<4;i++)
        #pragma unroll
        for (int j=0;j<4;j++)
          acc[i][j] = __builtin_amdgcn_mfma_f32_16x16x32_bf16(afb[cur][i], bfb[cur][j], acc[i][j], 0, 0, 0);
    }
  }

  if (swp){
    // lane holds C[m = m0+wm+i*16+lm][cols colb..colb+3]
    #pragma unroll
    for (int i=0;i<4;i++){
      const int m = m0 + wm + i*16 + lm;
      #pragma unroll
      for (int j=0;j<4;j++){
        const int colb = n0 + wn + j*16 + lq*4;
        const float4 bv4 = *(const float4*)&bias[colb];
        uint2 pkd;
        pkd.x = f2bf2(acc[i][j][0]+bv4.x, acc[i][j][1]+bv4.y);
        pkd.y = f2bf2(acc[i][j][2]+bv4.z, acc[i][j][3]+bv4.w);
        *(uint2*)(qkc + (size_t)m*2048 + colb) = pkd;
      }
    }
  } else {
    // lane holds C[rows row0..row0+3][col] -> contiguous in vT[col-2048][tok]
    #pragma unroll
    for (int i=0;i<4;i++){
      const int row0 = m0 + wm + i*16 + lq*4;
      #pragma unroll
      for (int j=0;j<4;j++){
        const int col = n0 + wn + j*16 + lm;
        const float bv = bias[col];
        uint2 pkd;
        pkd.x = f2bf2(acc[i][j][0]+bv, acc[i][j][1]+bv);
        pkd.y = f2bf2(acc[i][j][2]+bv, acc[i][j][3]+bv);
        *(uint2*)(vTc + (size_t)(col-2048)*Mdim + row0) = pkd;
      }
    }
  }
}

// =================== fused proj+LN + ffn+mish + dual-LN (+pool partial) ===================
__global__ __launch_bounds__(256) void projffn_k(
    const u16* __restrict__ vals, const u16* __restrict__ fwT,
    const float* __restrict__ fbp, const float* __restrict__ outb,
    const u16* __restrict__ ffnWT, const float* __restrict__ fnb,
    const float* __restrict__ g1, const float* __restrict__ b1,
    const float* __restrict__ g2, const float* __restrict__ b2,
    float* __restrict__ x_io, u16* __restrict__ xn_io,
    const float* __restrict__ w, float* __restrict__ pp)
{
  constexpr int BM = 32, BK = 128, LDK = BK + 8;
  __shared__ u16 As[BM*LDK];        // proj A tiles; then xn2 (bf16)
  __shared__ u16 Bs[EE*LDK];        // fwT tiles; then ffnWT
  __shared__ float sred[BM*8];
  const int tid = threadIdx.x;
  const int wv = tid>>6, lane = tid&63;
  const int lm = lane&15, lq = lane>>4;
  const int m0 = blockIdx.x*BM;
  const int wn = wv*32;             // 4 waves x 32 cols

  f32x4 acc[2][2];
  #pragma unroll
  for (int i=0;i<2;i++)
    #pragma unroll
    for (int j=0;j<2;j++) acc[i][j] = (f32x4){0.f,0.f,0.f,0.f};

  // ---- phase A: proj GEMM, K=1024 ----
  for (int k0=0; k0<EHH; k0+=BK){
    #pragma unroll
    for (int c = tid; c < BM*BK/8; c += 256){
      const int r = c>>4, kg = c&15;
      *(float4*)&As[r*LDK + kg*8] = *(const float4*)(vals + (size_t)(m0+r)*EHH + k0 + kg*8);
    }
    #pragma unroll
    for (int c = tid; c < EE*BK/8; c += 256){
      const int r = c>>4, kg = c&15;
      *(float4*)&Bs[r*LDK + kg*8] = *(const float4*)(fwT + (size_t)r*EHH + k0 + kg*8);
    }
    __syncthreads();
    #pragma unroll
    for (int kk=0; kk<BK/32; kk++){
      bf16x8 af[2], bfr[2];
      #pragma unroll
      for (int i=0;i<2;i++)
        af[i] = *(const bf16x8*)&As[(i*16 + lm)*LDK + kk*32 + lq*8];
      #pragma unroll
      for (int j=0;j<2;j++)
        bfr[j] = *(const bf16x8*)&Bs[(wn + j*16 + lm)*LDK + kk*32 + lq*8];
      #pragma unroll
      for (int i=0;i<2;i++)
        #pragma unroll
        for (int j=0;j<2;j++)
          acc[i][j] = __builtin_amdgcn_mfma_f32_16x16x32_bf16(af[i], bfr[j], acc[i][j], 0, 0, 0);
    }
    __syncthreads();
  }

  // ---- phase A epilogue: vout = acc + fb + x ; LN stats ----
  float vout[2][2][4];
  float ps[2][4], qs[2][4];
  #pragma unroll
  for (int i=0;i<2;i++)
    #pragma unroll
    for (int r=0;r<4;r++){ ps[i][r]=0.f; qs[i][r]=0.f; }
  #pragma unroll
  for (int i=0;i<2;i++){
    #pragma unroll
    for (int j=0;j<2;j++){
      const int col = wn + j*16 + lm;
      const float bv = outb[col]
        + ((fbp[0*EE+col]+fbp[1*EE+col])+(fbp[2*EE+col]+fbp[3*EE+col]))
        + ((fbp[4*EE+col]+fbp[5*EE+col])+(fbp[6*EE+col]+fbp[7*EE+col]));
      #pragma unroll
      for (int r=0;r<4;r++){
        const int row = m0 + i*16 + lq*4 + r;
        const float v = acc[i][j][r] + bv + x_io[(size_t)row*EE + col];
        vout[i][j][r] = v;
        ps[i][r] += v; qs[i][r] += v*v;
      }
    }
  }
  #pragma unroll
  for (int i=0;i<2;i++)
    #pragma unroll
    for (int r=0;r<4;r++){
      float s = ps[i][r], q = qs[i][r];
      s += __shfl_xor(s,1); s += __shfl_xor(s,2); s += __shfl_xor(s,4); s += __shfl_xor(s,8);
      q += __shfl_xor(q,1); q += __shfl_xor(q,2); q += __shfl_xor(q,4); q += __shfl_xor(q,8);
      if (lm==0){
        const int row = i*16 + lq*4 + r;
        sred[row*4 + wv] = s;
        sred[BM*4 + row*4 + wv] = q;
      }
    }
  __syncthreads();
  // xn2 -> As (bf16), and stage ffnWT -> Bs
  #pragma unroll
  for (int i=0;i<2;i++)
    #pragma unroll
    for (int r=0;r<4;r++){
      const int row = i*16 + lq*4 + r;
      const float s = sred[row*4+0]+sred[row*4+1]+sred[row*4+2]+sred[row*4+3];
      const float q = sred[BM*4+row*4+0]+sred[BM*4+row*4+1]+sred[BM*4+row*4+2]+sred[BM*4+row*4+3];
      const float mean = s*(1.0f/128.0f);
      const float var  = q*(1.0f/128.0f) - mean*mean;
      const float rstd = rsqrtf(var + 1e-5f);
      #pragma unroll
      for (int j=0;j<2;j++){
        const int col = wn + j*16 + lm;
        const float xnv = (vout[i][j][r]-mean)*rstd*g1[col] + b1[col];
        As[row*LDK + col] = f2bf(xnv);
      }
    }
  #pragma unroll
  for (int c = tid; c < EE*EE/8; c += 256){
    const int r = c>>4, kg = c&15;
    *(float4*)&Bs[r*LDK + kg*8] = *(const float4*)(ffnWT + (size_t)r*EE + kg*8);
  }
  __syncthreads();

  // ---- phase B: ffn GEMM, K=128 from LDS ----
  f32x4 fa[2][2];
  #pragma unroll
  for (int i=0;i<2;i++)
    #pragma unroll
    for (int j=0;j<2;j++) fa[i][j] = (f32x4){0.f,0.f,0.f,0.f};
  #pragma unroll
  for (int kk=0; kk<4; kk++){
    bf16x8 af[2], bfr[2];
    #pragma unroll
    for (int i=0;i<2;i++)
      af[i] = *(const bf16x8*)&As[(i*16 + lm)*LDK + kk*32 + lq*8];
    #pragma unroll
    for (int j=0;j<2;j++)
      bfr[j] = *(const bf16x8*)&Bs[(wn + j*16 + lm)*LDK + kk*32 + lq*8];
    #pragma unroll
    for (int i=0;i<2;i++)
      #pragma unroll
      for (int j=0;j<2;j++)
        fa[i][j] = __builtin_amdgcn_mfma_f32_16x16x32_bf16(af[i], bfr[j], fa[i][j], 0, 0, 0);
  }

  // ---- phase C: t = vout + mish(fa + fnb); dual row-LN ----
  float tv[2][2][4];
  #pragma unroll
  for (int i=0;i<2;i++)
    #pragma unroll
    for (int r=0;r<4;r++){ ps[i][r]=0.f; qs[i][r]=0.f; }
  #pragma unroll
  for (int i=0;i<2;i++){
    #pragma unroll
    for (int j=0;j<2;j++){
      const int col = wn + j*16 + lm;
      const float bv = fnb[col];
      #pragma unroll
      for (int r=0;r<4;r++){
        const float v = fa[i][j][r] + bv;
        const float E = __expf(v);
        const float uu = E*E + 2.f*E;
        const float mi = (v > 20.f) ? v : v*(uu/(uu+2.f));
        const float t = vout[i][j][r] + mi;
        tv[i][j][r] = t;
        ps[i][r] += t; qs[i][r] += t*t;
      }
    }
  }
  #pragma unroll
  for (int i=0;i<2;i++)
    #pragma unroll
    for (int r=0;r<4;r++){
      float s = ps[i][r], q = qs[i][r];
      s += __shfl_xor(s,1); s += __shfl_xor(s,2); s += __shfl_xor(s,4); s += __shfl_xor(s,8);
      q += __shfl_xor(q,1); q += __shfl_xor(q,2); q += __shfl_xor(q,4); q += __shfl_xor(q,8);
      if (lm==0){
        const int row = i*16 + lq*4 + r;
        sred[row*4 + wv] = s;
        sred[BM*4 + row*4 + wv] = q;
      }
    }
  __syncthreads();
  float xv[2][2][4];
  float ps2[2][4], qs2[2][4];
  #pragma unroll
  for (int i=0;i<2;i++)
    #pragma unroll
    for (int r=0;r<4;r++){
      const int row = i*16 + lq*4 + r;
      const float s = sred[row*4+0]+sred[row*4+1]+sred[row*4+2]+sred[row*4+3];
      const float q = sred[BM*4+row*4+0]+sred[BM*4+row*4+1]+sred[BM*4+row*4+2]+sred[BM*4+row*4+3];
      const float mean = s*(1.0f/128.0f);
      const float var  = q*(1.0f/128.0f) - mean*mean;
      const float rstd = rsqrtf(var + 1e-5f);
      float s2 = 0.f, q2 = 0.f;
      #pragma unroll
      for (int j=0;j<2;j++){
        const int col = wn + j*16 + lm;
        const float xnv = (tv[i][j][r]-mean)*rstd*g1[col] + b1[col];
        x_io[(size_t)(m0+row)*EE + col] = xnv;
        xv[i][j][r] = xnv;
        s2 += xnv; q2 += xnv*xnv;
      }
      ps2[i][r] = s2; qs2[i][r] = q2;
    }
  // fused pool partial (last layer): pp[block][col] = sum_rows w[row]*x[row][col]
  if (pp){
    float pz[2] = {0.f, 0.f};
    #pragma unroll
    for (int i=0;i<2;i++)
      #pragma unroll
      for (int r=0;r<4;r++){
        const float wr = w[m0 + i*16 + lq*4 + r];
        pz[0] = fmaf(wr, xv[i][0][r], pz[0]);
        pz[1] = fmaf(wr, xv[i][1][r], pz[1]);
      }
    #pragma unroll
    for (int j=0;j<2;j++){
      pz[j] += __shfl_xor(pz[j], 16);
      pz[j] += __shfl_xor(pz[j], 32);
      if (lq==0) pp[(size_t)blockIdx.x*EE + wn + j*16 + lm] = pz[j];
    }
  }
  __syncthreads();
  #pragma unroll
  for (int i=0;i<2;i++)
    #pragma unroll
    for (int r=0;r<4;r++){
      float s = ps2[i][r], q = qs2[i][r];
      s += __shfl_xor(s,1); s += __shfl_xor(s,2); s += __shfl_xor(s,4); s += __shfl_xor(s,8);
      q += __shfl_xor(q,1); q += __shfl_xor(q,2); q += __shfl_xor(q,4); q += __shfl_xor(q,8);
      if (lm==0){
        const int row = i*16 + lq*4 + r;
        sred[row*4 + wv] = s;
        sred[BM*4 + row*4 + wv] = q;
      }
    }
  __syncthreads();
  #pragma unroll
  for (int i=0;i<2;i++)
    #pragma unroll
    for (int r=0;r<4;r++){
      const int row = i*16 + lq*4 + r;
      const float s = sred[row*4+0]+sred[row*4+1]+sred[row*4+2]+sred[row*4+3];
      const float q = sred[BM*4+row*4+0]+sred[BM*4+row*4+1]+sred[BM*4+row*4+2]+sred[BM*4+row*4+3];
      const float mean = s*(1.0f/128.0f);
      const float var  = q*(1.0f/128.0f) - mean*mean;
      const float rstd = rsqrtf(var + 1e-5f);
      #pragma unroll
      for (int j=0;j<2;j++){
        const int col = wn + j*16 + lm;
        const float xnv = (xv[i][j][r]-mean)*rstd*g2[col] + b2[col];
        xn_io[(size_t)(m0+row)*EE + col] = f2bf(xnv);
      }
    }
}

// =================== MFMA flash attention (swapped operands, in-reg P) ===================
// qkc: [tok][h*256 + (q:0..127 | k:128..255)] bf16, tok chunk-local.
// vTc: [h*128+d][tok] bf16 (pre-transposed V), tok chunk-local.
__global__ __launch_bounds__(256, 4) void attn_mf_k(
    const u16* __restrict__ qkc, const u16* __restrict__ vTc,
    const float* __restrict__ w, u16* __restrict__ vals_c, int b0)
{
  const int bl = blockIdx.x;   // id%8 -> XCD-local batch groups
  const int h  = blockIdx.y;
  const int qt = blockIdx.z;
  const int tid = threadIdx.x;
  const int wv = tid>>6, lane = tid&63;
  const int lm = lane&15, lq = lane>>4;

  __shared__ u16 Ks[64][136];
  __shared__ u16 Vts[128][72];
  __shared__ float wt[64], qwt[64];

  const size_t rs = 2048;
  const u16* qk = qkc + (size_t)bl*SEQ*rs + (size_t)h*256;
  const u16* vb = vTc + (size_t)h*128*CTOK + (size_t)bl*SEQ;
  const int q0 = qt*64;

  // Q fragments in registers (constant across all kt)
  bf16x8 qf[4];
  #pragma unroll
  for (int kk=0; kk<4; kk++)
    qf[kk] = *(const bf16x8*)(qk + (size_t)(q0 + wv*16 + lm)*rs + kk*32 + lq*8);
  if (tid < 64) qwt[tid] = w[(b0+bl)*SEQ + q0 + tid];
  __syncthreads();
  const float qw = qwt[wv*16 + lm];   // this lane's q-row weight

  f32x4 oacc[8];
  #pragma unroll
  for (int j=0;j<8;j++) oacc[j] = (f32x4){0.f,0.f,0.f,0.f};
  float mrow = -INFINITY, lrow = 0.f;
  const float scale = 0.08838834764831845f;  // 1/sqrt(128)

  const int srcA = ((lq&1)<<1)*16 + lm;   // source lane for P elems 0..3
  const int srcB = srcA + 16;             // source lane for P elems 4..7
  const bool selhi = (lq>>1) != 0;

  for (int kt=0; kt<8; kt++){
    __syncthreads();
    #pragma unroll
    for (int it=0; it<4; it++){
      const int fi = it*256 + tid;
      const int r = fi >> 4, g = fi & 15;
      *(float4*)&Ks[r][g*8] = *(const float4*)(qk + (size_t)(kt*64+r)*rs + 128 + g*8);
    }
    #pragma unroll
    for (int it=0; it<4; it++){
      const int fi = it*256 + tid;
      const int d = fi >> 3, g = fi & 7;
      *(float4*)&Vts[d][g*8] = *(const float4*)(vb + (size_t)d*CTOK + kt*64 + g*8);
    }
    if (tid < 64) wt[tid] = w[(b0+bl)*SEQ + kt*64 + tid];
    __syncthreads();

    // QK^T swapped: sacc[j] = D[k-local][q], A = K rows, B = Q rows
    f32x4 sacc[4];
    #pragma unroll
    for (int j=0;j<4;j++) sacc[j] = (f32x4){0.f,0.f,0.f,0.f};
    __builtin_amdgcn_s_setprio(1);
    #pragma unroll
    for (int kk=0; kk<4; kk++){
      const bf16x8 bfq = qf[kk];
      #pragma unroll
      for (int j=0;j<4;j++){
        const bf16x8 afk = *(const bf16x8*)&Ks[j*16+lm][kk*32+lq*8];
        sacc[j] = __builtin_amdgcn_mfma_f32_16x16x32_bf16(afk, bfq, sacc[j], 0, 0, 0);
      }
    }
    __builtin_amdgcn_s_setprio(0);

    // lane (lm,lq) holds S[k=16j+4lq+r][q=wv*16+lm]
    float s[4][4], wk[4][4];
    const bool qpos = qw > 0.f;
    #pragma unroll
    for (int j=0;j<4;j++)
      #pragma unroll
      for (int r=0;r<4;r++){
        wk[j][r] = wt[j*16 + lq*4 + r];
        const bool keep = qpos && (wk[j][r] > 0.f);
        s[j][r] = keep ? sacc[j][r]*scale : -9.0e15f;
      }
    // per-q (per-lane) max over 16 + cross-lq
    float rm = s[0][0];
    #pragma unroll
    for (int j=0;j<4;j++)
      #pragma unroll
      for (int r=0;r<4;r++) if (j|r) rm = fmaxf(rm, s[j][r]);
    rm = fmaxf(rm, __shfl_xor(rm, 16));
    rm = fmaxf(rm, __shfl_xor(rm, 32));
    const float newm = fmaxf(mrow, rm);
    const float alpha = __expf(mrow - newm);
    float ls = 0.f;
    int pk[4][2];
    #pragma unroll
    for (int j=0;j<4;j++){
      const float p0 = wk[j][0]*__expf(s[j][0]-newm);
      const float p1 = wk[j][1]*__expf(s[j][1]-newm);
      const float p2 = wk[j][2]*__expf(s[j][2]-newm);
      const float p3 = wk[j][3]*__expf(s[j][3]-newm);
      ls += ((p0+p1)+(p2+p3));
      pk[j][0] = (int)f2bf2(p0, p1);
      pk[j][1] = (int)f2bf2(p2, p3);
    }
    ls += __shfl_xor(ls, 16);
    ls += __shfl_xor(ls, 32);
    lrow = lrow*alpha + ls;
    mrow = newm;
    #pragma unroll
    for (int j=0;j<8;j++)
      #pragma unroll
      for (int r=0;r<4;r++) oacc[j][r] *= alpha;

    // PV swapped: B-fragment for lane = P[q=wv*16+lm][k=kk*32+lq*8..+7]
    __builtin_amdgcn_s_setprio(1);
    #pragma unroll
    for (int kk=0; kk<2; kk++){
      const int j0 = 2*kk, j1 = 2*kk+1;
      const int a00 = __shfl(pk[j0][0], srcA), a01 = __shfl(pk[j0][1], srcA);
      const int b00 = __shfl(pk[j0][0], srcB), b01 = __shfl(pk[j0][1], srcB);
      const int a10 = __shfl(pk[j1][0], srcA), a11 = __shfl(pk[j1][1], srcA);
      const int b10 = __shfl(pk[j1][0], srcB), b11 = __shfl(pk[j1][1], srcB);
      union { int i[4]; bf16x8 v; } pf;
      pf.i[0] = selhi ? a10 : a00;
      pf.i[1] = selhi ? a11 : a01;
      pf.i[2] = selhi ? b10 : b00;
      pf.i[3] = selhi ? b11 : b01;
      #pragma unroll
      for (int j=0;j<8;j++){
        const bf16x8 vf = *(const bf16x8*)&Vts[j*16+lm][kk*32+lq*8];
        oacc[j] = __builtin_amdgcn_mfma_f32_16x16x32_bf16(vf, pf.v, oacc[j], 0, 0, 0);
      }
    }
    __builtin_amdgcn_s_setprio(0);
  }
  // output: lane holds O[d=16j+4lq+r][q=wv*16+lm]; pack 4 u16 -> 8B stores
  const float inv = 1.0f / lrow;
  u16* orow = vals_c + ((size_t)(bl*SEQ + q0 + wv*16 + lm))*EHH + h*EE;
  #pragma unroll
  for (int j=0;j<8;j++){
    uint2 pkd;
    pkd.x = f2bf2(oacc[j][0]*inv, oacc[j][1]*inv);
    pkd.y = f2bf2(oacc[j][2]*inv, oacc[j][3]*inv);
    *(uint2*)(orow + j*16 + lq*4) = pkd;
  }
}

// =================== pool phase 2: sum pp + eparts + LN + head ===================
__global__ __launch_bounds__(128) void pool2_k(
    const float* __restrict__ pp, const float* __restrict__ epart,
    const float* __restrict__ g2, const float* __restrict__ b2,
    const float* __restrict__ head_W, const float* __restrict__ head_b,
    float* __restrict__ out)
{
  const int b = blockIdx.x;
  const int e = threadIdx.x;
  __shared__ float red[128];
  float acc = 0.f;
  #pragma unroll
  for (int k=0;k<16;k++) acc += pp[(size_t)(b*16+k)*EE+e];
  #pragma unroll
  for (int k=0;k<16;k++) acc += epart[(size_t)(b*16+k)*EE+e];
  red[e]=acc; __syncthreads();
  for (int s=64;s>0;s>>=1){ if(e<s) red[e]+=red[e+s]; __syncthreads(); }
  const float mean = red[0]*(1.0f/128.0f);
  __syncthreads();
  const float d = acc-mean;
  red[e]=d*d; __syncthreads();
  for (int s=64;s>0;s>>=1){ if(e<s) red[e]+=red[e+s]; __syncthreads(); }
  const float var = red[0]*(1.0f/128.0f);
  const float p = d*rsqrtf(var+1e-5f)*g2[e]+b2[e];
  __syncthreads();
  red[e] = p*head_W[e]; __syncthreads();
  for (int s=64;s>0;s>>=1){ if(e<s) red[e]+=red[e+s]; __syncthreads(); }
  if (e==0) out[b] = red[0] + head_b[0];
}

// =================== launch ===================
extern "C" void kernel_launch(void* const* d_in, const int* in_sizes, int n_in,
                              void* d_out, int out_size, void* d_ws, size_t ws_size,
                              hipStream_t stream)
{
  const float* str_fea   = (const float*)d_in[0];
  const int*   comp_fea  = (const int*)  d_in[1];
  // d_in[2] cell_fea unused by reference
  const float* atom_table= (const float*)d_in[3];
  const float* comp_W    = (const float*)d_in[4];
  const float* comp_b    = (const float*)d_in[5];
  const float* pdd_W     = (const float*)d_in[6];
  const float* pdd_b     = (const float*)d_in[7];
  const float* enc_ln_g  = (const float*)d_in[8];
  const float* enc_ln_b  = (const float*)d_in[9];
  const float* qkv_W     = (const float*)d_in[10];
  const float* qkv_b     = (const float*)d_in[11];
  const float* o_W       = (const float*)d_in[12];
  const float* o_b       = (const float*)d_in[13];
  const float* out_W     = (const float*)d_in[14];
  const float* out_b     = (const float*)d_in[15];
  const float* ffn_W     = (const float*)d_in[16];
  const float* ffn_b     = (const float*)d_in[17];
  const float* ln2_g     = (const float*)d_in[18];
  const float* ln2_b     = (const float*)d_in[19];
  const float* head_W    = (const float*)d_in[20];
  const float* head_b    = (const float*)d_in[21];
  float* out = (float*)d_out;

  // ---- diagnostic 1: input layout model ----
  bool sizes_ok = (n_in >= 22);
  if (sizes_ok){
    sizes_ok = in_sizes[0]==BB*SEQ*KF && in_sizes[1]==NTOK &&
               in_sizes[3]==NATOM*ADIM && in_sizes[4]==ADIM*EE &&
               in_sizes[10]==LL*EE*3*EHH && in_sizes[12]==LL*EHH*EHH &&
               in_sizes[14]==LL*EHH*EE   && in_sizes[16]==LL*EE*EE &&
               in_sizes[20]==EE;
  }
  if (!sizes_ok){
    sentinel_k<<<(out_size+63)/64,64,0,stream>>>(out, 99999.0f, out_size);
    return;
  }

  // ---- workspace layout (~101.6 MB; <= 109.7 MB proven) ----
  char* p = (char*)d_ws;
  size_t off = 0;
  auto alloc = [&](size_t bytes)->void*{
    off = (off + 255) & ~(size_t)255;
    void* r = p + off; off += bytes; return r;
  };
  float* w        = (float*)alloc((size_t)NTOK*4);
  float* x        = (float*)alloc((size_t)NTOK*EE*4);
  u16*   xn_bf    = (u16*)  alloc((size_t)NTOK*EE*2);
  u16*   qkc      = (u16*)  alloc((size_t)CTOK*2048*2);   // 33.6 MB chunk (Q|K)
  u16*   vTc      = (u16*)  alloc((size_t)EHH*CTOK*2);    // 16.8 MB chunk (V^T)
  u16*   vals_bf  = (u16*)  alloc((size_t)NTOK*EHH*2);    // 33.6 MB
  u16*   qkvWT_a  = (u16*)  alloc((size_t)LL*3*EHH*EE*2); // 2.36 MB (reordered)
  float* rqkv_b   = (float*)alloc((size_t)LL*3*EHH*4);    // reordered bias
  u16*   fwT_a    = (u16*)  alloc((size_t)LL*EE*EHH*2);   // 0.79 MB
  u16*   ffnWT_a  = (u16*)  alloc((size_t)LL*EE*EE*2);
  u16*   outWT_a  = (u16*)  alloc((size_t)LL*EE*EHH*2);
  float* fbp_a    = (float*)alloc((size_t)LL*8*EE*4);     // fuse_b partials
  float* atom_emb = (float*)alloc((size_t)NATOM*EE*4);
  float* epart    = (float*)alloc((size_t)(NTOK/32)*EE*4); // embed pooled partials
  float* pp       = (float*)alloc((size_t)(NTOK/32)*EE*4); // projffn pooled partials

  // ---- diagnostic 2: workspace size ----
  if (off > ws_size){
    sentinel_k<<<(out_size+63)/64,64,0,stream>>>(out, 12345.0f, out_size);
    return;
  }

  // ---- hoisted weight prep (merged; serial roles first) ----
  prep_k<<<1763,256,0,stream>>>(qkv_W, qkvWT_a, ffn_W, ffnWT_a,
                                out_W, outWT_a, qkv_b, rqkv_b,
                                atom_table, comp_W, comp_b, pdd_b, atom_emb,
                                o_b, fbp_a);
  // fwT = (o_W @ out_W)^T per layer; A = o_W f32 converted in staging
  mgemm_k<4,32,64,128,1><<<dim3(EE/64, EHH/32, LL),256,0,stream>>>(
      o_W, outWT_a, nullptr, fwT_a, EE, EHH, EHH, nullptr,
      (size_t)EHH*EHH, (size_t)EE*EHH, (size_t)EE*EHH*2);

  embed_ln_k<<<NTOK/32,512,0,stream>>>(str_fea, comp_fea, atom_emb, pdd_W,
                                       enc_ln_g, enc_ln_b, x, w, xn_bf, epart);

  for (int i=0;i<LL;i++){
    const float* gi = enc_ln_g + i*EE;
    const float* bi = enc_ln_b + i*EE;
    for (int cb=0; cb<NCHUNK; cb++){
      const int t0 = cb*CTOK;
      const int b0 = cb*CB;
      // QKV (barrier-free reg-direct): Q|K -> qkc, V -> vTc (transposed)
      qkv_k<<<dim3(3*EHH/128, CTOK/128),256,0,stream>>>(
          xn_bf + (size_t)t0*EE, qkvWT_a + (size_t)i*3*EHH*EE,
          rqkv_b + (size_t)i*3*EHH, qkc, vTc, CTOK);
      attn_mf_k<<<dim3(CB, HH, SEQ/64),256,0,stream>>>(
          qkc, vTc, w, vals_bf + (size_t)t0*EHH, b0);
    }
    // proj + resid + LN + ffn + mish + dual-LN (+pool partial on last layer)
    const float* gn = (i<LL-1) ? enc_ln_g + (i+1)*EE : gi;
    const float* bn = (i<LL-1) ? enc_ln_b + (i+1)*EE : bi;
    projffn_k<<<NTOK/32,256,0,stream>>>(
        vals_bf, fwT_a + (size_t)i*EE*EHH,
        fbp_a + (size_t)i*8*EE, out_b + (size_t)i*EE,
        ffnWT_a + (size_t)i*EE*EE, ffn_b + (size_t)i*EE,
        gi, bi, gn, bn, x, xn_bf,
        w, (i==LL-1) ? pp : nullptr);
  }
  pool2_k<<<BB,128,0,stream>>>(pp, epart, ln2_g, ln2_b, head_W, head_b, out);
}

// Round 14
// 705.610 us; speedup vs baseline: 1.4652x; 1.0158x over previous
//
#include <hip/hip_runtime.h>
#include <math.h>

#define DI __device__ __forceinline__

// ---- problem constants ----
#define BB 32
#define SEQ 512
#define KF 101
#define EE 128
#define HH 8
#define EHH 1024
#define LL 3
#define ADIM 200
#define NATOM 119
#define NTOK (BB*SEQ)   // 16384
#define CB 16           // batches per chunk
#define NCHUNK (BB/CB)  // 2
#define CTOK (CB*SEQ)   // 8192 tokens per chunk

// R28: attn SQ_LDS_BANK_CONFLICT = 5.24M/dispatch (the +8 pads give row
// strides = 4 dwords mod 32 -> 8-quad clustering on ds_read_b128). Fix =
// guide G4's XOR swizzle: unpadded Ks[64][128]/Vts[128][64], element
// (row, 16B-unit u) stored at u^(row&7), read with the same XOR (write
// r&7 / d&7, read lm&7 - same involution, 16B-aligned). Pure layout
// permutation -> bitwise. LDS 35.5->32.5KB. Rest identical to R27.

typedef unsigned short u16;
typedef __attribute__((ext_vector_type(8))) short bf16x8;
typedef __attribute__((ext_vector_type(4))) float f32x4;

DI float bf2f(u16 s){ union{unsigned int u; float f;} x; x.u = ((unsigned int)s)<<16; return x.f; }
DI u16 f2bf(float f){
  union{float f; unsigned int u;} x; x.f = f;
  unsigned int u = x.u;
  u += 0x7fffu + ((u>>16)&1u);           // RNE
  return (u16)(u>>16);
}
DI unsigned int f2bf2(float lo, float hi){
  return (unsigned int)f2bf(lo) | ((unsigned int)f2bf(hi)<<16);
}
DI float rdl(float v, int l){
  return __int_as_float(__builtin_amdgcn_readlane(__float_as_int(v), l));
}

// =================== sentinel ===================
__global__ void sentinel_k(float* out, float v, int n){
  int i = blockIdx.x*64 + threadIdx.x;
  if (i < n) out[i] = v;
}

// =================== embed + layer-0 LN (32 tokens/block, 8 waves) ===================
// x = atom_emb[idx] + str[1:]@pdd_W ; xn = LN(x); epart = per-block sum w*x
__global__ __launch_bounds__(512, 4) void embed_ln_k(
    const float* __restrict__ str_fea, const int* __restrict__ comp_fea,
    const float* __restrict__ atom_emb, const float* __restrict__ pdd_W,
    const float* __restrict__ g, const float* __restrict__ bta,
    float* __restrict__ x, float* __restrict__ w,
    u16* __restrict__ xn, float* __restrict__ epart)
{
  const int t0 = blockIdx.x*32;
  const int tid = threadIdx.x;
  const int wv = tid>>6, lane = tid&63;
  __shared__ float2 sPdd[100*64];      // 51.2 KB
  __shared__ float sEp[8][128];        // 4 KB
  for (int k2=tid; k2<100*64; k2+=512)
    sPdd[k2] = ((const float2*)pdd_W)[k2];

  float sv0[4], sv1[4];
  int idx[4];
  #pragma unroll
  for (int tk=0; tk<4; ++tk){
    const int t = t0 + wv*4 + tk;
    const float* sr0 = str_fea + (size_t)t*KF;
    sv0[tk] = sr0[lane];
    sv1[tk] = (lane+64 < KF) ? sr0[lane+64] : 0.f;
    idx[tk] = comp_fea[t];
  }
  __syncthreads();

  float a0[4],a1[4],a2[4],a3[4],c0[4],c1[4],c2[4],c3[4];
  #pragma unroll
  for (int tk=0; tk<4; ++tk){
    const float2 ae = ((const float2*)(atom_emb + (size_t)idx[tk]*EE))[lane];
    a0[tk]=ae.x; a1[tk]=0.f; a2[tk]=0.f; a3[tk]=0.f;
    c0[tk]=ae.y; c1[tk]=0.f; c2[tk]=0.f; c3[tk]=0.f;
  }
  #pragma unroll 5
  for (int j=0; j<100; j+=4){
    const float2 w0 = sPdd[(j  )*64 + lane];
    const float2 w1 = sPdd[(j+1)*64 + lane];
    const float2 w2 = sPdd[(j+2)*64 + lane];
    const float2 w3 = sPdd[(j+3)*64 + lane];
    #pragma unroll
    for (int tk=0; tk<4; ++tk){
      const float s1 = (1+j<64) ? rdl(sv0[tk],1+j) : rdl(sv1[tk],1+j-64);
      const float s2 = (2+j<64) ? rdl(sv0[tk],2+j) : rdl(sv1[tk],2+j-64);
      const float s3 = (3+j<64) ? rdl(sv0[tk],3+j) : rdl(sv1[tk],3+j-64);
      const float s4 = (4+j<64) ? rdl(sv0[tk],4+j) : rdl(sv1[tk],4+j-64);
      a0[tk] = fmaf(s1, w0.x, a0[tk]);  c0[tk] = fmaf(s1, w0.y, c0[tk]);
      a1[tk] = fmaf(s2, w1.x, a1[tk]);  c1[tk] = fmaf(s2, w1.y, c1[tk]);
      a2[tk] = fmaf(s3, w2.x, a2[tk]);  c2[tk] = fmaf(s3, w2.y, c2[tk]);
      a3[tk] = fmaf(s4, w3.x, a3[tk]);  c3[tk] = fmaf(s4, w3.y, c3[tk]);
    }
  }
  const float2 gg = ((const float2*)g)[lane];
  const float2 bb = ((const float2*)bta)[lane];
  const int e0 = lane*2;
  float ep0 = 0.f, ep1 = 0.f;
  #pragma unroll
  for (int tk=0; tk<4; ++tk){
    const int t = t0 + wv*4 + tk;
    const float vx = (a0[tk]+a1[tk])+(a2[tk]+a3[tk]);
    const float vy = (c0[tk]+c1[tk])+(c2[tk]+c3[tk]);
    ((float2*)(x + (size_t)t*EE))[lane] = make_float2(vx, vy);
    const float wt_ = rdl(sv0[tk], 0);
    if (lane==0) w[t] = sv0[tk];
    ep0 = fmaf(wt_, vx, ep0);
    ep1 = fmaf(wt_, vy, ep1);
    float s = vx + vy;
    #pragma unroll
    for (int off=32; off; off>>=1) s += __shfl_xor(s, off);
    const float mean = s*(1.0f/128.0f);
    const float d0 = vx-mean, d1 = vy-mean;
    float q = d0*d0 + d1*d1;
    #pragma unroll
    for (int off=32; off; off>>=1) q += __shfl_xor(q, off);
    const float rstd = rsqrtf(q*(1.0f/128.0f) + 1e-5f);
    u16* o = xn + (size_t)t*EE + e0;
    o[0] = f2bf(d0*rstd*gg.x + bb.x);
    o[1] = f2bf(d1*rstd*gg.y + bb.y);
  }
  sEp[wv][e0]   = ep0;
  sEp[wv][e0+1] = ep1;
  __syncthreads();
  if (tid < 128){
    float s = 0.f;
    #pragma unroll
    for (int v=0; v<8; ++v) s += sEp[v][tid];
    epart[(size_t)blockIdx.x*EE + tid] = s;
  }
}

// =================== merged weight prep ===================
DI void trans32(const float* __restrict__ W, u16* __restrict__ WT,
                int Nn, int Kk, int srcCol0, int n0, int k0, int tid,
                u16 (&tile)[32][33])
{
  const int lr = tid>>5, lc = tid&31;
  #pragma unroll
  for (int i=0;i<4;i++)
    tile[lr+i*8][lc] = f2bf(W[(size_t)(k0+lr+i*8)*Nn + srcCol0 + lc]);
  __syncthreads();
  #pragma unroll
  for (int i=0;i<4;i++)
    WT[(size_t)(n0+lr+i*8)*Kk + k0 + lc] = tile[lc][lr+i*8];
}

// roles (slow serial roles FIRST so their chains overlap the fast blocks):
// [0,119) atomemb | [119,143) fuse_b partials | [143,1295) qkvT |
// [1295,1343) ffnT | [1343,1727) outWT | [1727,1763) qkv bias reorder
__global__ __launch_bounds__(256) void prep_k(
    const float* __restrict__ qkv_W, u16* __restrict__ qkvWT,
    const float* __restrict__ ffn_W, u16* __restrict__ ffnWT,
    const float* __restrict__ out_W, u16* __restrict__ outWT,
    const float* __restrict__ qkv_b, float* __restrict__ rqkv_b,
    const float* __restrict__ atom_table, const float* __restrict__ comp_W,
    const float* __restrict__ comp_b, const float* __restrict__ pdd_b,
    float* __restrict__ atom_emb,
    const float* __restrict__ o_b, float* __restrict__ fbp)
{
  __shared__ u16 tile[32][33];
  __shared__ float sbuf[456];
  int bid = blockIdx.x;
  const int tid = threadIdx.x;
  if (bid < NATOM){
    // atom embedding: atom_emb[a] = comp_b + pdd_b + atom_table[a]@comp_W
    const int a = bid;
    const int e = tid & 127, half = tid >> 7;
    float* sAtom = sbuf;
    float* red   = sbuf + 200;
    for (int d=tid; d<ADIM; d+=256) sAtom[d] = atom_table[a*ADIM+d];
    __syncthreads();
    const int d0 = half*100;
    float b0 = half ? 0.f : (comp_b[e] + pdd_b[e]);
    float b1 = 0.f, b2 = 0.f, b3 = 0.f;
    #pragma unroll 5
    for (int d=d0; d<d0+100; d+=4){
      b0 = fmaf(sAtom[d  ], comp_W[(d  )*EE+e], b0);
      b1 = fmaf(sAtom[d+1], comp_W[(d+1)*EE+e], b1);
      b2 = fmaf(sAtom[d+2], comp_W[(d+2)*EE+e], b2);
      b3 = fmaf(sAtom[d+3], comp_W[(d+3)*EE+e], b3);
    }
    red[tid] = (b0+b1)+(b2+b3);
    __syncthreads();
    if (half==0) atom_emb[a*EE+e] = red[e] + red[128+e];
    return;
  }
  bid -= NATOM;
  if (bid < 24){
    // fuse_b partials: fbp[ly][s][n] = sum_{k in s-slice} o_b[k]*out_W[k][n]
    const int ly = bid >> 3, s = bid & 7;
    const float* ob = o_b + (size_t)ly*EHH;
    const float* oW = out_W + (size_t)ly*EHH*EE;
    const int n = tid & 127, h2 = tid >> 7;
    const int kb = s*128 + h2*64;
    float b0=0.f,b1=0.f,b2=0.f,b3=0.f;
    #pragma unroll 4
    for (int k2=kb; k2<kb+64; k2+=4){
      b0 = fmaf(ob[k2  ], oW[(size_t)(k2  )*EE+n], b0);
      b1 = fmaf(ob[k2+1], oW[(size_t)(k2+1)*EE+n], b1);
      b2 = fmaf(ob[k2+2], oW[(size_t)(k2+2)*EE+n], b2);
      b3 = fmaf(ob[k2+3], oW[(size_t)(k2+3)*EE+n], b3);
    }
    float* red = sbuf;
    red[tid] = (b0+b1)+(b2+b3);
    __syncthreads();
    if (h2==0) fbp[((size_t)ly*8 + s)*EE + n] = red[n] + red[128+n];
    return;
  }
  bid -= 24;
  if (bid < 1152){
    const int xb = bid%96, yb = (bid/96)%4, zb = bid/384;
    const int n0 = xb*32, k0 = yb*32;
    int c0;
    if (n0 < 2048) c0 = (n0>>8)*384 + (n0&255);
    else { const int m0 = n0-2048; c0 = (m0>>7)*384 + 256 + (m0&127); }
    trans32(qkv_W + (size_t)zb*EE*3*EHH, qkvWT + (size_t)zb*3*EHH*EE,
            3*EHH, EE, c0, n0, k0, tid, tile);
    return;
  }
  bid -= 1152;
  if (bid < 48){
    const int xb = bid%4, yb = (bid/4)%4, zb = bid/16;
    trans32(ffn_W + (size_t)zb*EE*EE, ffnWT + (size_t)zb*EE*EE,
            EE, EE, xb*32, xb*32, yb*32, tid, tile);
    return;
  }
  bid -= 48;
  if (bid < 384){
    const int xb = bid%4, yb = (bid/4)%32, zb = bid/128;
    trans32(out_W + (size_t)zb*EHH*EE, outWT + (size_t)zb*EE*EHH,
            EE, EHH, xb*32, xb*32, yb*32, tid, tile);
    return;
  }
  bid -= 384;
  {
    const int l = bid/12;
    const int n = (bid%12)*256 + tid;
    int c;
    if (n < 2048) c = (n>>8)*384 + (n&255);
    else { const int m = n-2048; c = (m>>7)*384 + 256 + (m&127); }
    rqkv_b[(size_t)l*3*EHH + n] = qkv_b[(size_t)l*3*EHH + c];
  }
}

// =================== MFMA bf16 GEMM (prep fwT only; layer-batched) ===================
// A: M x Kk row-major (f32 when AF32 — converted in staging).
// BT: Nn x Kk bf16. EPI 4: bf16 transposed store (no bias).
template<int EPI, int BM, int BN, int BK, int AF32>
__global__ __launch_bounds__(256) void mgemm_k(
    const void* __restrict__ Av, const u16* __restrict__ BT,
    const float* __restrict__ bias, void* __restrict__ Cv,
    int Nn, int Kk, int Mdim, void* __restrict__ C2,
    size_t sA, size_t sBT, size_t sCb)
{
  const int lz = blockIdx.z;
  BT += (size_t)lz*sBT;
  void* C = (void*)((char*)Cv + (size_t)lz*sCb);

  constexpr int LDK = BK + 8;
  __shared__ u16 As[BM*LDK];
  __shared__ u16 Bs[BN*LDK];
  const int tid = threadIdx.x;
  const int m0 = blockIdx.y*BM, n0 = blockIdx.x*BN;
  constexpr int WMN = (BM>=128)?2:1;
  constexpr int WNN = 4/WMN;
  constexpr int WM = BM/WMN;
  constexpr int WN = BN/WNN;
  constexpr int FM = WM/16, FN = WN/16;
  const int wv = tid>>6, lane = tid&63;
  const int wm = (wv/WNN)*WM;
  const int wn = (wv%WNN)*WN;
  const int lm = lane&15, lq = lane>>4;

  f32x4 acc[FM][FN];
  #pragma unroll
  for (int i=0;i<FM;i++)
    #pragma unroll
    for (int j=0;j<FN;j++) acc[i][j] = (f32x4){0.f,0.f,0.f,0.f};

  constexpr int BCH = BN*BK/8;

  for (int k0=0; k0<Kk; k0+=BK){
    if constexpr (AF32){
      const float* A = (const float*)Av + (size_t)lz*sA;
      #pragma unroll
      for (int c = tid; c < BM*BK/4; c += 256){
        const int r = c/(BK/4), kg = c - r*(BK/4);
        const float4 v = *(const float4*)(A + (size_t)(m0+r)*Kk + k0 + kg*4);
        union { u16 u[4]; unsigned long long ll; } t;
        t.u[0]=f2bf(v.x); t.u[1]=f2bf(v.y); t.u[2]=f2bf(v.z); t.u[3]=f2bf(v.w);
        *(unsigned long long*)&As[r*LDK + kg*4] = t.ll;
      }
    } else {
      const u16* A = (const u16*)Av + (size_t)lz*sA;
      #pragma unroll
      for (int c = tid; c < BM*BK/8; c += 256){
        const int r = c/(BK/8), kg = c - r*(BK/8);
        const float4 v = *(const float4*)(A + (size_t)(m0+r)*Kk + k0 + kg*8);
        *(float4*)&As[r*LDK + kg*8] = v;
      }
    }
    #pragma unroll
    for (int c = tid; c < BCH; c += 256){
      const int r = c/(BK/8), kg = c - r*(BK/8);
      const float4 v = *(const float4*)(BT + (size_t)(n0+r)*Kk + k0 + kg*8);
      *(float4*)&Bs[r*LDK + kg*8] = v;
    }
    __syncthreads();
    #pragma unroll
    for (int kk=0; kk<BK/32; kk++){
      bf16x8 af[FM], bfr[FN];
      #pragma unroll
      for (int i=0;i<FM;i++)
        af[i] = *(const bf16x8*)&As[(wm + i*16 + lm)*LDK + kk*32 + lq*8];
      #pragma unroll
      for (int j=0;j<FN;j++)
        bfr[j] = *(const bf16x8*)&Bs[(wn + j*16 + lm)*LDK + kk*32 + lq*8];
      #pragma unroll
      for (int i=0;i<FM;i++)
        #pragma unroll
        for (int j=0;j<FN;j++)
          acc[i][j] = __builtin_amdgcn_mfma_f32_16x16x32_bf16(af[i], bfr[j], acc[i][j], 0, 0, 0);
    }
    __syncthreads();
  }
  #pragma unroll
  for (int i=0;i<FM;i++){
    #pragma unroll
    for (int j=0;j<FN;j++){
      const int col = n0 + wn + j*16 + lm;
      const float bv = (EPI==4) ? 0.f : bias[col];
      #pragma unroll
      for (int r=0;r<4;r++){
        const int row = m0 + wm + i*16 + lq*4 + r;
        float v = acc[i][j][r] + bv;
        if constexpr (EPI==4){
          ((u16*)C)[(size_t)col*Mdim + row] = f2bf(v);
        } else {
          ((u16*)C)[(size_t)row*Nn + col] = f2bf(v);
        }
      }
    }
  }
}

// =================== QKV GEMM: barrier-free, LDS-free, reg-direct ===================
// A: xn chunk [CTOK][128] bf16; BT: qkvWT layer [3072][128] bf16.
// Fragments loaded direct from global (L2-resident), kk double-buffered.
// n0<2048 (Q|K): SWAPPED mfma -> packed 8B stores into qkc[m][col];
// n0>=2048 (V): normal -> packed 8B stores into vTc[col-2048][tok].
__global__ __launch_bounds__(256) void qkv_k(
    const u16* __restrict__ A, const u16* __restrict__ BT,
    const float* __restrict__ bias, u16* __restrict__ qkc,
    u16* __restrict__ vTc, int Mdim)
{
  const int n0 = blockIdx.x*128, m0 = blockIdx.y*128;
  const int tid = threadIdx.x;
  const int wv = tid>>6, lane = tid&63;
  const int lm = lane&15, lq = lane>>4;
  const int wm = (wv>>1)*64, wn = (wv&1)*64;   // WMN=2, WNN=2
  const bool swp = (n0 < 2048);

  const u16* Ab = A  + (size_t)(m0+wm+lm)*EE + lq*8;
  const u16* Bb = BT + (size_t)(n0+wn+lm)*EE + lq*8;

  f32x4 acc[4][4];
  #pragma unroll
  for (int i=0;i<4;i++)
    #pragma unroll
    for (int j=0;j<4;j++) acc[i][j] = (f32x4){0.f,0.f,0.f,0.f};

  bf16x8 afb[2][4], bfb[2][4];
  #pragma unroll
  for (int i=0;i<4;i++){
    afb[0][i] = *(const bf16x8*)(Ab + (size_t)i*16*EE);
    bfb[0][i] = *(const bf16x8*)(Bb + (size_t)i*16*EE);
  }
  #pragma unroll
  for (int kk=0; kk<4; kk++){
    const int cur = kk&1, nxt = cur^1;
    if (kk<3){
      #pragma unroll
      for (int i=0;i<4;i++){
        afb[nxt][i] = *(const bf16x8*)(Ab + (size_t)i*16*EE + (kk+1)*32);
        bfb[nxt][i] = *(const bf16x8*)(Bb + (size_t)i*16*EE + (kk+1)*32);
      }
    }
    if (swp){
      #pragma unroll
      for (int i=0;i<4;i++)
        #pragma unroll
        for (int j=0;j<4;j++)
          acc[i][j] = __builtin_amdgcn_mfma_f32_16x16x32_bf16(bfb[cur][j], afb[cur][i], acc[i][j], 0, 0, 0);
    } else {
      #pragma unroll
      for (int i=0;i<4;i++)
        #pragma unroll
        for (int j=0;j<4;j++)
          acc[i][j] = __builtin_amdgcn_mfma_f32_16x16x32_bf16(afb[cur][i], bfb[cur][j], acc[i][j], 0, 0, 0);
    }
  }

  if (swp){
    #pragma unroll
    for (int i=0;i<4;i++){
      const int m = m0 + wm + i*16 + lm;
      #pragma unroll
      for (int j=0;j<4;j++){
        const int colb = n0 + wn + j*16 + lq*4;
        const float4 bv4 = *(const float4*)&bias[colb];
        uint2 pkd;
        pkd.x = f2bf2(acc[i][j][0]+bv4.x, acc[i][j][1]+bv4.y);
        pkd.y = f2bf2(acc[i][j][2]+bv4.z, acc[i][j][3]+bv4.w);
        *(uint2*)(qkc + (size_t)m*2048 + colb) = pkd;
      }
    }
  } else {
    #pragma unroll
    for (int i=0;i<4;i++){
      const int row0 = m0 + wm + i*16 + lq*4;
      #pragma unroll
      for (int j=0;j<4;j++){
        const int col = n0 + wn + j*16 + lm;
        const float bv = bias[col];
        uint2 pkd;
        pkd.x = f2bf2(acc[i][j][0]+bv, acc[i][j][1]+bv);
        pkd.y = f2bf2(acc[i][j][2]+bv, acc[i][j][3]+bv);
        *(uint2*)(vTc + (size_t)(col-2048)*Mdim + row0) = pkd;
      }
    }
  }
}

// =================== fused proj+LN + ffn+mish + dual-LN (+pool partial) ===================
__global__ __launch_bounds__(256) void projffn_k(
    const u16* __restrict__ vals, const u16* __restrict__ fwT,
    const float* __restrict__ fbp, const float* __restrict__ outb,
    const u16* __restrict__ ffnWT, const float* __restrict__ fnb,
    const float* __restrict__ g1, const float* __restrict__ b1,
    const float* __restrict__ g2, const float* __restrict__ b2,
    float* __restrict__ x_io, u16* __restrict__ xn_io,
    const float* __restrict__ w, float* __restrict__ pp)
{
  constexpr int BM = 32, BK = 128, LDK = BK + 8;
  __shared__ u16 As[BM*LDK];        // proj A tiles; then xn2 (bf16)
  __shared__ u16 Bs[EE*LDK];        // fwT tiles; then ffnWT
  __shared__ float sred[BM*8];
  const int tid = threadIdx.x;
  const int wv = tid>>6, lane = tid&63;
  const int lm = lane&15, lq = lane>>4;
  const int m0 = blockIdx.x*BM;
  const int wn = wv*32;             // 4 waves x 32 cols

  f32x4 acc[2][2];
  #pragma unroll
  for (int i=0;i<2;i++)
    #pragma unroll
    for (int j=0;j<2;j++) acc[i][j] = (f32x4){0.f,0.f,0.f,0.f};

  // ---- phase A: proj GEMM, K=1024 ----
  for (int k0=0; k0<EHH; k0+=BK){
    #pragma unroll
    for (int c = tid; c < BM*BK/8; c += 256){
      const int r = c>>4, kg = c&15;
      *(float4*)&As[r*LDK + kg*8] = *(const float4*)(vals + (size_t)(m0+r)*EHH + k0 + kg*8);
    }
    #pragma unroll
    for (int c = tid; c < EE*BK/8; c += 256){
      const int r = c>>4, kg = c&15;
      *(float4*)&Bs[r*LDK + kg*8] = *(const float4*)(fwT + (size_t)r*EHH + k0 + kg*8);
    }
    __syncthreads();
    #pragma unroll
    for (int kk=0; kk<BK/32; kk++){
      bf16x8 af[2], bfr[2];
      #pragma unroll
      for (int i=0;i<2;i++)
        af[i] = *(const bf16x8*)&As[(i*16 + lm)*LDK + kk*32 + lq*8];
      #pragma unroll
      for (int j=0;j<2;j++)
        bfr[j] = *(const bf16x8*)&Bs[(wn + j*16 + lm)*LDK + kk*32 + lq*8];
      #pragma unroll
      for (int i=0;i<2;i++)
        #pragma unroll
        for (int j=0;j<2;j++)
          acc[i][j] = __builtin_amdgcn_mfma_f32_16x16x32_bf16(af[i], bfr[j], acc[i][j], 0, 0, 0);
    }
    __syncthreads();
  }

  // ---- phase A epilogue: vout = acc + fb + x ; LN stats ----
  float vout[2][2][4];
  float ps[2][4], qs[2][4];
  #pragma unroll
  for (int i=0;i<2;i++)
    #pragma unroll
    for (int r=0;r<4;r++){ ps[i][r]=0.f; qs[i][r]=0.f; }
  #pragma unroll
  for (int i=0;i<2;i++){
    #pragma unroll
    for (int j=0;j<2;j++){
      const int col = wn + j*16 + lm;
      const float bv = outb[col]
        + ((fbp[0*EE+col]+fbp[1*EE+col])+(fbp[2*EE+col]+fbp[3*EE+col]))
        + ((fbp[4*EE+col]+fbp[5*EE+col])+(fbp[6*EE+col]+fbp[7*EE+col]));
      #pragma unroll
      for (int r=0;r<4;r++){
        const int row = m0 + i*16 + lq*4 + r;
        const float v = acc[i][j][r] + bv + x_io[(size_t)row*EE + col];
        vout[i][j][r] = v;
        ps[i][r] += v; qs[i][r] += v*v;
      }
    }
  }
  #pragma unroll
  for (int i=0;i<2;i++)
    #pragma unroll
    for (int r=0;r<4;r++){
      float s = ps[i][r], q = qs[i][r];
      s += __shfl_xor(s,1); s += __shfl_xor(s,2); s += __shfl_xor(s,4); s += __shfl_xor(s,8);
      q += __shfl_xor(q,1); q += __shfl_xor(q,2); q += __shfl_xor(q,4); q += __shfl_xor(q,8);
      if (lm==0){
        const int row = i*16 + lq*4 + r;
        sred[row*4 + wv] = s;
        sred[BM*4 + row*4 + wv] = q;
      }
    }
  __syncthreads();
  // xn2 -> As (bf16), and stage ffnWT -> Bs
  #pragma unroll
  for (int i=0;i<2;i++)
    #pragma unroll
    for (int r=0;r<4;r++){
      const int row = i*16 + lq*4 + r;
      const float s = sred[row*4+0]+sred[row*4+1]+sred[row*4+2]+sred[row*4+3];
      const float q = sred[BM*4+row*4+0]+sred[BM*4+row*4+1]+sred[BM*4+row*4+2]+sred[BM*4+row*4+3];
      const float mean = s*(1.0f/128.0f);
      const float var  = q*(1.0f/128.0f) - mean*mean;
      const float rstd = rsqrtf(var + 1e-5f);
      #pragma unroll
      for (int j=0;j<2;j++){
        const int col = wn + j*16 + lm;
        const float xnv = (vout[i][j][r]-mean)*rstd*g1[col] + b1[col];
        As[row*LDK + col] = f2bf(xnv);
      }
    }
  #pragma unroll
  for (int c = tid; c < EE*EE/8; c += 256){
    const int r = c>>4, kg = c&15;
    *(float4*)&Bs[r*LDK + kg*8] = *(const float4*)(ffnWT + (size_t)r*EE + kg*8);
  }
  __syncthreads();

  // ---- phase B: ffn GEMM, K=128 from LDS ----
  f32x4 fa[2][2];
  #pragma unroll
  for (int i=0;i<2;i++)
    #pragma unroll
    for (int j=0;j<2;j++) fa[i][j] = (f32x4){0.f,0.f,0.f,0.f};
  #pragma unroll
  for (int kk=0; kk<4; kk++){
    bf16x8 af[2], bfr[2];
    #pragma unroll
    for (int i=0;i<2;i++)
      af[i] = *(const bf16x8*)&As[(i*16 + lm)*LDK + kk*32 + lq*8];
    #pragma unroll
    for (int j=0;j<2;j++)
      bfr[j] = *(const bf16x8*)&Bs[(wn + j*16 + lm)*LDK + kk*32 + lq*8];
    #pragma unroll
    for (int i=0;i<2;i++)
      #pragma unroll
      for (int j=0;j<2;j++)
        fa[i][j] = __builtin_amdgcn_mfma_f32_16x16x32_bf16(af[i], bfr[j], fa[i][j], 0, 0, 0);
  }

  // ---- phase C: t = vout + mish(fa + fnb); dual row-LN ----
  float tv[2][2][4];
  #pragma unroll
  for (int i=0;i<2;i++)
    #pragma unroll
    for (int r=0;r<4;r++){ ps[i][r]=0.f; qs[i][r]=0.f; }
  #pragma unroll
  for (int i=0;i<2;i++){
    #pragma unroll
    for (int j=0;j<2;j++){
      const int col = wn + j*16 + lm;
      const float bv = fnb[col];
      #pragma unroll
      for (int r=0;r<4;r++){
        const float v = fa[i][j][r] + bv;
        const float E = __expf(v);
        const float uu = E*E + 2.f*E;
        const float mi = (v > 20.f) ? v : v*(uu/(uu+2.f));
        const float t = vout[i][j][r] + mi;
        tv[i][j][r] = t;
        ps[i][r] += t; qs[i][r] += t*t;
      }
    }
  }
  #pragma unroll
  for (int i=0;i<2;i++)
    #pragma unroll
    for (int r=0;r<4;r++){
      float s = ps[i][r], q = qs[i][r];
      s += __shfl_xor(s,1); s += __shfl_xor(s,2); s += __shfl_xor(s,4); s += __shfl_xor(s,8);
      q += __shfl_xor(q,1); q += __shfl_xor(q,2); q += __shfl_xor(q,4); q += __shfl_xor(q,8);
      if (lm==0){
        const int row = i*16 + lq*4 + r;
        sred[row*4 + wv] = s;
        sred[BM*4 + row*4 + wv] = q;
      }
    }
  __syncthreads();
  float xv[2][2][4];
  float ps2[2][4], qs2[2][4];
  #pragma unroll
  for (int i=0;i<2;i++)
    #pragma unroll
    for (int r=0;r<4;r++){
      const int row = i*16 + lq*4 + r;
      const float s = sred[row*4+0]+sred[row*4+1]+sred[row*4+2]+sred[row*4+3];
      const float q = sred[BM*4+row*4+0]+sred[BM*4+row*4+1]+sred[BM*4+row*4+2]+sred[BM*4+row*4+3];
      const float mean = s*(1.0f/128.0f);
      const float var  = q*(1.0f/128.0f) - mean*mean;
      const float rstd = rsqrtf(var + 1e-5f);
      float s2 = 0.f, q2 = 0.f;
      #pragma unroll
      for (int j=0;j<2;j++){
        const int col = wn + j*16 + lm;
        const float xnv = (tv[i][j][r]-mean)*rstd*g1[col] + b1[col];
        x_io[(size_t)(m0+row)*EE + col] = xnv;
        xv[i][j][r] = xnv;
        s2 += xnv; q2 += xnv*xnv;
      }
      ps2[i][r] = s2; qs2[i][r] = q2;
    }
  // fused pool partial (last layer): pp[block][col] = sum_rows w[row]*x[row][col]
  if (pp){
    float pz[2] = {0.f, 0.f};
    #pragma unroll
    for (int i=0;i<2;i++)
      #pragma unroll
      for (int r=0;r<4;r++){
        const float wr = w[m0 + i*16 + lq*4 + r];
        pz[0] = fmaf(wr, xv[i][0][r], pz[0]);
        pz[1] = fmaf(wr, xv[i][1][r], pz[1]);
      }
    #pragma unroll
    for (int j=0;j<2;j++){
      pz[j] += __shfl_xor(pz[j], 16);
      pz[j] += __shfl_xor(pz[j], 32);
      if (lq==0) pp[(size_t)blockIdx.x*EE + wn + j*16 + lm] = pz[j];
    }
  }
  __syncthreads();
  #pragma unroll
  for (int i=0;i<2;i++)
    #pragma unroll
    for (int r=0;r<4;r++){
      float s = ps2[i][r], q = qs2[i][r];
      s += __shfl_xor(s,1); s += __shfl_xor(s,2); s += __shfl_xor(s,4); s += __shfl_xor(s,8);
      q += __shfl_xor(q,1); q += __shfl_xor(q,2); q += __shfl_xor(q,4); q += __shfl_xor(q,8);
      if (lm==0){
        const int row = i*16 + lq*4 + r;
        sred[row*4 + wv] = s;
        sred[BM*4 + row*4 + wv] = q;
      }
    }
  __syncthreads();
  #pragma unroll
  for (int i=0;i<2;i++)
    #pragma unroll
    for (int r=0;r<4;r++){
      const int row = i*16 + lq*4 + r;
      const float s = sred[row*4+0]+sred[row*4+1]+sred[row*4+2]+sred[row*4+3];
      const float q = sred[BM*4+row*4+0]+sred[BM*4+row*4+1]+sred[BM*4+row*4+2]+sred[BM*4+row*4+3];
      const float mean = s*(1.0f/128.0f);
      const float var  = q*(1.0f/128.0f) - mean*mean;
      const float rstd = rsqrtf(var + 1e-5f);
      #pragma unroll
      for (int j=0;j<2;j++){
        const int col = wn + j*16 + lm;
        const float xnv = (xv[i][j][r]-mean)*rstd*g2[col] + b2[col];
        xn_io[(size_t)(m0+row)*EE + col] = f2bf(xnv);
      }
    }
}

// =================== MFMA flash attention (swapped operands, in-reg P, XOR-swz LDS) ===================
// qkc: [tok][h*256 + (q:0..127 | k:128..255)] bf16, tok chunk-local.
// vTc: [h*128+d][tok] bf16 (pre-transposed V), tok chunk-local.
// Ks/Vts unpadded; 16B-unit u stored at u^(row&7) (G4 XOR swizzle).
__global__ __launch_bounds__(256, 4) void attn_mf_k(
    const u16* __restrict__ qkc, const u16* __restrict__ vTc,
    const float* __restrict__ w, u16* __restrict__ vals_c, int b0)
{
  const int bl = blockIdx.x;   // id%8 -> XCD-local batch groups
  const int h  = blockIdx.y;
  const int qt = blockIdx.z;
  const int tid = threadIdx.x;
  const int wv = tid>>6, lane = tid&63;
  const int lm = lane&15, lq = lane>>4;

  __shared__ u16 Ks[64*128];    // swizzled, 16 KB
  __shared__ u16 Vts[128*64];   // swizzled, 16 KB
  __shared__ float wt[64], qwt[64];

  const size_t rs = 2048;
  const u16* qk = qkc + (size_t)bl*SEQ*rs + (size_t)h*256;
  const u16* vb = vTc + (size_t)h*128*CTOK + (size_t)bl*SEQ;
  const int q0 = qt*64;

  // Q fragments in registers (constant across all kt)
  bf16x8 qf[4];
  #pragma unroll
  for (int kk=0; kk<4; kk++)
    qf[kk] = *(const bf16x8*)(qk + (size_t)(q0 + wv*16 + lm)*rs + kk*32 + lq*8);
  if (tid < 64) qwt[tid] = w[(b0+bl)*SEQ + q0 + tid];
  __syncthreads();
  const float qw = qwt[wv*16 + lm];   // this lane's q-row weight

  f32x4 oacc[8];
  #pragma unroll
  for (int j=0;j<8;j++) oacc[j] = (f32x4){0.f,0.f,0.f,0.f};
  float mrow = -INFINITY, lrow = 0.f;
  const float scale = 0.08838834764831845f;  // 1/sqrt(128)

  const int srcA = ((lq&1)<<1)*16 + lm;   // source lane for P elems 0..3
  const int srcB = srcA + 16;             // source lane for P elems 4..7
  const bool selhi = (lq>>1) != 0;
  const int swl = lm & 7;                 // read-side XOR key (row&7 = lm&7)

  for (int kt=0; kt<8; kt++){
    __syncthreads();
    #pragma unroll
    for (int it=0; it<4; it++){
      const int fi = it*256 + tid;
      const int r = fi >> 4, g = fi & 15;          // row r, 16B-unit g
      *(float4*)&Ks[r*128 + ((g ^ (r&7))*8)] =
          *(const float4*)(qk + (size_t)(kt*64+r)*rs + 128 + g*8);
    }
    #pragma unroll
    for (int it=0; it<4; it++){
      const int fi = it*256 + tid;
      const int d = fi >> 3, g = fi & 7;           // row d, 16B-unit g
      *(float4*)&Vts[d*64 + ((g ^ (d&7))*8)] =
          *(const float4*)(vb + (size_t)d*CTOK + kt*64 + g*8);
    }
    if (tid < 64) wt[tid] = w[(b0+bl)*SEQ + kt*64 + tid];
    __syncthreads();

    // QK^T swapped: sacc[j] = D[k-local][q], A = K rows, B = Q rows
    f32x4 sacc[4];
    #pragma unroll
    for (int j=0;j<4;j++) sacc[j] = (f32x4){0.f,0.f,0.f,0.f};
    __builtin_amdgcn_s_setprio(1);
    #pragma unroll
    for (int kk=0; kk<4; kk++){
      const bf16x8 bfq = qf[kk];
      #pragma unroll
      for (int j=0;j<4;j++){
        const bf16x8 afk = *(const bf16x8*)&Ks[(j*16+lm)*128 + (((kk*4+lq) ^ swl)*8)];
        sacc[j] = __builtin_amdgcn_mfma_f32_16x16x32_bf16(afk, bfq, sacc[j], 0, 0, 0);
      }
    }
    __builtin_amdgcn_s_setprio(0);

    // lane (lm,lq) holds S[k=16j+4lq+r][q=wv*16+lm]
    float s[4][4], wk[4][4];
    const bool qpos = qw > 0.f;
    #pragma unroll
    for (int j=0;j<4;j++)
      #pragma unroll
      for (int r=0;r<4;r++){
        wk[j][r] = wt[j*16 + lq*4 + r];
        const bool keep = qpos && (wk[j][r] > 0.f);
        s[j][r] = keep ? sacc[j][r]*scale : -9.0e15f;
      }
    // per-q (per-lane) max over 16 + cross-lq
    float rm = s[0][0];
    #pragma unroll
    for (int j=0;j<4;j++)
      #pragma unroll
      for (int r=0;r<4;r++) if (j|r) rm = fmaxf(rm, s[j][r]);
    rm = fmaxf(rm, __shfl_xor(rm, 16));
    rm = fmaxf(rm, __shfl_xor(rm, 32));
    const float newm = fmaxf(mrow, rm);
    const float alpha = __expf(mrow - newm);
    float ls = 0.f;
    int pk[4][2];
    #pragma unroll
    for (int j=0;j<4;j++){
      const float p0 = wk[j][0]*__expf(s[j][0]-newm);
      const float p1 = wk[j][1]*__expf(s[j][1]-newm);
      const float p2 = wk[j][2]*__expf(s[j][2]-newm);
      const float p3 = wk[j][3]*__expf(s[j][3]-newm);
      ls += ((p0+p1)+(p2+p3));
      pk[j][0] = (int)f2bf2(p0, p1);
      pk[j][1] = (int)f2bf2(p2, p3);
    }
    ls += __shfl_xor(ls, 16);
    ls += __shfl_xor(ls, 32);
    lrow = lrow*alpha + ls;
    mrow = newm;
    #pragma unroll
    for (int j=0;j<8;j++)
      #pragma unroll
      for (int r=0;r<4;r++) oacc[j][r] *= alpha;

    // PV swapped: B-fragment for lane = P[q=wv*16+lm][k=kk*32+lq*8..+7]
    __builtin_amdgcn_s_setprio(1);
    #pragma unroll
    for (int kk=0; kk<2; kk++){
      const int j0 = 2*kk, j1 = 2*kk+1;
      const int a00 = __shfl(pk[j0][0], srcA), a01 = __shfl(pk[j0][1], srcA);
      const int b00 = __shfl(pk[j0][0], srcB), b01 = __shfl(pk[j0][1], srcB);
      const int a10 = __shfl(pk[j1][0], srcA), a11 = __shfl(pk[j1][1], srcA);
      const int b10 = __shfl(pk[j1][0], srcB), b11 = __shfl(pk[j1][1], srcB);
      union { int i[4]; bf16x8 v; } pf;
      pf.i[0] = selhi ? a10 : a00;
      pf.i[1] = selhi ? a11 : a01;
      pf.i[2] = selhi ? b10 : b00;
      pf.i[3] = selhi ? b11 : b01;
      #pragma unroll
      for (int j=0;j<8;j++){
        const bf16x8 vf = *(const bf16x8*)&Vts[(j*16+lm)*64 + (((kk*4+lq) ^ swl)*8)];
        oacc[j] = __builtin_amdgcn_mfma_f32_16x16x32_bf16(vf, pf.v, oacc[j], 0, 0, 0);
      }
    }
    __builtin_amdgcn_s_setprio(0);
  }
  // output: lane holds O[d=16j+4lq+r][q=wv*16+lm]; pack 4 u16 -> 8B stores
  const float inv = 1.0f / lrow;
  u16* orow = vals_c + ((size_t)(bl*SEQ + q0 + wv*16 + lm))*EHH + h*EE;
  #pragma unroll
  for (int j=0;j<8;j++){
    uint2 pkd;
    pkd.x = f2bf2(oacc[j][0]*inv, oacc[j][1]*inv);
    pkd.y = f2bf2(oacc[j][2]*inv, oacc[j][3]*inv);
    *(uint2*)(orow + j*16 + lq*4) = pkd;
  }
}

// =================== pool phase 2: sum pp + eparts + LN + head ===================
__global__ __launch_bounds__(128) void pool2_k(
    const float* __restrict__ pp, const float* __restrict__ epart,
    const float* __restrict__ g2, const float* __restrict__ b2,
    const float* __restrict__ head_W, const float* __restrict__ head_b,
    float* __restrict__ out)
{
  const int b = blockIdx.x;
  const int e = threadIdx.x;
  __shared__ float red[128];
  float acc = 0.f;
  #pragma unroll
  for (int k=0;k<16;k++) acc += pp[(size_t)(b*16+k)*EE+e];
  #pragma unroll
  for (int k=0;k<16;k++) acc += epart[(size_t)(b*16+k)*EE+e];
  red[e]=acc; __syncthreads();
  for (int s=64;s>0;s>>=1){ if(e<s) red[e]+=red[e+s]; __syncthreads(); }
  const float mean = red[0]*(1.0f/128.0f);
  __syncthreads();
  const float d = acc-mean;
  red[e]=d*d; __syncthreads();
  for (int s=64;s>0;s>>=1){ if(e<s) red[e]+=red[e+s]; __syncthreads(); }
  const float var = red[0]*(1.0f/128.0f);
  const float p = d*rsqrtf(var+1e-5f)*g2[e]+b2[e];
  __syncthreads();
  red[e] = p*head_W[e]; __syncthreads();
  for (int s=64;s>0;s>>=1){ if(e<s) red[e]+=red[e+s]; __syncthreads(); }
  if (e==0) out[b] = red[0] + head_b[0];
}

// =================== launch ===================
extern "C" void kernel_launch(void* const* d_in, const int* in_sizes, int n_in,
                              void* d_out, int out_size, void* d_ws, size_t ws_size,
                              hipStream_t stream)
{
  const float* str_fea   = (const float*)d_in[0];
  const int*   comp_fea  = (const int*)  d_in[1];
  // d_in[2] cell_fea unused by reference
  const float* atom_table= (const float*)d_in[3];
  const float* comp_W    = (const float*)d_in[4];
  const float* comp_b    = (const float*)d_in[5];
  const float* pdd_W     = (const float*)d_in[6];
  const float* pdd_b     = (const float*)d_in[7];
  const float* enc_ln_g  = (const float*)d_in[8];
  const float* enc_ln_b  = (const float*)d_in[9];
  const float* qkv_W     = (const float*)d_in[10];
  const float* qkv_b     = (const float*)d_in[11];
  const float* o_W       = (const float*)d_in[12];
  const float* o_b       = (const float*)d_in[13];
  const float* out_W     = (const float*)d_in[14];
  const float* out_b     = (const float*)d_in[15];
  const float* ffn_W     = (const float*)d_in[16];
  const float* ffn_b     = (const float*)d_in[17];
  const float* ln2_g     = (const float*)d_in[18];
  const float* ln2_b     = (const float*)d_in[19];
  const float* head_W    = (const float*)d_in[20];
  const float* head_b    = (const float*)d_in[21];
  float* out = (float*)d_out;

  // ---- diagnostic 1: input layout model ----
  bool sizes_ok = (n_in >= 22);
  if (sizes_ok){
    sizes_ok = in_sizes[0]==BB*SEQ*KF && in_sizes[1]==NTOK &&
               in_sizes[3]==NATOM*ADIM && in_sizes[4]==ADIM*EE &&
               in_sizes[10]==LL*EE*3*EHH && in_sizes[12]==LL*EHH*EHH &&
               in_sizes[14]==LL*EHH*EE   && in_sizes[16]==LL*EE*EE &&
               in_sizes[20]==EE;
  }
  if (!sizes_ok){
    sentinel_k<<<(out_size+63)/64,64,0,stream>>>(out, 99999.0f, out_size);
    return;
  }

  // ---- workspace layout (~101.6 MB; <= 109.7 MB proven) ----
  char* p = (char*)d_ws;
  size_t off = 0;
  auto alloc = [&](size_t bytes)->void*{
    off = (off + 255) & ~(size_t)255;
    void* r = p + off; off += bytes; return r;
  };
  float* w        = (float*)alloc((size_t)NTOK*4);
  float* x        = (float*)alloc((size_t)NTOK*EE*4);
  u16*   xn_bf    = (u16*)  alloc((size_t)NTOK*EE*2);
  u16*   qkc      = (u16*)  alloc((size_t)CTOK*2048*2);   // 33.6 MB chunk (Q|K)
  u16*   vTc      = (u16*)  alloc((size_t)EHH*CTOK*2);    // 16.8 MB chunk (V^T)
  u16*   vals_bf  = (u16*)  alloc((size_t)NTOK*EHH*2);    // 33.6 MB
  u16*   qkvWT_a  = (u16*)  alloc((size_t)LL*3*EHH*EE*2); // 2.36 MB (reordered)
  float* rqkv_b   = (float*)alloc((size_t)LL*3*EHH*4);    // reordered bias
  u16*   fwT_a    = (u16*)  alloc((size_t)LL*EE*EHH*2);   // 0.79 MB
  u16*   ffnWT_a  = (u16*)  alloc((size_t)LL*EE*EE*2);
  u16*   outWT_a  = (u16*)  alloc((size_t)LL*EE*EHH*2);
  float* fbp_a    = (float*)alloc((size_t)LL*8*EE*4);     // fuse_b partials
  float* atom_emb = (float*)alloc((size_t)NATOM*EE*4);
  float* epart    = (float*)alloc((size_t)(NTOK/32)*EE*4); // embed pooled partials
  float* pp       = (float*)alloc((size_t)(NTOK/32)*EE*4); // projffn pooled partials

  // ---- diagnostic 2: workspace size ----
  if (off > ws_size){
    sentinel_k<<<(out_size+63)/64,64,0,stream>>>(out, 12345.0f, out_size);
    return;
  }

  // ---- hoisted weight prep (merged; serial roles first) ----
  prep_k<<<1763,256,0,stream>>>(qkv_W, qkvWT_a, ffn_W, ffnWT_a,
                                out_W, outWT_a, qkv_b, rqkv_b,
                                atom_table, comp_W, comp_b, pdd_b, atom_emb,
                                o_b, fbp_a);
  // fwT = (o_W @ out_W)^T per layer; A = o_W f32 converted in staging
  mgemm_k<4,32,64,128,1><<<dim3(EE/64, EHH/32, LL),256,0,stream>>>(
      o_W, outWT_a, nullptr, fwT_a, EE, EHH, EHH, nullptr,
      (size_t)EHH*EHH, (size_t)EE*EHH, (size_t)EE*EHH*2);

  embed_ln_k<<<NTOK/32,512,0,stream>>>(str_fea, comp_fea, atom_emb, pdd_W,
                                       enc_ln_g, enc_ln_b, x, w, xn_bf, epart);

  for (int i=0;i<LL;i++){
    const float* gi = enc_ln_g + i*EE;
    const float* bi = enc_ln_b + i*EE;
    for (int cb=0; cb<NCHUNK; cb++){
      const int t0 = cb*CTOK;
      const int b0 = cb*CB;
      // QKV (barrier-free reg-direct): Q|K -> qkc, V -> vTc (transposed)
      qkv_k<<<dim3(3*EHH/128, CTOK/128),256,0,stream>>>(
          xn_bf + (size_t)t0*EE, qkvWT_a + (size_t)i*3*EHH*EE,
          rqkv_b + (size_t)i*3*EHH, qkc, vTc, CTOK);
      attn_mf_k<<<dim3(CB, HH, SEQ/64),256,0,stream>>>(
          qkc, vTc, w, vals_bf + (size_t)t0*EHH, b0);
    }
    // proj + resid + LN + ffn + mish + dual-LN (+pool partial on last layer)
    const float* gn = (i<LL-1) ? enc_ln_g + (i+1)*EE : gi;
    const float* bn = (i<LL-1) ? enc_ln_b + (i+1)*EE : bi;
    projffn_k<<<NTOK/32,256,0,stream>>>(
        vals_bf, fwT_a + (size_t)i*EE*EHH,
        fbp_a + (size_t)i*8*EE, out_b + (size_t)i*EE,
        ffnWT_a + (size_t)i*EE*EE, ffn_b + (size_t)i*EE,
        gi, bi, gn, bn, x, xn_bf,
        w, (i==LL-1) ? pp : nullptr);
  }
  pool2_k<<<BB,128,0,stream>>>(pp, epart, ln2_g, ln2_b, head_W, head_b, out);
}